// Round 1
// baseline (2225.936 us; speedup 1.0000x reference)
//
#include <hip/hip_runtime.h>
#include <hip/hip_bf16.h>
#include <math.h>

#define N_NODES 50000
#define N_EDGES 800000
#define F_IN 128
#define HID 64
#define HEADS 4
#define FEAT 256        // HEADS*HID
#define OUT_DIM 128
#define N_CLS 2
#define NG 500
#define SLOPE 0.2f
#define BN_EPS 1e-5f

// ---------------- generic fp32 GEMM: C = A[M,K] @ B[K,N] (+bias, +relu) ----------------
template<bool RELU, bool BIAS>
__global__ void gemm_rrr(const float* __restrict__ A, const float* __restrict__ B,
                         const float* __restrict__ bias, float* __restrict__ C,
                         int M, int K, int Nc) {
    __shared__ float As[32][33];
    __shared__ float Bs[32][33];
    int tx = threadIdx.x;          // 0..15
    int ty = threadIdx.y;          // 0..15
    int row0 = blockIdx.y * 32;
    int col0 = blockIdx.x * 32;
    float acc00 = 0.f, acc01 = 0.f, acc10 = 0.f, acc11 = 0.f;
    int tid = ty * 16 + tx;
    for (int k0 = 0; k0 < K; k0 += 32) {
        for (int i = tid; i < 32 * 32; i += 256) {
            int r = i >> 5, c = i & 31;
            int gr = row0 + r, gc = k0 + c;
            As[r][c] = (gr < M && gc < K) ? A[(long long)gr * K + gc] : 0.f;
            int br = k0 + r, bc = col0 + c;
            Bs[r][c] = (br < K && bc < Nc) ? B[(long long)br * Nc + bc] : 0.f;
        }
        __syncthreads();
        #pragma unroll
        for (int kk = 0; kk < 32; kk++) {
            float a0 = As[ty * 2][kk], a1 = As[ty * 2 + 1][kk];
            float b0 = Bs[kk][tx * 2], b1 = Bs[kk][tx * 2 + 1];
            acc00 += a0 * b0; acc01 += a0 * b1;
            acc10 += a1 * b0; acc11 += a1 * b1;
        }
        __syncthreads();
    }
    float accs[2][2] = {{acc00, acc01}, {acc10, acc11}};
    for (int i = 0; i < 2; i++)
        for (int j = 0; j < 2; j++) {
            int r = row0 + ty * 2 + i, c = col0 + tx * 2 + j;
            if (r < M && c < Nc) {
                float v = accs[i][j];
                if (BIAS) v += bias[c];
                if (RELU) v = fmaxf(v, 0.f);
                C[(long long)r * Nc + c] = v;
            }
        }
}

// ---------------- attention scores: a_s[n,h] = sum_c h[n,h,c]*att_src[h,c] ----------------
__global__ void attn_scores(const float* __restrict__ h, const float* __restrict__ att_src,
                            const float* __restrict__ att_dst, float* __restrict__ a_s,
                            float* __restrict__ a_d) {
    int node = blockIdx.x;
    int t = threadIdx.x;                 // 0..255 ; wave = one head
    int head = t >> 6, c = t & 63;
    float hv = h[(long long)node * FEAT + t];
    float ps = hv * att_src[t];
    float pd = hv * att_dst[t];
    for (int off = 32; off > 0; off >>= 1) {
        ps += __shfl_down(ps, off);
        pd += __shfl_down(pd, off);
    }
    if (c == 0) {
        a_s[node * HEADS + head] = ps;
        a_d[node * HEADS + head] = pd;
    }
}

__device__ inline float edge_logit(const float* __restrict__ a_s, const float* __restrict__ a_d,
                                   int s, int d, int head) {
    float e = a_s[s * HEADS + head] + a_d[d * HEADS + head];
    return e > 0.f ? e : SLOPE * e;
}

// -------- pass 1: per-dst max of edge logits (monotone uint key trick) --------
__global__ void edge_max(const int* __restrict__ src, const int* __restrict__ dst,
                         const float* __restrict__ a_s, const float* __restrict__ a_d,
                         unsigned int* __restrict__ mkey) {
    int gid = blockIdx.x * blockDim.x + threadIdx.x;
    int total = (N_EDGES + N_NODES) * HEADS;
    if (gid >= total) return;
    int e = gid >> 2, head = gid & 3;
    int s, d;
    if (e < N_EDGES) { s = src[e]; d = dst[e]; } else { s = d = e - N_EDGES; }
    float el = edge_logit(a_s, a_d, s, d, head);
    unsigned int u = __float_as_uint(el);
    unsigned int key = (u & 0x80000000u) ? ~u : (u | 0x80000000u);
    atomicMax(&mkey[d * HEADS + head], key);
}

__global__ void decode_max(const unsigned int* __restrict__ mkey, float* __restrict__ m) {
    int gid = blockIdx.x * blockDim.x + threadIdx.x;
    if (gid >= N_NODES * HEADS) return;
    unsigned int key = mkey[gid];
    unsigned int u = (key & 0x80000000u) ? (key ^ 0x80000000u) : ~key;
    m[gid] = __uint_as_float(u);
}

// -------- pass 2: per-dst sum of exp(logit - max) --------
__global__ void edge_expsum(const int* __restrict__ src, const int* __restrict__ dst,
                            const float* __restrict__ a_s, const float* __restrict__ a_d,
                            const float* __restrict__ m, float* __restrict__ denom) {
    int gid = blockIdx.x * blockDim.x + threadIdx.x;
    int total = (N_EDGES + N_NODES) * HEADS;
    if (gid >= total) return;
    int e = gid >> 2, head = gid & 3;
    int s, d;
    if (e < N_EDGES) { s = src[e]; d = dst[e]; } else { s = d = e - N_EDGES; }
    float el = edge_logit(a_s, a_d, s, d, head);
    float ex = expf(el - m[d * HEADS + head]);
    atomicAdd(&denom[d * HEADS + head], ex);
}

// -------- pass 3: weighted aggregation; one block per edge, 256 channels --------
__global__ void edge_aggregate(const int* __restrict__ src, const int* __restrict__ dst,
                               const float* __restrict__ a_s, const float* __restrict__ a_d,
                               const float* __restrict__ m, const float* __restrict__ denom,
                               const float* __restrict__ h, float* __restrict__ out) {
    int e = blockIdx.x;
    int t = threadIdx.x;             // 0..255
    int head = t >> 6;
    int s, d;
    if (e < N_EDGES) { s = src[e]; d = dst[e]; } else { s = d = e - N_EDGES; }
    float el = edge_logit(a_s, a_d, s, d, head);
    float w = expf(el - m[d * HEADS + head]) / denom[d * HEADS + head];
    atomicAdd(&out[(long long)d * FEAT + t], w * h[(long long)s * FEAT + t]);
}

// -------- bias + relu + BN (eval), in place --------
__global__ void post_bn(float* __restrict__ x, const float* __restrict__ b,
                        const float* __restrict__ g, const float* __restrict__ be,
                        const float* __restrict__ rm, const float* __restrict__ rv) {
    long long idx = (long long)blockIdx.x * blockDim.x + threadIdx.x;
    if (idx >= (long long)N_NODES * FEAT) return;
    int f = (int)(idx & (FEAT - 1));
    float v = x[idx] + b[f];
    v = fmaxf(v, 0.f);
    v = (v - rm[f]) * rsqrtf(rv[f] + BN_EPS) * g[f] + be[f];
    x[idx] = v;
}

// -------- mean pool over graphs --------
__global__ void pool_sum(const float* __restrict__ h, const int* __restrict__ batch,
                         float* __restrict__ pooled) {
    long long idx = (long long)blockIdx.x * blockDim.x + threadIdx.x;
    if (idx >= (long long)N_NODES * FEAT) return;
    int node = (int)(idx >> 8);
    int f = (int)(idx & (FEAT - 1));
    atomicAdd(&pooled[batch[node] * FEAT + f], h[idx]);
}

__global__ void pool_cnt(const int* __restrict__ batch, float* __restrict__ cnt) {
    int gid = blockIdx.x * blockDim.x + threadIdx.x;
    if (gid >= N_NODES) return;
    atomicAdd(&cnt[batch[gid]], 1.f);
}

__global__ void pool_div(float* __restrict__ pooled, const float* __restrict__ cnt) {
    int idx = blockIdx.x * blockDim.x + threadIdx.x;
    if (idx >= NG * FEAT) return;
    int g = idx >> 8;
    pooled[idx] /= fmaxf(cnt[g], 1.f);
}

// -------- final tiny FC: out[g,c] = z[g,:] @ lw2[:,c] + lb2[c] --------
__global__ void final_fc(const float* __restrict__ z, const float* __restrict__ lw2,
                         const float* __restrict__ lb2, float* __restrict__ out) {
    int gid = blockIdx.x * blockDim.x + threadIdx.x;
    if (gid >= NG * N_CLS) return;
    int g = gid >> 1, c = gid & 1;
    float acc = lb2[c];
    #pragma unroll 8
    for (int k = 0; k < OUT_DIM; k++) acc += z[g * OUT_DIM + k] * lw2[k * N_CLS + c];
    out[gid] = acc;
}

extern "C" void kernel_launch(void* const* d_in, const int* in_sizes, int n_in,
                              void* d_out, int out_size, void* d_ws, size_t ws_size,
                              hipStream_t stream) {
    const float* x       = (const float*)d_in[0];
    const int*   ei      = (const int*)d_in[1];      // [2, E]
    const int*   batch   = (const int*)d_in[2];
    const float* W1      = (const float*)d_in[3];
    const float* att_s1  = (const float*)d_in[4];
    const float* att_d1  = (const float*)d_in[5];
    const float* b1      = (const float*)d_in[6];
    const float* g1      = (const float*)d_in[7];
    const float* be1     = (const float*)d_in[8];
    const float* rm1     = (const float*)d_in[9];
    const float* rv1     = (const float*)d_in[10];
    const float* W2      = (const float*)d_in[11];
    const float* att_s2  = (const float*)d_in[12];
    const float* att_d2  = (const float*)d_in[13];
    const float* b2      = (const float*)d_in[14];
    const float* g2      = (const float*)d_in[15];
    const float* be2     = (const float*)d_in[16];
    const float* rm2     = (const float*)d_in[17];
    const float* rv2     = (const float*)d_in[18];
    const float* lw1     = (const float*)d_in[19];
    const float* lb1     = (const float*)d_in[20];
    const float* lw2     = (const float*)d_in[21];
    const float* lb2     = (const float*)d_in[22];
    float* out           = (float*)d_out;

    const int* src = ei;
    const int* dst = ei + N_EDGES;

    // ---- workspace carve-up (floats) ----
    float* ws = (float*)d_ws;
    float*    bufA  = ws;                          // N*FEAT : GEMM outputs (h)
    float*    bufB  = bufA + (long long)N_NODES * FEAT;  // N*FEAT : aggregation / layer IO
    float*    a_s   = bufB + (long long)N_NODES * FEAT;  // N*HEADS
    float*    a_d   = a_s + N_NODES * HEADS;
    unsigned* mkey  = (unsigned*)(a_d + N_NODES * HEADS); // N*HEADS
    float*    m     = (float*)(mkey + N_NODES * HEADS);   // N*HEADS
    float*    denom = m + N_NODES * HEADS;                // N*HEADS
    float*    pooled= denom + N_NODES * HEADS;            // NG*FEAT
    float*    cnt   = pooled + NG * FEAT;                 // NG
    float*    z     = cnt + NG;                           // NG*OUT_DIM

    const int Et = N_EDGES + N_NODES;
    dim3 gemm_blk(16, 16);

    // ================= Layer 1 =================
    {
        dim3 grid((FEAT + 31) / 32, (N_NODES + 31) / 32);
        gemm_rrr<false, false><<<grid, gemm_blk, 0, stream>>>(x, W1, nullptr, bufA,
                                                              N_NODES, F_IN, FEAT);
    }
    attn_scores<<<N_NODES, 256, 0, stream>>>(bufA, att_s1, att_d1, a_s, a_d);
    hipMemsetAsync(mkey, 0, sizeof(unsigned) * N_NODES * HEADS, stream);
    hipMemsetAsync(denom, 0, sizeof(float) * N_NODES * HEADS, stream);
    hipMemsetAsync(bufB, 0, sizeof(float) * (size_t)N_NODES * FEAT, stream);
    {
        int total = Et * HEADS;
        edge_max<<<(total + 255) / 256, 256, 0, stream>>>(src, dst, a_s, a_d, mkey);
        decode_max<<<(N_NODES * HEADS + 255) / 256, 256, 0, stream>>>(mkey, m);
        edge_expsum<<<(total + 255) / 256, 256, 0, stream>>>(src, dst, a_s, a_d, m, denom);
        edge_aggregate<<<Et, 256, 0, stream>>>(src, dst, a_s, a_d, m, denom, bufA, bufB);
    }
    post_bn<<<(N_NODES * FEAT + 255) / 256, 256, 0, stream>>>(bufB, b1, g1, be1, rm1, rv1);

    // ================= Layer 2 =================
    {
        dim3 grid((FEAT + 31) / 32, (N_NODES + 31) / 32);
        gemm_rrr<false, false><<<grid, gemm_blk, 0, stream>>>(bufB, W2, nullptr, bufA,
                                                              N_NODES, FEAT, FEAT);
    }
    attn_scores<<<N_NODES, 256, 0, stream>>>(bufA, att_s2, att_d2, a_s, a_d);
    hipMemsetAsync(mkey, 0, sizeof(unsigned) * N_NODES * HEADS, stream);
    hipMemsetAsync(denom, 0, sizeof(float) * N_NODES * HEADS, stream);
    hipMemsetAsync(bufB, 0, sizeof(float) * (size_t)N_NODES * FEAT, stream);
    {
        int total = Et * HEADS;
        edge_max<<<(total + 255) / 256, 256, 0, stream>>>(src, dst, a_s, a_d, mkey);
        decode_max<<<(N_NODES * HEADS + 255) / 256, 256, 0, stream>>>(mkey, m);
        edge_expsum<<<(total + 255) / 256, 256, 0, stream>>>(src, dst, a_s, a_d, m, denom);
        edge_aggregate<<<Et, 256, 0, stream>>>(src, dst, a_s, a_d, m, denom, bufA, bufB);
    }
    post_bn<<<(N_NODES * FEAT + 255) / 256, 256, 0, stream>>>(bufB, b2, g2, be2, rm2, rv2);

    // ================= Pool + MLP head =================
    hipMemsetAsync(pooled, 0, sizeof(float) * NG * FEAT, stream);
    hipMemsetAsync(cnt, 0, sizeof(float) * NG, stream);
    pool_sum<<<(N_NODES * FEAT + 255) / 256, 256, 0, stream>>>(bufB, batch, pooled);
    pool_cnt<<<(N_NODES + 255) / 256, 256, 0, stream>>>(batch, cnt);
    pool_div<<<(NG * FEAT + 255) / 256, 256, 0, stream>>>(pooled, cnt);
    {
        dim3 grid((OUT_DIM + 31) / 32, (NG + 31) / 32);
        gemm_rrr<true, true><<<grid, gemm_blk, 0, stream>>>(pooled, lw1, lb1, z,
                                                            NG, FEAT, OUT_DIM);
    }
    final_fc<<<(NG * N_CLS + 255) / 256, 256, 0, stream>>>(z, lw2, lb2, out);
}

// Round 2
// 916.298 us; speedup vs baseline: 2.4293x; 2.4293x over previous
//
#include <hip/hip_runtime.h>
#include <hip/hip_bf16.h>
#include <math.h>

#define N_NODES 50000
#define N_EDGES 800000
#define F_IN 128
#define HID 64
#define HEADS 4
#define FEAT 256        // HEADS*HID
#define OUT_DIM 128
#define N_CLS 2
#define NG 500
#define SLOPE 0.2f
#define BN_EPS 1e-5f
#define CAP 256         // edges per chunk in fused GAT kernel

// ================= fp32 GEMM: C = A[M,K] @ B[K,N], 64x64 tile, BK=16 =================
template<bool RELU, bool BIAS>
__global__ __launch_bounds__(256) void gemm64(const float* __restrict__ A,
                                              const float* __restrict__ B,
                                              const float* __restrict__ bias,
                                              float* __restrict__ C,
                                              int M, int K, int Nc) {
    __shared__ float Ast[16][68];   // k-major: [k][row]
    __shared__ float Bst[16][68];   // [k][col]
    int tx = threadIdx.x, ty = threadIdx.y;
    int tid = ty * 16 + tx;
    int row0 = blockIdx.y * 64, col0 = blockIdx.x * 64;
    float acc[4][4] = {};
    int ar = tid >> 2;            // 0..63 (A row within tile)
    int ak = (tid & 3) * 4;       // 0,4,8,12 (A k within tile)
    int bk = tid >> 4;            // 0..15 (B k row)
    int bc = (tid & 15) * 4;      // B col within tile

    for (int k0 = 0; k0 < K; k0 += 16) {
        float4 av = make_float4(0.f, 0.f, 0.f, 0.f);
        if (row0 + ar < M) av = *(const float4*)&A[(long long)(row0 + ar) * K + k0 + ak];
        float4 bv = *(const float4*)&B[(long long)(k0 + bk) * Nc + col0 + bc];
        Ast[ak + 0][ar] = av.x; Ast[ak + 1][ar] = av.y;
        Ast[ak + 2][ar] = av.z; Ast[ak + 3][ar] = av.w;
        *(float4*)&Bst[bk][bc] = bv;
        __syncthreads();
        #pragma unroll
        for (int kk = 0; kk < 16; kk++) {
            float4 af = *(const float4*)&Ast[kk][ty * 4];
            float4 bf = *(const float4*)&Bst[kk][tx * 4];
            float a[4] = {af.x, af.y, af.z, af.w};
            float b[4] = {bf.x, bf.y, bf.z, bf.w};
            #pragma unroll
            for (int i = 0; i < 4; i++)
                #pragma unroll
                for (int j = 0; j < 4; j++)
                    acc[i][j] += a[i] * b[j];
        }
        __syncthreads();
    }
    #pragma unroll
    for (int i = 0; i < 4; i++) {
        int r = row0 + ty * 4 + i;
        if (r < M) {
            float4 o;
            float v[4];
            #pragma unroll
            for (int j = 0; j < 4; j++) {
                v[j] = acc[i][j];
                if (BIAS) v[j] += bias[col0 + tx * 4 + j];
                if (RELU) v[j] = fmaxf(v[j], 0.f);
            }
            o.x = v[0]; o.y = v[1]; o.z = v[2]; o.w = v[3];
            *(float4*)&C[(long long)r * Nc + col0 + tx * 4] = o;
        }
    }
}

// ================= attention scores =================
__global__ void attn_scores(const float* __restrict__ h, const float* __restrict__ att_src,
                            const float* __restrict__ att_dst, float* __restrict__ a_s,
                            float* __restrict__ a_d) {
    int node = blockIdx.x;
    int t = threadIdx.x;                 // 0..255 ; wave = one head
    int head = t >> 6, c = t & 63;
    float hv = h[(long long)node * FEAT + t];
    float ps = hv * att_src[t];
    float pd = hv * att_dst[t];
    for (int off = 32; off > 0; off >>= 1) {
        ps += __shfl_down(ps, off);
        pd += __shfl_down(pd, off);
    }
    if (c == 0) {
        a_s[node * HEADS + head] = ps;
        a_d[node * HEADS + head] = pd;
    }
}

// ================= CSR build =================
__global__ void degree_count(const int* __restrict__ src, const int* __restrict__ dst,
                             int* __restrict__ deg) {
    int e = blockIdx.x * blockDim.x + threadIdx.x;
    if (e >= N_EDGES + N_NODES) return;
    int d = (e < N_EDGES) ? dst[e] : (e - N_EDGES);
    atomicAdd(&deg[d], 1);
}

// single-block exclusive scan (wave-level shuffles + cross-wave LDS)
__global__ __launch_bounds__(256) void scan_deg(const int* __restrict__ deg,
                                                int* __restrict__ row_start) {
    __shared__ int wsum[4];
    __shared__ int woff[4];
    __shared__ int carry_s;
    int t = threadIdx.x;
    int lane = t & 63, wid = t >> 6;
    if (t == 0) carry_s = 0;
    __syncthreads();
    for (int base = 0; base < N_NODES; base += 256) {
        int v = (base + t < N_NODES) ? deg[base + t] : 0;
        int x = v;
        #pragma unroll
        for (int off = 1; off < 64; off <<= 1) {
            int y = __shfl_up(x, off);
            if (lane >= off) x += y;
        }
        if (lane == 63) wsum[wid] = x;
        __syncthreads();
        if (t == 0) {
            int s = carry_s;
            #pragma unroll
            for (int w = 0; w < 4; w++) { int tw = wsum[w]; woff[w] = s; s += tw; }
            carry_s = s;
        }
        __syncthreads();
        int incl = x + woff[wid];
        if (base + t < N_NODES) row_start[base + t] = incl - v;
    }
    if (t == 0) row_start[N_NODES] = carry_s;
}

__global__ void scatter_edges(const int* __restrict__ src, const int* __restrict__ dst,
                              const int* __restrict__ row_start, int* __restrict__ cursor,
                              int* __restrict__ csr_src) {
    int e = blockIdx.x * blockDim.x + threadIdx.x;
    if (e >= N_EDGES + N_NODES) return;
    int s, d;
    if (e < N_EDGES) { s = src[e]; d = dst[e]; } else { s = d = e - N_EDGES; }
    int pos = atomicAdd(&cursor[d], 1);
    csr_src[row_start[d] + pos] = s;
}

// ================= fused GAT: softmax + aggregate + bias/relu/BN =================
__global__ __launch_bounds__(256) void gat_fused(
    const int* __restrict__ row_start, const int* __restrict__ csr_src,
    const float* __restrict__ a_s, const float* __restrict__ a_d,
    const float* __restrict__ h, const float* __restrict__ bias,
    const float* __restrict__ g, const float* __restrict__ be,
    const float* __restrict__ rm, const float* __restrict__ rv,
    float* __restrict__ out) {
    int d = blockIdx.x;
    int t = threadIdx.x;
    int head = t >> 6;
    int lane = t & 63;
    __shared__ int s_lds[CAP];
    __shared__ float p_lds[4 * CAP];     // [head][edge]
    __shared__ float m_st[4], l_st[4], alpha_st[4];

    int rs = row_start[d], re = row_start[d + 1];
    int deg = re - rs;
    if (t < 4) { m_st[t] = -INFINITY; l_st[t] = 0.f; }
    float4 ad4 = *(const float4*)&a_d[d * 4];
    float acc = 0.f;
    __syncthreads();

    for (int base = 0; base < deg; base += CAP) {
        int cl = min(CAP, deg - base);
        if (t < cl) s_lds[t] = csr_src[rs + base + t];
        __syncthreads();
        if (t < cl) {
            int s = s_lds[t];
            float4 as4 = *(const float4*)&a_s[s * 4];
            float e0 = as4.x + ad4.x; e0 = e0 > 0.f ? e0 : SLOPE * e0;
            float e1 = as4.y + ad4.y; e1 = e1 > 0.f ? e1 : SLOPE * e1;
            float e2 = as4.z + ad4.z; e2 = e2 > 0.f ? e2 : SLOPE * e2;
            float e3 = as4.w + ad4.w; e3 = e3 > 0.f ? e3 : SLOPE * e3;
            p_lds[0 * CAP + t] = e0; p_lds[1 * CAP + t] = e1;
            p_lds[2 * CAP + t] = e2; p_lds[3 * CAP + t] = e3;
        }
        __syncthreads();
        // per-head online softmax update; wave `head` owns head `head`
        float mloc = -INFINITY;
        for (int e = lane; e < cl; e += 64) mloc = fmaxf(mloc, p_lds[head * CAP + e]);
        #pragma unroll
        for (int off = 1; off < 64; off <<= 1) mloc = fmaxf(mloc, __shfl_xor(mloc, off));
        float m_old = m_st[head];
        float m_new = fmaxf(m_old, mloc);
        float csum = 0.f;
        for (int e = lane; e < cl; e += 64) {
            float p = __expf(p_lds[head * CAP + e] - m_new);
            p_lds[head * CAP + e] = p;
            csum += p;
        }
        #pragma unroll
        for (int off = 1; off < 64; off <<= 1) csum += __shfl_xor(csum, off);
        float alpha = __expf(m_old - m_new);     // exp(-inf)=0 on first chunk
        if (lane == 0) {
            m_st[head] = m_new;
            l_st[head] = l_st[head] * alpha + csum;
            alpha_st[head] = alpha;
        }
        __syncthreads();
        // weighted gather for this thread's channel
        acc *= alpha_st[head];
        #pragma unroll 4
        for (int e = 0; e < cl; e++) {
            acc += p_lds[head * CAP + e] * h[(long long)s_lds[e] * FEAT + t];
        }
        __syncthreads();
    }
    float v = acc / l_st[head];
    v += bias[t];
    v = fmaxf(v, 0.f);
    v = (v - rm[t]) * rsqrtf(rv[t] + BN_EPS) * g[t] + be[t];
    out[(long long)d * FEAT + t] = v;
}

// ================= pooling + head =================
__global__ void pool_sum(const float* __restrict__ h, const int* __restrict__ batch,
                         float* __restrict__ pooled) {
    long long idx = (long long)blockIdx.x * blockDim.x + threadIdx.x;
    if (idx >= (long long)N_NODES * FEAT) return;
    int node = (int)(idx >> 8);
    int f = (int)(idx & (FEAT - 1));
    atomicAdd(&pooled[batch[node] * FEAT + f], h[idx]);
}

__global__ void pool_cnt(const int* __restrict__ batch, float* __restrict__ cnt) {
    int gid = blockIdx.x * blockDim.x + threadIdx.x;
    if (gid >= N_NODES) return;
    atomicAdd(&cnt[batch[gid]], 1.f);
}

__global__ void pool_div(float* __restrict__ pooled, const float* __restrict__ cnt) {
    int idx = blockIdx.x * blockDim.x + threadIdx.x;
    if (idx >= NG * FEAT) return;
    int g = idx >> 8;
    pooled[idx] /= fmaxf(cnt[g], 1.f);
}

__global__ void final_fc(const float* __restrict__ z, const float* __restrict__ lw2,
                         const float* __restrict__ lb2, float* __restrict__ out) {
    int gid = blockIdx.x * blockDim.x + threadIdx.x;
    if (gid >= NG * N_CLS) return;
    int g = gid >> 1, c = gid & 1;
    float acc = lb2[c];
    #pragma unroll 8
    for (int k = 0; k < OUT_DIM; k++) acc += z[g * OUT_DIM + k] * lw2[k * N_CLS + c];
    out[gid] = acc;
}

extern "C" void kernel_launch(void* const* d_in, const int* in_sizes, int n_in,
                              void* d_out, int out_size, void* d_ws, size_t ws_size,
                              hipStream_t stream) {
    const float* x       = (const float*)d_in[0];
    const int*   ei      = (const int*)d_in[1];      // [2, E]
    const int*   batch   = (const int*)d_in[2];
    const float* W1      = (const float*)d_in[3];
    const float* att_s1  = (const float*)d_in[4];
    const float* att_d1  = (const float*)d_in[5];
    const float* b1      = (const float*)d_in[6];
    const float* g1      = (const float*)d_in[7];
    const float* be1     = (const float*)d_in[8];
    const float* rm1     = (const float*)d_in[9];
    const float* rv1     = (const float*)d_in[10];
    const float* W2      = (const float*)d_in[11];
    const float* att_s2  = (const float*)d_in[12];
    const float* att_d2  = (const float*)d_in[13];
    const float* b2      = (const float*)d_in[14];
    const float* g2      = (const float*)d_in[15];
    const float* be2     = (const float*)d_in[16];
    const float* rm2     = (const float*)d_in[17];
    const float* rv2     = (const float*)d_in[18];
    const float* lw1     = (const float*)d_in[19];
    const float* lb1     = (const float*)d_in[20];
    const float* lw2     = (const float*)d_in[21];
    const float* lb2     = (const float*)d_in[22];
    float* out           = (float*)d_out;

    const int* src = ei;
    const int* dst = ei + N_EDGES;

    // ---- workspace carve-up (all offsets multiples of 4 elements => 16B aligned) ----
    float* ws = (float*)d_ws;
    float* bufA   = ws;                                       // N*FEAT
    float* bufB   = bufA + (long long)N_NODES * FEAT;         // N*FEAT
    float* a_s    = bufB + (long long)N_NODES * FEAT;         // N*HEADS
    float* a_d    = a_s + N_NODES * HEADS;                    // N*HEADS
    int*   deg    = (int*)(a_d + N_NODES * HEADS);            // N
    int*   cursor = deg + N_NODES;                            // N
    int*   csr    = cursor + N_NODES;                         // E+N
    int*   rstart = csr + (N_EDGES + N_NODES);                // N+1 (padded 50004)
    float* pooled = (float*)(rstart + 50004);                 // NG*FEAT
    float* cnt    = pooled + NG * FEAT;                       // NG
    float* z      = cnt + NG;                                 // NG*OUT_DIM

    const int Et = N_EDGES + N_NODES;
    dim3 blk16(16, 16);

    // ---- CSR build (shared by both layers) ----
    hipMemsetAsync(deg, 0, sizeof(int) * N_NODES, stream);
    hipMemsetAsync(cursor, 0, sizeof(int) * N_NODES, stream);
    degree_count<<<(Et + 255) / 256, 256, 0, stream>>>(src, dst, deg);
    scan_deg<<<1, 256, 0, stream>>>(deg, rstart);
    scatter_edges<<<(Et + 255) / 256, 256, 0, stream>>>(src, dst, rstart, cursor, csr);

    // ---- Layer 1 ----
    {
        dim3 grid(FEAT / 64, (N_NODES + 63) / 64);
        gemm64<false, false><<<grid, blk16, 0, stream>>>(x, W1, nullptr, bufA,
                                                         N_NODES, F_IN, FEAT);
    }
    attn_scores<<<N_NODES, 256, 0, stream>>>(bufA, att_s1, att_d1, a_s, a_d);
    gat_fused<<<N_NODES, 256, 0, stream>>>(rstart, csr, a_s, a_d, bufA,
                                           b1, g1, be1, rm1, rv1, bufB);

    // ---- Layer 2 ----
    {
        dim3 grid(FEAT / 64, (N_NODES + 63) / 64);
        gemm64<false, false><<<grid, blk16, 0, stream>>>(bufB, W2, nullptr, bufA,
                                                         N_NODES, FEAT, FEAT);
    }
    attn_scores<<<N_NODES, 256, 0, stream>>>(bufA, att_s2, att_d2, a_s, a_d);
    gat_fused<<<N_NODES, 256, 0, stream>>>(rstart, csr, a_s, a_d, bufA,
                                           b2, g2, be2, rm2, rv2, bufB);

    // ---- Pool + MLP head ----
    hipMemsetAsync(pooled, 0, sizeof(float) * NG * FEAT, stream);
    hipMemsetAsync(cnt, 0, sizeof(float) * NG, stream);
    pool_sum<<<((long long)N_NODES * FEAT + 255) / 256, 256, 0, stream>>>(bufB, batch, pooled);
    pool_cnt<<<(N_NODES + 255) / 256, 256, 0, stream>>>(batch, cnt);
    pool_div<<<(NG * FEAT + 255) / 256, 256, 0, stream>>>(pooled, cnt);
    {
        dim3 grid(OUT_DIM / 64, (NG + 63) / 64);
        gemm64<true, true><<<grid, blk16, 0, stream>>>(pooled, lw1, lb1, z,
                                                       NG, FEAT, OUT_DIM);
    }
    final_fc<<<(NG * N_CLS + 255) / 256, 256, 0, stream>>>(z, lw2, lb2, out);
}

// Round 3
// 908.351 us; speedup vs baseline: 2.4505x; 1.0087x over previous
//
#include <hip/hip_runtime.h>
#include <hip/hip_bf16.h>
#include <math.h>

#define N_NODES 50000
#define N_EDGES 800000
#define F_IN 128
#define HID 64
#define HEADS 4
#define FEAT 256        // HEADS*HID
#define OUT_DIM 128
#define N_CLS 2
#define NG 500
#define SLOPE 0.2f
#define BN_EPS 1e-5f
#define CAP 256         // edges per chunk in fused GAT kernel

// ======== fp32 GEMM: C = A[M,K] @ B[K,N], 128x128 tile, BK=16, 8x8/thread ========
// thread (tx,ty) owns rows {ty*4+i, 64+ty*4+i} and cols {tx*4+j, 64+tx*4+j}
// => all LDS fragment reads are broadcast or 2-way (free on gfx950, m136).
template<bool RELU, bool BIAS>
__global__ __launch_bounds__(256) void gemm128(const float* __restrict__ A,
                                               const float* __restrict__ B,
                                               const float* __restrict__ bias,
                                               float* __restrict__ C,
                                               int M, int K, int Nc) {
    __shared__ float As[16][132];   // k-major [k][m]
    __shared__ float Bs[16][132];   // [k][n]
    int tx = threadIdx.x, ty = threadIdx.y;
    int tid = ty * 16 + tx;
    int row0 = blockIdx.y * 128, col0 = blockIdx.x * 128;

    int arow = tid >> 1;            // 0..127
    int akk  = (tid & 1) * 8;       // 0 or 8
    int brow = tid >> 4;            // 0..15
    int bcol = (tid & 15) * 8;      // 0..120

    float acc[8][8] = {};
    float4 a0v = make_float4(0.f,0.f,0.f,0.f), a1v = a0v, b0v, b1v;

    // prefetch tile 0
    {
        long long ar = row0 + arow;
        if (ar < M) {
            a0v = *(const float4*)&A[ar * K + akk];
            a1v = *(const float4*)&A[ar * K + akk + 4];
        }
        b0v = *(const float4*)&B[(long long)brow * Nc + col0 + bcol];
        b1v = *(const float4*)&B[(long long)brow * Nc + col0 + bcol + 4];
    }

    for (int k0 = 0; k0 < K; k0 += 16) {
        As[akk + 0][arow] = a0v.x; As[akk + 1][arow] = a0v.y;
        As[akk + 2][arow] = a0v.z; As[akk + 3][arow] = a0v.w;
        As[akk + 4][arow] = a1v.x; As[akk + 5][arow] = a1v.y;
        As[akk + 6][arow] = a1v.z; As[akk + 7][arow] = a1v.w;
        *(float4*)&Bs[brow][bcol]     = b0v;
        *(float4*)&Bs[brow][bcol + 4] = b1v;
        __syncthreads();

        int k1 = k0 + 16;
        if (k1 < K) {
            long long ar = row0 + arow;
            if (ar < M) {
                a0v = *(const float4*)&A[ar * K + k1 + akk];
                a1v = *(const float4*)&A[ar * K + k1 + akk + 4];
            } else { a0v = make_float4(0.f,0.f,0.f,0.f); a1v = a0v; }
            b0v = *(const float4*)&B[(long long)(k1 + brow) * Nc + col0 + bcol];
            b1v = *(const float4*)&B[(long long)(k1 + brow) * Nc + col0 + bcol + 4];
        }

        #pragma unroll
        for (int kk = 0; kk < 16; kk++) {
            float4 af0 = *(const float4*)&As[kk][ty * 4];
            float4 af1 = *(const float4*)&As[kk][64 + ty * 4];
            float4 bf0 = *(const float4*)&Bs[kk][tx * 4];
            float4 bf1 = *(const float4*)&Bs[kk][64 + tx * 4];
            float a[8] = {af0.x, af0.y, af0.z, af0.w, af1.x, af1.y, af1.z, af1.w};
            float b[8] = {bf0.x, bf0.y, bf0.z, bf0.w, bf1.x, bf1.y, bf1.z, bf1.w};
            #pragma unroll
            for (int i = 0; i < 8; i++)
                #pragma unroll
                for (int j = 0; j < 8; j++)
                    acc[i][j] += a[i] * b[j];
        }
        __syncthreads();
    }

    #pragma unroll
    for (int i = 0; i < 8; i++) {
        int r = row0 + ((i >> 2) * 64) + ty * 4 + (i & 3);
        if (r >= M) continue;
        #pragma unroll
        for (int jh = 0; jh < 2; jh++) {
            int c0 = col0 + jh * 64 + tx * 4;
            float v[4];
            #pragma unroll
            for (int j = 0; j < 4; j++) {
                v[j] = acc[i][jh * 4 + j];
                if (BIAS) v[j] += bias[c0 + j];
                if (RELU) v[j] = fmaxf(v[j], 0.f);
            }
            float4 o; o.x = v[0]; o.y = v[1]; o.z = v[2]; o.w = v[3];
            *(float4*)&C[(long long)r * Nc + c0] = o;
        }
    }
}

// ======== small fp32 GEMM (64x64) for the tiny head matmul ========
template<bool RELU, bool BIAS>
__global__ __launch_bounds__(256) void gemm64(const float* __restrict__ A,
                                              const float* __restrict__ B,
                                              const float* __restrict__ bias,
                                              float* __restrict__ C,
                                              int M, int K, int Nc) {
    __shared__ float Ast[16][68];
    __shared__ float Bst[16][68];
    int tx = threadIdx.x, ty = threadIdx.y;
    int tid = ty * 16 + tx;
    int row0 = blockIdx.y * 64, col0 = blockIdx.x * 64;
    float acc[4][4] = {};
    int ar = tid >> 2;
    int ak = (tid & 3) * 4;
    int bk = tid >> 4;
    int bc = (tid & 15) * 4;

    for (int k0 = 0; k0 < K; k0 += 16) {
        float4 av = make_float4(0.f, 0.f, 0.f, 0.f);
        if (row0 + ar < M) av = *(const float4*)&A[(long long)(row0 + ar) * K + k0 + ak];
        float4 bv = *(const float4*)&B[(long long)(k0 + bk) * Nc + col0 + bc];
        Ast[ak + 0][ar] = av.x; Ast[ak + 1][ar] = av.y;
        Ast[ak + 2][ar] = av.z; Ast[ak + 3][ar] = av.w;
        *(float4*)&Bst[bk][bc] = bv;
        __syncthreads();
        #pragma unroll
        for (int kk = 0; kk < 16; kk++) {
            float4 af = *(const float4*)&Ast[kk][ty * 4];
            float4 bf = *(const float4*)&Bst[kk][tx * 4];
            float a[4] = {af.x, af.y, af.z, af.w};
            float b[4] = {bf.x, bf.y, bf.z, bf.w};
            #pragma unroll
            for (int i = 0; i < 4; i++)
                #pragma unroll
                for (int j = 0; j < 4; j++)
                    acc[i][j] += a[i] * b[j];
        }
        __syncthreads();
    }
    #pragma unroll
    for (int i = 0; i < 4; i++) {
        int r = row0 + ty * 4 + i;
        if (r < M) {
            float v[4];
            #pragma unroll
            for (int j = 0; j < 4; j++) {
                v[j] = acc[i][j];
                if (BIAS) v[j] += bias[col0 + tx * 4 + j];
                if (RELU) v[j] = fmaxf(v[j], 0.f);
            }
            float4 o; o.x = v[0]; o.y = v[1]; o.z = v[2]; o.w = v[3];
            *(float4*)&C[(long long)r * Nc + col0 + tx * 4] = o;
        }
    }
}

// ================= attention scores =================
__global__ void attn_scores(const float* __restrict__ h, const float* __restrict__ att_src,
                            const float* __restrict__ att_dst, float* __restrict__ a_s,
                            float* __restrict__ a_d) {
    int node = blockIdx.x;
    int t = threadIdx.x;
    int head = t >> 6, c = t & 63;
    float hv = h[(long long)node * FEAT + t];
    float ps = hv * att_src[t];
    float pd = hv * att_dst[t];
    for (int off = 32; off > 0; off >>= 1) {
        ps += __shfl_down(ps, off);
        pd += __shfl_down(pd, off);
    }
    if (c == 0) {
        a_s[node * HEADS + head] = ps;
        a_d[node * HEADS + head] = pd;
    }
}

// ================= CSR build =================
__global__ void degree_count(const int* __restrict__ src, const int* __restrict__ dst,
                             int* __restrict__ deg) {
    int e = blockIdx.x * blockDim.x + threadIdx.x;
    if (e >= N_EDGES + N_NODES) return;
    int d = (e < N_EDGES) ? dst[e] : (e - N_EDGES);
    atomicAdd(&deg[d], 1);
}

__global__ __launch_bounds__(256) void scan_deg(const int* __restrict__ deg,
                                                int* __restrict__ row_start) {
    __shared__ int wsum[4];
    __shared__ int woff[4];
    __shared__ int carry_s;
    int t = threadIdx.x;
    int lane = t & 63, wid = t >> 6;
    if (t == 0) carry_s = 0;
    __syncthreads();
    for (int base = 0; base < N_NODES; base += 256) {
        int v = (base + t < N_NODES) ? deg[base + t] : 0;
        int x = v;
        #pragma unroll
        for (int off = 1; off < 64; off <<= 1) {
            int y = __shfl_up(x, off);
            if (lane >= off) x += y;
        }
        if (lane == 63) wsum[wid] = x;
        __syncthreads();
        if (t == 0) {
            int s = carry_s;
            #pragma unroll
            for (int w = 0; w < 4; w++) { int tw = wsum[w]; woff[w] = s; s += tw; }
            carry_s = s;
        }
        __syncthreads();
        int incl = x + woff[wid];
        if (base + t < N_NODES) row_start[base + t] = incl - v;
        __syncthreads();
    }
    if (t == 0) row_start[N_NODES] = carry_s;
}

__global__ void scatter_edges(const int* __restrict__ src, const int* __restrict__ dst,
                              const int* __restrict__ row_start, int* __restrict__ cursor,
                              int* __restrict__ csr_src) {
    int e = blockIdx.x * blockDim.x + threadIdx.x;
    if (e >= N_EDGES + N_NODES) return;
    int s, d;
    if (e < N_EDGES) { s = src[e]; d = dst[e]; } else { s = d = e - N_EDGES; }
    int pos = atomicAdd(&cursor[d], 1);
    csr_src[row_start[d] + pos] = s;
}

// ================= fused GAT: softmax + aggregate + bias/relu/BN =================
__global__ __launch_bounds__(256) void gat_fused(
    const int* __restrict__ row_start, const int* __restrict__ csr_src,
    const float* __restrict__ a_s, const float* __restrict__ a_d,
    const float* __restrict__ h, const float* __restrict__ bias,
    const float* __restrict__ g, const float* __restrict__ be,
    const float* __restrict__ rm, const float* __restrict__ rv,
    float* __restrict__ out) {
    int d = blockIdx.x;
    int t = threadIdx.x;
    int head = t >> 6;
    int lane = t & 63;
    __shared__ int s_lds[CAP];
    __shared__ float p_lds[4 * CAP];
    __shared__ float m_st[4], l_st[4], alpha_st[4];

    int rs = row_start[d], re = row_start[d + 1];
    int deg = re - rs;
    if (t < 4) { m_st[t] = -INFINITY; l_st[t] = 0.f; }
    float4 ad4 = *(const float4*)&a_d[d * 4];
    float acc = 0.f;
    __syncthreads();

    for (int base = 0; base < deg; base += CAP) {
        int cl = min(CAP, deg - base);
        if (t < cl) s_lds[t] = csr_src[rs + base + t];
        __syncthreads();
        if (t < cl) {
            int s = s_lds[t];
            float4 as4 = *(const float4*)&a_s[s * 4];
            float e0 = as4.x + ad4.x; e0 = e0 > 0.f ? e0 : SLOPE * e0;
            float e1 = as4.y + ad4.y; e1 = e1 > 0.f ? e1 : SLOPE * e1;
            float e2 = as4.z + ad4.z; e2 = e2 > 0.f ? e2 : SLOPE * e2;
            float e3 = as4.w + ad4.w; e3 = e3 > 0.f ? e3 : SLOPE * e3;
            p_lds[0 * CAP + t] = e0; p_lds[1 * CAP + t] = e1;
            p_lds[2 * CAP + t] = e2; p_lds[3 * CAP + t] = e3;
        }
        __syncthreads();
        float mloc = -INFINITY;
        for (int e = lane; e < cl; e += 64) mloc = fmaxf(mloc, p_lds[head * CAP + e]);
        #pragma unroll
        for (int off = 1; off < 64; off <<= 1) mloc = fmaxf(mloc, __shfl_xor(mloc, off));
        float m_old = m_st[head];
        float m_new = fmaxf(m_old, mloc);
        float csum = 0.f;
        for (int e = lane; e < cl; e += 64) {
            float p = __expf(p_lds[head * CAP + e] - m_new);
            p_lds[head * CAP + e] = p;
            csum += p;
        }
        #pragma unroll
        for (int off = 1; off < 64; off <<= 1) csum += __shfl_xor(csum, off);
        float alpha = __expf(m_old - m_new);
        if (lane == 0) {
            m_st[head] = m_new;
            l_st[head] = l_st[head] * alpha + csum;
            alpha_st[head] = alpha;
        }
        __syncthreads();
        acc *= alpha_st[head];
        #pragma unroll 4
        for (int e = 0; e < cl; e++) {
            acc += p_lds[head * CAP + e] * h[(long long)s_lds[e] * FEAT + t];
        }
        __syncthreads();
    }
    float v = acc / l_st[head];
    v += bias[t];
    v = fmaxf(v, 0.f);
    v = (v - rm[t]) * rsqrtf(rv[t] + BN_EPS) * g[t] + be[t];
    out[(long long)d * FEAT + t] = v;
}

// ================= pooling (batch is sorted): one block per graph =================
__global__ __launch_bounds__(256) void graph_pool(const float* __restrict__ h,
                                                  const int* __restrict__ batch,
                                                  float* __restrict__ pooled) {
    int gph = blockIdx.x;
    int t = threadIdx.x;
    __shared__ int lo_s, hi_s;
    if (t == 0) {
        int lo = 0, hi = N_NODES;
        while (lo < hi) { int mid = (lo + hi) >> 1; if (batch[mid] < gph) lo = mid + 1; else hi = mid; }
        lo_s = lo;
        int lo2 = 0, hi2 = N_NODES;
        while (lo2 < hi2) { int mid = (lo2 + hi2) >> 1; if (batch[mid] < gph + 1) lo2 = mid + 1; else hi2 = mid; }
        hi_s = lo2;
    }
    __syncthreads();
    int lo = lo_s, hi = hi_s;
    float acc = 0.f;
    for (int n = lo; n < hi; n++) acc += h[(long long)n * FEAT + t];
    float cnt = (float)(hi - lo);
    pooled[gph * FEAT + t] = acc / fmaxf(cnt, 1.f);
}

__global__ void final_fc(const float* __restrict__ z, const float* __restrict__ lw2,
                         const float* __restrict__ lb2, float* __restrict__ out) {
    int gid = blockIdx.x * blockDim.x + threadIdx.x;
    if (gid >= NG * N_CLS) return;
    int g = gid >> 1, c = gid & 1;
    float acc = lb2[c];
    #pragma unroll 8
    for (int k = 0; k < OUT_DIM; k++) acc += z[g * OUT_DIM + k] * lw2[k * N_CLS + c];
    out[gid] = acc;
}

extern "C" void kernel_launch(void* const* d_in, const int* in_sizes, int n_in,
                              void* d_out, int out_size, void* d_ws, size_t ws_size,
                              hipStream_t stream) {
    const float* x       = (const float*)d_in[0];
    const int*   ei      = (const int*)d_in[1];
    const int*   batch   = (const int*)d_in[2];
    const float* W1      = (const float*)d_in[3];
    const float* att_s1  = (const float*)d_in[4];
    const float* att_d1  = (const float*)d_in[5];
    const float* b1      = (const float*)d_in[6];
    const float* g1      = (const float*)d_in[7];
    const float* be1     = (const float*)d_in[8];
    const float* rm1     = (const float*)d_in[9];
    const float* rv1     = (const float*)d_in[10];
    const float* W2      = (const float*)d_in[11];
    const float* att_s2  = (const float*)d_in[12];
    const float* att_d2  = (const float*)d_in[13];
    const float* b2      = (const float*)d_in[14];
    const float* g2      = (const float*)d_in[15];
    const float* be2     = (const float*)d_in[16];
    const float* rm2     = (const float*)d_in[17];
    const float* rv2     = (const float*)d_in[18];
    const float* lw1     = (const float*)d_in[19];
    const float* lb1     = (const float*)d_in[20];
    const float* lw2     = (const float*)d_in[21];
    const float* lb2     = (const float*)d_in[22];
    float* out           = (float*)d_out;

    const int* src = ei;
    const int* dst = ei + N_EDGES;

    float* ws = (float*)d_ws;
    float* bufA   = ws;                                       // N*FEAT
    float* bufB   = bufA + (long long)N_NODES * FEAT;         // N*FEAT
    float* a_s    = bufB + (long long)N_NODES * FEAT;         // N*HEADS
    float* a_d    = a_s + N_NODES * HEADS;                    // N*HEADS
    int*   deg    = (int*)(a_d + N_NODES * HEADS);            // N
    int*   cursor = deg + N_NODES;                            // N
    int*   csr    = cursor + N_NODES;                         // E+N
    int*   rstart = csr + (N_EDGES + N_NODES);                // N+1 (padded)
    float* pooled = (float*)(rstart + 50004);                 // NG*FEAT
    float* z      = pooled + NG * FEAT;                       // NG*OUT_DIM

    const int Et = N_EDGES + N_NODES;
    dim3 blk16(16, 16);

    // ---- CSR build (shared by both layers) ----
    hipMemsetAsync(deg, 0, sizeof(int) * N_NODES, stream);
    hipMemsetAsync(cursor, 0, sizeof(int) * N_NODES, stream);
    degree_count<<<(Et + 255) / 256, 256, 0, stream>>>(src, dst, deg);
    scan_deg<<<1, 256, 0, stream>>>(deg, rstart);
    scatter_edges<<<(Et + 255) / 256, 256, 0, stream>>>(src, dst, rstart, cursor, csr);

    // ---- Layer 1 ----
    {
        dim3 grid(FEAT / 128, (N_NODES + 127) / 128);
        gemm128<false, false><<<grid, blk16, 0, stream>>>(x, W1, nullptr, bufA,
                                                          N_NODES, F_IN, FEAT);
    }
    attn_scores<<<N_NODES, 256, 0, stream>>>(bufA, att_s1, att_d1, a_s, a_d);
    gat_fused<<<N_NODES, 256, 0, stream>>>(rstart, csr, a_s, a_d, bufA,
                                           b1, g1, be1, rm1, rv1, bufB);

    // ---- Layer 2 ----
    {
        dim3 grid(FEAT / 128, (N_NODES + 127) / 128);
        gemm128<false, false><<<grid, blk16, 0, stream>>>(bufB, W2, nullptr, bufA,
                                                          N_NODES, FEAT, FEAT);
    }
    attn_scores<<<N_NODES, 256, 0, stream>>>(bufA, att_s2, att_d2, a_s, a_d);
    gat_fused<<<N_NODES, 256, 0, stream>>>(rstart, csr, a_s, a_d, bufA,
                                           b2, g2, be2, rm2, rv2, bufB);

    // ---- Pool + MLP head ----
    graph_pool<<<NG, 256, 0, stream>>>(bufB, batch, pooled);
    {
        dim3 grid(OUT_DIM / 64, (NG + 63) / 64);
        gemm64<true, true><<<grid, blk16, 0, stream>>>(pooled, lw1, lb1, z,
                                                       NG, FEAT, OUT_DIM);
    }
    final_fc<<<(NG * N_CLS + 255) / 256, 256, 0, stream>>>(z, lw2, lb2, out);
}

// Round 4
// 710.911 us; speedup vs baseline: 3.1311x; 1.2777x over previous
//
#include <hip/hip_runtime.h>
#include <hip/hip_bf16.h>
#include <math.h>

#define N_NODES 50000
#define N_EDGES 800000
#define F_IN 128
#define HID 64
#define HEADS 4
#define FEAT 256        // HEADS*HID
#define OUT_DIM 128
#define N_CLS 2
#define NG 500
#define SLOPE 0.2f
#define BN_EPS 1e-5f
#define CAP 256         // edges per chunk in fused GAT kernel
#define CAPP 260        // padded stride for p_lds (breaks 4-way bank conflict)
#define NCHUNK ((N_NODES + 255) / 256)   // 196 scan chunks

// ======== fp32 GEMM: C = A[M,K] @ B[K,N], 128x128 tile, BK=16, 8x8/thread ========
template<bool RELU, bool BIAS>
__global__ __launch_bounds__(256) void gemm128(const float* __restrict__ A,
                                               const float* __restrict__ B,
                                               const float* __restrict__ bias,
                                               float* __restrict__ C,
                                               int M, int K, int Nc) {
    __shared__ float As[16][132];   // k-major [k][m]
    __shared__ float Bs[16][132];   // [k][n]
    int tx = threadIdx.x, ty = threadIdx.y;
    int tid = ty * 16 + tx;
    int row0 = blockIdx.y * 128, col0 = blockIdx.x * 128;

    int arow = tid >> 1;
    int akk  = (tid & 1) * 8;
    int brow = tid >> 4;
    int bcol = (tid & 15) * 8;

    float acc[8][8] = {};
    float4 a0v = make_float4(0.f,0.f,0.f,0.f), a1v = a0v, b0v, b1v;

    {
        long long ar = row0 + arow;
        if (ar < M) {
            a0v = *(const float4*)&A[ar * K + akk];
            a1v = *(const float4*)&A[ar * K + akk + 4];
        }
        b0v = *(const float4*)&B[(long long)brow * Nc + col0 + bcol];
        b1v = *(const float4*)&B[(long long)brow * Nc + col0 + bcol + 4];
    }

    for (int k0 = 0; k0 < K; k0 += 16) {
        As[akk + 0][arow] = a0v.x; As[akk + 1][arow] = a0v.y;
        As[akk + 2][arow] = a0v.z; As[akk + 3][arow] = a0v.w;
        As[akk + 4][arow] = a1v.x; As[akk + 5][arow] = a1v.y;
        As[akk + 6][arow] = a1v.z; As[akk + 7][arow] = a1v.w;
        *(float4*)&Bs[brow][bcol]     = b0v;
        *(float4*)&Bs[brow][bcol + 4] = b1v;
        __syncthreads();

        int k1 = k0 + 16;
        if (k1 < K) {
            long long ar = row0 + arow;
            if (ar < M) {
                a0v = *(const float4*)&A[ar * K + k1 + akk];
                a1v = *(const float4*)&A[ar * K + k1 + akk + 4];
            } else { a0v = make_float4(0.f,0.f,0.f,0.f); a1v = a0v; }
            b0v = *(const float4*)&B[(long long)(k1 + brow) * Nc + col0 + bcol];
            b1v = *(const float4*)&B[(long long)(k1 + brow) * Nc + col0 + bcol + 4];
        }

        #pragma unroll
        for (int kk = 0; kk < 16; kk++) {
            float4 af0 = *(const float4*)&As[kk][ty * 4];
            float4 af1 = *(const float4*)&As[kk][64 + ty * 4];
            float4 bf0 = *(const float4*)&Bs[kk][tx * 4];
            float4 bf1 = *(const float4*)&Bs[kk][64 + tx * 4];
            float a[8] = {af0.x, af0.y, af0.z, af0.w, af1.x, af1.y, af1.z, af1.w};
            float b[8] = {bf0.x, bf0.y, bf0.z, bf0.w, bf1.x, bf1.y, bf1.z, bf1.w};
            #pragma unroll
            for (int i = 0; i < 8; i++)
                #pragma unroll
                for (int j = 0; j < 8; j++)
                    acc[i][j] += a[i] * b[j];
        }
        __syncthreads();
    }

    #pragma unroll
    for (int i = 0; i < 8; i++) {
        int r = row0 + ((i >> 2) * 64) + ty * 4 + (i & 3);
        if (r >= M) continue;
        #pragma unroll
        for (int jh = 0; jh < 2; jh++) {
            int c0 = col0 + jh * 64 + tx * 4;
            float v[4];
            #pragma unroll
            for (int j = 0; j < 4; j++) {
                v[j] = acc[i][jh * 4 + j];
                if (BIAS) v[j] += bias[c0 + j];
                if (RELU) v[j] = fmaxf(v[j], 0.f);
            }
            float4 o; o.x = v[0]; o.y = v[1]; o.z = v[2]; o.w = v[3];
            *(float4*)&C[(long long)r * Nc + c0] = o;
        }
    }
}

// ======== small fp32 GEMM (64x64) for the tiny head matmul ========
template<bool RELU, bool BIAS>
__global__ __launch_bounds__(256) void gemm64(const float* __restrict__ A,
                                              const float* __restrict__ B,
                                              const float* __restrict__ bias,
                                              float* __restrict__ C,
                                              int M, int K, int Nc) {
    __shared__ float Ast[16][68];
    __shared__ float Bst[16][68];
    int tx = threadIdx.x, ty = threadIdx.y;
    int tid = ty * 16 + tx;
    int row0 = blockIdx.y * 64, col0 = blockIdx.x * 64;
    float acc[4][4] = {};
    int ar = tid >> 2;
    int ak = (tid & 3) * 4;
    int bk = tid >> 4;
    int bc = (tid & 15) * 4;

    for (int k0 = 0; k0 < K; k0 += 16) {
        float4 av = make_float4(0.f, 0.f, 0.f, 0.f);
        if (row0 + ar < M) av = *(const float4*)&A[(long long)(row0 + ar) * K + k0 + ak];
        float4 bv = *(const float4*)&B[(long long)(k0 + bk) * Nc + col0 + bc];
        Ast[ak + 0][ar] = av.x; Ast[ak + 1][ar] = av.y;
        Ast[ak + 2][ar] = av.z; Ast[ak + 3][ar] = av.w;
        *(float4*)&Bst[bk][bc] = bv;
        __syncthreads();
        #pragma unroll
        for (int kk = 0; kk < 16; kk++) {
            float4 af = *(const float4*)&Ast[kk][ty * 4];
            float4 bf = *(const float4*)&Bst[kk][tx * 4];
            float a[4] = {af.x, af.y, af.z, af.w};
            float b[4] = {bf.x, bf.y, bf.z, bf.w};
            #pragma unroll
            for (int i = 0; i < 4; i++)
                #pragma unroll
                for (int j = 0; j < 4; j++)
                    acc[i][j] += a[i] * b[j];
        }
        __syncthreads();
    }
    #pragma unroll
    for (int i = 0; i < 4; i++) {
        int r = row0 + ty * 4 + i;
        if (r < M) {
            float v[4];
            #pragma unroll
            for (int j = 0; j < 4; j++) {
                v[j] = acc[i][j];
                if (BIAS) v[j] += bias[col0 + tx * 4 + j];
                if (RELU) v[j] = fmaxf(v[j], 0.f);
            }
            float4 o; o.x = v[0]; o.y = v[1]; o.z = v[2]; o.w = v[3];
            *(float4*)&C[(long long)r * Nc + col0 + tx * 4] = o;
        }
    }
}

// ======== attention scores + bf16 conversion of h ========
__global__ void attn_scores_cvt(const float* __restrict__ h,
                                const float* __restrict__ att_src,
                                const float* __restrict__ att_dst,
                                float* __restrict__ a_s, float* __restrict__ a_d,
                                unsigned short* __restrict__ h16) {
    int node = blockIdx.x;
    int t = threadIdx.x;
    int head = t >> 6, c = t & 63;
    float hv = h[(long long)node * FEAT + t];
    // bf16 RNE pack
    unsigned int u = __float_as_uint(hv);
    unsigned int lsb = (u >> 16) & 1u;
    unsigned short b = (unsigned short)((u + 0x7fffu + lsb) >> 16);
    h16[(long long)node * FEAT + t] = b;
    float ps = hv * att_src[t];
    float pd = hv * att_dst[t];
    for (int off = 32; off > 0; off >>= 1) {
        ps += __shfl_down(ps, off);
        pd += __shfl_down(pd, off);
    }
    if (c == 0) {
        a_s[node * HEADS + head] = ps;
        a_d[node * HEADS + head] = pd;
    }
}

// ================= CSR build =================
__global__ void degree_count(const int* __restrict__ src, const int* __restrict__ dst,
                             int* __restrict__ deg) {
    int e = blockIdx.x * blockDim.x + threadIdx.x;
    if (e >= N_EDGES + N_NODES) return;
    int d = (e < N_EDGES) ? dst[e] : (e - N_EDGES);
    atomicAdd(&deg[d], 1);
}

// multi-block scan, phase 1: per-256-chunk sums
__global__ __launch_bounds__(256) void scan_k1(const int* __restrict__ deg,
                                               int* __restrict__ bsum) {
    int b = blockIdx.x, t = threadIdx.x;
    int i = b * 256 + t;
    int v = (i < N_NODES) ? deg[i] : 0;
    #pragma unroll
    for (int off = 32; off > 0; off >>= 1) v += __shfl_down(v, off);
    __shared__ int ws[4];
    if ((t & 63) == 0) ws[t >> 6] = v;
    __syncthreads();
    if (t == 0) bsum[b] = ws[0] + ws[1] + ws[2] + ws[3];
}

// phase 2: single block, exclusive scan of the 196 chunk sums
__global__ __launch_bounds__(256) void scan_k2(const int* __restrict__ bsum,
                                               int* __restrict__ boff,
                                               int* __restrict__ row_start) {
    int t = threadIdx.x;
    int lane = t & 63, wid = t >> 6;
    int v = (t < NCHUNK) ? bsum[t] : 0;
    int x = v;
    #pragma unroll
    for (int off = 1; off < 64; off <<= 1) {
        int y = __shfl_up(x, off);
        if (lane >= off) x += y;
    }
    __shared__ int wsum[4], woff[4];
    if (lane == 63) wsum[wid] = x;
    __syncthreads();
    if (t == 0) {
        int s = 0;
        #pragma unroll
        for (int w = 0; w < 4; w++) { int tw = wsum[w]; woff[w] = s; s += tw; }
        row_start[N_NODES] = s;
    }
    __syncthreads();
    if (t < NCHUNK) boff[t] = x - v + woff[wid];
}

// phase 3: in-chunk exclusive scan + chunk offset
__global__ __launch_bounds__(256) void scan_k3(const int* __restrict__ deg,
                                               const int* __restrict__ boff,
                                               int* __restrict__ row_start) {
    int b = blockIdx.x, t = threadIdx.x;
    int lane = t & 63, wid = t >> 6;
    int i = b * 256 + t;
    int v = (i < N_NODES) ? deg[i] : 0;
    int x = v;
    #pragma unroll
    for (int off = 1; off < 64; off <<= 1) {
        int y = __shfl_up(x, off);
        if (lane >= off) x += y;
    }
    __shared__ int wsum[4], woff[4];
    if (lane == 63) wsum[wid] = x;
    __syncthreads();
    if (t == 0) {
        int s = boff[b];
        #pragma unroll
        for (int w = 0; w < 4; w++) { int tw = wsum[w]; woff[w] = s; s += tw; }
    }
    __syncthreads();
    if (i < N_NODES) row_start[i] = x - v + woff[wid];
}

__global__ void scatter_edges(const int* __restrict__ src, const int* __restrict__ dst,
                              const int* __restrict__ row_start, int* __restrict__ cursor,
                              int* __restrict__ csr_src) {
    int e = blockIdx.x * blockDim.x + threadIdx.x;
    if (e >= N_EDGES + N_NODES) return;
    int s, d;
    if (e < N_EDGES) { s = src[e]; d = dst[e]; } else { s = d = e - N_EDGES; }
    int pos = atomicAdd(&cursor[d], 1);
    csr_src[row_start[d] + pos] = s;
}

// ===== fused GAT: softmax (fp32) + bf16 wave-per-edge gather + bias/relu/BN =====
__global__ __launch_bounds__(256) void gat_fused(
    const int* __restrict__ row_start, const int* __restrict__ csr_src,
    const float* __restrict__ a_s, const float* __restrict__ a_d,
    const unsigned short* __restrict__ h16, const float* __restrict__ bias,
    const float* __restrict__ g, const float* __restrict__ be,
    const float* __restrict__ rm, const float* __restrict__ rv,
    float* __restrict__ out) {
    int d = blockIdx.x;
    int t = threadIdx.x;
    int lane = t & 63;
    int w = t >> 6;                         // wave id
    int hd = lane >> 4;                     // head owned by this lane's 4 channels
    __shared__ int s_lds[CAP];
    __shared__ int off_lds[CAP];            // s * 64 (uint2 units of row base)
    __shared__ float p_lds[4 * CAPP];
    __shared__ float partial[4][FEAT];
    __shared__ float m_st[4], l_st[4], alpha_st[4];

    const uint2* __restrict__ H2 = (const uint2*)h16;

    int rs = row_start[d], re = row_start[d + 1];
    int deg = re - rs;
    if (t < 4) { m_st[t] = -INFINITY; l_st[t] = 0.f; }
    float4 ad4 = *(const float4*)&a_d[d * 4];
    float4 acc = make_float4(0.f, 0.f, 0.f, 0.f);
    __syncthreads();

    for (int base = 0; base < deg; base += CAP) {
        int cl = min(CAP, deg - base);
        if (t < cl) {
            int s = csr_src[rs + base + t];
            s_lds[t] = s;
            off_lds[t] = s * 64;
        }
        __syncthreads();
        if (t < cl) {
            int s = s_lds[t];
            float4 as4 = *(const float4*)&a_s[s * 4];
            float e0 = as4.x + ad4.x; e0 = e0 > 0.f ? e0 : SLOPE * e0;
            float e1 = as4.y + ad4.y; e1 = e1 > 0.f ? e1 : SLOPE * e1;
            float e2 = as4.z + ad4.z; e2 = e2 > 0.f ? e2 : SLOPE * e2;
            float e3 = as4.w + ad4.w; e3 = e3 > 0.f ? e3 : SLOPE * e3;
            p_lds[0 * CAPP + t] = e0; p_lds[1 * CAPP + t] = e1;
            p_lds[2 * CAPP + t] = e2; p_lds[3 * CAPP + t] = e3;
        }
        __syncthreads();
        // per-head online softmax; wave w owns head w
        float mloc = -INFINITY;
        for (int e = lane; e < cl; e += 64) mloc = fmaxf(mloc, p_lds[w * CAPP + e]);
        #pragma unroll
        for (int off = 1; off < 64; off <<= 1) mloc = fmaxf(mloc, __shfl_xor(mloc, off));
        float m_old = m_st[w];
        float m_new = fmaxf(m_old, mloc);
        float csum = 0.f;
        for (int e = lane; e < cl; e += 64) {
            float p = __expf(p_lds[w * CAPP + e] - m_new);
            p_lds[w * CAPP + e] = p;
            csum += p;
        }
        #pragma unroll
        for (int off = 1; off < 64; off <<= 1) csum += __shfl_xor(csum, off);
        float alpha = __expf(m_old - m_new);
        if (lane == 0) {
            m_st[w] = m_new;
            l_st[w] = l_st[w] * alpha + csum;
            alpha_st[w] = alpha;
        }
        __syncthreads();
        // wave-per-edge gather: wave w takes edges w, w+4, ...; lane covers 4 channels
        float al = alpha_st[hd];
        acc.x *= al; acc.y *= al; acc.z *= al; acc.w *= al;
        #pragma unroll 2
        for (int e = w; e < cl; e += 4) {
            float p = p_lds[hd * CAPP + e];
            uint2 hv = H2[off_lds[e] + lane];
            float f0 = __uint_as_float(hv.x << 16);
            float f1 = __uint_as_float(hv.x & 0xffff0000u);
            float f2 = __uint_as_float(hv.y << 16);
            float f3 = __uint_as_float(hv.y & 0xffff0000u);
            acc.x += p * f0; acc.y += p * f1;
            acc.z += p * f2; acc.w += p * f3;
        }
        __syncthreads();
    }
    // cross-wave reduction: wave w's partials for channels 4*lane..4*lane+3
    *(float4*)&partial[w][4 * lane] = acc;
    __syncthreads();
    float v = partial[0][t] + partial[1][t] + partial[2][t] + partial[3][t];
    v /= l_st[t >> 6];
    v += bias[t];
    v = fmaxf(v, 0.f);
    v = (v - rm[t]) * rsqrtf(rv[t] + BN_EPS) * g[t] + be[t];
    out[(long long)d * FEAT + t] = v;
}

// ================= pooling (batch sorted): one block per graph =================
__global__ __launch_bounds__(256) void graph_pool(const float* __restrict__ h,
                                                  const int* __restrict__ batch,
                                                  float* __restrict__ pooled) {
    int gph = blockIdx.x;
    int t = threadIdx.x;
    __shared__ int lo_s, hi_s;
    if (t == 0) {
        int lo = 0, hi = N_NODES;
        while (lo < hi) { int mid = (lo + hi) >> 1; if (batch[mid] < gph) lo = mid + 1; else hi = mid; }
        lo_s = lo;
        int lo2 = 0, hi2 = N_NODES;
        while (lo2 < hi2) { int mid = (lo2 + hi2) >> 1; if (batch[mid] < gph + 1) lo2 = mid + 1; else hi2 = mid; }
        hi_s = lo2;
    }
    __syncthreads();
    int lo = lo_s, hi = hi_s;
    float acc = 0.f;
    for (int n = lo; n < hi; n++) acc += h[(long long)n * FEAT + t];
    float cnt = (float)(hi - lo);
    pooled[gph * FEAT + t] = acc / fmaxf(cnt, 1.f);
}

__global__ void final_fc(const float* __restrict__ z, const float* __restrict__ lw2,
                         const float* __restrict__ lb2, float* __restrict__ out) {
    int gid = blockIdx.x * blockDim.x + threadIdx.x;
    if (gid >= NG * N_CLS) return;
    int g = gid >> 1, c = gid & 1;
    float acc = lb2[c];
    #pragma unroll 8
    for (int k = 0; k < OUT_DIM; k++) acc += z[g * OUT_DIM + k] * lw2[k * N_CLS + c];
    out[gid] = acc;
}

extern "C" void kernel_launch(void* const* d_in, const int* in_sizes, int n_in,
                              void* d_out, int out_size, void* d_ws, size_t ws_size,
                              hipStream_t stream) {
    const float* x       = (const float*)d_in[0];
    const int*   ei      = (const int*)d_in[1];
    const int*   batch   = (const int*)d_in[2];
    const float* W1      = (const float*)d_in[3];
    const float* att_s1  = (const float*)d_in[4];
    const float* att_d1  = (const float*)d_in[5];
    const float* b1      = (const float*)d_in[6];
    const float* g1      = (const float*)d_in[7];
    const float* be1     = (const float*)d_in[8];
    const float* rm1     = (const float*)d_in[9];
    const float* rv1     = (const float*)d_in[10];
    const float* W2      = (const float*)d_in[11];
    const float* att_s2  = (const float*)d_in[12];
    const float* att_d2  = (const float*)d_in[13];
    const float* b2      = (const float*)d_in[14];
    const float* g2      = (const float*)d_in[15];
    const float* be2     = (const float*)d_in[16];
    const float* rm2     = (const float*)d_in[17];
    const float* rv2     = (const float*)d_in[18];
    const float* lw1     = (const float*)d_in[19];
    const float* lb1     = (const float*)d_in[20];
    const float* lw2     = (const float*)d_in[21];
    const float* lb2     = (const float*)d_in[22];
    float* out           = (float*)d_out;

    const int* src = ei;
    const int* dst = ei + N_EDGES;

    float* ws = (float*)d_ws;
    float* bufA   = ws;                                       // N*FEAT
    float* bufB   = bufA + (long long)N_NODES * FEAT;         // N*FEAT
    float* a_s    = bufB + (long long)N_NODES * FEAT;         // N*HEADS
    float* a_d    = a_s + N_NODES * HEADS;                    // N*HEADS
    int*   deg    = (int*)(a_d + N_NODES * HEADS);            // N
    int*   cursor = deg + N_NODES;                            // N
    int*   csr    = cursor + N_NODES;                         // E+N
    int*   rstart = csr + (N_EDGES + N_NODES);                // N+1 (padded)
    int*   bsum   = rstart + 50004;                           // NCHUNK (pad 256)
    int*   boff   = bsum + 256;                               // NCHUNK (pad 256)
    float* pooled = (float*)(boff + 256);                     // NG*FEAT
    float* z      = pooled + NG * FEAT;                       // NG*OUT_DIM
    unsigned short* h16 = (unsigned short*)(z + NG * OUT_DIM); // N*FEAT bf16

    const int Et = N_EDGES + N_NODES;
    dim3 blk16(16, 16);

    // ---- CSR build (shared by both layers) ----
    hipMemsetAsync(deg, 0, sizeof(int) * N_NODES, stream);
    hipMemsetAsync(cursor, 0, sizeof(int) * N_NODES, stream);
    degree_count<<<(Et + 255) / 256, 256, 0, stream>>>(src, dst, deg);
    scan_k1<<<NCHUNK, 256, 0, stream>>>(deg, bsum);
    scan_k2<<<1, 256, 0, stream>>>(bsum, boff, rstart);
    scan_k3<<<NCHUNK, 256, 0, stream>>>(deg, boff, rstart);
    scatter_edges<<<(Et + 255) / 256, 256, 0, stream>>>(src, dst, rstart, cursor, csr);

    // ---- Layer 1 ----
    {
        dim3 grid(FEAT / 128, (N_NODES + 127) / 128);
        gemm128<false, false><<<grid, blk16, 0, stream>>>(x, W1, nullptr, bufA,
                                                          N_NODES, F_IN, FEAT);
    }
    attn_scores_cvt<<<N_NODES, 256, 0, stream>>>(bufA, att_s1, att_d1, a_s, a_d, h16);
    gat_fused<<<N_NODES, 256, 0, stream>>>(rstart, csr, a_s, a_d, h16,
                                           b1, g1, be1, rm1, rv1, bufB);

    // ---- Layer 2 ----
    {
        dim3 grid(FEAT / 128, (N_NODES + 127) / 128);
        gemm128<false, false><<<grid, blk16, 0, stream>>>(bufB, W2, nullptr, bufA,
                                                          N_NODES, FEAT, FEAT);
    }
    attn_scores_cvt<<<N_NODES, 256, 0, stream>>>(bufA, att_s2, att_d2, a_s, a_d, h16);
    gat_fused<<<N_NODES, 256, 0, stream>>>(rstart, csr, a_s, a_d, h16,
                                           b2, g2, be2, rm2, rv2, bufB);

    // ---- Pool + MLP head ----
    graph_pool<<<NG, 256, 0, stream>>>(bufB, batch, pooled);
    {
        dim3 grid(OUT_DIM / 64, (NG + 63) / 64);
        gemm64<true, true><<<grid, blk16, 0, stream>>>(pooled, lw1, lb1, z,
                                                       NG, FEAT, OUT_DIM);
    }
    final_fc<<<(NG * N_CLS + 255) / 256, 256, 0, stream>>>(z, lw2, lb2, out);
}

// Round 5
// 584.136 us; speedup vs baseline: 3.8106x; 1.2170x over previous
//
#include <hip/hip_runtime.h>
#include <hip/hip_bf16.h>
#include <math.h>

#define N_NODES 50000
#define M_PAD   50048                    // 391 * 128
#define N_EDGES 800000
#define F_IN 128
#define HID 64
#define HEADS 4
#define FEAT 256        // HEADS*HID
#define OUT_DIM 128
#define N_CLS 2
#define NG 500
#define SLOPE 0.2f
#define BN_EPS 1e-5f
#define CAP 256
#define CAPP 260
#define NCHUNK ((N_NODES + 255) / 256)

typedef __attribute__((ext_vector_type(8))) short short8;
typedef __attribute__((ext_vector_type(4))) float floatx4;

__device__ inline unsigned short f2bf(float f) {
    unsigned int u = __float_as_uint(f);
    unsigned int lsb = (u >> 16) & 1u;
    return (unsigned short)((u + 0x7fffu + lsb) >> 16);
}

// ======== bf16 MFMA GEMM: C[M,Nc] = A[Mpad,K] @ BT[Nc,K]^T, 128x128 tile, BK=32 ========
// A, BT bf16 row-major; C fp32. Fragment loads are contiguous ds_read_b128.
__global__ __launch_bounds__(256) void gemm_mfma(const unsigned short* __restrict__ A,
                                                 const unsigned short* __restrict__ BT,
                                                 float* __restrict__ C,
                                                 int M, int K, int Nc) {
    constexpr int LS = 40;                 // padded row stride (bf16) -> 80B
    __shared__ unsigned short As[128 * LS];
    __shared__ unsigned short Bs[128 * LS];
    int t = threadIdx.x;
    int lane = t & 63, w = t >> 6;
    int wm = (w >> 1) * 64, wn = (w & 1) * 64;
    int row0 = blockIdx.y * 128, col0 = blockIdx.x * 128;

    floatx4 acc[4][4] = {};

    int r0 = t >> 2,            c0 = (t & 3) * 8;          // staging round 0
    int r1 = (t + 256) >> 2,    c1 = ((t + 256) & 3) * 8;  // staging round 1
    int mrow = lane & 15, quad = lane >> 4;

    for (int k0 = 0; k0 < K; k0 += 32) {
        *(uint4*)&As[r0 * LS + c0] = *(const uint4*)&A[(long long)(row0 + r0) * K + k0 + c0];
        *(uint4*)&As[r1 * LS + c1] = *(const uint4*)&A[(long long)(row0 + r1) * K + k0 + c1];
        *(uint4*)&Bs[r0 * LS + c0] = *(const uint4*)&BT[(long long)(col0 + r0) * K + k0 + c0];
        *(uint4*)&Bs[r1 * LS + c1] = *(const uint4*)&BT[(long long)(col0 + r1) * K + k0 + c1];
        __syncthreads();
        short8 af[4], bf[4];
        #pragma unroll
        for (int i = 0; i < 4; i++) {
            af[i] = *(const short8*)&As[(wm + i * 16 + mrow) * LS + quad * 8];
            bf[i] = *(const short8*)&Bs[(wn + i * 16 + mrow) * LS + quad * 8];
        }
        #pragma unroll
        for (int mi = 0; mi < 4; mi++)
            #pragma unroll
            for (int ni = 0; ni < 4; ni++)
                acc[mi][ni] = __builtin_amdgcn_mfma_f32_16x16x32_bf16(af[mi], bf[ni],
                                                                      acc[mi][ni], 0, 0, 0);
        __syncthreads();
    }

    #pragma unroll
    for (int mi = 0; mi < 4; mi++)
        #pragma unroll
        for (int ni = 0; ni < 4; ni++)
            #pragma unroll
            for (int r = 0; r < 4; r++) {
                int row = row0 + wm + mi * 16 + quad * 4 + r;
                int col = col0 + wn + ni * 16 + mrow;
                if (row < M) C[(long long)row * Nc + col] = acc[mi][ni][r];
            }
}

// ======== converts ========
__global__ void cvt_x_bf16(const float* __restrict__ x, unsigned short* __restrict__ x16) {
    long long i = (long long)blockIdx.x * 256 + threadIdx.x;   // over M_PAD*F_IN
    if (i >= (long long)M_PAD * F_IN) return;
    int row = (int)(i >> 7);
    x16[i] = (row < N_NODES) ? f2bf(x[i]) : 0;
}

__global__ void cvt_wT(const float* __restrict__ W, unsigned short* __restrict__ WT, int K) {
    int i = blockIdx.x * 256 + threadIdx.x;     // over K*256
    if (i >= K * 256) return;
    int k = i >> 8, n = i & 255;
    WT[n * K + k] = f2bf(W[i]);
}

// ======== small fp32 GEMM (64x64) for the head matmul ========
template<bool RELU, bool BIAS>
__global__ __launch_bounds__(256) void gemm64(const float* __restrict__ A,
                                              const float* __restrict__ B,
                                              const float* __restrict__ bias,
                                              float* __restrict__ C,
                                              int M, int K, int Nc) {
    __shared__ float Ast[16][68];
    __shared__ float Bst[16][68];
    int tx = threadIdx.x, ty = threadIdx.y;
    int tid = ty * 16 + tx;
    int row0 = blockIdx.y * 64, col0 = blockIdx.x * 64;
    float acc[4][4] = {};
    int ar = tid >> 2;
    int ak = (tid & 3) * 4;
    int bk = tid >> 4;
    int bc = (tid & 15) * 4;

    for (int k0 = 0; k0 < K; k0 += 16) {
        float4 av = make_float4(0.f, 0.f, 0.f, 0.f);
        if (row0 + ar < M) av = *(const float4*)&A[(long long)(row0 + ar) * K + k0 + ak];
        float4 bv = *(const float4*)&B[(long long)(k0 + bk) * Nc + col0 + bc];
        Ast[ak + 0][ar] = av.x; Ast[ak + 1][ar] = av.y;
        Ast[ak + 2][ar] = av.z; Ast[ak + 3][ar] = av.w;
        *(float4*)&Bst[bk][bc] = bv;
        __syncthreads();
        #pragma unroll
        for (int kk = 0; kk < 16; kk++) {
            float4 af = *(const float4*)&Ast[kk][ty * 4];
            float4 bfv = *(const float4*)&Bst[kk][tx * 4];
            float a[4] = {af.x, af.y, af.z, af.w};
            float b[4] = {bfv.x, bfv.y, bfv.z, bfv.w};
            #pragma unroll
            for (int i = 0; i < 4; i++)
                #pragma unroll
                for (int j = 0; j < 4; j++)
                    acc[i][j] += a[i] * b[j];
        }
        __syncthreads();
    }
    #pragma unroll
    for (int i = 0; i < 4; i++) {
        int r = row0 + ty * 4 + i;
        if (r < M) {
            float v[4];
            #pragma unroll
            for (int j = 0; j < 4; j++) {
                v[j] = acc[i][j];
                if (BIAS) v[j] += bias[col0 + tx * 4 + j];
                if (RELU) v[j] = fmaxf(v[j], 0.f);
            }
            float4 o; o.x = v[0]; o.y = v[1]; o.z = v[2]; o.w = v[3];
            *(float4*)&C[(long long)r * Nc + col0 + tx * 4] = o;
        }
    }
}

// ======== attention scores + bf16 conversion of h (gather source) ========
__global__ void attn_scores_cvt(const float* __restrict__ h,
                                const float* __restrict__ att_src,
                                const float* __restrict__ att_dst,
                                float* __restrict__ a_s, float* __restrict__ a_d,
                                unsigned short* __restrict__ h16) {
    int node = blockIdx.x;
    int t = threadIdx.x;
    int head = t >> 6, c = t & 63;
    float hv = h[(long long)node * FEAT + t];
    h16[(long long)node * FEAT + t] = f2bf(hv);
    float ps = hv * att_src[t];
    float pd = hv * att_dst[t];
    for (int off = 32; off > 0; off >>= 1) {
        ps += __shfl_down(ps, off);
        pd += __shfl_down(pd, off);
    }
    if (c == 0) {
        a_s[node * HEADS + head] = ps;
        a_d[node * HEADS + head] = pd;
    }
}

// ================= CSR build =================
__global__ void degree_count(const int* __restrict__ src, const int* __restrict__ dst,
                             int* __restrict__ deg) {
    int e = blockIdx.x * blockDim.x + threadIdx.x;
    if (e >= N_EDGES + N_NODES) return;
    int d = (e < N_EDGES) ? dst[e] : (e - N_EDGES);
    atomicAdd(&deg[d], 1);
}

__global__ __launch_bounds__(256) void scan_k1(const int* __restrict__ deg,
                                               int* __restrict__ bsum) {
    int b = blockIdx.x, t = threadIdx.x;
    int i = b * 256 + t;
    int v = (i < N_NODES) ? deg[i] : 0;
    #pragma unroll
    for (int off = 32; off > 0; off >>= 1) v += __shfl_down(v, off);
    __shared__ int ws[4];
    if ((t & 63) == 0) ws[t >> 6] = v;
    __syncthreads();
    if (t == 0) bsum[b] = ws[0] + ws[1] + ws[2] + ws[3];
}

__global__ __launch_bounds__(256) void scan_k2(const int* __restrict__ bsum,
                                               int* __restrict__ boff,
                                               int* __restrict__ row_start) {
    int t = threadIdx.x;
    int lane = t & 63, wid = t >> 6;
    int v = (t < NCHUNK) ? bsum[t] : 0;
    int x = v;
    #pragma unroll
    for (int off = 1; off < 64; off <<= 1) {
        int y = __shfl_up(x, off);
        if (lane >= off) x += y;
    }
    __shared__ int wsum[4], woff[4];
    if (lane == 63) wsum[wid] = x;
    __syncthreads();
    if (t == 0) {
        int s = 0;
        #pragma unroll
        for (int w = 0; w < 4; w++) { int tw = wsum[w]; woff[w] = s; s += tw; }
        row_start[N_NODES] = s;
    }
    __syncthreads();
    if (t < NCHUNK) boff[t] = x - v + woff[wid];
}

__global__ __launch_bounds__(256) void scan_k3(const int* __restrict__ deg,
                                               const int* __restrict__ boff,
                                               int* __restrict__ row_start) {
    int b = blockIdx.x, t = threadIdx.x;
    int lane = t & 63, wid = t >> 6;
    int i = b * 256 + t;
    int v = (i < N_NODES) ? deg[i] : 0;
    int x = v;
    #pragma unroll
    for (int off = 1; off < 64; off <<= 1) {
        int y = __shfl_up(x, off);
        if (lane >= off) x += y;
    }
    __shared__ int wsum[4], woff[4];
    if (lane == 63) wsum[wid] = x;
    __syncthreads();
    if (t == 0) {
        int s = boff[b];
        #pragma unroll
        for (int w = 0; w < 4; w++) { int tw = wsum[w]; woff[w] = s; s += tw; }
    }
    __syncthreads();
    if (i < N_NODES) row_start[i] = x - v + woff[wid];
}

__global__ void scatter_edges(const int* __restrict__ src, const int* __restrict__ dst,
                              const int* __restrict__ row_start, int* __restrict__ cursor,
                              int* __restrict__ csr_src) {
    int e = blockIdx.x * blockDim.x + threadIdx.x;
    if (e >= N_EDGES + N_NODES) return;
    int s, d;
    if (e < N_EDGES) { s = src[e]; d = dst[e]; } else { s = d = e - N_EDGES; }
    int pos = atomicAdd(&cursor[d], 1);
    csr_src[row_start[d] + pos] = s;
}

// ===== fused GAT: softmax (fp32) + bf16 wave-per-edge gather + bias/relu/BN =====
// writes fp32 `out` and bf16 `out16` (row-padded buffer for the next MFMA GEMM)
__global__ __launch_bounds__(256) void gat_fused(
    const int* __restrict__ row_start, const int* __restrict__ csr_src,
    const float* __restrict__ a_s, const float* __restrict__ a_d,
    const unsigned short* __restrict__ h16, const float* __restrict__ bias,
    const float* __restrict__ g, const float* __restrict__ be,
    const float* __restrict__ rm, const float* __restrict__ rv,
    float* __restrict__ out, unsigned short* __restrict__ out16) {
    int d = blockIdx.x;
    int t = threadIdx.x;
    int lane = t & 63;
    int w = t >> 6;
    int hd = lane >> 4;
    __shared__ int s_lds[CAP];
    __shared__ int off_lds[CAP];
    __shared__ float p_lds[4 * CAPP];
    __shared__ float partial[4][FEAT];
    __shared__ float m_st[4], l_st[4], alpha_st[4];

    const uint2* __restrict__ H2 = (const uint2*)h16;

    int rs = row_start[d], re = row_start[d + 1];
    int deg = re - rs;
    if (t < 4) { m_st[t] = -INFINITY; l_st[t] = 0.f; }
    float4 ad4 = *(const float4*)&a_d[d * 4];
    float4 acc = make_float4(0.f, 0.f, 0.f, 0.f);
    __syncthreads();

    for (int base = 0; base < deg; base += CAP) {
        int cl = min(CAP, deg - base);
        if (t < cl) {
            int s = csr_src[rs + base + t];
            s_lds[t] = s;
            off_lds[t] = s * 64;
        }
        __syncthreads();
        if (t < cl) {
            int s = s_lds[t];
            float4 as4 = *(const float4*)&a_s[s * 4];
            float e0 = as4.x + ad4.x; e0 = e0 > 0.f ? e0 : SLOPE * e0;
            float e1 = as4.y + ad4.y; e1 = e1 > 0.f ? e1 : SLOPE * e1;
            float e2 = as4.z + ad4.z; e2 = e2 > 0.f ? e2 : SLOPE * e2;
            float e3 = as4.w + ad4.w; e3 = e3 > 0.f ? e3 : SLOPE * e3;
            p_lds[0 * CAPP + t] = e0; p_lds[1 * CAPP + t] = e1;
            p_lds[2 * CAPP + t] = e2; p_lds[3 * CAPP + t] = e3;
        }
        __syncthreads();
        float mloc = -INFINITY;
        for (int e = lane; e < cl; e += 64) mloc = fmaxf(mloc, p_lds[w * CAPP + e]);
        #pragma unroll
        for (int off = 1; off < 64; off <<= 1) mloc = fmaxf(mloc, __shfl_xor(mloc, off));
        float m_old = m_st[w];
        float m_new = fmaxf(m_old, mloc);
        float csum = 0.f;
        for (int e = lane; e < cl; e += 64) {
            float p = __expf(p_lds[w * CAPP + e] - m_new);
            p_lds[w * CAPP + e] = p;
            csum += p;
        }
        #pragma unroll
        for (int off = 1; off < 64; off <<= 1) csum += __shfl_xor(csum, off);
        float alpha = __expf(m_old - m_new);
        if (lane == 0) {
            m_st[w] = m_new;
            l_st[w] = l_st[w] * alpha + csum;
            alpha_st[w] = alpha;
        }
        __syncthreads();
        float al = alpha_st[hd];
        acc.x *= al; acc.y *= al; acc.z *= al; acc.w *= al;
        #pragma unroll 2
        for (int e = w; e < cl; e += 4) {
            float p = p_lds[hd * CAPP + e];
            uint2 hv = H2[off_lds[e] + lane];
            float f0 = __uint_as_float(hv.x << 16);
            float f1 = __uint_as_float(hv.x & 0xffff0000u);
            float f2 = __uint_as_float(hv.y << 16);
            float f3 = __uint_as_float(hv.y & 0xffff0000u);
            acc.x += p * f0; acc.y += p * f1;
            acc.z += p * f2; acc.w += p * f3;
        }
        __syncthreads();
    }
    *(float4*)&partial[w][4 * lane] = acc;
    __syncthreads();
    float v = partial[0][t] + partial[1][t] + partial[2][t] + partial[3][t];
    v /= l_st[t >> 6];
    v += bias[t];
    v = fmaxf(v, 0.f);
    v = (v - rm[t]) * rsqrtf(rv[t] + BN_EPS) * g[t] + be[t];
    out[(long long)d * FEAT + t] = v;
    out16[(long long)d * FEAT + t] = f2bf(v);
}

// ================= pooling (batch sorted): one block per graph =================
__global__ __launch_bounds__(256) void graph_pool(const float* __restrict__ h,
                                                  const int* __restrict__ batch,
                                                  float* __restrict__ pooled) {
    int gph = blockIdx.x;
    int t = threadIdx.x;
    __shared__ int lo_s, hi_s;
    if (t == 0) {
        int lo = 0, hi = N_NODES;
        while (lo < hi) { int mid = (lo + hi) >> 1; if (batch[mid] < gph) lo = mid + 1; else hi = mid; }
        lo_s = lo;
        int lo2 = 0, hi2 = N_NODES;
        while (lo2 < hi2) { int mid = (lo2 + hi2) >> 1; if (batch[mid] < gph + 1) lo2 = mid + 1; else hi2 = mid; }
        hi_s = lo2;
    }
    __syncthreads();
    int lo = lo_s, hi = hi_s;
    float acc = 0.f;
    for (int n = lo; n < hi; n++) acc += h[(long long)n * FEAT + t];
    float cnt = (float)(hi - lo);
    pooled[gph * FEAT + t] = acc / fmaxf(cnt, 1.f);
}

__global__ void final_fc(const float* __restrict__ z, const float* __restrict__ lw2,
                         const float* __restrict__ lb2, float* __restrict__ out) {
    int gid = blockIdx.x * blockDim.x + threadIdx.x;
    if (gid >= NG * N_CLS) return;
    int g = gid >> 1, c = gid & 1;
    float acc = lb2[c];
    #pragma unroll 8
    for (int k = 0; k < OUT_DIM; k++) acc += z[g * OUT_DIM + k] * lw2[k * N_CLS + c];
    out[gid] = acc;
}

extern "C" void kernel_launch(void* const* d_in, const int* in_sizes, int n_in,
                              void* d_out, int out_size, void* d_ws, size_t ws_size,
                              hipStream_t stream) {
    const float* x       = (const float*)d_in[0];
    const int*   ei      = (const int*)d_in[1];
    const int*   batch   = (const int*)d_in[2];
    const float* W1      = (const float*)d_in[3];
    const float* att_s1  = (const float*)d_in[4];
    const float* att_d1  = (const float*)d_in[5];
    const float* b1      = (const float*)d_in[6];
    const float* g1      = (const float*)d_in[7];
    const float* be1     = (const float*)d_in[8];
    const float* rm1     = (const float*)d_in[9];
    const float* rv1     = (const float*)d_in[10];
    const float* W2      = (const float*)d_in[11];
    const float* att_s2  = (const float*)d_in[12];
    const float* att_d2  = (const float*)d_in[13];
    const float* b2      = (const float*)d_in[14];
    const float* g2      = (const float*)d_in[15];
    const float* be2     = (const float*)d_in[16];
    const float* rm2     = (const float*)d_in[17];
    const float* rv2     = (const float*)d_in[18];
    const float* lw1     = (const float*)d_in[19];
    const float* lb1     = (const float*)d_in[20];
    const float* lw2     = (const float*)d_in[21];
    const float* lb2     = (const float*)d_in[22];
    float* out           = (float*)d_out;

    const int* src = ei;
    const int* dst = ei + N_EDGES;

    // ---- workspace carve-up (64B-aligned chunks) ----
    char* p = (char*)d_ws;
    auto carve = [&p](size_t bytes) -> void* {
        void* r = (void*)p;
        p += (bytes + 63) & ~(size_t)63;
        return r;
    };
    float* bufA   = (float*)carve(sizeof(float) * (size_t)N_NODES * FEAT);
    float* bufB   = (float*)carve(sizeof(float) * (size_t)N_NODES * FEAT);
    float* a_s    = (float*)carve(sizeof(float) * N_NODES * HEADS);
    float* a_d    = (float*)carve(sizeof(float) * N_NODES * HEADS);
    int*   deg    = (int*)carve(sizeof(int) * N_NODES);
    int*   cursor = (int*)carve(sizeof(int) * N_NODES);
    int*   csr    = (int*)carve(sizeof(int) * (N_EDGES + N_NODES));
    int*   rstart = (int*)carve(sizeof(int) * (N_NODES + 4));
    int*   bsum   = (int*)carve(sizeof(int) * 256);
    int*   boff   = (int*)carve(sizeof(int) * 256);
    float* pooled = (float*)carve(sizeof(float) * NG * FEAT);
    float* z      = (float*)carve(sizeof(float) * NG * OUT_DIM);
    unsigned short* h16  = (unsigned short*)carve(sizeof(short) * (size_t)N_NODES * FEAT);
    unsigned short* x16  = (unsigned short*)carve(sizeof(short) * (size_t)M_PAD * F_IN);
    unsigned short* h1bf = (unsigned short*)carve(sizeof(short) * (size_t)M_PAD * FEAT);
    unsigned short* w1t  = (unsigned short*)carve(sizeof(short) * FEAT * F_IN);
    unsigned short* w2t  = (unsigned short*)carve(sizeof(short) * FEAT * FEAT);

    const int Et = N_EDGES + N_NODES;
    dim3 blk16(16, 16);

    // ---- converts (independent of CSR) ----
    cvt_x_bf16<<<((long long)M_PAD * F_IN + 255) / 256, 256, 0, stream>>>(x, x16);
    cvt_wT<<<(F_IN * 256 + 255) / 256, 256, 0, stream>>>(W1, w1t, F_IN);
    cvt_wT<<<(FEAT * 256 + 255) / 256, 256, 0, stream>>>(W2, w2t, FEAT);
    // zero pad rows of h1bf (rows N_NODES..M_PAD)
    hipMemsetAsync(h1bf + (size_t)N_NODES * FEAT, 0,
                   sizeof(short) * (size_t)(M_PAD - N_NODES) * FEAT, stream);

    // ---- CSR build (deg & cursor adjacent -> one memset) ----
    hipMemsetAsync(deg, 0, sizeof(int) * N_NODES, stream);
    hipMemsetAsync(cursor, 0, sizeof(int) * N_NODES, stream);
    degree_count<<<(Et + 255) / 256, 256, 0, stream>>>(src, dst, deg);
    scan_k1<<<NCHUNK, 256, 0, stream>>>(deg, bsum);
    scan_k2<<<1, 256, 0, stream>>>(bsum, boff, rstart);
    scan_k3<<<NCHUNK, 256, 0, stream>>>(deg, boff, rstart);
    scatter_edges<<<(Et + 255) / 256, 256, 0, stream>>>(src, dst, rstart, cursor, csr);

    // ---- Layer 1 ----
    {
        dim3 grid(FEAT / 128, M_PAD / 128);
        gemm_mfma<<<grid, 256, 0, stream>>>(x16, w1t, bufA, N_NODES, F_IN, FEAT);
    }
    attn_scores_cvt<<<N_NODES, 256, 0, stream>>>(bufA, att_s1, att_d1, a_s, a_d, h16);
    gat_fused<<<N_NODES, 256, 0, stream>>>(rstart, csr, a_s, a_d, h16,
                                           b1, g1, be1, rm1, rv1, bufB, h1bf);

    // ---- Layer 2 ----
    {
        dim3 grid(FEAT / 128, M_PAD / 128);
        gemm_mfma<<<grid, 256, 0, stream>>>(h1bf, w2t, bufA, N_NODES, FEAT, FEAT);
    }
    attn_scores_cvt<<<N_NODES, 256, 0, stream>>>(bufA, att_s2, att_d2, a_s, a_d, h16);
    gat_fused<<<N_NODES, 256, 0, stream>>>(rstart, csr, a_s, a_d, h16,
                                           b2, g2, be2, rm2, rv2, bufB, h1bf);

    // ---- Pool + MLP head ----
    graph_pool<<<NG, 256, 0, stream>>>(bufB, batch, pooled);
    {
        dim3 grid(OUT_DIM / 64, (NG + 63) / 64);
        gemm64<true, true><<<grid, blk16, 0, stream>>>(pooled, lw1, lb1, z,
                                                       NG, FEAT, OUT_DIM);
    }
    final_fc<<<(NG * N_CLS + 255) / 256, 256, 0, stream>>>(z, lw2, lb2, out);
}

// Round 6
// 548.921 us; speedup vs baseline: 4.0551x; 1.0642x over previous
//
#include <hip/hip_runtime.h>
#include <hip/hip_bf16.h>
#include <math.h>

#define N_NODES 50000
#define M_PAD   50048                    // 391 * 128
#define N_EDGES 800000
#define F_IN 128
#define HID 64
#define HEADS 4
#define FEAT 256        // HEADS*HID
#define OUT_DIM 128
#define N_CLS 2
#define NG 500
#define SLOPE 0.2f
#define BN_EPS 1e-5f
#define CAP 256
#define CAPP 260
#define NCHUNK ((N_NODES + 255) / 256)

typedef __attribute__((ext_vector_type(8))) short short8;
typedef __attribute__((ext_vector_type(4))) float floatx4;

__device__ inline unsigned short f2bf(float f) {
    unsigned int u = __float_as_uint(f);
    unsigned int lsb = (u >> 16) & 1u;
    return (unsigned short)((u + 0x7fffu + lsb) >> 16);
}

// ==== bf16 MFMA GEMM fused with GAT prologue ====
// C = A[Mpad,K] @ BT[256,K]^T. Writes bf16 h16[N,256] and fp32 attention
// scores a_s/a_d[N,4] computed from the fp32 accumulators (each wave's
// 64-col span == one head).
__global__ __launch_bounds__(256) void gemm_mfma_gat(
    const unsigned short* __restrict__ A, const unsigned short* __restrict__ BT,
    const float* __restrict__ att_src, const float* __restrict__ att_dst,
    unsigned short* __restrict__ h16, float* __restrict__ a_s,
    float* __restrict__ a_d, int K) {
    constexpr int LS = 40;                 // padded row stride (bf16)
    __shared__ unsigned short As[128 * LS];
    __shared__ unsigned short Bs[128 * LS];
    int t = threadIdx.x;
    int lane = t & 63, w = t >> 6;
    int wm = (w >> 1) * 64, wn = (w & 1) * 64;
    int row0 = blockIdx.y * 128, col0 = blockIdx.x * 128;

    floatx4 acc[4][4] = {};

    int r0 = t >> 2,            c0 = (t & 3) * 8;
    int r1 = (t + 256) >> 2,    c1 = ((t + 256) & 3) * 8;
    int mrow = lane & 15, quad = lane >> 4;

    for (int k0 = 0; k0 < K; k0 += 32) {
        *(uint4*)&As[r0 * LS + c0] = *(const uint4*)&A[(long long)(row0 + r0) * K + k0 + c0];
        *(uint4*)&As[r1 * LS + c1] = *(const uint4*)&A[(long long)(row0 + r1) * K + k0 + c1];
        *(uint4*)&Bs[r0 * LS + c0] = *(const uint4*)&BT[(long long)(col0 + r0) * K + k0 + c0];
        *(uint4*)&Bs[r1 * LS + c1] = *(const uint4*)&BT[(long long)(col0 + r1) * K + k0 + c1];
        __syncthreads();
        short8 af[4], bf[4];
        #pragma unroll
        for (int i = 0; i < 4; i++) {
            af[i] = *(const short8*)&As[(wm + i * 16 + mrow) * LS + quad * 8];
            bf[i] = *(const short8*)&Bs[(wn + i * 16 + mrow) * LS + quad * 8];
        }
        #pragma unroll
        for (int mi = 0; mi < 4; mi++)
            #pragma unroll
            for (int ni = 0; ni < 4; ni++)
                acc[mi][ni] = __builtin_amdgcn_mfma_f32_16x16x32_bf16(af[mi], bf[ni],
                                                                      acc[mi][ni], 0, 0, 0);
        __syncthreads();
    }

    int head = blockIdx.x * 2 + (w & 1);
    // per-lane att weights for cols ni*16+mrow of this head
    float ats[4], atd[4];
    #pragma unroll
    for (int ni = 0; ni < 4; ni++) {
        ats[ni] = att_src[head * 64 + ni * 16 + mrow];
        atd[ni] = att_dst[head * 64 + ni * 16 + mrow];
    }

    #pragma unroll
    for (int mi = 0; mi < 4; mi++) {
        #pragma unroll
        for (int r = 0; r < 4; r++) {
            int row = row0 + wm + mi * 16 + quad * 4 + r;
            float ps = 0.f, pd = 0.f;
            #pragma unroll
            for (int ni = 0; ni < 4; ni++) {
                float v = acc[mi][ni][r];
                ps += v * ats[ni];
                pd += v * atd[ni];
                if (row < N_NODES) {
                    int col = col0 + wn + ni * 16 + mrow;
                    h16[(long long)row * FEAT + col] = f2bf(v);
                }
            }
            #pragma unroll
            for (int off = 1; off < 16; off <<= 1) {
                ps += __shfl_xor(ps, off);
                pd += __shfl_xor(pd, off);
            }
            if (mrow == 0 && row < N_NODES) {
                a_s[row * 4 + head] = ps;
                a_d[row * 4 + head] = pd;
            }
        }
    }
}

// ======== converts ========
__global__ void cvt_x_bf16(const float* __restrict__ x, unsigned short* __restrict__ x16) {
    long long i = (long long)blockIdx.x * 256 + threadIdx.x;
    if (i >= (long long)M_PAD * F_IN) return;
    int row = (int)(i >> 7);
    x16[i] = (row < N_NODES) ? f2bf(x[i]) : 0;
}

__global__ void cvt_wT(const float* __restrict__ W, unsigned short* __restrict__ WT, int K) {
    int i = blockIdx.x * 256 + threadIdx.x;
    if (i >= K * 256) return;
    int k = i >> 8, n = i & 255;
    WT[n * K + k] = f2bf(W[i]);
}

// ======== small fp32 GEMM (64x64) for the head matmul ========
template<bool RELU, bool BIAS>
__global__ __launch_bounds__(256) void gemm64(const float* __restrict__ A,
                                              const float* __restrict__ B,
                                              const float* __restrict__ bias,
                                              float* __restrict__ C,
                                              int M, int K, int Nc) {
    __shared__ float Ast[16][68];
    __shared__ float Bst[16][68];
    int tx = threadIdx.x, ty = threadIdx.y;
    int tid = ty * 16 + tx;
    int row0 = blockIdx.y * 64, col0 = blockIdx.x * 64;
    float acc[4][4] = {};
    int ar = tid >> 2;
    int ak = (tid & 3) * 4;
    int bk = tid >> 4;
    int bc = (tid & 15) * 4;

    for (int k0 = 0; k0 < K; k0 += 16) {
        float4 av = make_float4(0.f, 0.f, 0.f, 0.f);
        if (row0 + ar < M) av = *(const float4*)&A[(long long)(row0 + ar) * K + k0 + ak];
        float4 bv = *(const float4*)&B[(long long)(k0 + bk) * Nc + col0 + bc];
        Ast[ak + 0][ar] = av.x; Ast[ak + 1][ar] = av.y;
        Ast[ak + 2][ar] = av.z; Ast[ak + 3][ar] = av.w;
        *(float4*)&Bst[bk][bc] = bv;
        __syncthreads();
        #pragma unroll
        for (int kk = 0; kk < 16; kk++) {
            float4 af = *(const float4*)&Ast[kk][ty * 4];
            float4 bfv = *(const float4*)&Bst[kk][tx * 4];
            float a[4] = {af.x, af.y, af.z, af.w};
            float b[4] = {bfv.x, bfv.y, bfv.z, bfv.w};
            #pragma unroll
            for (int i = 0; i < 4; i++)
                #pragma unroll
                for (int j = 0; j < 4; j++)
                    acc[i][j] += a[i] * b[j];
        }
        __syncthreads();
    }
    #pragma unroll
    for (int i = 0; i < 4; i++) {
        int r = row0 + ty * 4 + i;
        if (r < M) {
            float v[4];
            #pragma unroll
            for (int j = 0; j < 4; j++) {
                v[j] = acc[i][j];
                if (BIAS) v[j] += bias[col0 + tx * 4 + j];
                if (RELU) v[j] = fmaxf(v[j], 0.f);
            }
            float4 o; o.x = v[0]; o.y = v[1]; o.z = v[2]; o.w = v[3];
            *(float4*)&C[(long long)r * Nc + col0 + tx * 4] = o;
        }
    }
}

// ================= CSR build =================
__global__ void degree_count(const int* __restrict__ src, const int* __restrict__ dst,
                             int* __restrict__ deg) {
    int e = blockIdx.x * blockDim.x + threadIdx.x;
    if (e >= N_EDGES + N_NODES) return;
    int d = (e < N_EDGES) ? dst[e] : (e - N_EDGES);
    atomicAdd(&deg[d], 1);
}

__global__ __launch_bounds__(256) void scan_k1(const int* __restrict__ deg,
                                               int* __restrict__ bsum) {
    int b = blockIdx.x, t = threadIdx.x;
    int i = b * 256 + t;
    int v = (i < N_NODES) ? deg[i] : 0;
    #pragma unroll
    for (int off = 32; off > 0; off >>= 1) v += __shfl_down(v, off);
    __shared__ int ws[4];
    if ((t & 63) == 0) ws[t >> 6] = v;
    __syncthreads();
    if (t == 0) bsum[b] = ws[0] + ws[1] + ws[2] + ws[3];
}

__global__ __launch_bounds__(256) void scan_k2(const int* __restrict__ bsum,
                                               int* __restrict__ boff,
                                               int* __restrict__ row_start) {
    int t = threadIdx.x;
    int lane = t & 63, wid = t >> 6;
    int v = (t < NCHUNK) ? bsum[t] : 0;
    int x = v;
    #pragma unroll
    for (int off = 1; off < 64; off <<= 1) {
        int y = __shfl_up(x, off);
        if (lane >= off) x += y;
    }
    __shared__ int wsum[4], woff[4];
    if (lane == 63) wsum[wid] = x;
    __syncthreads();
    if (t == 0) {
        int s = 0;
        #pragma unroll
        for (int w = 0; w < 4; w++) { int tw = wsum[w]; woff[w] = s; s += tw; }
        row_start[N_NODES] = s;
    }
    __syncthreads();
    if (t < NCHUNK) boff[t] = x - v + woff[wid];
}

__global__ __launch_bounds__(256) void scan_k3(const int* __restrict__ deg,
                                               const int* __restrict__ boff,
                                               int* __restrict__ row_start) {
    int b = blockIdx.x, t = threadIdx.x;
    int lane = t & 63, wid = t >> 6;
    int i = b * 256 + t;
    int v = (i < N_NODES) ? deg[i] : 0;
    int x = v;
    #pragma unroll
    for (int off = 1; off < 64; off <<= 1) {
        int y = __shfl_up(x, off);
        if (lane >= off) x += y;
    }
    __shared__ int wsum[4], woff[4];
    if (lane == 63) wsum[wid] = x;
    __syncthreads();
    if (t == 0) {
        int s = boff[b];
        #pragma unroll
        for (int w = 0; w < 4; w++) { int tw = wsum[w]; woff[w] = s; s += tw; }
    }
    __syncthreads();
    if (i < N_NODES) row_start[i] = x - v + woff[wid];
}

__global__ void scatter_edges(const int* __restrict__ src, const int* __restrict__ dst,
                              const int* __restrict__ row_start, int* __restrict__ cursor,
                              int* __restrict__ csr_src) {
    int e = blockIdx.x * blockDim.x + threadIdx.x;
    if (e >= N_EDGES + N_NODES) return;
    int s, d;
    if (e < N_EDGES) { s = src[e]; d = dst[e]; } else { s = d = e - N_EDGES; }
    int pos = atomicAdd(&cursor[d], 1);
    csr_src[row_start[d] + pos] = s;
}

// ===== fused GAT: softmax (fp32) + bf16 wave-per-edge gather + bias/relu/BN =====
template<bool WRITE_F32, bool WRITE_BF16>
__global__ __launch_bounds__(256) void gat_fused(
    const int* __restrict__ row_start, const int* __restrict__ csr_src,
    const float* __restrict__ a_s, const float* __restrict__ a_d,
    const unsigned short* __restrict__ h16, const float* __restrict__ bias,
    const float* __restrict__ g, const float* __restrict__ be,
    const float* __restrict__ rm, const float* __restrict__ rv,
    float* __restrict__ out, unsigned short* __restrict__ out16) {
    int d = blockIdx.x;
    int t = threadIdx.x;
    int lane = t & 63;
    int w = t >> 6;
    int hd = lane >> 4;
    __shared__ int off_lds[CAP];
    __shared__ float p_lds[4 * CAPP];
    __shared__ float partial[4][FEAT];
    __shared__ float m_st[4], l_st[4], alpha_st[4];

    const uint2* __restrict__ H2 = (const uint2*)h16;

    int rs = row_start[d], re = row_start[d + 1];
    int deg = re - rs;
    if (t < 4) { m_st[t] = -INFINITY; l_st[t] = 0.f; }
    float4 ad4 = *(const float4*)&a_d[d * 4];
    float4 acc = make_float4(0.f, 0.f, 0.f, 0.f);
    __syncthreads();

    for (int base = 0; base < deg; base += CAP) {
        int cl = min(CAP, deg - base);
        if (t < cl) {
            int s = csr_src[rs + base + t];
            off_lds[t] = s * 64;
            float4 as4 = *(const float4*)&a_s[s * 4];
            float e0 = as4.x + ad4.x; e0 = e0 > 0.f ? e0 : SLOPE * e0;
            float e1 = as4.y + ad4.y; e1 = e1 > 0.f ? e1 : SLOPE * e1;
            float e2 = as4.z + ad4.z; e2 = e2 > 0.f ? e2 : SLOPE * e2;
            float e3 = as4.w + ad4.w; e3 = e3 > 0.f ? e3 : SLOPE * e3;
            p_lds[0 * CAPP + t] = e0; p_lds[1 * CAPP + t] = e1;
            p_lds[2 * CAPP + t] = e2; p_lds[3 * CAPP + t] = e3;
        }
        __syncthreads();
        float mloc = -INFINITY;
        for (int e = lane; e < cl; e += 64) mloc = fmaxf(mloc, p_lds[w * CAPP + e]);
        #pragma unroll
        for (int off = 1; off < 64; off <<= 1) mloc = fmaxf(mloc, __shfl_xor(mloc, off));
        float m_old = m_st[w];
        float m_new = fmaxf(m_old, mloc);
        float csum = 0.f;
        for (int e = lane; e < cl; e += 64) {
            float p = __expf(p_lds[w * CAPP + e] - m_new);
            p_lds[w * CAPP + e] = p;
            csum += p;
        }
        #pragma unroll
        for (int off = 1; off < 64; off <<= 1) csum += __shfl_xor(csum, off);
        float alpha = __expf(m_old - m_new);
        if (lane == 0) {
            m_st[w] = m_new;
            l_st[w] = l_st[w] * alpha + csum;
            alpha_st[w] = alpha;
        }
        __syncthreads();
        float al = alpha_st[hd];
        acc.x *= al; acc.y *= al; acc.z *= al; acc.w *= al;
        int e0;
        for (e0 = w; e0 + 4 < cl; e0 += 8) {
            float pA = p_lds[hd * CAPP + e0];
            float pB = p_lds[hd * CAPP + e0 + 4];
            uint2 hA = H2[off_lds[e0] + lane];
            uint2 hB = H2[off_lds[e0 + 4] + lane];
            acc.x += pA * __uint_as_float(hA.x << 16);
            acc.y += pA * __uint_as_float(hA.x & 0xffff0000u);
            acc.z += pA * __uint_as_float(hA.y << 16);
            acc.w += pA * __uint_as_float(hA.y & 0xffff0000u);
            acc.x += pB * __uint_as_float(hB.x << 16);
            acc.y += pB * __uint_as_float(hB.x & 0xffff0000u);
            acc.z += pB * __uint_as_float(hB.y << 16);
            acc.w += pB * __uint_as_float(hB.y & 0xffff0000u);
        }
        if (e0 < cl) {
            float pA = p_lds[hd * CAPP + e0];
            uint2 hA = H2[off_lds[e0] + lane];
            acc.x += pA * __uint_as_float(hA.x << 16);
            acc.y += pA * __uint_as_float(hA.x & 0xffff0000u);
            acc.z += pA * __uint_as_float(hA.y << 16);
            acc.w += pA * __uint_as_float(hA.y & 0xffff0000u);
        }
        __syncthreads();
    }
    *(float4*)&partial[w][4 * lane] = acc;
    __syncthreads();
    float v = partial[0][t] + partial[1][t] + partial[2][t] + partial[3][t];
    v /= l_st[t >> 6];
    v += bias[t];
    v = fmaxf(v, 0.f);
    v = (v - rm[t]) * rsqrtf(rv[t] + BN_EPS) * g[t] + be[t];
    if (WRITE_F32)  __builtin_nontemporal_store(v, &out[(long long)d * FEAT + t]);
    if (WRITE_BF16) __builtin_nontemporal_store(f2bf(v), &out16[(long long)d * FEAT + t]);
}

// ================= pooling (batch sorted): one block per graph =================
__global__ __launch_bounds__(256) void graph_pool(const float* __restrict__ h,
                                                  const int* __restrict__ batch,
                                                  float* __restrict__ pooled) {
    int gph = blockIdx.x;
    int t = threadIdx.x;
    __shared__ int lo_s, hi_s;
    if (t == 0) {
        int lo = 0, hi = N_NODES;
        while (lo < hi) { int mid = (lo + hi) >> 1; if (batch[mid] < gph) lo = mid + 1; else hi = mid; }
        lo_s = lo;
        int lo2 = 0, hi2 = N_NODES;
        while (lo2 < hi2) { int mid = (lo2 + hi2) >> 1; if (batch[mid] < gph + 1) lo2 = mid + 1; else hi2 = mid; }
        hi_s = lo2;
    }
    __syncthreads();
    int lo = lo_s, hi = hi_s;
    float acc = 0.f;
    for (int n = lo; n < hi; n++) acc += h[(long long)n * FEAT + t];
    float cnt = (float)(hi - lo);
    pooled[gph * FEAT + t] = acc / fmaxf(cnt, 1.f);
}

__global__ void final_fc(const float* __restrict__ z, const float* __restrict__ lw2,
                         const float* __restrict__ lb2, float* __restrict__ out) {
    int gid = blockIdx.x * blockDim.x + threadIdx.x;
    if (gid >= NG * N_CLS) return;
    int g = gid >> 1, c = gid & 1;
    float acc = lb2[c];
    #pragma unroll 8
    for (int k = 0; k < OUT_DIM; k++) acc += z[g * OUT_DIM + k] * lw2[k * N_CLS + c];
    out[gid] = acc;
}

extern "C" void kernel_launch(void* const* d_in, const int* in_sizes, int n_in,
                              void* d_out, int out_size, void* d_ws, size_t ws_size,
                              hipStream_t stream) {
    const float* x       = (const float*)d_in[0];
    const int*   ei      = (const int*)d_in[1];
    const int*   batch   = (const int*)d_in[2];
    const float* W1      = (const float*)d_in[3];
    const float* att_s1  = (const float*)d_in[4];
    const float* att_d1  = (const float*)d_in[5];
    const float* b1      = (const float*)d_in[6];
    const float* g1      = (const float*)d_in[7];
    const float* be1     = (const float*)d_in[8];
    const float* rm1     = (const float*)d_in[9];
    const float* rv1     = (const float*)d_in[10];
    const float* W2      = (const float*)d_in[11];
    const float* att_s2  = (const float*)d_in[12];
    const float* att_d2  = (const float*)d_in[13];
    const float* b2      = (const float*)d_in[14];
    const float* g2      = (const float*)d_in[15];
    const float* be2     = (const float*)d_in[16];
    const float* rm2     = (const float*)d_in[17];
    const float* rv2     = (const float*)d_in[18];
    const float* lw1     = (const float*)d_in[19];
    const float* lb1     = (const float*)d_in[20];
    const float* lw2     = (const float*)d_in[21];
    const float* lb2     = (const float*)d_in[22];
    float* out           = (float*)d_out;

    const int* src = ei;
    const int* dst = ei + N_EDGES;

    char* p = (char*)d_ws;
    auto carve = [&p](size_t bytes) -> void* {
        void* r = (void*)p;
        p += (bytes + 63) & ~(size_t)63;
        return r;
    };
    float* bufB   = (float*)carve(sizeof(float) * (size_t)N_NODES * FEAT);
    float* a_s    = (float*)carve(sizeof(float) * N_NODES * HEADS);
    float* a_d    = (float*)carve(sizeof(float) * N_NODES * HEADS);
    int*   deg    = (int*)carve(sizeof(int) * N_NODES);
    int*   cursor = (int*)carve(sizeof(int) * N_NODES);
    int*   csr    = (int*)carve(sizeof(int) * (N_EDGES + N_NODES));
    int*   rstart = (int*)carve(sizeof(int) * (N_NODES + 4));
    int*   bsum   = (int*)carve(sizeof(int) * 256);
    int*   boff   = (int*)carve(sizeof(int) * 256);
    float* pooled = (float*)carve(sizeof(float) * NG * FEAT);
    float* z      = (float*)carve(sizeof(float) * NG * OUT_DIM);
    unsigned short* h16  = (unsigned short*)carve(sizeof(short) * (size_t)N_NODES * FEAT);
    unsigned short* x16  = (unsigned short*)carve(sizeof(short) * (size_t)M_PAD * F_IN);
    unsigned short* h1bf = (unsigned short*)carve(sizeof(short) * (size_t)M_PAD * FEAT);
    unsigned short* w1t  = (unsigned short*)carve(sizeof(short) * FEAT * F_IN);
    unsigned short* w2t  = (unsigned short*)carve(sizeof(short) * FEAT * FEAT);

    const int Et = N_EDGES + N_NODES;
    dim3 blk16(16, 16);

    // ---- converts ----
    cvt_x_bf16<<<((long long)M_PAD * F_IN + 255) / 256, 256, 0, stream>>>(x, x16);
    cvt_wT<<<(F_IN * 256 + 255) / 256, 256, 0, stream>>>(W1, w1t, F_IN);
    cvt_wT<<<(FEAT * 256 + 255) / 256, 256, 0, stream>>>(W2, w2t, FEAT);
    hipMemsetAsync(h1bf + (size_t)N_NODES * FEAT, 0,
                   sizeof(short) * (size_t)(M_PAD - N_NODES) * FEAT, stream);

    // ---- CSR build ----
    hipMemsetAsync(deg, 0, sizeof(int) * N_NODES, stream);
    hipMemsetAsync(cursor, 0, sizeof(int) * N_NODES, stream);
    degree_count<<<(Et + 255) / 256, 256, 0, stream>>>(src, dst, deg);
    scan_k1<<<NCHUNK, 256, 0, stream>>>(deg, bsum);
    scan_k2<<<1, 256, 0, stream>>>(bsum, boff, rstart);
    scan_k3<<<NCHUNK, 256, 0, stream>>>(deg, boff, rstart);
    scatter_edges<<<(Et + 255) / 256, 256, 0, stream>>>(src, dst, rstart, cursor, csr);

    // ---- Layer 1 ----
    {
        dim3 grid(FEAT / 128, M_PAD / 128);
        gemm_mfma_gat<<<grid, 256, 0, stream>>>(x16, w1t, att_s1, att_d1,
                                                h16, a_s, a_d, F_IN);
    }
    gat_fused<false, true><<<N_NODES, 256, 0, stream>>>(rstart, csr, a_s, a_d, h16,
                                                        b1, g1, be1, rm1, rv1,
                                                        nullptr, h1bf);

    // ---- Layer 2 ----
    {
        dim3 grid(FEAT / 128, M_PAD / 128);
        gemm_mfma_gat<<<grid, 256, 0, stream>>>(h1bf, w2t, att_s2, att_d2,
                                                h16, a_s, a_d, FEAT);
    }
    gat_fused<true, false><<<N_NODES, 256, 0, stream>>>(rstart, csr, a_s, a_d, h16,
                                                        b2, g2, be2, rm2, rv2,
                                                        bufB, nullptr);

    // ---- Pool + MLP head ----
    graph_pool<<<NG, 256, 0, stream>>>(bufB, batch, pooled);
    {
        dim3 grid(OUT_DIM / 64, (NG + 63) / 64);
        gemm64<true, true><<<grid, blk16, 0, stream>>>(pooled, lw1, lb1, z,
                                                       NG, FEAT, OUT_DIM);
    }
    final_fc<<<(NG * N_CLS + 255) / 256, 256, 0, stream>>>(z, lw2, lb2, out);
}

// Round 8
// 508.077 us; speedup vs baseline: 4.3811x; 1.0804x over previous
//
#include <hip/hip_runtime.h>
#include <hip/hip_bf16.h>
#include <math.h>

#define N_NODES 50000
#define M_PAD   50048                    // 391 * 128
#define N_EDGES 800000
#define F_IN 128
#define HID 64
#define HEADS 4
#define FEAT 256        // HEADS*HID
#define OUT_DIM 128
#define N_CLS 2
#define NG 500
#define SLOPE 0.2f
#define BN_EPS 1e-5f
#define WCAP 64          // edges per chunk per wave in gat_fused
#define NCHUNK ((N_NODES + 255) / 256)

typedef __attribute__((ext_vector_type(8))) short short8;
typedef __attribute__((ext_vector_type(4))) float floatx4;

__device__ inline unsigned short f2bf(float f) {
    unsigned int u = __float_as_uint(f);
    unsigned int lsb = (u >> 16) & 1u;
    return (unsigned short)((u + 0x7fffu + lsb) >> 16);
}

// ==== bf16 MFMA GEMM fused with GAT prologue ====
__global__ __launch_bounds__(256) void gemm_mfma_gat(
    const unsigned short* __restrict__ A, const unsigned short* __restrict__ BT,
    const float* __restrict__ att_src, const float* __restrict__ att_dst,
    unsigned short* __restrict__ h16, float* __restrict__ a_s,
    float* __restrict__ a_d, int K) {
    constexpr int LS = 40;
    __shared__ unsigned short As[128 * LS];
    __shared__ unsigned short Bs[128 * LS];
    int t = threadIdx.x;
    int lane = t & 63, w = t >> 6;
    int wm = (w >> 1) * 64, wn = (w & 1) * 64;
    int row0 = blockIdx.y * 128, col0 = blockIdx.x * 128;

    floatx4 acc[4][4] = {};

    int r0 = t >> 2,            c0 = (t & 3) * 8;
    int r1 = (t + 256) >> 2,    c1 = ((t + 256) & 3) * 8;
    int mrow = lane & 15, quad = lane >> 4;

    for (int k0 = 0; k0 < K; k0 += 32) {
        *(uint4*)&As[r0 * LS + c0] = *(const uint4*)&A[(long long)(row0 + r0) * K + k0 + c0];
        *(uint4*)&As[r1 * LS + c1] = *(const uint4*)&A[(long long)(row0 + r1) * K + k0 + c1];
        *(uint4*)&Bs[r0 * LS + c0] = *(const uint4*)&BT[(long long)(col0 + r0) * K + k0 + c0];
        *(uint4*)&Bs[r1 * LS + c1] = *(const uint4*)&BT[(long long)(col0 + r1) * K + k0 + c1];
        __syncthreads();
        short8 af[4], bf[4];
        #pragma unroll
        for (int i = 0; i < 4; i++) {
            af[i] = *(const short8*)&As[(wm + i * 16 + mrow) * LS + quad * 8];
            bf[i] = *(const short8*)&Bs[(wn + i * 16 + mrow) * LS + quad * 8];
        }
        #pragma unroll
        for (int mi = 0; mi < 4; mi++)
            #pragma unroll
            for (int ni = 0; ni < 4; ni++)
                acc[mi][ni] = __builtin_amdgcn_mfma_f32_16x16x32_bf16(af[mi], bf[ni],
                                                                      acc[mi][ni], 0, 0, 0);
        __syncthreads();
    }

    int head = blockIdx.x * 2 + (w & 1);
    float ats[4], atd[4];
    #pragma unroll
    for (int ni = 0; ni < 4; ni++) {
        ats[ni] = att_src[head * 64 + ni * 16 + mrow];
        atd[ni] = att_dst[head * 64 + ni * 16 + mrow];
    }

    #pragma unroll
    for (int mi = 0; mi < 4; mi++) {
        #pragma unroll
        for (int r = 0; r < 4; r++) {
            int row = row0 + wm + mi * 16 + quad * 4 + r;
            float ps = 0.f, pd = 0.f;
            #pragma unroll
            for (int ni = 0; ni < 4; ni++) {
                float v = acc[mi][ni][r];
                ps += v * ats[ni];
                pd += v * atd[ni];
                if (row < N_NODES) {
                    int col = col0 + wn + ni * 16 + mrow;
                    h16[(long long)row * FEAT + col] = f2bf(v);
                }
            }
            #pragma unroll
            for (int off = 1; off < 16; off <<= 1) {
                ps += __shfl_xor(ps, off);
                pd += __shfl_xor(pd, off);
            }
            if (mrow == 0 && row < N_NODES) {
                a_s[row * 4 + head] = ps;
                a_d[row * 4 + head] = pd;
            }
        }
    }
}

// ======== converts ========
__global__ void cvt_x_bf16(const float* __restrict__ x, unsigned short* __restrict__ x16) {
    long long i = (long long)blockIdx.x * 256 + threadIdx.x;
    if (i >= (long long)M_PAD * F_IN) return;
    int row = (int)(i >> 7);
    x16[i] = (row < N_NODES) ? f2bf(x[i]) : 0;
}

__global__ void cvt_wT(const float* __restrict__ W, unsigned short* __restrict__ WT, int K) {
    int i = blockIdx.x * 256 + threadIdx.x;
    if (i >= K * 256) return;
    int k = i >> 8, n = i & 255;
    WT[n * K + k] = f2bf(W[i]);
}

// ======== small fp32 GEMM (64x64) for the head matmul ========
template<bool RELU, bool BIAS>
__global__ __launch_bounds__(256) void gemm64(const float* __restrict__ A,
                                              const float* __restrict__ B,
                                              const float* __restrict__ bias,
                                              float* __restrict__ C,
                                              int M, int K, int Nc) {
    __shared__ float Ast[16][68];
    __shared__ float Bst[16][68];
    int tx = threadIdx.x, ty = threadIdx.y;
    int tid = ty * 16 + tx;
    int row0 = blockIdx.y * 64, col0 = blockIdx.x * 64;
    float acc[4][4] = {};
    int ar = tid >> 2;
    int ak = (tid & 3) * 4;
    int bk = tid >> 4;
    int bc = (tid & 15) * 4;

    for (int k0 = 0; k0 < K; k0 += 16) {
        float4 av = make_float4(0.f, 0.f, 0.f, 0.f);
        if (row0 + ar < M) av = *(const float4*)&A[(long long)(row0 + ar) * K + k0 + ak];
        float4 bv = *(const float4*)&B[(long long)(k0 + bk) * Nc + col0 + bc];
        Ast[ak + 0][ar] = av.x; Ast[ak + 1][ar] = av.y;
        Ast[ak + 2][ar] = av.z; Ast[ak + 3][ar] = av.w;
        *(float4*)&Bst[bk][bc] = bv;
        __syncthreads();
        #pragma unroll
        for (int kk = 0; kk < 16; kk++) {
            float4 af = *(const float4*)&Ast[kk][ty * 4];
            float4 bfv = *(const float4*)&Bst[kk][tx * 4];
            float a[4] = {af.x, af.y, af.z, af.w};
            float b[4] = {bfv.x, bfv.y, bfv.z, bfv.w};
            #pragma unroll
            for (int i = 0; i < 4; i++)
                #pragma unroll
                for (int j = 0; j < 4; j++)
                    acc[i][j] += a[i] * b[j];
        }
        __syncthreads();
    }
    #pragma unroll
    for (int i = 0; i < 4; i++) {
        int r = row0 + ty * 4 + i;
        if (r < M) {
            float v[4];
            #pragma unroll
            for (int j = 0; j < 4; j++) {
                v[j] = acc[i][j];
                if (BIAS) v[j] += bias[col0 + tx * 4 + j];
                if (RELU) v[j] = fmaxf(v[j], 0.f);
            }
            float4 o; o.x = v[0]; o.y = v[1]; o.z = v[2]; o.w = v[3];
            *(float4*)&C[(long long)r * Nc + col0 + tx * 4] = o;
        }
    }
}

// ================= CSR build =================
__global__ void degree_count(const int* __restrict__ src, const int* __restrict__ dst,
                             int* __restrict__ deg) {
    int e = blockIdx.x * blockDim.x + threadIdx.x;
    if (e >= N_EDGES + N_NODES) return;
    int d = (e < N_EDGES) ? dst[e] : (e - N_EDGES);
    atomicAdd(&deg[d], 1);
}

__global__ __launch_bounds__(256) void scan_k1(const int* __restrict__ deg,
                                               int* __restrict__ bsum) {
    int b = blockIdx.x, t = threadIdx.x;
    int i = b * 256 + t;
    int v = (i < N_NODES) ? deg[i] : 0;
    #pragma unroll
    for (int off = 32; off > 0; off >>= 1) v += __shfl_down(v, off);
    __shared__ int ws[4];
    if ((t & 63) == 0) ws[t >> 6] = v;
    __syncthreads();
    if (t == 0) bsum[b] = ws[0] + ws[1] + ws[2] + ws[3];
}

__global__ __launch_bounds__(256) void scan_k2(const int* __restrict__ bsum,
                                               int* __restrict__ boff,
                                               int* __restrict__ row_start) {
    int t = threadIdx.x;
    int lane = t & 63, wid = t >> 6;
    int v = (t < NCHUNK) ? bsum[t] : 0;
    int x = v;
    #pragma unroll
    for (int off = 1; off < 64; off <<= 1) {
        int y = __shfl_up(x, off);
        if (lane >= off) x += y;
    }
    __shared__ int wsum[4], woff[4];
    if (lane == 63) wsum[wid] = x;
    __syncthreads();
    if (t == 0) {
        int s = 0;
        #pragma unroll
        for (int w = 0; w < 4; w++) { int tw = wsum[w]; woff[w] = s; s += tw; }
        row_start[N_NODES] = s;
    }
    __syncthreads();
    if (t < NCHUNK) boff[t] = x - v + woff[wid];
}

__global__ __launch_bounds__(256) void scan_k3(const int* __restrict__ deg,
                                               const int* __restrict__ boff,
                                               int* __restrict__ row_start) {
    int b = blockIdx.x, t = threadIdx.x;
    int lane = t & 63, wid = t >> 6;
    int i = b * 256 + t;
    int v = (i < N_NODES) ? deg[i] : 0;
    int x = v;
    #pragma unroll
    for (int off = 1; off < 64; off <<= 1) {
        int y = __shfl_up(x, off);
        if (lane >= off) x += y;
    }
    __shared__ int wsum[4], woff[4];
    if (lane == 63) wsum[wid] = x;
    __syncthreads();
    if (t == 0) {
        int s = boff[b];
        #pragma unroll
        for (int w = 0; w < 4; w++) { int tw = wsum[w]; woff[w] = s; s += tw; }
    }
    __syncthreads();
    if (i < N_NODES) row_start[i] = x - v + woff[wid];
}

__global__ void scatter_edges(const int* __restrict__ src, const int* __restrict__ dst,
                              const int* __restrict__ row_start, int* __restrict__ cursor,
                              int* __restrict__ csr_src) {
    int e = blockIdx.x * blockDim.x + threadIdx.x;
    if (e >= N_EDGES + N_NODES) return;
    int s, d;
    if (e < N_EDGES) { s = src[e]; d = dst[e]; } else { s = d = e - N_EDGES; }
    int pos = atomicAdd(&cursor[d], 1);
    csr_src[row_start[d] + pos] = s;
}

// ===== fused GAT, wave-per-node: softmax in registers, no block barriers =====
template<bool WRITE_F32, bool WRITE_BF16>
__global__ __launch_bounds__(256) void gat_fused(
    const int* __restrict__ row_start, const int* __restrict__ csr_src,
    const float* __restrict__ a_s, const float* __restrict__ a_d,
    const unsigned short* __restrict__ h16, const float* __restrict__ bias,
    const float* __restrict__ g, const float* __restrict__ be,
    const float* __restrict__ rm, const float* __restrict__ rv,
    float* __restrict__ out, unsigned short* __restrict__ out16) {
    int t = threadIdx.x;
    int lane = t & 63;
    int w = t >> 6;
    int hd = lane >> 4;                       // head for this lane's 4 channels
    int d = blockIdx.x * 4 + w;               // node handled by this wave

    __shared__ float p_lds[4 * WCAP * 4];     // [wave][edge][head]
    __shared__ int   o_lds[4 * WCAP];         // [wave][edge] : src*64 (uint2 units)
    float* pw = &p_lds[w * WCAP * 4];
    int*   ow = &o_lds[w * WCAP];

    const uint2* __restrict__ H2 = (const uint2*)h16;

    int rs = row_start[d], re = row_start[d + 1];
    int deg = re - rs;
    float4 ad4 = *(const float4*)&a_d[d * 4];

    float m_old[4] = {-INFINITY, -INFINITY, -INFINITY, -INFINITY};
    float l_run[4] = {0.f, 0.f, 0.f, 0.f};
    float4 acc = make_float4(0.f, 0.f, 0.f, 0.f);

    for (int base = 0; base < deg; base += WCAP) {
        int cl = min(WCAP, deg - base);
        float lg[4] = {-INFINITY, -INFINITY, -INFINITY, -INFINITY};
        if (lane < cl) {
            int s = csr_src[rs + base + lane];
            ow[lane] = s * 64;
            float4 as4 = *(const float4*)&a_s[s * 4];
            float e0 = as4.x + ad4.x; lg[0] = e0 > 0.f ? e0 : SLOPE * e0;
            float e1 = as4.y + ad4.y; lg[1] = e1 > 0.f ? e1 : SLOPE * e1;
            float e2 = as4.z + ad4.z; lg[2] = e2 > 0.f ? e2 : SLOPE * e2;
            float e3 = as4.w + ad4.w; lg[3] = e3 > 0.f ? e3 : SLOPE * e3;
        }
        float m_new[4], alpha[4];
        #pragma unroll
        for (int h = 0; h < 4; h++) {
            float mm = lg[h];
            #pragma unroll
            for (int off = 1; off < 64; off <<= 1) mm = fmaxf(mm, __shfl_xor(mm, off));
            m_new[h] = fmaxf(m_old[h], mm);
            alpha[h] = __expf(m_old[h] - m_new[h]);   // 0 on first chunk
            m_old[h] = m_new[h];
        }
        float pv[4];
        #pragma unroll
        for (int h = 0; h < 4; h++)
            pv[h] = (lane < cl) ? __expf(lg[h] - m_new[h]) : 0.f;
        if (lane < cl) {
            float4 pq; pq.x = pv[0]; pq.y = pv[1]; pq.z = pv[2]; pq.w = pv[3];
            *(float4*)&pw[lane * 4] = pq;
        }
        #pragma unroll
        for (int h = 0; h < 4; h++) {
            float cs = pv[h];
            #pragma unroll
            for (int off = 1; off < 64; off <<= 1) cs += __shfl_xor(cs, off);
            l_run[h] = l_run[h] * alpha[h] + cs;
        }
        // rescale accumulator by this lane's head alpha
        float al = hd < 2 ? (hd == 0 ? alpha[0] : alpha[1])
                          : (hd == 2 ? alpha[2] : alpha[3]);
        acc.x *= al; acc.y *= al; acc.z *= al; acc.w *= al;
        // gather
        int e = 0;
        for (; e + 1 < cl; e += 2) {
            int offA = ow[e], offB = ow[e + 1];
            float pA = pw[e * 4 + hd], pB = pw[(e + 1) * 4 + hd];
            uint2 hA = H2[offA + lane];
            uint2 hB = H2[offB + lane];
            acc.x += pA * __uint_as_float(hA.x << 16);
            acc.y += pA * __uint_as_float(hA.x & 0xffff0000u);
            acc.z += pA * __uint_as_float(hA.y << 16);
            acc.w += pA * __uint_as_float(hA.y & 0xffff0000u);
            acc.x += pB * __uint_as_float(hB.x << 16);
            acc.y += pB * __uint_as_float(hB.x & 0xffff0000u);
            acc.z += pB * __uint_as_float(hB.y << 16);
            acc.w += pB * __uint_as_float(hB.y & 0xffff0000u);
        }
        if (e < cl) {
            int offA = ow[e];
            float pA = pw[e * 4 + hd];
            uint2 hA = H2[offA + lane];
            acc.x += pA * __uint_as_float(hA.x << 16);
            acc.y += pA * __uint_as_float(hA.x & 0xffff0000u);
            acc.z += pA * __uint_as_float(hA.y << 16);
            acc.w += pA * __uint_as_float(hA.y & 0xffff0000u);
        }
    }
    float denom = hd < 2 ? (hd == 0 ? l_run[0] : l_run[1])
                         : (hd == 2 ? l_run[2] : l_run[3]);
    float inv = 1.f / denom;
    int c0 = lane * 4;
    float4 bi = *(const float4*)&bias[c0];
    float4 gg = *(const float4*)&g[c0];
    float4 bb = *(const float4*)&be[c0];
    float4 mm = *(const float4*)&rm[c0];
    float4 vv = *(const float4*)&rv[c0];
    float v0 = fmaxf(acc.x * inv + bi.x, 0.f);
    float v1 = fmaxf(acc.y * inv + bi.y, 0.f);
    float v2 = fmaxf(acc.z * inv + bi.z, 0.f);
    float v3 = fmaxf(acc.w * inv + bi.w, 0.f);
    v0 = (v0 - mm.x) * rsqrtf(vv.x + BN_EPS) * gg.x + bb.x;
    v1 = (v1 - mm.y) * rsqrtf(vv.y + BN_EPS) * gg.y + bb.y;
    v2 = (v2 - mm.z) * rsqrtf(vv.z + BN_EPS) * gg.z + bb.z;
    v3 = (v3 - mm.w) * rsqrtf(vv.w + BN_EPS) * gg.w + bb.w;
    if (WRITE_F32) {
        floatx4 o = {v0, v1, v2, v3};
        __builtin_nontemporal_store(o, (floatx4*)&out[(long long)d * FEAT + c0]);
    }
    if (WRITE_BF16) {
        unsigned long long o =
            (unsigned long long)f2bf(v0) |
            ((unsigned long long)f2bf(v1) << 16) |
            ((unsigned long long)f2bf(v2) << 32) |
            ((unsigned long long)f2bf(v3) << 48);
        __builtin_nontemporal_store(o, (unsigned long long*)&out16[(long long)d * FEAT + c0]);
    }
}

// ================= pooling (batch sorted): one block per graph =================
__global__ __launch_bounds__(256) void graph_pool(const float* __restrict__ h,
                                                  const int* __restrict__ batch,
                                                  float* __restrict__ pooled) {
    int gph = blockIdx.x;
    int t = threadIdx.x;
    __shared__ int lo_s, hi_s;
    if (t == 0) {
        int lo = 0, hi = N_NODES;
        while (lo < hi) { int mid = (lo + hi) >> 1; if (batch[mid] < gph) lo = mid + 1; else hi = mid; }
        lo_s = lo;
        int lo2 = 0, hi2 = N_NODES;
        while (lo2 < hi2) { int mid = (lo2 + hi2) >> 1; if (batch[mid] < gph + 1) lo2 = mid + 1; else hi2 = mid; }
        hi_s = lo2;
    }
    __syncthreads();
    int lo = lo_s, hi = hi_s;
    float acc = 0.f;
    for (int n = lo; n < hi; n++) acc += h[(long long)n * FEAT + t];
    float cnt = (float)(hi - lo);
    pooled[gph * FEAT + t] = acc / fmaxf(cnt, 1.f);
}

__global__ void final_fc(const float* __restrict__ z, const float* __restrict__ lw2,
                         const float* __restrict__ lb2, float* __restrict__ out) {
    int gid = blockIdx.x * blockDim.x + threadIdx.x;
    if (gid >= NG * N_CLS) return;
    int g = gid >> 1, c = gid & 1;
    float acc = lb2[c];
    #pragma unroll 8
    for (int k = 0; k < OUT_DIM; k++) acc += z[g * OUT_DIM + k] * lw2[k * N_CLS + c];
    out[gid] = acc;
}

extern "C" void kernel_launch(void* const* d_in, const int* in_sizes, int n_in,
                              void* d_out, int out_size, void* d_ws, size_t ws_size,
                              hipStream_t stream) {
    const float* x       = (const float*)d_in[0];
    const int*   ei      = (const int*)d_in[1];
    const int*   batch   = (const int*)d_in[2];
    const float* W1      = (const float*)d_in[3];
    const float* att_s1  = (const float*)d_in[4];
    const float* att_d1  = (const float*)d_in[5];
    const float* b1      = (const float*)d_in[6];
    const float* g1      = (const float*)d_in[7];
    const float* be1     = (const float*)d_in[8];
    const float* rm1     = (const float*)d_in[9];
    const float* rv1     = (const float*)d_in[10];
    const float* W2      = (const float*)d_in[11];
    const float* att_s2  = (const float*)d_in[12];
    const float* att_d2  = (const float*)d_in[13];
    const float* b2      = (const float*)d_in[14];
    const float* g2      = (const float*)d_in[15];
    const float* be2     = (const float*)d_in[16];
    const float* rm2     = (const float*)d_in[17];
    const float* rv2     = (const float*)d_in[18];
    const float* lw1     = (const float*)d_in[19];
    const float* lb1     = (const float*)d_in[20];
    const float* lw2     = (const float*)d_in[21];
    const float* lb2     = (const float*)d_in[22];
    float* out           = (float*)d_out;

    const int* src = ei;
    const int* dst = ei + N_EDGES;

    char* p = (char*)d_ws;
    auto carve = [&p](size_t bytes) -> void* {
        void* r = (void*)p;
        p += (bytes + 63) & ~(size_t)63;
        return r;
    };
    float* bufB   = (float*)carve(sizeof(float) * (size_t)N_NODES * FEAT);
    float* a_s    = (float*)carve(sizeof(float) * N_NODES * HEADS);
    float* a_d    = (float*)carve(sizeof(float) * N_NODES * HEADS);
    int*   deg    = (int*)carve(sizeof(int) * N_NODES);
    int*   cursor = (int*)carve(sizeof(int) * N_NODES);
    int*   csr    = (int*)carve(sizeof(int) * (N_EDGES + N_NODES));
    int*   rstart = (int*)carve(sizeof(int) * (N_NODES + 4));
    int*   bsum   = (int*)carve(sizeof(int) * 256);
    int*   boff   = (int*)carve(sizeof(int) * 256);
    float* pooled = (float*)carve(sizeof(float) * NG * FEAT);
    float* z      = (float*)carve(sizeof(float) * NG * OUT_DIM);
    unsigned short* h16  = (unsigned short*)carve(sizeof(short) * (size_t)N_NODES * FEAT);
    unsigned short* x16  = (unsigned short*)carve(sizeof(short) * (size_t)M_PAD * F_IN);
    unsigned short* h1bf = (unsigned short*)carve(sizeof(short) * (size_t)M_PAD * FEAT);
    unsigned short* w1t  = (unsigned short*)carve(sizeof(short) * FEAT * F_IN);
    unsigned short* w2t  = (unsigned short*)carve(sizeof(short) * FEAT * FEAT);

    const int Et = N_EDGES + N_NODES;
    dim3 blk16(16, 16);

    // ---- converts ----
    cvt_x_bf16<<<((long long)M_PAD * F_IN + 255) / 256, 256, 0, stream>>>(x, x16);
    cvt_wT<<<(F_IN * 256 + 255) / 256, 256, 0, stream>>>(W1, w1t, F_IN);
    cvt_wT<<<(FEAT * 256 + 255) / 256, 256, 0, stream>>>(W2, w2t, FEAT);
    (void)hipMemsetAsync(h1bf + (size_t)N_NODES * FEAT, 0,
                         sizeof(short) * (size_t)(M_PAD - N_NODES) * FEAT, stream);

    // ---- CSR build ----
    (void)hipMemsetAsync(deg, 0, sizeof(int) * N_NODES, stream);
    (void)hipMemsetAsync(cursor, 0, sizeof(int) * N_NODES, stream);
    degree_count<<<(Et + 255) / 256, 256, 0, stream>>>(src, dst, deg);
    scan_k1<<<NCHUNK, 256, 0, stream>>>(deg, bsum);
    scan_k2<<<1, 256, 0, stream>>>(bsum, boff, rstart);
    scan_k3<<<NCHUNK, 256, 0, stream>>>(deg, boff, rstart);
    scatter_edges<<<(Et + 255) / 256, 256, 0, stream>>>(src, dst, rstart, cursor, csr);

    // ---- Layer 1 ----
    {
        dim3 grid(FEAT / 128, M_PAD / 128);
        gemm_mfma_gat<<<grid, 256, 0, stream>>>(x16, w1t, att_s1, att_d1,
                                                h16, a_s, a_d, F_IN);
    }
    gat_fused<false, true><<<N_NODES / 4, 256, 0, stream>>>(rstart, csr, a_s, a_d, h16,
                                                            b1, g1, be1, rm1, rv1,
                                                            nullptr, h1bf);

    // ---- Layer 2 ----
    {
        dim3 grid(FEAT / 128, M_PAD / 128);
        gemm_mfma_gat<<<grid, 256, 0, stream>>>(h1bf, w2t, att_s2, att_d2,
                                                h16, a_s, a_d, FEAT);
    }
    gat_fused<true, false><<<N_NODES / 4, 256, 0, stream>>>(rstart, csr, a_s, a_d, h16,
                                                            b2, g2, be2, rm2, rv2,
                                                            bufB, nullptr);

    // ---- Pool + MLP head ----
    graph_pool<<<NG, 256, 0, stream>>>(bufB, batch, pooled);
    {
        dim3 grid(OUT_DIM / 64, (NG + 63) / 64);
        gemm64<true, true><<<grid, blk16, 0, stream>>>(pooled, lw1, lb1, z,
                                                       NG, FEAT, OUT_DIM);
    }
    final_fc<<<(NG * N_CLS + 255) / 256, 256, 0, stream>>>(z, lw2, lb2, out);
}

// Round 9
// 461.706 us; speedup vs baseline: 4.8211x; 1.1004x over previous
//
#include <hip/hip_runtime.h>
#include <hip/hip_bf16.h>
#include <math.h>

#define N_NODES 50000
#define M_PAD   50048                    // 391 * 128
#define N_EDGES 800000
#define F_IN 128
#define HID 64
#define HEADS 4
#define FEAT 256        // HEADS*HID
#define OUT_DIM 128
#define N_CLS 2
#define NG 500
#define SLOPE 0.2f
#define BN_EPS 1e-5f
#define WCAP 64          // edges per chunk per wave in gat_fused
#define NCHUNK ((N_NODES + 255) / 256)

typedef __attribute__((ext_vector_type(8))) short short8;
typedef __attribute__((ext_vector_type(4))) float floatx4;

__device__ inline unsigned short f2bf(float f) {
    unsigned int u = __float_as_uint(f);
    unsigned int lsb = (u >> 16) & 1u;
    return (unsigned short)((u + 0x7fffu + lsb) >> 16);
}

// ==== bf16 MFMA GEMM fused with GAT prologue ====
// C = A[Mpad,K] @ BT[256,K]^T. Writes bf16 h16[Mpad,256] (coalesced via LDS
// repack) and fp32 a_s/a_d[N,4] from the fp32 accumulators.
__global__ __launch_bounds__(256) void gemm_mfma_gat(
    const unsigned short* __restrict__ A, const unsigned short* __restrict__ BT,
    const float* __restrict__ att_src, const float* __restrict__ att_dst,
    unsigned short* __restrict__ h16, float* __restrict__ a_s,
    float* __restrict__ a_d, int K) {
    constexpr int LS = 40;     // staging row stride (bf16)
    constexpr int CS = 132;    // C-repack row stride (bf16): quads land on
                               // disjoint 8-bank groups (132*2/4=66≡2 mod 32, x4 rows -> +8 banks)
    __shared__ unsigned short smem[128 * CS];   // 33792 B; staging uses first 20480 B
    unsigned short* As = smem;
    unsigned short* Bs = smem + 128 * LS;
    int t = threadIdx.x;
    int lane = t & 63, w = t >> 6;
    int wm = (w >> 1) * 64, wn = (w & 1) * 64;
    int row0 = blockIdx.y * 128, col0 = blockIdx.x * 128;

    floatx4 acc[4][4] = {};

    int r0 = t >> 2,            c0 = (t & 3) * 8;
    int r1 = (t + 256) >> 2,    c1 = ((t + 256) & 3) * 8;
    int mrow = lane & 15, quad = lane >> 4;

    for (int k0 = 0; k0 < K; k0 += 32) {
        *(uint4*)&As[r0 * LS + c0] = *(const uint4*)&A[(long long)(row0 + r0) * K + k0 + c0];
        *(uint4*)&As[r1 * LS + c1] = *(const uint4*)&A[(long long)(row0 + r1) * K + k0 + c1];
        *(uint4*)&Bs[r0 * LS + c0] = *(const uint4*)&BT[(long long)(col0 + r0) * K + k0 + c0];
        *(uint4*)&Bs[r1 * LS + c1] = *(const uint4*)&BT[(long long)(col0 + r1) * K + k0 + c1];
        __syncthreads();
        short8 af[4], bf[4];
        #pragma unroll
        for (int i = 0; i < 4; i++) {
            af[i] = *(const short8*)&As[(wm + i * 16 + mrow) * LS + quad * 8];
            bf[i] = *(const short8*)&Bs[(wn + i * 16 + mrow) * LS + quad * 8];
        }
        #pragma unroll
        for (int mi = 0; mi < 4; mi++)
            #pragma unroll
            for (int ni = 0; ni < 4; ni++)
                acc[mi][ni] = __builtin_amdgcn_mfma_f32_16x16x32_bf16(af[mi], bf[ni],
                                                                      acc[mi][ni], 0, 0, 0);
        __syncthreads();
    }

    // ---- attention scores from fp32 accumulators (wave's 64-col span == one head) ----
    int head = blockIdx.x * 2 + (w & 1);
    float ats[4], atd[4];
    #pragma unroll
    for (int ni = 0; ni < 4; ni++) {
        ats[ni] = att_src[head * 64 + ni * 16 + mrow];
        atd[ni] = att_dst[head * 64 + ni * 16 + mrow];
    }
    #pragma unroll
    for (int mi = 0; mi < 4; mi++) {
        #pragma unroll
        for (int r = 0; r < 4; r++) {
            int row = row0 + wm + mi * 16 + quad * 4 + r;
            float ps = 0.f, pd = 0.f;
            #pragma unroll
            for (int ni = 0; ni < 4; ni++) {
                float v = acc[mi][ni][r];
                ps += v * ats[ni];
                pd += v * atd[ni];
            }
            #pragma unroll
            for (int off = 1; off < 16; off <<= 1) {
                ps += __shfl_xor(ps, off);
                pd += __shfl_xor(pd, off);
            }
            if (mrow == 0 && row < N_NODES) {
                a_s[row * 4 + head] = ps;
                a_d[row * 4 + head] = pd;
            }
        }
    }

    // ---- repack C tile through LDS, then coalesced uint4 stores ----
    #pragma unroll
    for (int mi = 0; mi < 4; mi++)
        #pragma unroll
        for (int ni = 0; ni < 4; ni++)
            #pragma unroll
            for (int r = 0; r < 4; r++)
                smem[(wm + mi * 16 + quad * 4 + r) * CS + wn + ni * 16 + mrow] =
                    f2bf(acc[mi][ni][r]);
    __syncthreads();
    {
        int r2 = t >> 1, half = t & 1;
        const unsigned short* sp = &smem[r2 * CS + half * 64];
        unsigned short* dp = &h16[(long long)(row0 + r2) * FEAT + col0 + half * 64];
        #pragma unroll
        for (int k = 0; k < 8; k++)
            ((uint4*)dp)[k] = ((const uint4*)sp)[k];
    }
}

// ======== converts ========
__global__ void cvt_x_bf16(const float* __restrict__ x, unsigned short* __restrict__ x16) {
    long long i = (long long)blockIdx.x * 256 + threadIdx.x;
    if (i >= (long long)M_PAD * F_IN) return;
    int row = (int)(i >> 7);
    x16[i] = (row < N_NODES) ? f2bf(x[i]) : 0;
}

// both weights transposed in one launch: W1 (F_IN x 256) -> w1t, W2 (256 x 256) -> w2t
__global__ void cvt_w_both(const float* __restrict__ W1, const float* __restrict__ W2,
                           unsigned short* __restrict__ W1T, unsigned short* __restrict__ W2T) {
    int i = blockIdx.x * 256 + threadIdx.x;
    if (i < F_IN * 256) {
        int k = i >> 8, n = i & 255;
        W1T[n * F_IN + k] = f2bf(W1[i]);
    }
    int j = i - F_IN * 256;
    if (j >= 0 && j < FEAT * 256) {
        int k = j >> 8, n = j & 255;
        W2T[n * FEAT + k] = f2bf(W2[j]);
    }
}

// ================= CSR build =================
__global__ void degree_count(const int* __restrict__ src, const int* __restrict__ dst,
                             int* __restrict__ deg) {
    int e = blockIdx.x * blockDim.x + threadIdx.x;
    if (e >= N_EDGES + N_NODES) return;
    int d = (e < N_EDGES) ? dst[e] : (e - N_EDGES);
    atomicAdd(&deg[d], 1);
}

__global__ __launch_bounds__(256) void scan_k1(const int* __restrict__ deg,
                                               int* __restrict__ bsum) {
    int b = blockIdx.x, t = threadIdx.x;
    int i = b * 256 + t;
    int v = (i < N_NODES) ? deg[i] : 0;
    #pragma unroll
    for (int off = 32; off > 0; off >>= 1) v += __shfl_down(v, off);
    __shared__ int ws[4];
    if ((t & 63) == 0) ws[t >> 6] = v;
    __syncthreads();
    if (t == 0) bsum[b] = ws[0] + ws[1] + ws[2] + ws[3];
}

__global__ __launch_bounds__(256) void scan_k2(const int* __restrict__ bsum,
                                               int* __restrict__ boff,
                                               int* __restrict__ row_start) {
    int t = threadIdx.x;
    int lane = t & 63, wid = t >> 6;
    int v = (t < NCHUNK) ? bsum[t] : 0;
    int x = v;
    #pragma unroll
    for (int off = 1; off < 64; off <<= 1) {
        int y = __shfl_up(x, off);
        if (lane >= off) x += y;
    }
    __shared__ int wsum[4], woff[4];
    if (lane == 63) wsum[wid] = x;
    __syncthreads();
    if (t == 0) {
        int s = 0;
        #pragma unroll
        for (int w = 0; w < 4; w++) { int tw = wsum[w]; woff[w] = s; s += tw; }
        row_start[N_NODES] = s;
    }
    __syncthreads();
    if (t < NCHUNK) boff[t] = x - v + woff[wid];
}

__global__ __launch_bounds__(256) void scan_k3(const int* __restrict__ deg,
                                               const int* __restrict__ boff,
                                               int* __restrict__ row_start) {
    int b = blockIdx.x, t = threadIdx.x;
    int lane = t & 63, wid = t >> 6;
    int i = b * 256 + t;
    int v = (i < N_NODES) ? deg[i] : 0;
    int x = v;
    #pragma unroll
    for (int off = 1; off < 64; off <<= 1) {
        int y = __shfl_up(x, off);
        if (lane >= off) x += y;
    }
    __shared__ int wsum[4], woff[4];
    if (lane == 63) wsum[wid] = x;
    __syncthreads();
    if (t == 0) {
        int s = boff[b];
        #pragma unroll
        for (int w = 0; w < 4; w++) { int tw = wsum[w]; woff[w] = s; s += tw; }
    }
    __syncthreads();
    if (i < N_NODES) row_start[i] = x - v + woff[wid];
}

__global__ void scatter_edges(const int* __restrict__ src, const int* __restrict__ dst,
                              const int* __restrict__ row_start, int* __restrict__ cursor,
                              int* __restrict__ csr_src) {
    int e = blockIdx.x * blockDim.x + threadIdx.x;
    if (e >= N_EDGES + N_NODES) return;
    int s, d;
    if (e < N_EDGES) { s = src[e]; d = dst[e]; } else { s = d = e - N_EDGES; }
    int pos = atomicAdd(&cursor[d], 1);
    csr_src[row_start[d] + pos] = s;
}

// ===== fused GAT, wave-per-node: softmax in registers, no block barriers =====
template<bool WRITE_F32, bool WRITE_BF16>
__global__ __launch_bounds__(256) void gat_fused(
    const int* __restrict__ row_start, const int* __restrict__ csr_src,
    const float* __restrict__ a_s, const float* __restrict__ a_d,
    const unsigned short* __restrict__ h16, const float* __restrict__ bias,
    const float* __restrict__ g, const float* __restrict__ be,
    const float* __restrict__ rm, const float* __restrict__ rv,
    float* __restrict__ out, unsigned short* __restrict__ out16) {
    int t = threadIdx.x;
    int lane = t & 63;
    int w = t >> 6;
    int hd = lane >> 4;
    int d = blockIdx.x * 4 + w;

    __shared__ float p_lds[4 * WCAP * 4];
    __shared__ int   o_lds[4 * WCAP];
    float* pw = &p_lds[w * WCAP * 4];
    int*   ow = &o_lds[w * WCAP];

    const uint2* __restrict__ H2 = (const uint2*)h16;

    int rs = row_start[d], re = row_start[d + 1];
    int deg = re - rs;
    float4 ad4 = *(const float4*)&a_d[d * 4];

    float m_old[4] = {-INFINITY, -INFINITY, -INFINITY, -INFINITY};
    float l_run[4] = {0.f, 0.f, 0.f, 0.f};
    float4 acc = make_float4(0.f, 0.f, 0.f, 0.f);

    for (int base = 0; base < deg; base += WCAP) {
        int cl = min(WCAP, deg - base);
        float lg[4] = {-INFINITY, -INFINITY, -INFINITY, -INFINITY};
        if (lane < cl) {
            int s = csr_src[rs + base + lane];
            ow[lane] = s * 64;
            float4 as4 = *(const float4*)&a_s[s * 4];
            float e0 = as4.x + ad4.x; lg[0] = e0 > 0.f ? e0 : SLOPE * e0;
            float e1 = as4.y + ad4.y; lg[1] = e1 > 0.f ? e1 : SLOPE * e1;
            float e2 = as4.z + ad4.z; lg[2] = e2 > 0.f ? e2 : SLOPE * e2;
            float e3 = as4.w + ad4.w; lg[3] = e3 > 0.f ? e3 : SLOPE * e3;
        }
        float m_new[4], alpha[4];
        #pragma unroll
        for (int h = 0; h < 4; h++) {
            float mm = lg[h];
            #pragma unroll
            for (int off = 1; off < 64; off <<= 1) mm = fmaxf(mm, __shfl_xor(mm, off));
            m_new[h] = fmaxf(m_old[h], mm);
            alpha[h] = __expf(m_old[h] - m_new[h]);
            m_old[h] = m_new[h];
        }
        float pv[4];
        #pragma unroll
        for (int h = 0; h < 4; h++)
            pv[h] = (lane < cl) ? __expf(lg[h] - m_new[h]) : 0.f;
        if (lane < cl) {
            float4 pq; pq.x = pv[0]; pq.y = pv[1]; pq.z = pv[2]; pq.w = pv[3];
            *(float4*)&pw[lane * 4] = pq;
        }
        #pragma unroll
        for (int h = 0; h < 4; h++) {
            float cs = pv[h];
            #pragma unroll
            for (int off = 1; off < 64; off <<= 1) cs += __shfl_xor(cs, off);
            l_run[h] = l_run[h] * alpha[h] + cs;
        }
        float al = hd < 2 ? (hd == 0 ? alpha[0] : alpha[1])
                          : (hd == 2 ? alpha[2] : alpha[3]);
        acc.x *= al; acc.y *= al; acc.z *= al; acc.w *= al;
        int e = 0;
        for (; e + 1 < cl; e += 2) {
            int offA = ow[e], offB = ow[e + 1];
            float pA = pw[e * 4 + hd], pB = pw[(e + 1) * 4 + hd];
            uint2 hA = H2[offA + lane];
            uint2 hB = H2[offB + lane];
            acc.x += pA * __uint_as_float(hA.x << 16);
            acc.y += pA * __uint_as_float(hA.x & 0xffff0000u);
            acc.z += pA * __uint_as_float(hA.y << 16);
            acc.w += pA * __uint_as_float(hA.y & 0xffff0000u);
            acc.x += pB * __uint_as_float(hB.x << 16);
            acc.y += pB * __uint_as_float(hB.x & 0xffff0000u);
            acc.z += pB * __uint_as_float(hB.y << 16);
            acc.w += pB * __uint_as_float(hB.y & 0xffff0000u);
        }
        if (e < cl) {
            int offA = ow[e];
            float pA = pw[e * 4 + hd];
            uint2 hA = H2[offA + lane];
            acc.x += pA * __uint_as_float(hA.x << 16);
            acc.y += pA * __uint_as_float(hA.x & 0xffff0000u);
            acc.z += pA * __uint_as_float(hA.y << 16);
            acc.w += pA * __uint_as_float(hA.y & 0xffff0000u);
        }
    }
    float denom = hd < 2 ? (hd == 0 ? l_run[0] : l_run[1])
                         : (hd == 2 ? l_run[2] : l_run[3]);
    float inv = 1.f / denom;
    int c0 = lane * 4;
    float4 bi = *(const float4*)&bias[c0];
    float4 gg = *(const float4*)&g[c0];
    float4 bb = *(const float4*)&be[c0];
    float4 mm = *(const float4*)&rm[c0];
    float4 vv = *(const float4*)&rv[c0];
    float v0 = fmaxf(acc.x * inv + bi.x, 0.f);
    float v1 = fmaxf(acc.y * inv + bi.y, 0.f);
    float v2 = fmaxf(acc.z * inv + bi.z, 0.f);
    float v3 = fmaxf(acc.w * inv + bi.w, 0.f);
    v0 = (v0 - mm.x) * rsqrtf(vv.x + BN_EPS) * gg.x + bb.x;
    v1 = (v1 - mm.y) * rsqrtf(vv.y + BN_EPS) * gg.y + bb.y;
    v2 = (v2 - mm.z) * rsqrtf(vv.z + BN_EPS) * gg.z + bb.z;
    v3 = (v3 - mm.w) * rsqrtf(vv.w + BN_EPS) * gg.w + bb.w;
    if (WRITE_F32) {
        floatx4 o = {v0, v1, v2, v3};
        __builtin_nontemporal_store(o, (floatx4*)&out[(long long)d * FEAT + c0]);
    }
    if (WRITE_BF16) {
        unsigned long long o =
            (unsigned long long)f2bf(v0) |
            ((unsigned long long)f2bf(v1) << 16) |
            ((unsigned long long)f2bf(v2) << 32) |
            ((unsigned long long)f2bf(v3) << 48);
        __builtin_nontemporal_store(o, (unsigned long long*)&out16[(long long)d * FEAT + c0]);
    }
}

// ===== fused head: mean-pool (sorted batch) + relu(pooled@lw1+lb1) @ lw2 + lb2 =====
__global__ __launch_bounds__(256) void head_fused(
    const float* __restrict__ h, const int* __restrict__ batch,
    const float* __restrict__ lw1, const float* __restrict__ lb1,
    const float* __restrict__ lw2, const float* __restrict__ lb2,
    float* __restrict__ out) {
    int gph = blockIdx.x;
    int t = threadIdx.x;
    __shared__ float pooled[FEAT];
    __shared__ float zl[OUT_DIM];
    __shared__ int lo_s, hi_s;
    if (t == 0) {
        int lo = 0, hi = N_NODES;
        while (lo < hi) { int mid = (lo + hi) >> 1; if (batch[mid] < gph) lo = mid + 1; else hi = mid; }
        lo_s = lo;
        int lo2 = 0, hi2 = N_NODES;
        while (lo2 < hi2) { int mid = (lo2 + hi2) >> 1; if (batch[mid] < gph + 1) lo2 = mid + 1; else hi2 = mid; }
        hi_s = lo2;
    }
    __syncthreads();
    int lo = lo_s, hi = hi_s;
    float a0 = 0.f, a1 = 0.f, a2 = 0.f, a3 = 0.f;
    int n = lo;
    for (; n + 3 < hi; n += 4) {
        a0 += h[(long long)n * FEAT + t];
        a1 += h[(long long)(n + 1) * FEAT + t];
        a2 += h[(long long)(n + 2) * FEAT + t];
        a3 += h[(long long)(n + 3) * FEAT + t];
    }
    for (; n < hi; n++) a0 += h[(long long)n * FEAT + t];
    float cnt = fmaxf((float)(hi - lo), 1.f);
    pooled[t] = (a0 + a1 + a2 + a3) / cnt;
    __syncthreads();
    // z[j] : 2 threads per j, each half of k
    int j = t >> 1, kh = t & 1;
    float zp = 0.f;
    #pragma unroll 8
    for (int k = kh * 128; k < kh * 128 + 128; k++)
        zp += pooled[k] * lw1[k * OUT_DIM + j];
    zp += __shfl_xor(zp, 1);
    if (kh == 0) zl[j] = fmaxf(zp + lb1[j], 0.f);
    __syncthreads();
    // out[c] : wave 0 -> c=0, wave 1 -> c=1
    int w = t >> 6, lane = t & 63;
    if (w < 2) {
        float p = zl[lane] * lw2[lane * 2 + w] + zl[lane + 64] * lw2[(lane + 64) * 2 + w];
        #pragma unroll
        for (int off = 1; off < 64; off <<= 1) p += __shfl_xor(p, off);
        if (lane == 0) out[gph * 2 + w] = p + lb2[w];
    }
}

extern "C" void kernel_launch(void* const* d_in, const int* in_sizes, int n_in,
                              void* d_out, int out_size, void* d_ws, size_t ws_size,
                              hipStream_t stream) {
    const float* x       = (const float*)d_in[0];
    const int*   ei      = (const int*)d_in[1];
    const int*   batch   = (const int*)d_in[2];
    const float* W1      = (const float*)d_in[3];
    const float* att_s1  = (const float*)d_in[4];
    const float* att_d1  = (const float*)d_in[5];
    const float* b1      = (const float*)d_in[6];
    const float* g1      = (const float*)d_in[7];
    const float* be1     = (const float*)d_in[8];
    const float* rm1     = (const float*)d_in[9];
    const float* rv1     = (const float*)d_in[10];
    const float* W2      = (const float*)d_in[11];
    const float* att_s2  = (const float*)d_in[12];
    const float* att_d2  = (const float*)d_in[13];
    const float* b2      = (const float*)d_in[14];
    const float* g2      = (const float*)d_in[15];
    const float* be2     = (const float*)d_in[16];
    const float* rm2     = (const float*)d_in[17];
    const float* rv2     = (const float*)d_in[18];
    const float* lw1     = (const float*)d_in[19];
    const float* lb1     = (const float*)d_in[20];
    const float* lw2     = (const float*)d_in[21];
    const float* lb2     = (const float*)d_in[22];
    float* out           = (float*)d_out;

    const int* src = ei;
    const int* dst = ei + N_EDGES;

    char* p = (char*)d_ws;
    auto carve = [&p](size_t bytes) -> void* {
        void* r = (void*)p;
        p += (bytes + 63) & ~(size_t)63;
        return r;
    };
    float* bufB   = (float*)carve(sizeof(float) * (size_t)N_NODES * FEAT);
    float* a_s    = (float*)carve(sizeof(float) * N_NODES * HEADS);
    float* a_d    = (float*)carve(sizeof(float) * N_NODES * HEADS);
    int*   deg    = (int*)carve(sizeof(int) * N_NODES);
    int*   cursor = (int*)carve(sizeof(int) * N_NODES);
    int*   csr    = (int*)carve(sizeof(int) * (N_EDGES + N_NODES));
    int*   rstart = (int*)carve(sizeof(int) * (N_NODES + 4));
    int*   bsum   = (int*)carve(sizeof(int) * 256);
    int*   boff   = (int*)carve(sizeof(int) * 256);
    unsigned short* h16  = (unsigned short*)carve(sizeof(short) * (size_t)M_PAD * FEAT);
    unsigned short* x16  = (unsigned short*)carve(sizeof(short) * (size_t)M_PAD * F_IN);
    unsigned short* h1bf = (unsigned short*)carve(sizeof(short) * (size_t)M_PAD * FEAT);
    unsigned short* w1t  = (unsigned short*)carve(sizeof(short) * FEAT * F_IN);
    unsigned short* w2t  = (unsigned short*)carve(sizeof(short) * FEAT * FEAT);

    const int Et = N_EDGES + N_NODES;

    // ---- converts ----
    cvt_x_bf16<<<((long long)M_PAD * F_IN + 255) / 256, 256, 0, stream>>>(x, x16);
    cvt_w_both<<<((F_IN + FEAT) * 256 + 255) / 256, 256, 0, stream>>>(W1, W2, w1t, w2t);
    (void)hipMemsetAsync(h1bf + (size_t)N_NODES * FEAT, 0,
                         sizeof(short) * (size_t)(M_PAD - N_NODES) * FEAT, stream);

    // ---- CSR build ----
    (void)hipMemsetAsync(deg, 0, sizeof(int) * N_NODES, stream);
    (void)hipMemsetAsync(cursor, 0, sizeof(int) * N_NODES, stream);
    degree_count<<<(Et + 255) / 256, 256, 0, stream>>>(src, dst, deg);
    scan_k1<<<NCHUNK, 256, 0, stream>>>(deg, bsum);
    scan_k2<<<1, 256, 0, stream>>>(bsum, boff, rstart);
    scan_k3<<<NCHUNK, 256, 0, stream>>>(deg, boff, rstart);
    scatter_edges<<<(Et + 255) / 256, 256, 0, stream>>>(src, dst, rstart, cursor, csr);

    // ---- Layer 1 ----
    {
        dim3 grid(FEAT / 128, M_PAD / 128);
        gemm_mfma_gat<<<grid, 256, 0, stream>>>(x16, w1t, att_s1, att_d1,
                                                h16, a_s, a_d, F_IN);
    }
    gat_fused<false, true><<<N_NODES / 4, 256, 0, stream>>>(rstart, csr, a_s, a_d, h16,
                                                            b1, g1, be1, rm1, rv1,
                                                            nullptr, h1bf);

    // ---- Layer 2 ----
    {
        dim3 grid(FEAT / 128, M_PAD / 128);
        gemm_mfma_gat<<<grid, 256, 0, stream>>>(h1bf, w2t, att_s2, att_d2,
                                                h16, a_s, a_d, FEAT);
    }
    gat_fused<true, false><<<N_NODES / 4, 256, 0, stream>>>(rstart, csr, a_s, a_d, h16,
                                                            b2, g2, be2, rm2, rv2,
                                                            bufB, nullptr);

    // ---- fused head: pool + MLP + FC ----
    head_fused<<<NG, 256, 0, stream>>>(bufB, batch, lw1, lb1, lw2, lb2, out);
}

// Round 10
// 435.268 us; speedup vs baseline: 5.1139x; 1.0607x over previous
//
#include <hip/hip_runtime.h>
#include <hip/hip_bf16.h>
#include <math.h>

#define N_NODES 50000
#define M_PAD   50048                    // 391 * 128
#define N_EDGES 800000
#define F_IN 128
#define HID 64
#define HEADS 4
#define FEAT 256        // HEADS*HID
#define OUT_DIM 128
#define N_CLS 2
#define NG 500
#define SLOPE 0.2f
#define BN_EPS 1e-5f
#define WCAP 64          // edges per chunk per wave in gat_fused
#define NCHUNK ((N_NODES + 255) / 256)

typedef __attribute__((ext_vector_type(8))) short short8;
typedef __attribute__((ext_vector_type(4))) float floatx4;
typedef __attribute__((ext_vector_type(4))) unsigned int uintx4;

__device__ inline unsigned short f2bf(float f) {
    unsigned int u = __float_as_uint(f);
    unsigned int lsb = (u >> 16) & 1u;
    return (unsigned short)((u + 0x7fffu + lsb) >> 16);
}

// ==== bf16 MFMA GEMM fused with GAT prologue ====
// C = A[Mpad,K] @ BT[256,K]^T. A is bf16 (AF32=false) or fp32 with N_NODES
// valid rows (AF32=true, converted in staging). Writes bf16 h16[Mpad,256]
// (coalesced via LDS repack) + fp32 a_s/a_d[N,4] from fp32 accumulators.
template<bool AF32>
__global__ __launch_bounds__(256) void gemm_mfma_gat(
    const void* __restrict__ Av, const unsigned short* __restrict__ BT,
    const float* __restrict__ att_src, const float* __restrict__ att_dst,
    unsigned short* __restrict__ h16, float* __restrict__ a_s,
    float* __restrict__ a_d, int K) {
    constexpr int LS = 40;     // staging row stride (bf16)
    constexpr int CS = 132;    // C-repack row stride (bf16)
    __shared__ unsigned short smem[128 * CS];
    unsigned short* As = smem;
    unsigned short* Bs = smem + 128 * LS;
    int t = threadIdx.x;
    int lane = t & 63, w = t >> 6;
    int wm = (w >> 1) * 64, wn = (w & 1) * 64;
    int row0 = blockIdx.y * 128, col0 = blockIdx.x * 128;

    floatx4 acc[4][4] = {};

    int r0 = t >> 2,            c0 = (t & 3) * 8;
    int r1 = (t + 256) >> 2,    c1 = ((t + 256) & 3) * 8;
    int mrow = lane & 15, quad = lane >> 4;

    const unsigned short* Ab = (const unsigned short*)Av;
    const float* Af = (const float*)Av;

    for (int k0 = 0; k0 < K; k0 += 32) {
        if (AF32) {
            uint4 p0 = make_uint4(0, 0, 0, 0), p1 = p0;
            if (row0 + r0 < N_NODES) {
                float4 f0 = *(const float4*)&Af[(long long)(row0 + r0) * K + k0 + c0];
                float4 f1 = *(const float4*)&Af[(long long)(row0 + r0) * K + k0 + c0 + 4];
                p0.x = (unsigned)f2bf(f0.x) | ((unsigned)f2bf(f0.y) << 16);
                p0.y = (unsigned)f2bf(f0.z) | ((unsigned)f2bf(f0.w) << 16);
                p0.z = (unsigned)f2bf(f1.x) | ((unsigned)f2bf(f1.y) << 16);
                p0.w = (unsigned)f2bf(f1.z) | ((unsigned)f2bf(f1.w) << 16);
            }
            if (row0 + r1 < N_NODES) {
                float4 f0 = *(const float4*)&Af[(long long)(row0 + r1) * K + k0 + c1];
                float4 f1 = *(const float4*)&Af[(long long)(row0 + r1) * K + k0 + c1 + 4];
                p1.x = (unsigned)f2bf(f0.x) | ((unsigned)f2bf(f0.y) << 16);
                p1.y = (unsigned)f2bf(f0.z) | ((unsigned)f2bf(f0.w) << 16);
                p1.z = (unsigned)f2bf(f1.x) | ((unsigned)f2bf(f1.y) << 16);
                p1.w = (unsigned)f2bf(f1.z) | ((unsigned)f2bf(f1.w) << 16);
            }
            *(uint4*)&As[r0 * LS + c0] = p0;
            *(uint4*)&As[r1 * LS + c1] = p1;
        } else {
            *(uint4*)&As[r0 * LS + c0] = *(const uint4*)&Ab[(long long)(row0 + r0) * K + k0 + c0];
            *(uint4*)&As[r1 * LS + c1] = *(const uint4*)&Ab[(long long)(row0 + r1) * K + k0 + c1];
        }
        *(uint4*)&Bs[r0 * LS + c0] = *(const uint4*)&BT[(long long)(col0 + r0) * K + k0 + c0];
        *(uint4*)&Bs[r1 * LS + c1] = *(const uint4*)&BT[(long long)(col0 + r1) * K + k0 + c1];
        __syncthreads();
        short8 af[4], bf[4];
        #pragma unroll
        for (int i = 0; i < 4; i++) {
            af[i] = *(const short8*)&As[(wm + i * 16 + mrow) * LS + quad * 8];
            bf[i] = *(const short8*)&Bs[(wn + i * 16 + mrow) * LS + quad * 8];
        }
        #pragma unroll
        for (int mi = 0; mi < 4; mi++)
            #pragma unroll
            for (int ni = 0; ni < 4; ni++)
                acc[mi][ni] = __builtin_amdgcn_mfma_f32_16x16x32_bf16(af[mi], bf[ni],
                                                                      acc[mi][ni], 0, 0, 0);
        __syncthreads();
    }

    // ---- attention scores (wave's 64-col span == one head) ----
    int head = blockIdx.x * 2 + (w & 1);
    float ats[4], atd[4];
    #pragma unroll
    for (int ni = 0; ni < 4; ni++) {
        ats[ni] = att_src[head * 64 + ni * 16 + mrow];
        atd[ni] = att_dst[head * 64 + ni * 16 + mrow];
    }
    #pragma unroll
    for (int mi = 0; mi < 4; mi++) {
        #pragma unroll
        for (int r = 0; r < 4; r++) {
            int row = row0 + wm + mi * 16 + quad * 4 + r;
            float ps = 0.f, pd = 0.f;
            #pragma unroll
            for (int ni = 0; ni < 4; ni++) {
                float v = acc[mi][ni][r];
                ps += v * ats[ni];
                pd += v * atd[ni];
            }
            #pragma unroll
            for (int off = 1; off < 16; off <<= 1) {
                ps += __shfl_xor(ps, off);
                pd += __shfl_xor(pd, off);
            }
            if (mrow == 0 && row < N_NODES) {
                a_s[row * 4 + head] = ps;
                a_d[row * 4 + head] = pd;
            }
        }
    }

    // ---- repack C tile through LDS, coalesced uint4 stores ----
    #pragma unroll
    for (int mi = 0; mi < 4; mi++)
        #pragma unroll
        for (int ni = 0; ni < 4; ni++)
            #pragma unroll
            for (int r = 0; r < 4; r++)
                smem[(wm + mi * 16 + quad * 4 + r) * CS + wn + ni * 16 + mrow] =
                    f2bf(acc[mi][ni][r]);
    __syncthreads();
    {
        int r2 = t >> 1, half = t & 1;
        const unsigned short* sp = &smem[r2 * CS + half * 64];
        unsigned short* dp = &h16[(long long)(row0 + r2) * FEAT + col0 + half * 64];
        #pragma unroll
        for (int k = 0; k < 8; k++)
            ((uint4*)dp)[k] = ((const uint4*)sp)[k];
    }
}

// both weights transposed in one launch
__global__ void cvt_w_both(const float* __restrict__ W1, const float* __restrict__ W2,
                           unsigned short* __restrict__ W1T, unsigned short* __restrict__ W2T) {
    int i = blockIdx.x * 256 + threadIdx.x;
    if (i < F_IN * 256) {
        int k = i >> 8, n = i & 255;
        W1T[n * F_IN + k] = f2bf(W1[i]);
    }
    int j = i - F_IN * 256;
    if (j >= 0 && j < FEAT * 256) {
        int k = j >> 8, n = j & 255;
        W2T[n * FEAT + k] = f2bf(W2[j]);
    }
}

// ================= CSR build =================
// counts degrees AND records each edge's slot within its destination bucket
__global__ void degree_count(const int* __restrict__ src, const int* __restrict__ dst,
                             int* __restrict__ deg, int* __restrict__ epos) {
    int e = blockIdx.x * blockDim.x + threadIdx.x;
    if (e >= N_EDGES + N_NODES) return;
    int d = (e < N_EDGES) ? dst[e] : (e - N_EDGES);
    epos[e] = atomicAdd(&deg[d], 1);
}

__global__ __launch_bounds__(256) void scan_k1(const int* __restrict__ deg,
                                               int* __restrict__ bsum) {
    int b = blockIdx.x, t = threadIdx.x;
    int i = b * 256 + t;
    int v = (i < N_NODES) ? deg[i] : 0;
    #pragma unroll
    for (int off = 32; off > 0; off >>= 1) v += __shfl_down(v, off);
    __shared__ int ws[4];
    if ((t & 63) == 0) ws[t >> 6] = v;
    __syncthreads();
    if (t == 0) bsum[b] = ws[0] + ws[1] + ws[2] + ws[3];
}

__global__ __launch_bounds__(256) void scan_k2(const int* __restrict__ bsum,
                                               int* __restrict__ boff,
                                               int* __restrict__ row_start) {
    int t = threadIdx.x;
    int lane = t & 63, wid = t >> 6;
    int v = (t < NCHUNK) ? bsum[t] : 0;
    int x = v;
    #pragma unroll
    for (int off = 1; off < 64; off <<= 1) {
        int y = __shfl_up(x, off);
        if (lane >= off) x += y;
    }
    __shared__ int wsum[4], woff[4];
    if (lane == 63) wsum[wid] = x;
    __syncthreads();
    if (t == 0) {
        int s = 0;
        #pragma unroll
        for (int w = 0; w < 4; w++) { int tw = wsum[w]; woff[w] = s; s += tw; }
        row_start[N_NODES] = s;
    }
    __syncthreads();
    if (t < NCHUNK) boff[t] = x - v + woff[wid];
}

__global__ __launch_bounds__(256) void scan_k3(const int* __restrict__ deg,
                                               const int* __restrict__ boff,
                                               int* __restrict__ row_start) {
    int b = blockIdx.x, t = threadIdx.x;
    int lane = t & 63, wid = t >> 6;
    int i = b * 256 + t;
    int v = (i < N_NODES) ? deg[i] : 0;
    int x = v;
    #pragma unroll
    for (int off = 1; off < 64; off <<= 1) {
        int y = __shfl_up(x, off);
        if (lane >= off) x += y;
    }
    __shared__ int wsum[4], woff[4];
    if (lane == 63) wsum[wid] = x;
    __syncthreads();
    if (t == 0) {
        int s = boff[b];
        #pragma unroll
        for (int w = 0; w < 4; w++) { int tw = wsum[w]; woff[w] = s; s += tw; }
    }
    __syncthreads();
    if (i < N_NODES) row_start[i] = x - v + woff[wid];
}

__global__ void scatter_edges(const int* __restrict__ src, const int* __restrict__ dst,
                              const int* __restrict__ row_start, const int* __restrict__ epos,
                              int* __restrict__ csr_src) {
    int e = blockIdx.x * blockDim.x + threadIdx.x;
    if (e >= N_EDGES + N_NODES) return;
    int s, d;
    if (e < N_EDGES) { s = src[e]; d = dst[e]; } else { s = d = e - N_EDGES; }
    csr_src[row_start[d] + epos[e]] = s;
}

// ===== fused GAT, wave-per-node; gather: uint4/lane, 2 edges per load =====
template<bool WRITE_F32, bool WRITE_BF16>
__global__ __launch_bounds__(256) void gat_fused(
    const int* __restrict__ row_start, const int* __restrict__ csr_src,
    const float* __restrict__ a_s, const float* __restrict__ a_d,
    const unsigned short* __restrict__ h16, const float* __restrict__ bias,
    const float* __restrict__ g, const float* __restrict__ be,
    const float* __restrict__ rm, const float* __restrict__ rv,
    float* __restrict__ out, unsigned short* __restrict__ out16) {
    int t = threadIdx.x;
    int lane = t & 63;
    int w = t >> 6;
    int d = blockIdx.x * 4 + w;
    int half = lane >> 5;            // which edge of a pair
    int sl = lane & 31;              // channels 8*sl .. 8*sl+7
    int hd2 = sl >> 3;               // head of those channels

    __shared__ float p_lds[4 * WCAP * 4];   // [wave][edge][head]
    __shared__ int   o_lds[4 * WCAP];       // [wave][edge] : src*32 (uint4 units)
    float* pw = &p_lds[w * WCAP * 4];
    int*   ow = &o_lds[w * WCAP];

    const uint4* __restrict__ H4 = (const uint4*)h16;

    int rs = row_start[d], re = row_start[d + 1];
    int deg = re - rs;
    float4 ad4 = *(const float4*)&a_d[d * 4];

    float m_old[4] = {-INFINITY, -INFINITY, -INFINITY, -INFINITY};
    float l_run[4] = {0.f, 0.f, 0.f, 0.f};
    float acc[8] = {};

    for (int base = 0; base < deg; base += WCAP) {
        int cl = min(WCAP, deg - base);
        float lg[4] = {-INFINITY, -INFINITY, -INFINITY, -INFINITY};
        if (lane < cl) {
            int s = csr_src[rs + base + lane];
            ow[lane] = s * 32;
            float4 as4 = *(const float4*)&a_s[s * 4];
            float e0 = as4.x + ad4.x; lg[0] = e0 > 0.f ? e0 : SLOPE * e0;
            float e1 = as4.y + ad4.y; lg[1] = e1 > 0.f ? e1 : SLOPE * e1;
            float e2 = as4.z + ad4.z; lg[2] = e2 > 0.f ? e2 : SLOPE * e2;
            float e3 = as4.w + ad4.w; lg[3] = e3 > 0.f ? e3 : SLOPE * e3;
        }
        float m_new[4], alpha[4];
        #pragma unroll
        for (int h = 0; h < 4; h++) {
            float mm = lg[h];
            #pragma unroll
            for (int off = 1; off < 64; off <<= 1) mm = fmaxf(mm, __shfl_xor(mm, off));
            m_new[h] = fmaxf(m_old[h], mm);
            alpha[h] = __expf(m_old[h] - m_new[h]);   // 0 on first chunk
            m_old[h] = m_new[h];
        }
        float pv[4];
        #pragma unroll
        for (int h = 0; h < 4; h++)
            pv[h] = (lane < cl) ? __expf(lg[h] - m_new[h]) : 0.f;
        if (lane < cl) {
            float4 pq; pq.x = pv[0]; pq.y = pv[1]; pq.z = pv[2]; pq.w = pv[3];
            *(float4*)&pw[lane * 4] = pq;
        }
        #pragma unroll
        for (int h = 0; h < 4; h++) {
            float cs = pv[h];
            #pragma unroll
            for (int off = 1; off < 64; off <<= 1) cs += __shfl_xor(cs, off);
            l_run[h] = l_run[h] * alpha[h] + cs;
        }
        float al = hd2 < 2 ? (hd2 == 0 ? alpha[0] : alpha[1])
                           : (hd2 == 2 ? alpha[2] : alpha[3]);
        #pragma unroll
        for (int i = 0; i < 8; i++) acc[i] *= al;
        // gather: iteration covers 4 edges via 2 uint4 loads per lane
        for (int e0 = 0; e0 < cl; e0 += 4) {
            int eA = e0 + half;
            int eB = e0 + 2 + half;
            bool vA = eA < cl, vB = eB < cl;
            int offA = ow[vA ? eA : 0];
            int offB = ow[vB ? eB : 0];
            float pA = vA ? pw[eA * 4 + hd2] : 0.f;
            float pB = vB ? pw[eB * 4 + hd2] : 0.f;
            uint4 hA = H4[offA + sl];
            uint4 hB = H4[offB + sl];
            acc[0] += pA * __uint_as_float(hA.x << 16);
            acc[1] += pA * __uint_as_float(hA.x & 0xffff0000u);
            acc[2] += pA * __uint_as_float(hA.y << 16);
            acc[3] += pA * __uint_as_float(hA.y & 0xffff0000u);
            acc[4] += pA * __uint_as_float(hA.z << 16);
            acc[5] += pA * __uint_as_float(hA.z & 0xffff0000u);
            acc[6] += pA * __uint_as_float(hA.w << 16);
            acc[7] += pA * __uint_as_float(hA.w & 0xffff0000u);
            acc[0] += pB * __uint_as_float(hB.x << 16);
            acc[1] += pB * __uint_as_float(hB.x & 0xffff0000u);
            acc[2] += pB * __uint_as_float(hB.y << 16);
            acc[3] += pB * __uint_as_float(hB.y & 0xffff0000u);
            acc[4] += pB * __uint_as_float(hB.z << 16);
            acc[5] += pB * __uint_as_float(hB.z & 0xffff0000u);
            acc[6] += pB * __uint_as_float(hB.w << 16);
            acc[7] += pB * __uint_as_float(hB.w & 0xffff0000u);
        }
    }
    // combine edge-halves: lanes sl and sl+32 hold partial sums of same channels
    #pragma unroll
    for (int i = 0; i < 8; i++) acc[i] += __shfl_xor(acc[i], 32);
    if (half == 0) {
        float denom = hd2 < 2 ? (hd2 == 0 ? l_run[0] : l_run[1])
                              : (hd2 == 2 ? l_run[2] : l_run[3]);
        float inv = 1.f / denom;
        int c0 = sl * 8;
        float v[8];
        #pragma unroll
        for (int q = 0; q < 2; q++) {
            float4 bi = *(const float4*)&bias[c0 + q * 4];
            float4 gg = *(const float4*)&g[c0 + q * 4];
            float4 bb = *(const float4*)&be[c0 + q * 4];
            float4 mm = *(const float4*)&rm[c0 + q * 4];
            float4 vv = *(const float4*)&rv[c0 + q * 4];
            float b4[4] = {bi.x, bi.y, bi.z, bi.w};
            float g4[4] = {gg.x, gg.y, gg.z, gg.w};
            float e4[4] = {bb.x, bb.y, bb.z, bb.w};
            float m4[4] = {mm.x, mm.y, mm.z, mm.w};
            float r4[4] = {vv.x, vv.y, vv.z, vv.w};
            #pragma unroll
            for (int j = 0; j < 4; j++) {
                float vj = fmaxf(acc[q * 4 + j] * inv + b4[j], 0.f);
                v[q * 4 + j] = (vj - m4[j]) * rsqrtf(r4[j] + BN_EPS) * g4[j] + e4[j];
            }
        }
        if (WRITE_F32) {
            floatx4 o0 = {v[0], v[1], v[2], v[3]};
            floatx4 o1 = {v[4], v[5], v[6], v[7]};
            __builtin_nontemporal_store(o0, (floatx4*)&out[(long long)d * FEAT + c0]);
            __builtin_nontemporal_store(o1, (floatx4*)&out[(long long)d * FEAT + c0 + 4]);
        }
        if (WRITE_BF16) {
            uintx4 o;
            o.x = (unsigned)f2bf(v[0]) | ((unsigned)f2bf(v[1]) << 16);
            o.y = (unsigned)f2bf(v[2]) | ((unsigned)f2bf(v[3]) << 16);
            o.z = (unsigned)f2bf(v[4]) | ((unsigned)f2bf(v[5]) << 16);
            o.w = (unsigned)f2bf(v[6]) | ((unsigned)f2bf(v[7]) << 16);
            __builtin_nontemporal_store(o, (uintx4*)&out16[(long long)d * FEAT + c0]);
        }
    }
}

// ===== fused head: mean-pool + relu(pooled@lw1+lb1) @ lw2 + lb2 =====
__global__ __launch_bounds__(256) void head_fused(
    const float* __restrict__ h, const int* __restrict__ batch,
    const float* __restrict__ lw1, const float* __restrict__ lb1,
    const float* __restrict__ lw2, const float* __restrict__ lb2,
    float* __restrict__ out) {
    int gph = blockIdx.x;
    int t = threadIdx.x;
    __shared__ float pooled[FEAT];
    __shared__ float zl[OUT_DIM];
    __shared__ int lo_s, hi_s;
    if (t == 0) {
        int lo = 0, hi = N_NODES;
        while (lo < hi) { int mid = (lo + hi) >> 1; if (batch[mid] < gph) lo = mid + 1; else hi = mid; }
        lo_s = lo;
        int lo2 = 0, hi2 = N_NODES;
        while (lo2 < hi2) { int mid = (lo2 + hi2) >> 1; if (batch[mid] < gph + 1) lo2 = mid + 1; else hi2 = mid; }
        hi_s = lo2;
    }
    __syncthreads();
    int lo = lo_s, hi = hi_s;
    float a0 = 0.f, a1 = 0.f, a2 = 0.f, a3 = 0.f;
    int n = lo;
    for (; n + 3 < hi; n += 4) {
        a0 += h[(long long)n * FEAT + t];
        a1 += h[(long long)(n + 1) * FEAT + t];
        a2 += h[(long long)(n + 2) * FEAT + t];
        a3 += h[(long long)(n + 3) * FEAT + t];
    }
    for (; n < hi; n++) a0 += h[(long long)n * FEAT + t];
    float cnt = fmaxf((float)(hi - lo), 1.f);
    pooled[t] = (a0 + a1 + a2 + a3) / cnt;
    __syncthreads();
    int j = t >> 1, kh = t & 1;
    float zp = 0.f;
    #pragma unroll 8
    for (int k = kh * 128; k < kh * 128 + 128; k++)
        zp += pooled[k] * lw1[k * OUT_DIM + j];
    zp += __shfl_xor(zp, 1);
    if (kh == 0) zl[j] = fmaxf(zp + lb1[j], 0.f);
    __syncthreads();
    int w = t >> 6, lane = t & 63;
    if (w < 2) {
        float p = zl[lane] * lw2[lane * 2 + w] + zl[lane + 64] * lw2[(lane + 64) * 2 + w];
        #pragma unroll
        for (int off = 1; off < 64; off <<= 1) p += __shfl_xor(p, off);
        if (lane == 0) out[gph * 2 + w] = p + lb2[w];
    }
}

extern "C" void kernel_launch(void* const* d_in, const int* in_sizes, int n_in,
                              void* d_out, int out_size, void* d_ws, size_t ws_size,
                              hipStream_t stream) {
    const float* x       = (const float*)d_in[0];
    const int*   ei      = (const int*)d_in[1];
    const int*   batch   = (const int*)d_in[2];
    const float* W1      = (const float*)d_in[3];
    const float* att_s1  = (const float*)d_in[4];
    const float* att_d1  = (const float*)d_in[5];
    const float* b1      = (const float*)d_in[6];
    const float* g1      = (const float*)d_in[7];
    const float* be1     = (const float*)d_in[8];
    const float* rm1     = (const float*)d_in[9];
    const float* rv1     = (const float*)d_in[10];
    const float* W2      = (const float*)d_in[11];
    const float* att_s2  = (const float*)d_in[12];
    const float* att_d2  = (const float*)d_in[13];
    const float* b2      = (const float*)d_in[14];
    const float* g2      = (const float*)d_in[15];
    const float* be2     = (const float*)d_in[16];
    const float* rm2     = (const float*)d_in[17];
    const float* rv2     = (const float*)d_in[18];
    const float* lw1     = (const float*)d_in[19];
    const float* lb1     = (const float*)d_in[20];
    const float* lw2     = (const float*)d_in[21];
    const float* lb2     = (const float*)d_in[22];
    float* out           = (float*)d_out;

    const int* src = ei;
    const int* dst = ei + N_EDGES;

    char* p = (char*)d_ws;
    auto carve = [&p](size_t bytes) -> void* {
        void* r = (void*)p;
        p += (bytes + 63) & ~(size_t)63;
        return r;
    };
    float* bufB   = (float*)carve(sizeof(float) * (size_t)N_NODES * FEAT);
    float* a_s    = (float*)carve(sizeof(float) * N_NODES * HEADS);
    float* a_d    = (float*)carve(sizeof(float) * N_NODES * HEADS);
    int*   deg    = (int*)carve(sizeof(int) * N_NODES);
    int*   epos   = (int*)carve(sizeof(int) * (N_EDGES + N_NODES));
    int*   csr    = (int*)carve(sizeof(int) * (N_EDGES + N_NODES));
    int*   rstart = (int*)carve(sizeof(int) * (N_NODES + 4));
    int*   bsum   = (int*)carve(sizeof(int) * 256);
    int*   boff   = (int*)carve(sizeof(int) * 256);
    unsigned short* h16  = (unsigned short*)carve(sizeof(short) * (size_t)M_PAD * FEAT);
    unsigned short* h1bf = (unsigned short*)carve(sizeof(short) * (size_t)M_PAD * FEAT);
    unsigned short* w1t  = (unsigned short*)carve(sizeof(short) * FEAT * F_IN);
    unsigned short* w2t  = (unsigned short*)carve(sizeof(short) * FEAT * FEAT);

    const int Et = N_EDGES + N_NODES;

    // ---- converts / pad zeroing ----
    cvt_w_both<<<((F_IN + FEAT) * 256 + 255) / 256, 256, 0, stream>>>(W1, W2, w1t, w2t);
    (void)hipMemsetAsync(h1bf + (size_t)N_NODES * FEAT, 0,
                         sizeof(short) * (size_t)(M_PAD - N_NODES) * FEAT, stream);

    // ---- CSR build ----
    (void)hipMemsetAsync(deg, 0, sizeof(int) * N_NODES, stream);
    degree_count<<<(Et + 255) / 256, 256, 0, stream>>>(src, dst, deg, epos);
    scan_k1<<<NCHUNK, 256, 0, stream>>>(deg, bsum);
    scan_k2<<<1, 256, 0, stream>>>(bsum, boff, rstart);
    scan_k3<<<NCHUNK, 256, 0, stream>>>(deg, boff, rstart);
    scatter_edges<<<(Et + 255) / 256, 256, 0, stream>>>(src, dst, rstart, epos, csr);

    // ---- Layer 1 (A = fp32 x, converted in staging) ----
    {
        dim3 grid(FEAT / 128, M_PAD / 128);
        gemm_mfma_gat<true><<<grid, 256, 0, stream>>>(x, w1t, att_s1, att_d1,
                                                      h16, a_s, a_d, F_IN);
    }
    gat_fused<false, true><<<N_NODES / 4, 256, 0, stream>>>(rstart, csr, a_s, a_d, h16,
                                                            b1, g1, be1, rm1, rv1,
                                                            nullptr, h1bf);

    // ---- Layer 2 ----
    {
        dim3 grid(FEAT / 128, M_PAD / 128);
        gemm_mfma_gat<false><<<grid, 256, 0, stream>>>(h1bf, w2t, att_s2, att_d2,
                                                       h16, a_s, a_d, FEAT);
    }
    gat_fused<true, false><<<N_NODES / 4, 256, 0, stream>>>(rstart, csr, a_s, a_d, h16,
                                                            b2, g2, be2, rm2, rv2,
                                                            bufB, nullptr);

    // ---- fused head ----
    head_fused<<<NG, 256, 0, stream>>>(bufB, batch, lw1, lb1, lw2, lb2, out);
}

// Round 11
// 426.515 us; speedup vs baseline: 5.2189x; 1.0205x over previous
//
#include <hip/hip_runtime.h>
#include <hip/hip_bf16.h>
#include <math.h>

#define N_NODES 50000
#define M_PAD   50048                    // 391 * 128
#define N_EDGES 800000
#define F_IN 128
#define HID 64
#define HEADS 4
#define FEAT 256        // HEADS*HID
#define OUT_DIM 128
#define N_CLS 2
#define NG 500
#define SLOPE 0.2f
#define BN_EPS 1e-5f
#define WCAP 64          // edges per chunk per wave in gat_fused
#define NCHUNK ((N_NODES + 255) / 256)

typedef __attribute__((ext_vector_type(8))) short short8;
typedef __attribute__((ext_vector_type(4))) float floatx4;

__device__ inline unsigned short f2bf(float f) {
    unsigned int u = __float_as_uint(f);
    unsigned int lsb = (u >> 16) & 1u;
    return (unsigned short)((u + 0x7fffu + lsb) >> 16);
}

// ==== bf16 MFMA GEMM fused with GAT prologue ====
// C = A[Mpad,K] @ BT[256,K]^T. A is bf16 (AF32=false) or fp32 with N_NODES
// valid rows (AF32=true, converted in staging). Writes bf16 h16[Mpad,256]
// (coalesced via LDS repack) + fp32 a_s/a_d[N,4] from fp32 accumulators.
template<bool AF32>
__global__ __launch_bounds__(256) void gemm_mfma_gat(
    const void* __restrict__ Av, const unsigned short* __restrict__ BT,
    const float* __restrict__ att_src, const float* __restrict__ att_dst,
    unsigned short* __restrict__ h16, float* __restrict__ a_s,
    float* __restrict__ a_d, int K) {
    constexpr int LS = 40;     // staging row stride (bf16)
    constexpr int CS = 132;    // C-repack row stride (bf16)
    __shared__ unsigned short smem[128 * CS];
    unsigned short* As = smem;
    unsigned short* Bs = smem + 128 * LS;
    int t = threadIdx.x;
    int lane = t & 63, w = t >> 6;
    int wm = (w >> 1) * 64, wn = (w & 1) * 64;
    int row0 = blockIdx.y * 128, col0 = blockIdx.x * 128;

    floatx4 acc[4][4] = {};

    int r0 = t >> 2,            c0 = (t & 3) * 8;
    int r1 = (t + 256) >> 2,    c1 = ((t + 256) & 3) * 8;
    int mrow = lane & 15, quad = lane >> 4;

    const unsigned short* Ab = (const unsigned short*)Av;
    const float* Af = (const float*)Av;

    for (int k0 = 0; k0 < K; k0 += 32) {
        if (AF32) {
            uint4 p0 = make_uint4(0, 0, 0, 0), p1 = p0;
            if (row0 + r0 < N_NODES) {
                float4 f0 = *(const float4*)&Af[(long long)(row0 + r0) * K + k0 + c0];
                float4 f1 = *(const float4*)&Af[(long long)(row0 + r0) * K + k0 + c0 + 4];
                p0.x = (unsigned)f2bf(f0.x) | ((unsigned)f2bf(f0.y) << 16);
                p0.y = (unsigned)f2bf(f0.z) | ((unsigned)f2bf(f0.w) << 16);
                p0.z = (unsigned)f2bf(f1.x) | ((unsigned)f2bf(f1.y) << 16);
                p0.w = (unsigned)f2bf(f1.z) | ((unsigned)f2bf(f1.w) << 16);
            }
            if (row0 + r1 < N_NODES) {
                float4 f0 = *(const float4*)&Af[(long long)(row0 + r1) * K + k0 + c1];
                float4 f1 = *(const float4*)&Af[(long long)(row0 + r1) * K + k0 + c1 + 4];
                p1.x = (unsigned)f2bf(f0.x) | ((unsigned)f2bf(f0.y) << 16);
                p1.y = (unsigned)f2bf(f0.z) | ((unsigned)f2bf(f0.w) << 16);
                p1.z = (unsigned)f2bf(f1.x) | ((unsigned)f2bf(f1.y) << 16);
                p1.w = (unsigned)f2bf(f1.z) | ((unsigned)f2bf(f1.w) << 16);
            }
            *(uint4*)&As[r0 * LS + c0] = p0;
            *(uint4*)&As[r1 * LS + c1] = p1;
        } else {
            *(uint4*)&As[r0 * LS + c0] = *(const uint4*)&Ab[(long long)(row0 + r0) * K + k0 + c0];
            *(uint4*)&As[r1 * LS + c1] = *(const uint4*)&Ab[(long long)(row0 + r1) * K + k0 + c1];
        }
        *(uint4*)&Bs[r0 * LS + c0] = *(const uint4*)&BT[(long long)(col0 + r0) * K + k0 + c0];
        *(uint4*)&Bs[r1 * LS + c1] = *(const uint4*)&BT[(long long)(col0 + r1) * K + k0 + c1];
        __syncthreads();
        short8 af[4], bf[4];
        #pragma unroll
        for (int i = 0; i < 4; i++) {
            af[i] = *(const short8*)&As[(wm + i * 16 + mrow) * LS + quad * 8];
            bf[i] = *(const short8*)&Bs[(wn + i * 16 + mrow) * LS + quad * 8];
        }
        #pragma unroll
        for (int mi = 0; mi < 4; mi++)
            #pragma unroll
            for (int ni = 0; ni < 4; ni++)
                acc[mi][ni] = __builtin_amdgcn_mfma_f32_16x16x32_bf16(af[mi], bf[ni],
                                                                      acc[mi][ni], 0, 0, 0);
        __syncthreads();
    }

    // ---- attention scores (wave's 64-col span == one head) ----
    int head = blockIdx.x * 2 + (w & 1);
    float ats[4], atd[4];
    #pragma unroll
    for (int ni = 0; ni < 4; ni++) {
        ats[ni] = att_src[head * 64 + ni * 16 + mrow];
        atd[ni] = att_dst[head * 64 + ni * 16 + mrow];
    }
    #pragma unroll
    for (int mi = 0; mi < 4; mi++) {
        #pragma unroll
        for (int r = 0; r < 4; r++) {
            int row = row0 + wm + mi * 16 + quad * 4 + r;
            float ps = 0.f, pd = 0.f;
            #pragma unroll
            for (int ni = 0; ni < 4; ni++) {
                float v = acc[mi][ni][r];
                ps += v * ats[ni];
                pd += v * atd[ni];
            }
            #pragma unroll
            for (int off = 1; off < 16; off <<= 1) {
                ps += __shfl_xor(ps, off);
                pd += __shfl_xor(pd, off);
            }
            if (mrow == 0 && row < N_NODES) {
                a_s[row * 4 + head] = ps;
                a_d[row * 4 + head] = pd;
            }
        }
    }

    // ---- repack C tile through LDS, coalesced uint4 stores ----
    #pragma unroll
    for (int mi = 0; mi < 4; mi++)
        #pragma unroll
        for (int ni = 0; ni < 4; ni++)
            #pragma unroll
            for (int r = 0; r < 4; r++)
                smem[(wm + mi * 16 + quad * 4 + r) * CS + wn + ni * 16 + mrow] =
                    f2bf(acc[mi][ni][r]);
    __syncthreads();
    {
        int r2 = t >> 1, half = t & 1;
        const unsigned short* sp = &smem[r2 * CS + half * 64];
        unsigned short* dp = &h16[(long long)(row0 + r2) * FEAT + col0 + half * 64];
        #pragma unroll
        for (int k = 0; k < 8; k++)
            ((uint4*)dp)[k] = ((const uint4*)sp)[k];
    }
}

// both weights transposed in one launch
__global__ void cvt_w_both(const float* __restrict__ W1, const float* __restrict__ W2,
                           unsigned short* __restrict__ W1T, unsigned short* __restrict__ W2T) {
    int i = blockIdx.x * 256 + threadIdx.x;
    if (i < F_IN * 256) {
        int k = i >> 8, n = i & 255;
        W1T[n * F_IN + k] = f2bf(W1[i]);
    }
    int j = i - F_IN * 256;
    if (j >= 0 && j < FEAT * 256) {
        int k = j >> 8, n = j & 255;
        W2T[n * FEAT + k] = f2bf(W2[j]);
    }
}

// ================= CSR build =================
__global__ void degree_count(const int* __restrict__ src, const int* __restrict__ dst,
                             int* __restrict__ deg, int* __restrict__ epos) {
    int e = blockIdx.x * blockDim.x + threadIdx.x;
    if (e >= N_EDGES + N_NODES) return;
    int d = (e < N_EDGES) ? dst[e] : (e - N_EDGES);
    epos[e] = atomicAdd(&deg[d], 1);
}

__global__ __launch_bounds__(256) void scan_k1(const int* __restrict__ deg,
                                               int* __restrict__ bsum) {
    int b = blockIdx.x, t = threadIdx.x;
    int i = b * 256 + t;
    int v = (i < N_NODES) ? deg[i] : 0;
    #pragma unroll
    for (int off = 32; off > 0; off >>= 1) v += __shfl_down(v, off);
    __shared__ int ws[4];
    if ((t & 63) == 0) ws[t >> 6] = v;
    __syncthreads();
    if (t == 0) bsum[b] = ws[0] + ws[1] + ws[2] + ws[3];
}

__global__ __launch_bounds__(256) void scan_k2(const int* __restrict__ bsum,
                                               int* __restrict__ boff,
                                               int* __restrict__ row_start) {
    int t = threadIdx.x;
    int lane = t & 63, wid = t >> 6;
    int v = (t < NCHUNK) ? bsum[t] : 0;
    int x = v;
    #pragma unroll
    for (int off = 1; off < 64; off <<= 1) {
        int y = __shfl_up(x, off);
        if (lane >= off) x += y;
    }
    __shared__ int wsum[4], woff[4];
    if (lane == 63) wsum[wid] = x;
    __syncthreads();
    if (t == 0) {
        int s = 0;
        #pragma unroll
        for (int w = 0; w < 4; w++) { int tw = wsum[w]; woff[w] = s; s += tw; }
        row_start[N_NODES] = s;
    }
    __syncthreads();
    if (t < NCHUNK) boff[t] = x - v + woff[wid];
}

__global__ __launch_bounds__(256) void scan_k3(const int* __restrict__ deg,
                                               const int* __restrict__ boff,
                                               int* __restrict__ row_start) {
    int b = blockIdx.x, t = threadIdx.x;
    int lane = t & 63, wid = t >> 6;
    int i = b * 256 + t;
    int v = (i < N_NODES) ? deg[i] : 0;
    int x = v;
    #pragma unroll
    for (int off = 1; off < 64; off <<= 1) {
        int y = __shfl_up(x, off);
        if (lane >= off) x += y;
    }
    __shared__ int wsum[4], woff[4];
    if (lane == 63) wsum[wid] = x;
    __syncthreads();
    if (t == 0) {
        int s = boff[b];
        #pragma unroll
        for (int w = 0; w < 4; w++) { int tw = wsum[w]; woff[w] = s; s += tw; }
    }
    __syncthreads();
    if (i < N_NODES) row_start[i] = x - v + woff[wid];
}

__global__ void scatter_edges(const int* __restrict__ src, const int* __restrict__ dst,
                              const int* __restrict__ row_start, const int* __restrict__ epos,
                              int* __restrict__ csr_src) {
    int e = blockIdx.x * blockDim.x + threadIdx.x;
    if (e >= N_EDGES + N_NODES) return;
    int s, d;
    if (e < N_EDGES) { s = src[e]; d = dst[e]; } else { s = d = e - N_EDGES; }
    csr_src[row_start[d] + epos[e]] = s;
}

// ===== fused GAT, wave-per-node; uniform uint2 gather, 4 rows in flight =====
template<bool WRITE_F32, bool WRITE_BF16>
__global__ __launch_bounds__(256) void gat_fused(
    const int* __restrict__ row_start, const int* __restrict__ csr_src,
    const float* __restrict__ a_s, const float* __restrict__ a_d,
    const unsigned short* __restrict__ h16, const float* __restrict__ bias,
    const float* __restrict__ g, const float* __restrict__ be,
    const float* __restrict__ rm, const float* __restrict__ rv,
    float* __restrict__ out, unsigned short* __restrict__ out16) {
    int t = threadIdx.x;
    int lane = t & 63;
    int w = t >> 6;
    int hd = lane >> 4;                       // head for this lane's 4 channels
    int d = blockIdx.x * 4 + w;               // node handled by this wave

    __shared__ float p_lds[4 * WCAP * 4];     // [wave][edge][head]
    __shared__ int   o_lds[4 * WCAP];         // [wave][edge] : src*64 (uint2 units)
    float* pw = &p_lds[w * WCAP * 4];
    int*   ow = &o_lds[w * WCAP];

    const uint2* __restrict__ H2 = (const uint2*)h16;

    int rs = row_start[d], re = row_start[d + 1];
    int deg = re - rs;
    float4 ad4 = *(const float4*)&a_d[d * 4];

    float m_old[4] = {-INFINITY, -INFINITY, -INFINITY, -INFINITY};
    float l_run[4] = {0.f, 0.f, 0.f, 0.f};
    float4 acc = make_float4(0.f, 0.f, 0.f, 0.f);

    for (int base = 0; base < deg; base += WCAP) {
        int cl = min(WCAP, deg - base);
        float lg[4] = {-INFINITY, -INFINITY, -INFINITY, -INFINITY};
        if (lane < cl) {
            int s = csr_src[rs + base + lane];
            ow[lane] = s * 64;
            float4 as4 = *(const float4*)&a_s[s * 4];
            float e0 = as4.x + ad4.x; lg[0] = e0 > 0.f ? e0 : SLOPE * e0;
            float e1 = as4.y + ad4.y; lg[1] = e1 > 0.f ? e1 : SLOPE * e1;
            float e2 = as4.z + ad4.z; lg[2] = e2 > 0.f ? e2 : SLOPE * e2;
            float e3 = as4.w + ad4.w; lg[3] = e3 > 0.f ? e3 : SLOPE * e3;
        }
        float m_new[4], alpha[4];
        #pragma unroll
        for (int h = 0; h < 4; h++) {
            float mm = lg[h];
            #pragma unroll
            for (int off = 1; off < 64; off <<= 1) mm = fmaxf(mm, __shfl_xor(mm, off));
            m_new[h] = fmaxf(m_old[h], mm);
            alpha[h] = __expf(m_old[h] - m_new[h]);   // 0 on first chunk
            m_old[h] = m_new[h];
        }
        float pv[4];
        #pragma unroll
        for (int h = 0; h < 4; h++)
            pv[h] = (lane < cl) ? __expf(lg[h] - m_new[h]) : 0.f;
        if (lane < cl) {
            float4 pq; pq.x = pv[0]; pq.y = pv[1]; pq.z = pv[2]; pq.w = pv[3];
            *(float4*)&pw[lane * 4] = pq;
        }
        #pragma unroll
        for (int h = 0; h < 4; h++) {
            float cs = pv[h];
            #pragma unroll
            for (int off = 1; off < 64; off <<= 1) cs += __shfl_xor(cs, off);
            l_run[h] = l_run[h] * alpha[h] + cs;
        }
        float al = hd < 2 ? (hd == 0 ? alpha[0] : alpha[1])
                          : (hd == 2 ? alpha[2] : alpha[3]);
        acc.x *= al; acc.y *= al; acc.z *= al; acc.w *= al;
        // gather: 4 independent row loads in flight per iteration
        int e = 0;
        for (; e + 3 < cl; e += 4) {
            int oA = ow[e], oB = ow[e + 1], oC = ow[e + 2], oD = ow[e + 3];
            float pA = pw[e * 4 + hd];
            float pB = pw[(e + 1) * 4 + hd];
            float pC = pw[(e + 2) * 4 + hd];
            float pD = pw[(e + 3) * 4 + hd];
            uint2 hA = H2[oA + lane];
            uint2 hB = H2[oB + lane];
            uint2 hC = H2[oC + lane];
            uint2 hD = H2[oD + lane];
            acc.x += pA * __uint_as_float(hA.x << 16);
            acc.y += pA * __uint_as_float(hA.x & 0xffff0000u);
            acc.z += pA * __uint_as_float(hA.y << 16);
            acc.w += pA * __uint_as_float(hA.y & 0xffff0000u);
            acc.x += pB * __uint_as_float(hB.x << 16);
            acc.y += pB * __uint_as_float(hB.x & 0xffff0000u);
            acc.z += pB * __uint_as_float(hB.y << 16);
            acc.w += pB * __uint_as_float(hB.y & 0xffff0000u);
            acc.x += pC * __uint_as_float(hC.x << 16);
            acc.y += pC * __uint_as_float(hC.x & 0xffff0000u);
            acc.z += pC * __uint_as_float(hC.y << 16);
            acc.w += pC * __uint_as_float(hC.y & 0xffff0000u);
            acc.x += pD * __uint_as_float(hD.x << 16);
            acc.y += pD * __uint_as_float(hD.x & 0xffff0000u);
            acc.z += pD * __uint_as_float(hD.y << 16);
            acc.w += pD * __uint_as_float(hD.y & 0xffff0000u);
        }
        for (; e < cl; e++) {
            int oA = ow[e];
            float pA = pw[e * 4 + hd];
            uint2 hA = H2[oA + lane];
            acc.x += pA * __uint_as_float(hA.x << 16);
            acc.y += pA * __uint_as_float(hA.x & 0xffff0000u);
            acc.z += pA * __uint_as_float(hA.y << 16);
            acc.w += pA * __uint_as_float(hA.y & 0xffff0000u);
        }
    }
    float denom = hd < 2 ? (hd == 0 ? l_run[0] : l_run[1])
                         : (hd == 2 ? l_run[2] : l_run[3]);
    float inv = 1.f / denom;
    int c0 = lane * 4;
    float4 bi = *(const float4*)&bias[c0];
    float4 gg = *(const float4*)&g[c0];
    float4 bb = *(const float4*)&be[c0];
    float4 mm = *(const float4*)&rm[c0];
    float4 vv = *(const float4*)&rv[c0];
    float v0 = fmaxf(acc.x * inv + bi.x, 0.f);
    float v1 = fmaxf(acc.y * inv + bi.y, 0.f);
    float v2 = fmaxf(acc.z * inv + bi.z, 0.f);
    float v3 = fmaxf(acc.w * inv + bi.w, 0.f);
    v0 = (v0 - mm.x) * rsqrtf(vv.x + BN_EPS) * gg.x + bb.x;
    v1 = (v1 - mm.y) * rsqrtf(vv.y + BN_EPS) * gg.y + bb.y;
    v2 = (v2 - mm.z) * rsqrtf(vv.z + BN_EPS) * gg.z + bb.z;
    v3 = (v3 - mm.w) * rsqrtf(vv.w + BN_EPS) * gg.w + bb.w;
    if (WRITE_F32) {
        floatx4 o = {v0, v1, v2, v3};
        __builtin_nontemporal_store(o, (floatx4*)&out[(long long)d * FEAT + c0]);
    }
    if (WRITE_BF16) {
        unsigned long long o =
            (unsigned long long)f2bf(v0) |
            ((unsigned long long)f2bf(v1) << 16) |
            ((unsigned long long)f2bf(v2) << 32) |
            ((unsigned long long)f2bf(v3) << 48);
        __builtin_nontemporal_store(o, (unsigned long long*)&out16[(long long)d * FEAT + c0]);
    }
}

// ===== fused head: mean-pool + relu(pooled@lw1+lb1) @ lw2 + lb2 =====
__global__ __launch_bounds__(256) void head_fused(
    const float* __restrict__ h, const int* __restrict__ batch,
    const float* __restrict__ lw1, const float* __restrict__ lb1,
    const float* __restrict__ lw2, const float* __restrict__ lb2,
    float* __restrict__ out) {
    int gph = blockIdx.x;
    int t = threadIdx.x;
    __shared__ float pooled[FEAT];
    __shared__ float zl[OUT_DIM];
    __shared__ int lo_s, hi_s;
    if (t == 0) {
        int lo = 0, hi = N_NODES;
        while (lo < hi) { int mid = (lo + hi) >> 1; if (batch[mid] < gph) lo = mid + 1; else hi = mid; }
        lo_s = lo;
        int lo2 = 0, hi2 = N_NODES;
        while (lo2 < hi2) { int mid = (lo2 + hi2) >> 1; if (batch[mid] < gph + 1) lo2 = mid + 1; else hi2 = mid; }
        hi_s = lo2;
    }
    __syncthreads();
    int lo = lo_s, hi = hi_s;
    float a0 = 0.f, a1 = 0.f, a2 = 0.f, a3 = 0.f;
    int n = lo;
    for (; n + 3 < hi; n += 4) {
        a0 += h[(long long)n * FEAT + t];
        a1 += h[(long long)(n + 1) * FEAT + t];
        a2 += h[(long long)(n + 2) * FEAT + t];
        a3 += h[(long long)(n + 3) * FEAT + t];
    }
    for (; n < hi; n++) a0 += h[(long long)n * FEAT + t];
    float cnt = fmaxf((float)(hi - lo), 1.f);
    pooled[t] = (a0 + a1 + a2 + a3) / cnt;
    __syncthreads();
    int j = t >> 1, kh = t & 1;
    float zp = 0.f;
    #pragma unroll 8
    for (int k = kh * 128; k < kh * 128 + 128; k++)
        zp += pooled[k] * lw1[k * OUT_DIM + j];
    zp += __shfl_xor(zp, 1);
    if (kh == 0) zl[j] = fmaxf(zp + lb1[j], 0.f);
    __syncthreads();
    int w = t >> 6, lane = t & 63;
    if (w < 2) {
        float p = zl[lane] * lw2[lane * 2 + w] + zl[lane + 64] * lw2[(lane + 64) * 2 + w];
        #pragma unroll
        for (int off = 1; off < 64; off <<= 1) p += __shfl_xor(p, off);
        if (lane == 0) out[gph * 2 + w] = p + lb2[w];
    }
}

extern "C" void kernel_launch(void* const* d_in, const int* in_sizes, int n_in,
                              void* d_out, int out_size, void* d_ws, size_t ws_size,
                              hipStream_t stream) {
    const float* x       = (const float*)d_in[0];
    const int*   ei      = (const int*)d_in[1];
    const int*   batch   = (const int*)d_in[2];
    const float* W1      = (const float*)d_in[3];
    const float* att_s1  = (const float*)d_in[4];
    const float* att_d1  = (const float*)d_in[5];
    const float* b1      = (const float*)d_in[6];
    const float* g1      = (const float*)d_in[7];
    const float* be1     = (const float*)d_in[8];
    const float* rm1     = (const float*)d_in[9];
    const float* rv1     = (const float*)d_in[10];
    const float* W2      = (const float*)d_in[11];
    const float* att_s2  = (const float*)d_in[12];
    const float* att_d2  = (const float*)d_in[13];
    const float* b2      = (const float*)d_in[14];
    const float* g2      = (const float*)d_in[15];
    const float* be2     = (const float*)d_in[16];
    const float* rm2     = (const float*)d_in[17];
    const float* rv2     = (const float*)d_in[18];
    const float* lw1     = (const float*)d_in[19];
    const float* lb1     = (const float*)d_in[20];
    const float* lw2     = (const float*)d_in[21];
    const float* lb2     = (const float*)d_in[22];
    float* out           = (float*)d_out;

    const int* src = ei;
    const int* dst = ei + N_EDGES;

    char* p = (char*)d_ws;
    auto carve = [&p](size_t bytes) -> void* {
        void* r = (void*)p;
        p += (bytes + 63) & ~(size_t)63;
        return r;
    };
    float* bufB   = (float*)carve(sizeof(float) * (size_t)N_NODES * FEAT);
    float* a_s    = (float*)carve(sizeof(float) * N_NODES * HEADS);
    float* a_d    = (float*)carve(sizeof(float) * N_NODES * HEADS);
    int*   deg    = (int*)carve(sizeof(int) * N_NODES);
    int*   epos   = (int*)carve(sizeof(int) * (N_EDGES + N_NODES));
    int*   csr    = (int*)carve(sizeof(int) * (N_EDGES + N_NODES));
    int*   rstart = (int*)carve(sizeof(int) * (N_NODES + 4));
    int*   bsum   = (int*)carve(sizeof(int) * 256);
    int*   boff   = (int*)carve(sizeof(int) * 256);
    unsigned short* h16  = (unsigned short*)carve(sizeof(short) * (size_t)M_PAD * FEAT);
    unsigned short* h1bf = (unsigned short*)carve(sizeof(short) * (size_t)M_PAD * FEAT);
    unsigned short* w1t  = (unsigned short*)carve(sizeof(short) * FEAT * F_IN);
    unsigned short* w2t  = (unsigned short*)carve(sizeof(short) * FEAT * FEAT);

    const int Et = N_EDGES + N_NODES;

    // ---- converts / pad zeroing ----
    cvt_w_both<<<((F_IN + FEAT) * 256 + 255) / 256, 256, 0, stream>>>(W1, W2, w1t, w2t);
    (void)hipMemsetAsync(h1bf + (size_t)N_NODES * FEAT, 0,
                         sizeof(short) * (size_t)(M_PAD - N_NODES) * FEAT, stream);

    // ---- CSR build ----
    (void)hipMemsetAsync(deg, 0, sizeof(int) * N_NODES, stream);
    degree_count<<<(Et + 255) / 256, 256, 0, stream>>>(src, dst, deg, epos);
    scan_k1<<<NCHUNK, 256, 0, stream>>>(deg, bsum);
    scan_k2<<<1, 256, 0, stream>>>(bsum, boff, rstart);
    scan_k3<<<NCHUNK, 256, 0, stream>>>(deg, boff, rstart);
    scatter_edges<<<(Et + 255) / 256, 256, 0, stream>>>(src, dst, rstart, epos, csr);

    // ---- Layer 1 (A = fp32 x, converted in staging) ----
    {
        dim3 grid(FEAT / 128, M_PAD / 128);
        gemm_mfma_gat<true><<<grid, 256, 0, stream>>>(x, w1t, att_s1, att_d1,
                                                      h16, a_s, a_d, F_IN);
    }
    gat_fused<false, true><<<N_NODES / 4, 256, 0, stream>>>(rstart, csr, a_s, a_d, h16,
                                                            b1, g1, be1, rm1, rv1,
                                                            nullptr, h1bf);

    // ---- Layer 2 ----
    {
        dim3 grid(FEAT / 128, M_PAD / 128);
        gemm_mfma_gat<false><<<grid, 256, 0, stream>>>(h1bf, w2t, att_s2, att_d2,
                                                       h16, a_s, a_d, FEAT);
    }
    gat_fused<true, false><<<N_NODES / 4, 256, 0, stream>>>(rstart, csr, a_s, a_d, h16,
                                                            b2, g2, be2, rm2, rv2,
                                                            bufB, nullptr);

    // ---- fused head ----
    head_fused<<<NG, 256, 0, stream>>>(bufB, batch, lw1, lb1, lw2, lb2, out);
}

// Round 12
// 417.784 us; speedup vs baseline: 5.3280x; 1.0209x over previous
//
#include <hip/hip_runtime.h>
#include <hip/hip_bf16.h>
#include <math.h>

#define N_NODES 50000
#define M_PAD   50048                    // 391 * 128
#define N_EDGES 800000
#define F_IN 128
#define HID 64
#define HEADS 4
#define FEAT 256        // HEADS*HID
#define OUT_DIM 128
#define N_CLS 2
#define NG 500
#define SLOPE 0.2f
#define BN_EPS 1e-5f
#define WCAP 64          // edges per chunk per wave in gat_fused
#define NCHUNK ((N_NODES + 255) / 256)

typedef __attribute__((ext_vector_type(8))) short short8;
typedef __attribute__((ext_vector_type(4))) float floatx4;

__device__ inline unsigned short f2bf(float f) {
    unsigned int u = __float_as_uint(f);
    unsigned int lsb = (u >> 16) & 1u;
    return (unsigned short)((u + 0x7fffu + lsb) >> 16);
}

// ==== bf16 MFMA GEMM fused with GAT prologue ====
// C = A[Mpad,K] @ BT[256,K]^T. A is bf16 (AF32=false) or fp32 with N_NODES
// valid rows (AF32=true, converted in staging). Writes bf16 h16[Mpad,256]
// (coalesced via LDS repack) + fp32 a_s/a_d[N,4] from fp32 accumulators.
template<bool AF32>
__global__ __launch_bounds__(256) void gemm_mfma_gat(
    const void* __restrict__ Av, const unsigned short* __restrict__ BT,
    const float* __restrict__ att_src, const float* __restrict__ att_dst,
    unsigned short* __restrict__ h16, float* __restrict__ a_s,
    float* __restrict__ a_d, int K) {
    constexpr int LS = 40;     // staging row stride (bf16)
    constexpr int CS = 132;    // C-repack row stride (bf16)
    __shared__ unsigned short smem[128 * CS];
    unsigned short* As = smem;
    unsigned short* Bs = smem + 128 * LS;
    int t = threadIdx.x;
    int lane = t & 63, w = t >> 6;
    int wm = (w >> 1) * 64, wn = (w & 1) * 64;
    int row0 = blockIdx.y * 128, col0 = blockIdx.x * 128;

    floatx4 acc[4][4] = {};

    int r0 = t >> 2,            c0 = (t & 3) * 8;
    int r1 = (t + 256) >> 2,    c1 = ((t + 256) & 3) * 8;
    int mrow = lane & 15, quad = lane >> 4;

    const unsigned short* Ab = (const unsigned short*)Av;
    const float* Af = (const float*)Av;

    for (int k0 = 0; k0 < K; k0 += 32) {
        if (AF32) {
            uint4 p0 = make_uint4(0, 0, 0, 0), p1 = p0;
            if (row0 + r0 < N_NODES) {
                float4 f0 = *(const float4*)&Af[(long long)(row0 + r0) * K + k0 + c0];
                float4 f1 = *(const float4*)&Af[(long long)(row0 + r0) * K + k0 + c0 + 4];
                p0.x = (unsigned)f2bf(f0.x) | ((unsigned)f2bf(f0.y) << 16);
                p0.y = (unsigned)f2bf(f0.z) | ((unsigned)f2bf(f0.w) << 16);
                p0.z = (unsigned)f2bf(f1.x) | ((unsigned)f2bf(f1.y) << 16);
                p0.w = (unsigned)f2bf(f1.z) | ((unsigned)f2bf(f1.w) << 16);
            }
            if (row0 + r1 < N_NODES) {
                float4 f0 = *(const float4*)&Af[(long long)(row0 + r1) * K + k0 + c1];
                float4 f1 = *(const float4*)&Af[(long long)(row0 + r1) * K + k0 + c1 + 4];
                p1.x = (unsigned)f2bf(f0.x) | ((unsigned)f2bf(f0.y) << 16);
                p1.y = (unsigned)f2bf(f0.z) | ((unsigned)f2bf(f0.w) << 16);
                p1.z = (unsigned)f2bf(f1.x) | ((unsigned)f2bf(f1.y) << 16);
                p1.w = (unsigned)f2bf(f1.z) | ((unsigned)f2bf(f1.w) << 16);
            }
            *(uint4*)&As[r0 * LS + c0] = p0;
            *(uint4*)&As[r1 * LS + c1] = p1;
        } else {
            *(uint4*)&As[r0 * LS + c0] = *(const uint4*)&Ab[(long long)(row0 + r0) * K + k0 + c0];
            *(uint4*)&As[r1 * LS + c1] = *(const uint4*)&Ab[(long long)(row0 + r1) * K + k0 + c1];
        }
        *(uint4*)&Bs[r0 * LS + c0] = *(const uint4*)&BT[(long long)(col0 + r0) * K + k0 + c0];
        *(uint4*)&Bs[r1 * LS + c1] = *(const uint4*)&BT[(long long)(col0 + r1) * K + k0 + c1];
        __syncthreads();
        short8 af[4], bf[4];
        #pragma unroll
        for (int i = 0; i < 4; i++) {
            af[i] = *(const short8*)&As[(wm + i * 16 + mrow) * LS + quad * 8];
            bf[i] = *(const short8*)&Bs[(wn + i * 16 + mrow) * LS + quad * 8];
        }
        #pragma unroll
        for (int mi = 0; mi < 4; mi++)
            #pragma unroll
            for (int ni = 0; ni < 4; ni++)
                acc[mi][ni] = __builtin_amdgcn_mfma_f32_16x16x32_bf16(af[mi], bf[ni],
                                                                      acc[mi][ni], 0, 0, 0);
        __syncthreads();
    }

    // ---- attention scores (wave's 64-col span == one head) ----
    int head = blockIdx.x * 2 + (w & 1);
    float ats[4], atd[4];
    #pragma unroll
    for (int ni = 0; ni < 4; ni++) {
        ats[ni] = att_src[head * 64 + ni * 16 + mrow];
        atd[ni] = att_dst[head * 64 + ni * 16 + mrow];
    }
    #pragma unroll
    for (int mi = 0; mi < 4; mi++) {
        #pragma unroll
        for (int r = 0; r < 4; r++) {
            int row = row0 + wm + mi * 16 + quad * 4 + r;
            float ps = 0.f, pd = 0.f;
            #pragma unroll
            for (int ni = 0; ni < 4; ni++) {
                float v = acc[mi][ni][r];
                ps += v * ats[ni];
                pd += v * atd[ni];
            }
            #pragma unroll
            for (int off = 1; off < 16; off <<= 1) {
                ps += __shfl_xor(ps, off);
                pd += __shfl_xor(pd, off);
            }
            if (mrow == 0 && row < N_NODES) {
                a_s[row * 4 + head] = ps;
                a_d[row * 4 + head] = pd;
            }
        }
    }

    // ---- repack C tile through LDS, coalesced uint4 stores ----
    #pragma unroll
    for (int mi = 0; mi < 4; mi++)
        #pragma unroll
        for (int ni = 0; ni < 4; ni++)
            #pragma unroll
            for (int r = 0; r < 4; r++)
                smem[(wm + mi * 16 + quad * 4 + r) * CS + wn + ni * 16 + mrow] =
                    f2bf(acc[mi][ni][r]);
    __syncthreads();
    {
        int r2 = t >> 1, half = t & 1;
        const unsigned short* sp = &smem[r2 * CS + half * 64];
        unsigned short* dp = &h16[(long long)(row0 + r2) * FEAT + col0 + half * 64];
        #pragma unroll
        for (int k = 0; k < 8; k++)
            ((uint4*)dp)[k] = ((const uint4*)sp)[k];
    }
}

// both weights transposed in one launch
__global__ void cvt_w_both(const float* __restrict__ W1, const float* __restrict__ W2,
                           unsigned short* __restrict__ W1T, unsigned short* __restrict__ W2T) {
    int i = blockIdx.x * 256 + threadIdx.x;
    if (i < F_IN * 256) {
        int k = i >> 8, n = i & 255;
        W1T[n * F_IN + k] = f2bf(W1[i]);
    }
    int j = i - F_IN * 256;
    if (j >= 0 && j < FEAT * 256) {
        int k = j >> 8, n = j & 255;
        W2T[n * FEAT + k] = f2bf(W2[j]);
    }
}

// ================= CSR build =================
__global__ void degree_count(const int* __restrict__ src, const int* __restrict__ dst,
                             int* __restrict__ deg, int* __restrict__ epos) {
    int e = blockIdx.x * blockDim.x + threadIdx.x;
    if (e >= N_EDGES + N_NODES) return;
    int d = (e < N_EDGES) ? dst[e] : (e - N_EDGES);
    epos[e] = atomicAdd(&deg[d], 1);
}

__global__ __launch_bounds__(256) void scan_k1(const int* __restrict__ deg,
                                               int* __restrict__ bsum) {
    int b = blockIdx.x, t = threadIdx.x;
    int i = b * 256 + t;
    int v = (i < N_NODES) ? deg[i] : 0;
    #pragma unroll
    for (int off = 32; off > 0; off >>= 1) v += __shfl_down(v, off);
    __shared__ int ws[4];
    if ((t & 63) == 0) ws[t >> 6] = v;
    __syncthreads();
    if (t == 0) bsum[b] = ws[0] + ws[1] + ws[2] + ws[3];
}

__global__ __launch_bounds__(256) void scan_k2(const int* __restrict__ bsum,
                                               int* __restrict__ boff,
                                               int* __restrict__ row_start) {
    int t = threadIdx.x;
    int lane = t & 63, wid = t >> 6;
    int v = (t < NCHUNK) ? bsum[t] : 0;
    int x = v;
    #pragma unroll
    for (int off = 1; off < 64; off <<= 1) {
        int y = __shfl_up(x, off);
        if (lane >= off) x += y;
    }
    __shared__ int wsum[4], woff[4];
    if (lane == 63) wsum[wid] = x;
    __syncthreads();
    if (t == 0) {
        int s = 0;
        #pragma unroll
        for (int w = 0; w < 4; w++) { int tw = wsum[w]; woff[w] = s; s += tw; }
        row_start[N_NODES] = s;
    }
    __syncthreads();
    if (t < NCHUNK) boff[t] = x - v + woff[wid];
}

__global__ __launch_bounds__(256) void scan_k3(const int* __restrict__ deg,
                                               const int* __restrict__ boff,
                                               int* __restrict__ row_start) {
    int b = blockIdx.x, t = threadIdx.x;
    int lane = t & 63, wid = t >> 6;
    int i = b * 256 + t;
    int v = (i < N_NODES) ? deg[i] : 0;
    int x = v;
    #pragma unroll
    for (int off = 1; off < 64; off <<= 1) {
        int y = __shfl_up(x, off);
        if (lane >= off) x += y;
    }
    __shared__ int wsum[4], woff[4];
    if (lane == 63) wsum[wid] = x;
    __syncthreads();
    if (t == 0) {
        int s = boff[b];
        #pragma unroll
        for (int w = 0; w < 4; w++) { int tw = wsum[w]; woff[w] = s; s += tw; }
    }
    __syncthreads();
    if (i < N_NODES) row_start[i] = x - v + woff[wid];
}

__global__ void scatter_edges(const int* __restrict__ src, const int* __restrict__ dst,
                              const int* __restrict__ row_start, const int* __restrict__ epos,
                              int* __restrict__ csr_src) {
    int e = blockIdx.x * blockDim.x + threadIdx.x;
    if (e >= N_EDGES + N_NODES) return;
    int s, d;
    if (e < N_EDGES) { s = src[e]; d = dst[e]; } else { s = d = e - N_EDGES; }
    csr_src[row_start[d] + epos[e]] = s;
}

// ===== fused GAT, wave-per-node; shared-max softmax, in-loop denominator =====
// bf16-only output.
__global__ __launch_bounds__(256) void gat_fused(
    const int* __restrict__ row_start, const int* __restrict__ csr_src,
    const float* __restrict__ a_s, const float* __restrict__ a_d,
    const unsigned short* __restrict__ h16, const float* __restrict__ bias,
    const float* __restrict__ g, const float* __restrict__ be,
    const float* __restrict__ rm, const float* __restrict__ rv,
    unsigned short* __restrict__ out16) {
    int t = threadIdx.x;
    int lane = t & 63;
    int w = t >> 6;
    int hd = lane >> 4;                       // head for this lane's 4 channels
    int d = blockIdx.x * 4 + w;               // node handled by this wave

    __shared__ float p_lds[4 * WCAP * 4];     // [wave][edge][head]
    __shared__ int   o_lds[4 * WCAP];         // [wave][edge] : src*64 (uint2 units)
    float* pw = &p_lds[w * WCAP * 4];
    int*   ow = &o_lds[w * WCAP];

    const uint2* __restrict__ H2 = (const uint2*)h16;

    int rs = row_start[d], re = row_start[d + 1];
    int deg = re - rs;
    float4 ad4 = *(const float4*)&a_d[d * 4];

    float m_old = -INFINITY;                  // shared max across heads (softmax
                                              // is shift-invariant => exact)
    float den = 0.f;                          // per-lane denominator for head hd
    float4 acc = make_float4(0.f, 0.f, 0.f, 0.f);

    for (int base = 0; base < deg; base += WCAP) {
        int cl = min(WCAP, deg - base);
        float lg[4] = {-INFINITY, -INFINITY, -INFINITY, -INFINITY};
        if (lane < cl) {
            int s = csr_src[rs + base + lane];
            ow[lane] = s * 64;
            float4 as4 = *(const float4*)&a_s[s * 4];
            float e0 = as4.x + ad4.x; lg[0] = e0 > 0.f ? e0 : SLOPE * e0;
            float e1 = as4.y + ad4.y; lg[1] = e1 > 0.f ? e1 : SLOPE * e1;
            float e2 = as4.z + ad4.z; lg[2] = e2 > 0.f ? e2 : SLOPE * e2;
            float e3 = as4.w + ad4.w; lg[3] = e3 > 0.f ? e3 : SLOPE * e3;
        }
        // single shared max over all heads & lanes
        float mm = fmaxf(fmaxf(lg[0], lg[1]), fmaxf(lg[2], lg[3]));
        #pragma unroll
        for (int off = 1; off < 64; off <<= 1) mm = fmaxf(mm, __shfl_xor(mm, off));
        float m_new = fmaxf(m_old, mm);
        float alpha = __expf(m_old - m_new);   // 0 on first chunk
        m_old = m_new;
        if (lane < cl) {
            float4 pq;
            pq.x = __expf(lg[0] - m_new);
            pq.y = __expf(lg[1] - m_new);
            pq.z = __expf(lg[2] - m_new);
            pq.w = __expf(lg[3] - m_new);
            *(float4*)&pw[lane * 4] = pq;
        }
        acc.x *= alpha; acc.y *= alpha; acc.z *= alpha; acc.w *= alpha;
        den *= alpha;
        // gather (2 rows in flight); denominator accumulated in-loop
        int e = 0;
        for (; e + 1 < cl; e += 2) {
            int oA = ow[e], oB = ow[e + 1];
            float pA = pw[e * 4 + hd], pB = pw[(e + 1) * 4 + hd];
            uint2 hA = H2[oA + lane];
            uint2 hB = H2[oB + lane];
            den += pA + pB;
            acc.x += pA * __uint_as_float(hA.x << 16);
            acc.y += pA * __uint_as_float(hA.x & 0xffff0000u);
            acc.z += pA * __uint_as_float(hA.y << 16);
            acc.w += pA * __uint_as_float(hA.y & 0xffff0000u);
            acc.x += pB * __uint_as_float(hB.x << 16);
            acc.y += pB * __uint_as_float(hB.x & 0xffff0000u);
            acc.z += pB * __uint_as_float(hB.y << 16);
            acc.w += pB * __uint_as_float(hB.y & 0xffff0000u);
        }
        if (e < cl) {
            int oA = ow[e];
            float pA = pw[e * 4 + hd];
            uint2 hA = H2[oA + lane];
            den += pA;
            acc.x += pA * __uint_as_float(hA.x << 16);
            acc.y += pA * __uint_as_float(hA.x & 0xffff0000u);
            acc.z += pA * __uint_as_float(hA.y << 16);
            acc.w += pA * __uint_as_float(hA.y & 0xffff0000u);
        }
    }
    float inv = 1.f / den;
    int c0 = lane * 4;
    float4 bi = *(const float4*)&bias[c0];
    float4 gg = *(const float4*)&g[c0];
    float4 bb = *(const float4*)&be[c0];
    float4 mm4 = *(const float4*)&rm[c0];
    float4 vv = *(const float4*)&rv[c0];
    float v0 = fmaxf(acc.x * inv + bi.x, 0.f);
    float v1 = fmaxf(acc.y * inv + bi.y, 0.f);
    float v2 = fmaxf(acc.z * inv + bi.z, 0.f);
    float v3 = fmaxf(acc.w * inv + bi.w, 0.f);
    v0 = (v0 - mm4.x) * rsqrtf(vv.x + BN_EPS) * gg.x + bb.x;
    v1 = (v1 - mm4.y) * rsqrtf(vv.y + BN_EPS) * gg.y + bb.y;
    v2 = (v2 - mm4.z) * rsqrtf(vv.z + BN_EPS) * gg.z + bb.z;
    v3 = (v3 - mm4.w) * rsqrtf(vv.w + BN_EPS) * gg.w + bb.w;
    unsigned long long o =
        (unsigned long long)f2bf(v0) |
        ((unsigned long long)f2bf(v1) << 16) |
        ((unsigned long long)f2bf(v2) << 32) |
        ((unsigned long long)f2bf(v3) << 48);
    __builtin_nontemporal_store(o, (unsigned long long*)&out16[(long long)d * FEAT + c0]);
}

// ===== fused head: mean-pool bf16 h2 + relu(pooled@lw1+lb1) @ lw2 + lb2 =====
__global__ __launch_bounds__(256) void head_fused(
    const unsigned short* __restrict__ h2, const int* __restrict__ batch,
    const float* __restrict__ lw1, const float* __restrict__ lb1,
    const float* __restrict__ lw2, const float* __restrict__ lb2,
    float* __restrict__ out) {
    int gph = blockIdx.x;
    int t = threadIdx.x;
    __shared__ float pooled[FEAT];
    __shared__ float zl[OUT_DIM];
    __shared__ int lo_s, hi_s;
    if (t == 0) {
        int lo = 0, hi = N_NODES;
        while (lo < hi) { int mid = (lo + hi) >> 1; if (batch[mid] < gph) lo = mid + 1; else hi = mid; }
        lo_s = lo;
        int lo2 = 0, hi2 = N_NODES;
        while (lo2 < hi2) { int mid = (lo2 + hi2) >> 1; if (batch[mid] < gph + 1) lo2 = mid + 1; else hi2 = mid; }
        hi_s = lo2;
    }
    __syncthreads();
    int lo = lo_s, hi = hi_s;
    float a0 = 0.f, a1 = 0.f, a2 = 0.f, a3 = 0.f;
    int n = lo;
    for (; n + 3 < hi; n += 4) {
        a0 += __uint_as_float((unsigned)h2[(long long)n * FEAT + t] << 16);
        a1 += __uint_as_float((unsigned)h2[(long long)(n + 1) * FEAT + t] << 16);
        a2 += __uint_as_float((unsigned)h2[(long long)(n + 2) * FEAT + t] << 16);
        a3 += __uint_as_float((unsigned)h2[(long long)(n + 3) * FEAT + t] << 16);
    }
    for (; n < hi; n++) a0 += __uint_as_float((unsigned)h2[(long long)n * FEAT + t] << 16);
    float cnt = fmaxf((float)(hi - lo), 1.f);
    pooled[t] = (a0 + a1 + a2 + a3) / cnt;
    __syncthreads();
    int j = t >> 1, kh = t & 1;
    float zp = 0.f;
    #pragma unroll 8
    for (int k = kh * 128; k < kh * 128 + 128; k++)
        zp += pooled[k] * lw1[k * OUT_DIM + j];
    zp += __shfl_xor(zp, 1);
    if (kh == 0) zl[j] = fmaxf(zp + lb1[j], 0.f);
    __syncthreads();
    int w = t >> 6, lane = t & 63;
    if (w < 2) {
        float p = zl[lane] * lw2[lane * 2 + w] + zl[lane + 64] * lw2[(lane + 64) * 2 + w];
        #pragma unroll
        for (int off = 1; off < 64; off <<= 1) p += __shfl_xor(p, off);
        if (lane == 0) out[gph * 2 + w] = p + lb2[w];
    }
}

extern "C" void kernel_launch(void* const* d_in, const int* in_sizes, int n_in,
                              void* d_out, int out_size, void* d_ws, size_t ws_size,
                              hipStream_t stream) {
    const float* x       = (const float*)d_in[0];
    const int*   ei      = (const int*)d_in[1];
    const int*   batch   = (const int*)d_in[2];
    const float* W1      = (const float*)d_in[3];
    const float* att_s1  = (const float*)d_in[4];
    const float* att_d1  = (const float*)d_in[5];
    const float* b1      = (const float*)d_in[6];
    const float* g1      = (const float*)d_in[7];
    const float* be1     = (const float*)d_in[8];
    const float* rm1     = (const float*)d_in[9];
    const float* rv1     = (const float*)d_in[10];
    const float* W2      = (const float*)d_in[11];
    const float* att_s2  = (const float*)d_in[12];
    const float* att_d2  = (const float*)d_in[13];
    const float* b2      = (const float*)d_in[14];
    const float* g2      = (const float*)d_in[15];
    const float* be2     = (const float*)d_in[16];
    const float* rm2     = (const float*)d_in[17];
    const float* rv2     = (const float*)d_in[18];
    const float* lw1     = (const float*)d_in[19];
    const float* lb1     = (const float*)d_in[20];
    const float* lw2     = (const float*)d_in[21];
    const float* lb2     = (const float*)d_in[22];
    float* out           = (float*)d_out;

    const int* src = ei;
    const int* dst = ei + N_EDGES;

    char* p = (char*)d_ws;
    auto carve = [&p](size_t bytes) -> void* {
        void* r = (void*)p;
        p += (bytes + 63) & ~(size_t)63;
        return r;
    };
    unsigned short* h2bf = (unsigned short*)carve(sizeof(short) * (size_t)N_NODES * FEAT);
    float* a_s    = (float*)carve(sizeof(float) * N_NODES * HEADS);
    float* a_d    = (float*)carve(sizeof(float) * N_NODES * HEADS);
    int*   deg    = (int*)carve(sizeof(int) * N_NODES);
    int*   epos   = (int*)carve(sizeof(int) * (N_EDGES + N_NODES));
    int*   csr    = (int*)carve(sizeof(int) * (N_EDGES + N_NODES));
    int*   rstart = (int*)carve(sizeof(int) * (N_NODES + 4));
    int*   bsum   = (int*)carve(sizeof(int) * 256);
    int*   boff   = (int*)carve(sizeof(int) * 256);
    unsigned short* h16  = (unsigned short*)carve(sizeof(short) * (size_t)M_PAD * FEAT);
    unsigned short* h1bf = (unsigned short*)carve(sizeof(short) * (size_t)M_PAD * FEAT);
    unsigned short* w1t  = (unsigned short*)carve(sizeof(short) * FEAT * F_IN);
    unsigned short* w2t  = (unsigned short*)carve(sizeof(short) * FEAT * FEAT);

    const int Et = N_EDGES + N_NODES;

    // ---- converts / pad zeroing ----
    cvt_w_both<<<((F_IN + FEAT) * 256 + 255) / 256, 256, 0, stream>>>(W1, W2, w1t, w2t);
    (void)hipMemsetAsync(h1bf + (size_t)N_NODES * FEAT, 0,
                         sizeof(short) * (size_t)(M_PAD - N_NODES) * FEAT, stream);

    // ---- CSR build ----
    (void)hipMemsetAsync(deg, 0, sizeof(int) * N_NODES, stream);
    degree_count<<<(Et + 255) / 256, 256, 0, stream>>>(src, dst, deg, epos);
    scan_k1<<<NCHUNK, 256, 0, stream>>>(deg, bsum);
    scan_k2<<<1, 256, 0, stream>>>(bsum, boff, rstart);
    scan_k3<<<NCHUNK, 256, 0, stream>>>(deg, boff, rstart);
    scatter_edges<<<(Et + 255) / 256, 256, 0, stream>>>(src, dst, rstart, epos, csr);

    // ---- Layer 1 (A = fp32 x, converted in staging) ----
    {
        dim3 grid(FEAT / 128, M_PAD / 128);
        gemm_mfma_gat<true><<<grid, 256, 0, stream>>>(x, w1t, att_s1, att_d1,
                                                      h16, a_s, a_d, F_IN);
    }
    gat_fused<<<N_NODES / 4, 256, 0, stream>>>(rstart, csr, a_s, a_d, h16,
                                               b1, g1, be1, rm1, rv1, h1bf);

    // ---- Layer 2 ----
    {
        dim3 grid(FEAT / 128, M_PAD / 128);
        gemm_mfma_gat<false><<<grid, 256, 0, stream>>>(h1bf, w2t, att_s2, att_d2,
                                                       h16, a_s, a_d, FEAT);
    }
    gat_fused<<<N_NODES / 4, 256, 0, stream>>>(rstart, csr, a_s, a_d, h16,
                                               b2, g2, be2, rm2, rv2, h2bf);

    // ---- fused head ----
    head_fused<<<NG, 256, 0, stream>>>(h2bf, batch, lw1, lb1, lw2, lb2, out);
}

// Round 13
// 358.393 us; speedup vs baseline: 6.2109x; 1.1657x over previous
//
#include <hip/hip_runtime.h>
#include <hip/hip_bf16.h>
#include <math.h>

#define N_NODES 50000
#define M_PAD   50048                    // 391 * 128
#define N_EDGES 800000
#define F_IN 128
#define HID 64
#define HEADS 4
#define FEAT 256        // HEADS*HID
#define OUT_DIM 128
#define N_CLS 2
#define NG 500
#define SLOPE 0.2f
#define BN_EPS 1e-5f
#define WCAP 64          // edges per chunk per wave in gat_fused
#define NCHUNK ((N_NODES + 255) / 256)

typedef __attribute__((ext_vector_type(8))) short short8;
typedef __attribute__((ext_vector_type(4))) float floatx4;

__device__ inline unsigned short f2bf(float f) {
    unsigned int u = __float_as_uint(f);
    unsigned int lsb = (u >> 16) & 1u;
    return (unsigned short)((u + 0x7fffu + lsb) >> 16);
}

// ==== bf16 MFMA GEMM fused with GAT prologue ====
// C = A[Mpad,K] @ BT[256,K]^T. A is bf16 (AF32=false) or fp32 with N_NODES
// valid rows (AF32=true, converted in staging). Writes fp8-e4m3 h8[Mpad,256]
// (gather source; coalesced via LDS repack) + fp32 a_s/a_d[N,4] from fp32
// accumulators.
template<bool AF32>
__global__ __launch_bounds__(256) void gemm_mfma_gat(
    const void* __restrict__ Av, const unsigned short* __restrict__ BT,
    const float* __restrict__ att_src, const float* __restrict__ att_dst,
    unsigned char* __restrict__ h8, float* __restrict__ a_s,
    float* __restrict__ a_d, int K) {
    constexpr int LS = 40;      // staging row stride (bf16)
    constexpr int C8 = 144;     // fp8 C-repack row stride (bytes, 16B-aligned)
    __shared__ unsigned short smem[128 * 132];   // 33792 B shared scratch
    unsigned short* As = smem;
    unsigned short* Bs = smem + 128 * LS;
    unsigned char*  s8 = (unsigned char*)smem;   // reused after last barrier
    int t = threadIdx.x;
    int lane = t & 63, w = t >> 6;
    int wm = (w >> 1) * 64, wn = (w & 1) * 64;
    int row0 = blockIdx.y * 128, col0 = blockIdx.x * 128;

    floatx4 acc[4][4] = {};

    int r0 = t >> 2,            c0 = (t & 3) * 8;
    int r1 = (t + 256) >> 2,    c1 = ((t + 256) & 3) * 8;
    int mrow = lane & 15, quad = lane >> 4;

    const unsigned short* Ab = (const unsigned short*)Av;
    const float* Af = (const float*)Av;

    for (int k0 = 0; k0 < K; k0 += 32) {
        if (AF32) {
            uint4 p0 = make_uint4(0, 0, 0, 0), p1 = p0;
            if (row0 + r0 < N_NODES) {
                float4 f0 = *(const float4*)&Af[(long long)(row0 + r0) * K + k0 + c0];
                float4 f1 = *(const float4*)&Af[(long long)(row0 + r0) * K + k0 + c0 + 4];
                p0.x = (unsigned)f2bf(f0.x) | ((unsigned)f2bf(f0.y) << 16);
                p0.y = (unsigned)f2bf(f0.z) | ((unsigned)f2bf(f0.w) << 16);
                p0.z = (unsigned)f2bf(f1.x) | ((unsigned)f2bf(f1.y) << 16);
                p0.w = (unsigned)f2bf(f1.z) | ((unsigned)f2bf(f1.w) << 16);
            }
            if (row0 + r1 < N_NODES) {
                float4 f0 = *(const float4*)&Af[(long long)(row0 + r1) * K + k0 + c1];
                float4 f1 = *(const float4*)&Af[(long long)(row0 + r1) * K + k0 + c1 + 4];
                p1.x = (unsigned)f2bf(f0.x) | ((unsigned)f2bf(f0.y) << 16);
                p1.y = (unsigned)f2bf(f0.z) | ((unsigned)f2bf(f0.w) << 16);
                p1.z = (unsigned)f2bf(f1.x) | ((unsigned)f2bf(f1.y) << 16);
                p1.w = (unsigned)f2bf(f1.z) | ((unsigned)f2bf(f1.w) << 16);
            }
            *(uint4*)&As[r0 * LS + c0] = p0;
            *(uint4*)&As[r1 * LS + c1] = p1;
        } else {
            *(uint4*)&As[r0 * LS + c0] = *(const uint4*)&Ab[(long long)(row0 + r0) * K + k0 + c0];
            *(uint4*)&As[r1 * LS + c1] = *(const uint4*)&Ab[(long long)(row0 + r1) * K + k0 + c1];
        }
        *(uint4*)&Bs[r0 * LS + c0] = *(const uint4*)&BT[(long long)(col0 + r0) * K + k0 + c0];
        *(uint4*)&Bs[r1 * LS + c1] = *(const uint4*)&BT[(long long)(col0 + r1) * K + k0 + c1];
        __syncthreads();
        short8 af[4], bf[4];
        #pragma unroll
        for (int i = 0; i < 4; i++) {
            af[i] = *(const short8*)&As[(wm + i * 16 + mrow) * LS + quad * 8];
            bf[i] = *(const short8*)&Bs[(wn + i * 16 + mrow) * LS + quad * 8];
        }
        #pragma unroll
        for (int mi = 0; mi < 4; mi++)
            #pragma unroll
            for (int ni = 0; ni < 4; ni++)
                acc[mi][ni] = __builtin_amdgcn_mfma_f32_16x16x32_bf16(af[mi], bf[ni],
                                                                      acc[mi][ni], 0, 0, 0);
        __syncthreads();
    }

    // ---- attention scores (wave's 64-col span == one head) ----
    int head = blockIdx.x * 2 + (w & 1);
    float ats[4], atd[4];
    #pragma unroll
    for (int ni = 0; ni < 4; ni++) {
        ats[ni] = att_src[head * 64 + ni * 16 + mrow];
        atd[ni] = att_dst[head * 64 + ni * 16 + mrow];
    }
    #pragma unroll
    for (int mi = 0; mi < 4; mi++) {
        #pragma unroll
        for (int r = 0; r < 4; r++) {
            int row = row0 + wm + mi * 16 + quad * 4 + r;
            float ps = 0.f, pd = 0.f;
            #pragma unroll
            for (int ni = 0; ni < 4; ni++) {
                float v = acc[mi][ni][r];
                ps += v * ats[ni];
                pd += v * atd[ni];
            }
            #pragma unroll
            for (int off = 1; off < 16; off <<= 1) {
                ps += __shfl_xor(ps, off);
                pd += __shfl_xor(pd, off);
            }
            if (mrow == 0 && row < N_NODES) {
                a_s[row * 4 + head] = ps;
                a_d[row * 4 + head] = pd;
            }
        }
    }

    // ---- repack C tile as fp8 through LDS, coalesced uint4 stores ----
    #pragma unroll
    for (int mi = 0; mi < 4; mi++)
        #pragma unroll
        for (int r = 0; r < 4; r++) {
            int row = wm + mi * 16 + quad * 4 + r;
            #pragma unroll
            for (int ni = 0; ni < 4; ni += 2) {
                int pk = __builtin_amdgcn_cvt_pk_fp8_f32(acc[mi][ni][r],
                                                         acc[mi][ni + 1][r], 0, false);
                s8[row * C8 + wn + ni * 16 + mrow]       = (unsigned char)(pk & 0xff);
                s8[row * C8 + wn + (ni + 1) * 16 + mrow] = (unsigned char)((pk >> 8) & 0xff);
            }
        }
    __syncthreads();
    {
        int r2 = t >> 1, half = t & 1;
        const uint4* sp = (const uint4*)&s8[r2 * C8 + half * 64];
        uint4* dp = (uint4*)&h8[(long long)(row0 + r2) * FEAT + col0 + half * 64];
        #pragma unroll
        for (int k = 0; k < 4; k++)
            dp[k] = sp[k];
    }
}

// both weights transposed in one launch
__global__ void cvt_w_both(const float* __restrict__ W1, const float* __restrict__ W2,
                           unsigned short* __restrict__ W1T, unsigned short* __restrict__ W2T) {
    int i = blockIdx.x * 256 + threadIdx.x;
    if (i < F_IN * 256) {
        int k = i >> 8, n = i & 255;
        W1T[n * F_IN + k] = f2bf(W1[i]);
    }
    int j = i - F_IN * 256;
    if (j >= 0 && j < FEAT * 256) {
        int k = j >> 8, n = j & 255;
        W2T[n * FEAT + k] = f2bf(W2[j]);
    }
}

// ================= CSR build =================
__global__ void degree_count(const int* __restrict__ src, const int* __restrict__ dst,
                             int* __restrict__ deg, int* __restrict__ epos) {
    int e = blockIdx.x * blockDim.x + threadIdx.x;
    if (e >= N_EDGES + N_NODES) return;
    int d = (e < N_EDGES) ? dst[e] : (e - N_EDGES);
    epos[e] = atomicAdd(&deg[d], 1);
}

__global__ __launch_bounds__(256) void scan_k1(const int* __restrict__ deg,
                                               int* __restrict__ bsum) {
    int b = blockIdx.x, t = threadIdx.x;
    int i = b * 256 + t;
    int v = (i < N_NODES) ? deg[i] : 0;
    #pragma unroll
    for (int off = 32; off > 0; off >>= 1) v += __shfl_down(v, off);
    __shared__ int ws[4];
    if ((t & 63) == 0) ws[t >> 6] = v;
    __syncthreads();
    if (t == 0) bsum[b] = ws[0] + ws[1] + ws[2] + ws[3];
}

__global__ __launch_bounds__(256) void scan_k2(const int* __restrict__ bsum,
                                               int* __restrict__ boff,
                                               int* __restrict__ row_start) {
    int t = threadIdx.x;
    int lane = t & 63, wid = t >> 6;
    int v = (t < NCHUNK) ? bsum[t] : 0;
    int x = v;
    #pragma unroll
    for (int off = 1; off < 64; off <<= 1) {
        int y = __shfl_up(x, off);
        if (lane >= off) x += y;
    }
    __shared__ int wsum[4], woff[4];
    if (lane == 63) wsum[wid] = x;
    __syncthreads();
    if (t == 0) {
        int s = 0;
        #pragma unroll
        for (int w = 0; w < 4; w++) { int tw = wsum[w]; woff[w] = s; s += tw; }
        row_start[N_NODES] = s;
    }
    __syncthreads();
    if (t < NCHUNK) boff[t] = x - v + woff[wid];
}

__global__ __launch_bounds__(256) void scan_k3(const int* __restrict__ deg,
                                               const int* __restrict__ boff,
                                               int* __restrict__ row_start) {
    int b = blockIdx.x, t = threadIdx.x;
    int lane = t & 63, wid = t >> 6;
    int i = b * 256 + t;
    int v = (i < N_NODES) ? deg[i] : 0;
    int x = v;
    #pragma unroll
    for (int off = 1; off < 64; off <<= 1) {
        int y = __shfl_up(x, off);
        if (lane >= off) x += y;
    }
    __shared__ int wsum[4], woff[4];
    if (lane == 63) wsum[wid] = x;
    __syncthreads();
    if (t == 0) {
        int s = boff[b];
        #pragma unroll
        for (int w = 0; w < 4; w++) { int tw = wsum[w]; woff[w] = s; s += tw; }
    }
    __syncthreads();
    if (i < N_NODES) row_start[i] = x - v + woff[wid];
}

__global__ void scatter_edges(const int* __restrict__ src, const int* __restrict__ dst,
                              const int* __restrict__ row_start, const int* __restrict__ epos,
                              int* __restrict__ csr_src) {
    int e = blockIdx.x * blockDim.x + threadIdx.x;
    if (e >= N_EDGES + N_NODES) return;
    int s, d;
    if (e < N_EDGES) { s = src[e]; d = dst[e]; } else { s = d = e - N_EDGES; }
    csr_src[row_start[d] + epos[e]] = s;
}

// ===== fused GAT, wave-per-node; fp8 gather (1 dword/lane/edge) =====
// shared-max softmax (exact), in-loop denominator, bf16 output.
__global__ __launch_bounds__(256) void gat_fused(
    const int* __restrict__ row_start, const int* __restrict__ csr_src,
    const float* __restrict__ a_s, const float* __restrict__ a_d,
    const unsigned char* __restrict__ h8, const float* __restrict__ bias,
    const float* __restrict__ g, const float* __restrict__ be,
    const float* __restrict__ rm, const float* __restrict__ rv,
    unsigned short* __restrict__ out16) {
    int t = threadIdx.x;
    int lane = t & 63;
    int w = t >> 6;
    int hd = lane >> 4;                       // head for this lane's 4 channels
    int d = blockIdx.x * 4 + w;               // node handled by this wave

    __shared__ float p_lds[4 * WCAP * 4];     // [wave][edge][head]
    __shared__ int   o_lds[4 * WCAP];         // [wave][edge] : src*64 (dword units)
    float* pw = &p_lds[w * WCAP * 4];
    int*   ow = &o_lds[w * WCAP];

    const unsigned int* __restrict__ H1 = (const unsigned int*)h8;

    int rs = row_start[d], re = row_start[d + 1];
    int deg = re - rs;
    float4 ad4 = *(const float4*)&a_d[d * 4];

    float m_old = -INFINITY;                  // shared max across heads (exact)
    float den = 0.f;                          // per-lane denominator for head hd
    float4 acc = make_float4(0.f, 0.f, 0.f, 0.f);

    for (int base = 0; base < deg; base += WCAP) {
        int cl = min(WCAP, deg - base);
        float lg[4] = {-INFINITY, -INFINITY, -INFINITY, -INFINITY};
        if (lane < cl) {
            int s = csr_src[rs + base + lane];
            ow[lane] = s * 64;
            float4 as4 = *(const float4*)&a_s[s * 4];
            float e0 = as4.x + ad4.x; lg[0] = e0 > 0.f ? e0 : SLOPE * e0;
            float e1 = as4.y + ad4.y; lg[1] = e1 > 0.f ? e1 : SLOPE * e1;
            float e2 = as4.z + ad4.z; lg[2] = e2 > 0.f ? e2 : SLOPE * e2;
            float e3 = as4.w + ad4.w; lg[3] = e3 > 0.f ? e3 : SLOPE * e3;
        }
        float mm = fmaxf(fmaxf(lg[0], lg[1]), fmaxf(lg[2], lg[3]));
        #pragma unroll
        for (int off = 1; off < 64; off <<= 1) mm = fmaxf(mm, __shfl_xor(mm, off));
        float m_new = fmaxf(m_old, mm);
        float alpha = __expf(m_old - m_new);   // 0 on first chunk
        m_old = m_new;
        if (lane < cl) {
            float4 pq;
            pq.x = __expf(lg[0] - m_new);
            pq.y = __expf(lg[1] - m_new);
            pq.z = __expf(lg[2] - m_new);
            pq.w = __expf(lg[3] - m_new);
            *(float4*)&pw[lane * 4] = pq;
        }
        acc.x *= alpha; acc.y *= alpha; acc.z *= alpha; acc.w *= alpha;
        den *= alpha;
        // gather (2 rows in flight), fp8 decode; denominator in-loop
        int e = 0;
        for (; e + 1 < cl; e += 2) {
            int oA = ow[e], oB = ow[e + 1];
            float pA = pw[e * 4 + hd], pB = pw[(e + 1) * 4 + hd];
            int uA = (int)H1[oA + lane];
            int uB = (int)H1[oB + lane];
            den += pA + pB;
            acc.x += pA * __builtin_amdgcn_cvt_f32_fp8(uA, 0);
            acc.y += pA * __builtin_amdgcn_cvt_f32_fp8(uA, 1);
            acc.z += pA * __builtin_amdgcn_cvt_f32_fp8(uA, 2);
            acc.w += pA * __builtin_amdgcn_cvt_f32_fp8(uA, 3);
            acc.x += pB * __builtin_amdgcn_cvt_f32_fp8(uB, 0);
            acc.y += pB * __builtin_amdgcn_cvt_f32_fp8(uB, 1);
            acc.z += pB * __builtin_amdgcn_cvt_f32_fp8(uB, 2);
            acc.w += pB * __builtin_amdgcn_cvt_f32_fp8(uB, 3);
        }
        if (e < cl) {
            int oA = ow[e];
            float pA = pw[e * 4 + hd];
            int uA = (int)H1[oA + lane];
            den += pA;
            acc.x += pA * __builtin_amdgcn_cvt_f32_fp8(uA, 0);
            acc.y += pA * __builtin_amdgcn_cvt_f32_fp8(uA, 1);
            acc.z += pA * __builtin_amdgcn_cvt_f32_fp8(uA, 2);
            acc.w += pA * __builtin_amdgcn_cvt_f32_fp8(uA, 3);
        }
    }
    float inv = 1.f / den;
    int c0 = lane * 4;
    float4 bi = *(const float4*)&bias[c0];
    float4 gg = *(const float4*)&g[c0];
    float4 bb = *(const float4*)&be[c0];
    float4 mm4 = *(const float4*)&rm[c0];
    float4 vv = *(const float4*)&rv[c0];
    float v0 = fmaxf(acc.x * inv + bi.x, 0.f);
    float v1 = fmaxf(acc.y * inv + bi.y, 0.f);
    float v2 = fmaxf(acc.z * inv + bi.z, 0.f);
    float v3 = fmaxf(acc.w * inv + bi.w, 0.f);
    v0 = (v0 - mm4.x) * rsqrtf(vv.x + BN_EPS) * gg.x + bb.x;
    v1 = (v1 - mm4.y) * rsqrtf(vv.y + BN_EPS) * gg.y + bb.y;
    v2 = (v2 - mm4.z) * rsqrtf(vv.z + BN_EPS) * gg.z + bb.z;
    v3 = (v3 - mm4.w) * rsqrtf(vv.w + BN_EPS) * gg.w + bb.w;
    unsigned long long o =
        (unsigned long long)f2bf(v0) |
        ((unsigned long long)f2bf(v1) << 16) |
        ((unsigned long long)f2bf(v2) << 32) |
        ((unsigned long long)f2bf(v3) << 48);
    __builtin_nontemporal_store(o, (unsigned long long*)&out16[(long long)d * FEAT + c0]);
}

// ===== fused head: mean-pool bf16 h2 + relu(pooled@lw1+lb1) @ lw2 + lb2 =====
__global__ __launch_bounds__(256) void head_fused(
    const unsigned short* __restrict__ h2, const int* __restrict__ batch,
    const float* __restrict__ lw1, const float* __restrict__ lb1,
    const float* __restrict__ lw2, const float* __restrict__ lb2,
    float* __restrict__ out) {
    int gph = blockIdx.x;
    int t = threadIdx.x;
    __shared__ float pooled[FEAT];
    __shared__ float zl[OUT_DIM];
    __shared__ int lo_s, hi_s;
    if (t == 0) {
        int lo = 0, hi = N_NODES;
        while (lo < hi) { int mid = (lo + hi) >> 1; if (batch[mid] < gph) lo = mid + 1; else hi = mid; }
        lo_s = lo;
        int lo2 = 0, hi2 = N_NODES;
        while (lo2 < hi2) { int mid = (lo2 + hi2) >> 1; if (batch[mid] < gph + 1) lo2 = mid + 1; else hi2 = mid; }
        hi_s = lo2;
    }
    __syncthreads();
    int lo = lo_s, hi = hi_s;
    float a0 = 0.f, a1 = 0.f, a2 = 0.f, a3 = 0.f;
    int n = lo;
    for (; n + 3 < hi; n += 4) {
        a0 += __uint_as_float((unsigned)h2[(long long)n * FEAT + t] << 16);
        a1 += __uint_as_float((unsigned)h2[(long long)(n + 1) * FEAT + t] << 16);
        a2 += __uint_as_float((unsigned)h2[(long long)(n + 2) * FEAT + t] << 16);
        a3 += __uint_as_float((unsigned)h2[(long long)(n + 3) * FEAT + t] << 16);
    }
    for (; n < hi; n++) a0 += __uint_as_float((unsigned)h2[(long long)n * FEAT + t] << 16);
    float cnt = fmaxf((float)(hi - lo), 1.f);
    pooled[t] = (a0 + a1 + a2 + a3) / cnt;
    __syncthreads();
    int j = t >> 1, kh = t & 1;
    float zp = 0.f;
    #pragma unroll 8
    for (int k = kh * 128; k < kh * 128 + 128; k++)
        zp += pooled[k] * lw1[k * OUT_DIM + j];
    zp += __shfl_xor(zp, 1);
    if (kh == 0) zl[j] = fmaxf(zp + lb1[j], 0.f);
    __syncthreads();
    int w = t >> 6, lane = t & 63;
    if (w < 2) {
        float p = zl[lane] * lw2[lane * 2 + w] + zl[lane + 64] * lw2[(lane + 64) * 2 + w];
        #pragma unroll
        for (int off = 1; off < 64; off <<= 1) p += __shfl_xor(p, off);
        if (lane == 0) out[gph * 2 + w] = p + lb2[w];
    }
}

extern "C" void kernel_launch(void* const* d_in, const int* in_sizes, int n_in,
                              void* d_out, int out_size, void* d_ws, size_t ws_size,
                              hipStream_t stream) {
    const float* x       = (const float*)d_in[0];
    const int*   ei      = (const int*)d_in[1];
    const int*   batch   = (const int*)d_in[2];
    const float* W1      = (const float*)d_in[3];
    const float* att_s1  = (const float*)d_in[4];
    const float* att_d1  = (const float*)d_in[5];
    const float* b1      = (const float*)d_in[6];
    const float* g1      = (const float*)d_in[7];
    const float* be1     = (const float*)d_in[8];
    const float* rm1     = (const float*)d_in[9];
    const float* rv1     = (const float*)d_in[10];
    const float* W2      = (const float*)d_in[11];
    const float* att_s2  = (const float*)d_in[12];
    const float* att_d2  = (const float*)d_in[13];
    const float* b2      = (const float*)d_in[14];
    const float* g2      = (const float*)d_in[15];
    const float* be2     = (const float*)d_in[16];
    const float* rm2     = (const float*)d_in[17];
    const float* rv2     = (const float*)d_in[18];
    const float* lw1     = (const float*)d_in[19];
    const float* lb1     = (const float*)d_in[20];
    const float* lw2     = (const float*)d_in[21];
    const float* lb2     = (const float*)d_in[22];
    float* out           = (float*)d_out;

    const int* src = ei;
    const int* dst = ei + N_EDGES;

    char* p = (char*)d_ws;
    auto carve = [&p](size_t bytes) -> void* {
        void* r = (void*)p;
        p += (bytes + 63) & ~(size_t)63;
        return r;
    };
    unsigned short* h2bf = (unsigned short*)carve(sizeof(short) * (size_t)N_NODES * FEAT);
    float* a_s    = (float*)carve(sizeof(float) * N_NODES * HEADS);
    float* a_d    = (float*)carve(sizeof(float) * N_NODES * HEADS);
    int*   deg    = (int*)carve(sizeof(int) * N_NODES);
    int*   epos   = (int*)carve(sizeof(int) * (N_EDGES + N_NODES));
    int*   csr    = (int*)carve(sizeof(int) * (N_EDGES + N_NODES));
    int*   rstart = (int*)carve(sizeof(int) * (N_NODES + 4));
    int*   bsum   = (int*)carve(sizeof(int) * 256);
    int*   boff   = (int*)carve(sizeof(int) * 256);
    unsigned char*  h8   = (unsigned char*)carve((size_t)M_PAD * FEAT);
    unsigned short* h1bf = (unsigned short*)carve(sizeof(short) * (size_t)M_PAD * FEAT);
    unsigned short* w1t  = (unsigned short*)carve(sizeof(short) * FEAT * F_IN);
    unsigned short* w2t  = (unsigned short*)carve(sizeof(short) * FEAT * FEAT);

    const int Et = N_EDGES + N_NODES;

    // ---- converts / pad zeroing ----
    cvt_w_both<<<((F_IN + FEAT) * 256 + 255) / 256, 256, 0, stream>>>(W1, W2, w1t, w2t);
    (void)hipMemsetAsync(h1bf + (size_t)N_NODES * FEAT, 0,
                         sizeof(short) * (size_t)(M_PAD - N_NODES) * FEAT, stream);

    // ---- CSR build ----
    (void)hipMemsetAsync(deg, 0, sizeof(int) * N_NODES, stream);
    degree_count<<<(Et + 255) / 256, 256, 0, stream>>>(src, dst, deg, epos);
    scan_k1<<<NCHUNK, 256, 0, stream>>>(deg, bsum);
    scan_k2<<<1, 256, 0, stream>>>(bsum, boff, rstart);
    scan_k3<<<NCHUNK, 256, 0, stream>>>(deg, boff, rstart);
    scatter_edges<<<(Et + 255) / 256, 256, 0, stream>>>(src, dst, rstart, epos, csr);

    // ---- Layer 1 (A = fp32 x, converted in staging) ----
    {
        dim3 grid(FEAT / 128, M_PAD / 128);
        gemm_mfma_gat<true><<<grid, 256, 0, stream>>>(x, w1t, att_s1, att_d1,
                                                      h8, a_s, a_d, F_IN);
    }
    gat_fused<<<N_NODES / 4, 256, 0, stream>>>(rstart, csr, a_s, a_d, h8,
                                               b1, g1, be1, rm1, rv1, h1bf);

    // ---- Layer 2 ----
    {
        dim3 grid(FEAT / 128, M_PAD / 128);
        gemm_mfma_gat<false><<<grid, 256, 0, stream>>>(h1bf, w2t, att_s2, att_d2,
                                                       h8, a_s, a_d, FEAT);
    }
    gat_fused<<<N_NODES / 4, 256, 0, stream>>>(rstart, csr, a_s, a_d, h8,
                                               b2, g2, be2, rm2, rv2, h2bf);

    // ---- fused head ----
    head_fused<<<NG, 256, 0, stream>>>(h2bf, batch, lw1, lb1, lw2, lb2, out);
}

// Round 14
// 354.372 us; speedup vs baseline: 6.2814x; 1.0113x over previous
//
#include <hip/hip_runtime.h>
#include <hip/hip_bf16.h>
#include <math.h>

#define N_NODES 50000
#define M_PAD   50048                    // 391 * 128
#define N_EDGES 800000
#define F_IN 128
#define HID 64
#define HEADS 4
#define FEAT 256        // HEADS*HID
#define OUT_DIM 128
#define N_CLS 2
#define NG 500
#define SLOPE 0.2f
#define BN_EPS 1e-5f
#define WCAP 64          // edges per chunk per wave in gat_fused
#define NCHUNK ((N_NODES + 255) / 256)

typedef __attribute__((ext_vector_type(8))) short short8;
typedef __attribute__((ext_vector_type(4))) float floatx4;
typedef __attribute__((ext_vector_type(2))) float floatx2;

__device__ inline unsigned short f2bf(float f) {
    unsigned int u = __float_as_uint(f);
    unsigned int lsb = (u >> 16) & 1u;
    return (unsigned short)((u + 0x7fffu + lsb) >> 16);
}

// ==== bf16 MFMA GEMM fused with GAT prologue ====
// C = A[Mpad,K] @ BT[256,K]^T. A is bf16 (AF32=false) or fp32 with N_NODES
// valid rows (AF32=true, converted in staging). Writes fp8-e4m3 h8[Mpad,256]
// (gather source; coalesced via LDS repack) + fp32 a_s/a_d[N,4] from fp32
// accumulators.
template<bool AF32>
__global__ __launch_bounds__(256) void gemm_mfma_gat(
    const void* __restrict__ Av, const unsigned short* __restrict__ BT,
    const float* __restrict__ att_src, const float* __restrict__ att_dst,
    unsigned char* __restrict__ h8, float* __restrict__ a_s,
    float* __restrict__ a_d, int K) {
    constexpr int LS = 40;      // staging row stride (bf16)
    constexpr int C8 = 144;     // fp8 C-repack row stride (bytes, 16B-aligned)
    __shared__ unsigned short smem[128 * 132];   // 33792 B shared scratch
    unsigned short* As = smem;
    unsigned short* Bs = smem + 128 * LS;
    unsigned char*  s8 = (unsigned char*)smem;   // reused after last barrier
    int t = threadIdx.x;
    int lane = t & 63, w = t >> 6;
    int wm = (w >> 1) * 64, wn = (w & 1) * 64;
    int row0 = blockIdx.y * 128, col0 = blockIdx.x * 128;

    floatx4 acc[4][4] = {};

    int r0 = t >> 2,            c0 = (t & 3) * 8;
    int r1 = (t + 256) >> 2,    c1 = ((t + 256) & 3) * 8;
    int mrow = lane & 15, quad = lane >> 4;

    const unsigned short* Ab = (const unsigned short*)Av;
    const float* Af = (const float*)Av;

    for (int k0 = 0; k0 < K; k0 += 32) {
        if (AF32) {
            uint4 p0 = make_uint4(0, 0, 0, 0), p1 = p0;
            if (row0 + r0 < N_NODES) {
                float4 f0 = *(const float4*)&Af[(long long)(row0 + r0) * K + k0 + c0];
                float4 f1 = *(const float4*)&Af[(long long)(row0 + r0) * K + k0 + c0 + 4];
                p0.x = (unsigned)f2bf(f0.x) | ((unsigned)f2bf(f0.y) << 16);
                p0.y = (unsigned)f2bf(f0.z) | ((unsigned)f2bf(f0.w) << 16);
                p0.z = (unsigned)f2bf(f1.x) | ((unsigned)f2bf(f1.y) << 16);
                p0.w = (unsigned)f2bf(f1.z) | ((unsigned)f2bf(f1.w) << 16);
            }
            if (row0 + r1 < N_NODES) {
                float4 f0 = *(const float4*)&Af[(long long)(row0 + r1) * K + k0 + c1];
                float4 f1 = *(const float4*)&Af[(long long)(row0 + r1) * K + k0 + c1 + 4];
                p1.x = (unsigned)f2bf(f0.x) | ((unsigned)f2bf(f0.y) << 16);
                p1.y = (unsigned)f2bf(f0.z) | ((unsigned)f2bf(f0.w) << 16);
                p1.z = (unsigned)f2bf(f1.x) | ((unsigned)f2bf(f1.y) << 16);
                p1.w = (unsigned)f2bf(f1.z) | ((unsigned)f2bf(f1.w) << 16);
            }
            *(uint4*)&As[r0 * LS + c0] = p0;
            *(uint4*)&As[r1 * LS + c1] = p1;
        } else {
            *(uint4*)&As[r0 * LS + c0] = *(const uint4*)&Ab[(long long)(row0 + r0) * K + k0 + c0];
            *(uint4*)&As[r1 * LS + c1] = *(const uint4*)&Ab[(long long)(row0 + r1) * K + k0 + c1];
        }
        *(uint4*)&Bs[r0 * LS + c0] = *(const uint4*)&BT[(long long)(col0 + r0) * K + k0 + c0];
        *(uint4*)&Bs[r1 * LS + c1] = *(const uint4*)&BT[(long long)(col0 + r1) * K + k0 + c1];
        __syncthreads();
        short8 af[4], bf[4];
        #pragma unroll
        for (int i = 0; i < 4; i++) {
            af[i] = *(const short8*)&As[(wm + i * 16 + mrow) * LS + quad * 8];
            bf[i] = *(const short8*)&Bs[(wn + i * 16 + mrow) * LS + quad * 8];
        }
        #pragma unroll
        for (int mi = 0; mi < 4; mi++)
            #pragma unroll
            for (int ni = 0; ni < 4; ni++)
                acc[mi][ni] = __builtin_amdgcn_mfma_f32_16x16x32_bf16(af[mi], bf[ni],
                                                                      acc[mi][ni], 0, 0, 0);
        __syncthreads();
    }

    // ---- attention scores (wave's 64-col span == one head) ----
    int head = blockIdx.x * 2 + (w & 1);
    float ats[4], atd[4];
    #pragma unroll
    for (int ni = 0; ni < 4; ni++) {
        ats[ni] = att_src[head * 64 + ni * 16 + mrow];
        atd[ni] = att_dst[head * 64 + ni * 16 + mrow];
    }
    #pragma unroll
    for (int mi = 0; mi < 4; mi++) {
        #pragma unroll
        for (int r = 0; r < 4; r++) {
            int row = row0 + wm + mi * 16 + quad * 4 + r;
            float ps = 0.f, pd = 0.f;
            #pragma unroll
            for (int ni = 0; ni < 4; ni++) {
                float v = acc[mi][ni][r];
                ps += v * ats[ni];
                pd += v * atd[ni];
            }
            #pragma unroll
            for (int off = 1; off < 16; off <<= 1) {
                ps += __shfl_xor(ps, off);
                pd += __shfl_xor(pd, off);
            }
            if (mrow == 0 && row < N_NODES) {
                a_s[row * 4 + head] = ps;
                a_d[row * 4 + head] = pd;
            }
        }
    }

    // ---- repack C tile as fp8 through LDS, coalesced uint4 stores ----
    #pragma unroll
    for (int mi = 0; mi < 4; mi++)
        #pragma unroll
        for (int r = 0; r < 4; r++) {
            int row = wm + mi * 16 + quad * 4 + r;
            #pragma unroll
            for (int ni = 0; ni < 4; ni += 2) {
                int pk = __builtin_amdgcn_cvt_pk_fp8_f32(acc[mi][ni][r],
                                                         acc[mi][ni + 1][r], 0, false);
                s8[row * C8 + wn + ni * 16 + mrow]       = (unsigned char)(pk & 0xff);
                s8[row * C8 + wn + (ni + 1) * 16 + mrow] = (unsigned char)((pk >> 8) & 0xff);
            }
        }
    __syncthreads();
    {
        int r2 = t >> 1, half = t & 1;
        const uint4* sp = (const uint4*)&s8[r2 * C8 + half * 64];
        uint4* dp = (uint4*)&h8[(long long)(row0 + r2) * FEAT + col0 + half * 64];
        #pragma unroll
        for (int k = 0; k < 4; k++)
            dp[k] = sp[k];
    }
}

// ===== prep: weight transposes + deg zero + h1bf pad zero (one launch) =====
__global__ void prep(const float* __restrict__ W1, const float* __restrict__ W2,
                     unsigned short* __restrict__ W1T, unsigned short* __restrict__ W2T,
                     int* __restrict__ deg, unsigned long long* __restrict__ h1bf_pad) {
    int i = blockIdx.x * 256 + threadIdx.x;   // grid covers 98304 threads
    if (i < F_IN * 256) {
        int k = i >> 8, n = i & 255;
        W1T[n * F_IN + k] = f2bf(W1[i]);
    }
    int j = i - F_IN * 256;
    if (j >= 0 && j < FEAT * 256) {
        int k = j >> 8, n = j & 255;
        W2T[n * FEAT + k] = f2bf(W2[j]);
    }
    if (i < N_NODES) deg[i] = 0;
    if (i < (M_PAD - N_NODES) * FEAT / 4) h1bf_pad[i] = 0ULL;
}

// ================= CSR build =================
__global__ void degree_count(const int* __restrict__ src, const int* __restrict__ dst,
                             int* __restrict__ deg, int* __restrict__ epos) {
    int e = blockIdx.x * blockDim.x + threadIdx.x;
    if (e >= N_EDGES + N_NODES) return;
    int d = (e < N_EDGES) ? dst[e] : (e - N_EDGES);
    epos[e] = atomicAdd(&deg[d], 1);
}

__global__ __launch_bounds__(256) void scan_k1(const int* __restrict__ deg,
                                               int* __restrict__ bsum) {
    int b = blockIdx.x, t = threadIdx.x;
    int i = b * 256 + t;
    int v = (i < N_NODES) ? deg[i] : 0;
    #pragma unroll
    for (int off = 32; off > 0; off >>= 1) v += __shfl_down(v, off);
    __shared__ int ws[4];
    if ((t & 63) == 0) ws[t >> 6] = v;
    __syncthreads();
    if (t == 0) bsum[b] = ws[0] + ws[1] + ws[2] + ws[3];
}

__global__ __launch_bounds__(256) void scan_k2(const int* __restrict__ bsum,
                                               int* __restrict__ boff,
                                               int* __restrict__ row_start) {
    int t = threadIdx.x;
    int lane = t & 63, wid = t >> 6;
    int v = (t < NCHUNK) ? bsum[t] : 0;
    int x = v;
    #pragma unroll
    for (int off = 1; off < 64; off <<= 1) {
        int y = __shfl_up(x, off);
        if (lane >= off) x += y;
    }
    __shared__ int wsum[4], woff[4];
    if (lane == 63) wsum[wid] = x;
    __syncthreads();
    if (t == 0) {
        int s = 0;
        #pragma unroll
        for (int w = 0; w < 4; w++) { int tw = wsum[w]; woff[w] = s; s += tw; }
        row_start[N_NODES] = s;
    }
    __syncthreads();
    if (t < NCHUNK) boff[t] = x - v + woff[wid];
}

__global__ __launch_bounds__(256) void scan_k3(const int* __restrict__ deg,
                                               const int* __restrict__ boff,
                                               int* __restrict__ row_start) {
    int b = blockIdx.x, t = threadIdx.x;
    int lane = t & 63, wid = t >> 6;
    int i = b * 256 + t;
    int v = (i < N_NODES) ? deg[i] : 0;
    int x = v;
    #pragma unroll
    for (int off = 1; off < 64; off <<= 1) {
        int y = __shfl_up(x, off);
        if (lane >= off) x += y;
    }
    __shared__ int wsum[4], woff[4];
    if (lane == 63) wsum[wid] = x;
    __syncthreads();
    if (t == 0) {
        int s = boff[b];
        #pragma unroll
        for (int w = 0; w < 4; w++) { int tw = wsum[w]; woff[w] = s; s += tw; }
    }
    __syncthreads();
    if (i < N_NODES) row_start[i] = x - v + woff[wid];
}

__global__ void scatter_edges(const int* __restrict__ src, const int* __restrict__ dst,
                              const int* __restrict__ row_start, const int* __restrict__ epos,
                              int* __restrict__ csr_src) {
    int e = blockIdx.x * blockDim.x + threadIdx.x;
    if (e >= N_EDGES + N_NODES) return;
    int s, d;
    if (e < N_EDGES) { s = src[e]; d = dst[e]; } else { s = d = e - N_EDGES; }
    csr_src[row_start[d] + epos[e]] = s;
}

// ===== fused GAT, wave-per-node; fp8 gather with packed decode =====
// shared-max softmax (exact), in-loop denominator, bf16 output.
__global__ __launch_bounds__(256) void gat_fused(
    const int* __restrict__ row_start, const int* __restrict__ csr_src,
    const float* __restrict__ a_s, const float* __restrict__ a_d,
    const unsigned char* __restrict__ h8, const float* __restrict__ bias,
    const float* __restrict__ g, const float* __restrict__ be,
    const float* __restrict__ rm, const float* __restrict__ rv,
    unsigned short* __restrict__ out16) {
    int t = threadIdx.x;
    int lane = t & 63;
    int w = t >> 6;
    int hd = lane >> 4;                       // head for this lane's 4 channels
    int d = blockIdx.x * 4 + w;               // node handled by this wave

    __shared__ float p_lds[4 * WCAP * 4];     // [wave][edge][head]
    __shared__ int   o_lds[4 * WCAP];         // [wave][edge] : src*64 (dword units)
    float* pw = &p_lds[w * WCAP * 4];
    int*   ow = &o_lds[w * WCAP];

    const unsigned int* __restrict__ H1 = (const unsigned int*)h8;

    int rs = row_start[d], re = row_start[d + 1];
    int deg = re - rs;
    float4 ad4 = *(const float4*)&a_d[d * 4];

    float m_old = -INFINITY;                  // shared max across heads (exact)
    float den = 0.f;                          // per-lane denominator for head hd
    float4 acc = make_float4(0.f, 0.f, 0.f, 0.f);

    for (int base = 0; base < deg; base += WCAP) {
        int cl = min(WCAP, deg - base);
        float lg[4] = {-INFINITY, -INFINITY, -INFINITY, -INFINITY};
        if (lane < cl) {
            int s = csr_src[rs + base + lane];
            ow[lane] = s * 64;
            float4 as4 = *(const float4*)&a_s[s * 4];
            float e0 = as4.x + ad4.x; lg[0] = e0 > 0.f ? e0 : SLOPE * e0;
            float e1 = as4.y + ad4.y; lg[1] = e1 > 0.f ? e1 : SLOPE * e1;
            float e2 = as4.z + ad4.z; lg[2] = e2 > 0.f ? e2 : SLOPE * e2;
            float e3 = as4.w + ad4.w; lg[3] = e3 > 0.f ? e3 : SLOPE * e3;
        }
        float mm = fmaxf(fmaxf(lg[0], lg[1]), fmaxf(lg[2], lg[3]));
        #pragma unroll
        for (int off = 1; off < 64; off <<= 1) mm = fmaxf(mm, __shfl_xor(mm, off));
        float m_new = fmaxf(m_old, mm);
        float alpha = __expf(m_old - m_new);   // 0 on first chunk
        m_old = m_new;
        if (lane < cl) {
            float4 pq;
            pq.x = __expf(lg[0] - m_new);
            pq.y = __expf(lg[1] - m_new);
            pq.z = __expf(lg[2] - m_new);
            pq.w = __expf(lg[3] - m_new);
            *(float4*)&pw[lane * 4] = pq;
        }
        acc.x *= alpha; acc.y *= alpha; acc.z *= alpha; acc.w *= alpha;
        den *= alpha;
        // gather (2 rows in flight), packed fp8 decode; denominator in-loop
        int e = 0;
        for (; e + 1 < cl; e += 2) {
            int oA = ow[e], oB = ow[e + 1];
            float pA = pw[e * 4 + hd], pB = pw[(e + 1) * 4 + hd];
            int uA = (int)H1[oA + lane];
            int uB = (int)H1[oB + lane];
            den += pA + pB;
            floatx2 a0 = __builtin_amdgcn_cvt_pk_f32_fp8(uA, false);
            floatx2 a1 = __builtin_amdgcn_cvt_pk_f32_fp8(uA, true);
            floatx2 b0 = __builtin_amdgcn_cvt_pk_f32_fp8(uB, false);
            floatx2 b1 = __builtin_amdgcn_cvt_pk_f32_fp8(uB, true);
            acc.x += pA * a0.x; acc.y += pA * a0.y;
            acc.z += pA * a1.x; acc.w += pA * a1.y;
            acc.x += pB * b0.x; acc.y += pB * b0.y;
            acc.z += pB * b1.x; acc.w += pB * b1.y;
        }
        if (e < cl) {
            int oA = ow[e];
            float pA = pw[e * 4 + hd];
            int uA = (int)H1[oA + lane];
            den += pA;
            floatx2 a0 = __builtin_amdgcn_cvt_pk_f32_fp8(uA, false);
            floatx2 a1 = __builtin_amdgcn_cvt_pk_f32_fp8(uA, true);
            acc.x += pA * a0.x; acc.y += pA * a0.y;
            acc.z += pA * a1.x; acc.w += pA * a1.y;
        }
    }
    float inv = 1.f / den;
    int c0 = lane * 4;
    float4 bi = *(const float4*)&bias[c0];
    float4 gg = *(const float4*)&g[c0];
    float4 bb = *(const float4*)&be[c0];
    float4 mm4 = *(const float4*)&rm[c0];
    float4 vv = *(const float4*)&rv[c0];
    float v0 = fmaxf(acc.x * inv + bi.x, 0.f);
    float v1 = fmaxf(acc.y * inv + bi.y, 0.f);
    float v2 = fmaxf(acc.z * inv + bi.z, 0.f);
    float v3 = fmaxf(acc.w * inv + bi.w, 0.f);
    v0 = (v0 - mm4.x) * rsqrtf(vv.x + BN_EPS) * gg.x + bb.x;
    v1 = (v1 - mm4.y) * rsqrtf(vv.y + BN_EPS) * gg.y + bb.y;
    v2 = (v2 - mm4.z) * rsqrtf(vv.z + BN_EPS) * gg.z + bb.z;
    v3 = (v3 - mm4.w) * rsqrtf(vv.w + BN_EPS) * gg.w + bb.w;
    unsigned long long o =
        (unsigned long long)f2bf(v0) |
        ((unsigned long long)f2bf(v1) << 16) |
        ((unsigned long long)f2bf(v2) << 32) |
        ((unsigned long long)f2bf(v3) << 48);
    __builtin_nontemporal_store(o, (unsigned long long*)&out16[(long long)d * FEAT + c0]);
}

// ===== fused head: mean-pool bf16 h2 + relu(pooled@lw1+lb1) @ lw2 + lb2 =====
__global__ __launch_bounds__(256) void head_fused(
    const unsigned short* __restrict__ h2, const int* __restrict__ batch,
    const float* __restrict__ lw1, const float* __restrict__ lb1,
    const float* __restrict__ lw2, const float* __restrict__ lb2,
    float* __restrict__ out) {
    int gph = blockIdx.x;
    int t = threadIdx.x;
    __shared__ float pooled[FEAT];
    __shared__ float zl[OUT_DIM];
    __shared__ int lo_s, hi_s;
    if (t == 0) {
        int lo = 0, hi = N_NODES;
        while (lo < hi) { int mid = (lo + hi) >> 1; if (batch[mid] < gph) lo = mid + 1; else hi = mid; }
        lo_s = lo;
        int lo2 = 0, hi2 = N_NODES;
        while (lo2 < hi2) { int mid = (lo2 + hi2) >> 1; if (batch[mid] < gph + 1) lo2 = mid + 1; else hi2 = mid; }
        hi_s = lo2;
    }
    __syncthreads();
    int lo = lo_s, hi = hi_s;
    float a0 = 0.f, a1 = 0.f, a2 = 0.f, a3 = 0.f;
    int n = lo;
    for (; n + 3 < hi; n += 4) {
        a0 += __uint_as_float((unsigned)h2[(long long)n * FEAT + t] << 16);
        a1 += __uint_as_float((unsigned)h2[(long long)(n + 1) * FEAT + t] << 16);
        a2 += __uint_as_float((unsigned)h2[(long long)(n + 2) * FEAT + t] << 16);
        a3 += __uint_as_float((unsigned)h2[(long long)(n + 3) * FEAT + t] << 16);
    }
    for (; n < hi; n++) a0 += __uint_as_float((unsigned)h2[(long long)n * FEAT + t] << 16);
    float cnt = fmaxf((float)(hi - lo), 1.f);
    pooled[t] = (a0 + a1 + a2 + a3) / cnt;
    __syncthreads();
    int j = t >> 1, kh = t & 1;
    float zp = 0.f;
    #pragma unroll 8
    for (int k = kh * 128; k < kh * 128 + 128; k++)
        zp += pooled[k] * lw1[k * OUT_DIM + j];
    zp += __shfl_xor(zp, 1);
    if (kh == 0) zl[j] = fmaxf(zp + lb1[j], 0.f);
    __syncthreads();
    int w = t >> 6, lane = t & 63;
    if (w < 2) {
        float p = zl[lane] * lw2[lane * 2 + w] + zl[lane + 64] * lw2[(lane + 64) * 2 + w];
        #pragma unroll
        for (int off = 1; off < 64; off <<= 1) p += __shfl_xor(p, off);
        if (lane == 0) out[gph * 2 + w] = p + lb2[w];
    }
}

extern "C" void kernel_launch(void* const* d_in, const int* in_sizes, int n_in,
                              void* d_out, int out_size, void* d_ws, size_t ws_size,
                              hipStream_t stream) {
    const float* x       = (const float*)d_in[0];
    const int*   ei      = (const int*)d_in[1];
    const int*   batch   = (const int*)d_in[2];
    const float* W1      = (const float*)d_in[3];
    const float* att_s1  = (const float*)d_in[4];
    const float* att_d1  = (const float*)d_in[5];
    const float* b1      = (const float*)d_in[6];
    const float* g1      = (const float*)d_in[7];
    const float* be1     = (const float*)d_in[8];
    const float* rm1     = (const float*)d_in[9];
    const float* rv1     = (const float*)d_in[10];
    const float* W2      = (const float*)d_in[11];
    const float* att_s2  = (const float*)d_in[12];
    const float* att_d2  = (const float*)d_in[13];
    const float* b2      = (const float*)d_in[14];
    const float* g2      = (const float*)d_in[15];
    const float* be2     = (const float*)d_in[16];
    const float* rm2     = (const float*)d_in[17];
    const float* rv2     = (const float*)d_in[18];
    const float* lw1     = (const float*)d_in[19];
    const float* lb1     = (const float*)d_in[20];
    const float* lw2     = (const float*)d_in[21];
    const float* lb2     = (const float*)d_in[22];
    float* out           = (float*)d_out;

    const int* src = ei;
    const int* dst = ei + N_EDGES;

    char* p = (char*)d_ws;
    auto carve = [&p](size_t bytes) -> void* {
        void* r = (void*)p;
        p += (bytes + 63) & ~(size_t)63;
        return r;
    };
    unsigned short* h2bf = (unsigned short*)carve(sizeof(short) * (size_t)N_NODES * FEAT);
    float* a_s    = (float*)carve(sizeof(float) * N_NODES * HEADS);
    float* a_d    = (float*)carve(sizeof(float) * N_NODES * HEADS);
    int*   deg    = (int*)carve(sizeof(int) * N_NODES);
    int*   epos   = (int*)carve(sizeof(int) * (N_EDGES + N_NODES));
    int*   csr    = (int*)carve(sizeof(int) * (N_EDGES + N_NODES));
    int*   rstart = (int*)carve(sizeof(int) * (N_NODES + 4));
    int*   bsum   = (int*)carve(sizeof(int) * 256);
    int*   boff   = (int*)carve(sizeof(int) * 256);
    unsigned char*  h8   = (unsigned char*)carve((size_t)M_PAD * FEAT);
    unsigned short* h1bf = (unsigned short*)carve(sizeof(short) * (size_t)M_PAD * FEAT);
    unsigned short* w1t  = (unsigned short*)carve(sizeof(short) * FEAT * F_IN);
    unsigned short* w2t  = (unsigned short*)carve(sizeof(short) * FEAT * FEAT);

    const int Et = N_EDGES + N_NODES;

    // ---- prep: weight transposes + deg zero + h1bf pad zero ----
    prep<<<((F_IN + FEAT) * 256 + 255) / 256, 256, 0, stream>>>(
        W1, W2, w1t, w2t, deg,
        (unsigned long long*)(h1bf + (size_t)N_NODES * FEAT));

    // ---- CSR build ----
    degree_count<<<(Et + 255) / 256, 256, 0, stream>>>(src, dst, deg, epos);
    scan_k1<<<NCHUNK, 256, 0, stream>>>(deg, bsum);
    scan_k2<<<1, 256, 0, stream>>>(bsum, boff, rstart);
    scan_k3<<<NCHUNK, 256, 0, stream>>>(deg, boff, rstart);
    scatter_edges<<<(Et + 255) / 256, 256, 0, stream>>>(src, dst, rstart, epos, csr);

    // ---- Layer 1 (A = fp32 x, converted in staging) ----
    {
        dim3 grid(FEAT / 128, M_PAD / 128);
        gemm_mfma_gat<true><<<grid, 256, 0, stream>>>(x, w1t, att_s1, att_d1,
                                                      h8, a_s, a_d, F_IN);
    }
    gat_fused<<<N_NODES / 4, 256, 0, stream>>>(rstart, csr, a_s, a_d, h8,
                                               b1, g1, be1, rm1, rv1, h1bf);

    // ---- Layer 2 ----
    {
        dim3 grid(FEAT / 128, M_PAD / 128);
        gemm_mfma_gat<false><<<grid, 256, 0, stream>>>(h1bf, w2t, att_s2, att_d2,
                                                       h8, a_s, a_d, FEAT);
    }
    gat_fused<<<N_NODES / 4, 256, 0, stream>>>(rstart, csr, a_s, a_d, h8,
                                               b2, g2, be2, rm2, rv2, h2bf);

    // ---- fused head ----
    head_fused<<<NG, 256, 0, stream>>>(h2bf, batch, lw1, lb1, lw2, lb2, out);
}

// Round 15
// 339.922 us; speedup vs baseline: 6.5484x; 1.0425x over previous
//
#include <hip/hip_runtime.h>
#include <hip/hip_bf16.h>
#include <math.h>

#define N_NODES 50000
#define M_PAD   50048                    // 391 * 128
#define N_EDGES 800000
#define F_IN 128
#define HID 64
#define HEADS 4
#define FEAT 256        // HEADS*HID
#define OUT_DIM 128
#define N_CLS 2
#define NG 500
#define SLOPE 0.2f
#define BN_EPS 1e-5f
#define WCAP 64          // edges per chunk per wave in gat_fused
#define NCHUNK ((N_NODES + 255) / 256)

typedef __attribute__((ext_vector_type(8))) short short8;
typedef __attribute__((ext_vector_type(4))) float floatx4;
typedef __attribute__((ext_vector_type(2))) float floatx2;

__device__ inline unsigned short f2bf(float f) {
    unsigned int u = __float_as_uint(f);
    unsigned int lsb = (u >> 16) & 1u;
    return (unsigned short)((u + 0x7fffu + lsb) >> 16);
}

// ==== bf16 MFMA GEMM fused with GAT prologue; full-width 128x256 tile ====
// C = A[Mpad,K] @ BT[256,K]^T. One block per 128-row stripe (A staged ONCE).
// Wave w owns head w: cols w*64..w*64+63, all 128 rows (8x4 MFMA tiles).
// Writes fp8-e4m3 h8[Mpad,256] + fp32 a_s/a_d[N,4] from fp32 accumulators.
template<bool AF32>
__global__ __launch_bounds__(256, 2) void gemm_mfma_gat(
    const void* __restrict__ Av, const unsigned short* __restrict__ BT,
    const float* __restrict__ att_src, const float* __restrict__ att_dst,
    unsigned char* __restrict__ h8, float* __restrict__ a_s,
    float* __restrict__ a_d, int K) {
    constexpr int LS = 40;      // staging row stride (bf16)
    constexpr int C8 = 272;     // fp8 C-repack row stride (bytes, 16B-aligned)
    __shared__ __align__(16) unsigned char smem_raw[128 * C8];   // 34816 B
    unsigned short* As = (unsigned short*)smem_raw;              // 128*LS shorts
    unsigned short* Bs = As + 128 * LS;                          // 256*LS shorts
    unsigned char*  s8 = smem_raw;                               // reused after barrier
    int t = threadIdx.x;
    int lane = t & 63, w = t >> 6;
    int row0 = blockIdx.x * 128;
    int mrow = lane & 15, quad = lane >> 4;

    floatx4 acc[8][4] = {};

    int rA = t >> 2, cA = (t & 3) * 8;          // A staging round 0 (row 0..63)
    // round 1: rA+64? no: (t+256)>>2 = rA+64

    const unsigned short* Ab = (const unsigned short*)Av;
    const float* Af = (const float*)Av;

    for (int k0 = 0; k0 < K; k0 += 32) {
        // ---- stage A: 128 rows x 32 cols (2 rounds) ----
        #pragma unroll
        for (int j = 0; j < 2; j++) {
            int r = rA + j * 64;
            if (AF32) {
                uint4 pk = make_uint4(0, 0, 0, 0);
                if (row0 + r < N_NODES) {
                    float4 f0 = *(const float4*)&Af[(long long)(row0 + r) * K + k0 + cA];
                    float4 f1 = *(const float4*)&Af[(long long)(row0 + r) * K + k0 + cA + 4];
                    pk.x = (unsigned)f2bf(f0.x) | ((unsigned)f2bf(f0.y) << 16);
                    pk.y = (unsigned)f2bf(f0.z) | ((unsigned)f2bf(f0.w) << 16);
                    pk.z = (unsigned)f2bf(f1.x) | ((unsigned)f2bf(f1.y) << 16);
                    pk.w = (unsigned)f2bf(f1.z) | ((unsigned)f2bf(f1.w) << 16);
                }
                *(uint4*)&As[r * LS + cA] = pk;
            } else {
                *(uint4*)&As[r * LS + cA] = *(const uint4*)&Ab[(long long)(row0 + r) * K + k0 + cA];
            }
        }
        // ---- stage B^T: 256 rows x 32 cols (4 rounds) ----
        #pragma unroll
        for (int j = 0; j < 4; j++) {
            int r = rA + j * 64;
            *(uint4*)&Bs[r * LS + cA] = *(const uint4*)&BT[(long long)r * K + k0 + cA];
        }
        __syncthreads();
        short8 bf[4];
        #pragma unroll
        for (int ni = 0; ni < 4; ni++)
            bf[ni] = *(const short8*)&Bs[(w * 64 + ni * 16 + mrow) * LS + quad * 8];
        #pragma unroll
        for (int mi = 0; mi < 8; mi++) {
            short8 af = *(const short8*)&As[(mi * 16 + mrow) * LS + quad * 8];
            #pragma unroll
            for (int ni = 0; ni < 4; ni++)
                acc[mi][ni] = __builtin_amdgcn_mfma_f32_16x16x32_bf16(af, bf[ni],
                                                                      acc[mi][ni], 0, 0, 0);
        }
        __syncthreads();
    }

    // ---- attention scores (wave w == head w) ----
    float ats[4], atd[4];
    #pragma unroll
    for (int ni = 0; ni < 4; ni++) {
        ats[ni] = att_src[w * 64 + ni * 16 + mrow];
        atd[ni] = att_dst[w * 64 + ni * 16 + mrow];
    }
    #pragma unroll
    for (int mi = 0; mi < 8; mi++) {
        #pragma unroll
        for (int r = 0; r < 4; r++) {
            int row = row0 + mi * 16 + quad * 4 + r;
            float ps = 0.f, pd = 0.f;
            #pragma unroll
            for (int ni = 0; ni < 4; ni++) {
                float v = acc[mi][ni][r];
                ps += v * ats[ni];
                pd += v * atd[ni];
            }
            #pragma unroll
            for (int off = 1; off < 16; off <<= 1) {
                ps += __shfl_xor(ps, off);
                pd += __shfl_xor(pd, off);
            }
            if (mrow == 0 && row < N_NODES) {
                a_s[row * 4 + w] = ps;
                a_d[row * 4 + w] = pd;
            }
        }
    }

    // ---- repack C tile as fp8 through LDS, coalesced uint4 stores ----
    #pragma unroll
    for (int mi = 0; mi < 8; mi++)
        #pragma unroll
        for (int r = 0; r < 4; r++) {
            int row = mi * 16 + quad * 4 + r;
            #pragma unroll
            for (int ni = 0; ni < 4; ni += 2) {
                int pk = __builtin_amdgcn_cvt_pk_fp8_f32(acc[mi][ni][r],
                                                         acc[mi][ni + 1][r], 0, false);
                s8[row * C8 + w * 64 + ni * 16 + mrow]       = (unsigned char)(pk & 0xff);
                s8[row * C8 + w * 64 + (ni + 1) * 16 + mrow] = (unsigned char)((pk >> 8) & 0xff);
            }
        }
    __syncthreads();
    {
        int r2 = t >> 1, half = t & 1;
        const uint4* sp = (const uint4*)&s8[r2 * C8 + half * 128];
        uint4* dp = (uint4*)&h8[(long long)(row0 + r2) * FEAT + half * 128];
        #pragma unroll
        for (int k = 0; k < 8; k++)
            dp[k] = sp[k];
    }
}

// ===== prep: weight transposes + deg zero + h1bf pad zero (one launch) =====
__global__ void prep(const float* __restrict__ W1, const float* __restrict__ W2,
                     unsigned short* __restrict__ W1T, unsigned short* __restrict__ W2T,
                     int* __restrict__ deg, unsigned long long* __restrict__ h1bf_pad) {
    int i = blockIdx.x * 256 + threadIdx.x;
    if (i < F_IN * 256) {
        int k = i >> 8, n = i & 255;
        W1T[n * F_IN + k] = f2bf(W1[i]);
    }
    int j = i - F_IN * 256;
    if (j >= 0 && j < FEAT * 256) {
        int k = j >> 8, n = j & 255;
        W2T[n * FEAT + k] = f2bf(W2[j]);
    }
    if (i < N_NODES) deg[i] = 0;
    if (i < (M_PAD - N_NODES) * FEAT / 4) h1bf_pad[i] = 0ULL;
}

// ================= CSR build =================
__global__ void degree_count(const int* __restrict__ src, const int* __restrict__ dst,
                             int* __restrict__ deg, int* __restrict__ epos) {
    int e = blockIdx.x * blockDim.x + threadIdx.x;
    if (e >= N_EDGES + N_NODES) return;
    int d = (e < N_EDGES) ? dst[e] : (e - N_EDGES);
    epos[e] = atomicAdd(&deg[d], 1);
}

__global__ __launch_bounds__(256) void scan_k1(const int* __restrict__ deg,
                                               int* __restrict__ bsum) {
    int b = blockIdx.x, t = threadIdx.x;
    int i = b * 256 + t;
    int v = (i < N_NODES) ? deg[i] : 0;
    #pragma unroll
    for (int off = 32; off > 0; off >>= 1) v += __shfl_down(v, off);
    __shared__ int ws[4];
    if ((t & 63) == 0) ws[t >> 6] = v;
    __syncthreads();
    if (t == 0) bsum[b] = ws[0] + ws[1] + ws[2] + ws[3];
}

__global__ __launch_bounds__(256) void scan_k2(const int* __restrict__ bsum,
                                               int* __restrict__ boff,
                                               int* __restrict__ row_start) {
    int t = threadIdx.x;
    int lane = t & 63, wid = t >> 6;
    int v = (t < NCHUNK) ? bsum[t] : 0;
    int x = v;
    #pragma unroll
    for (int off = 1; off < 64; off <<= 1) {
        int y = __shfl_up(x, off);
        if (lane >= off) x += y;
    }
    __shared__ int wsum[4], woff[4];
    if (lane == 63) wsum[wid] = x;
    __syncthreads();
    if (t == 0) {
        int s = 0;
        #pragma unroll
        for (int w = 0; w < 4; w++) { int tw = wsum[w]; woff[w] = s; s += tw; }
        row_start[N_NODES] = s;
    }
    __syncthreads();
    if (t < NCHUNK) boff[t] = x - v + woff[wid];
}

__global__ __launch_bounds__(256) void scan_k3(const int* __restrict__ deg,
                                               const int* __restrict__ boff,
                                               int* __restrict__ row_start) {
    int b = blockIdx.x, t = threadIdx.x;
    int lane = t & 63, wid = t >> 6;
    int i = b * 256 + t;
    int v = (i < N_NODES) ? deg[i] : 0;
    int x = v;
    #pragma unroll
    for (int off = 1; off < 64; off <<= 1) {
        int y = __shfl_up(x, off);
        if (lane >= off) x += y;
    }
    __shared__ int wsum[4], woff[4];
    if (lane == 63) wsum[wid] = x;
    __syncthreads();
    if (t == 0) {
        int s = boff[b];
        #pragma unroll
        for (int w = 0; w < 4; w++) { int tw = wsum[w]; woff[w] = s; s += tw; }
    }
    __syncthreads();
    if (i < N_NODES) row_start[i] = x - v + woff[wid];
}

__global__ void scatter_edges(const int* __restrict__ src, const int* __restrict__ dst,
                              const int* __restrict__ row_start, const int* __restrict__ epos,
                              int* __restrict__ csr_src) {
    int e = blockIdx.x * blockDim.x + threadIdx.x;
    if (e >= N_EDGES + N_NODES) return;
    int s, d;
    if (e < N_EDGES) { s = src[e]; d = dst[e]; } else { s = d = e - N_EDGES; }
    csr_src[row_start[d] + epos[e]] = s;
}

// ===== fused GAT, wave-per-node; fp8 gather, packed decode =====
// shared-max softmax (exact), in-loop denominator, bf16 output.
// Fast path for deg <= WCAP (virtually all nodes): no online rescale.
__global__ __launch_bounds__(256) void gat_fused(
    const int* __restrict__ row_start, const int* __restrict__ csr_src,
    const float* __restrict__ a_s, const float* __restrict__ a_d,
    const unsigned char* __restrict__ h8, const float* __restrict__ bias,
    const float* __restrict__ g, const float* __restrict__ be,
    const float* __restrict__ rm, const float* __restrict__ rv,
    unsigned short* __restrict__ out16) {
    int t = threadIdx.x;
    int lane = t & 63;
    int w = t >> 6;
    int hd = lane >> 4;
    int d = blockIdx.x * 4 + w;

    __shared__ float p_lds[4 * WCAP * 4];
    __shared__ int   o_lds[4 * WCAP];
    float* pw = &p_lds[w * WCAP * 4];
    int*   ow = &o_lds[w * WCAP];

    const unsigned int* __restrict__ H1 = (const unsigned int*)h8;

    int rs = row_start[d], re = row_start[d + 1];
    int deg = re - rs;
    float4 ad4 = *(const float4*)&a_d[d * 4];

    float den = 0.f;
    float4 acc = make_float4(0.f, 0.f, 0.f, 0.f);

    if (deg <= WCAP) {
        // ---- single-chunk fast path ----
        float lg[4] = {-INFINITY, -INFINITY, -INFINITY, -INFINITY};
        if (lane < deg) {
            int s = csr_src[rs + lane];
            ow[lane] = s * 64;
            float4 as4 = *(const float4*)&a_s[s * 4];
            float e0 = as4.x + ad4.x; lg[0] = e0 > 0.f ? e0 : SLOPE * e0;
            float e1 = as4.y + ad4.y; lg[1] = e1 > 0.f ? e1 : SLOPE * e1;
            float e2 = as4.z + ad4.z; lg[2] = e2 > 0.f ? e2 : SLOPE * e2;
            float e3 = as4.w + ad4.w; lg[3] = e3 > 0.f ? e3 : SLOPE * e3;
        }
        float mm = fmaxf(fmaxf(lg[0], lg[1]), fmaxf(lg[2], lg[3]));
        #pragma unroll
        for (int off = 1; off < 64; off <<= 1) mm = fmaxf(mm, __shfl_xor(mm, off));
        if (lane < deg) {
            float4 pq;
            pq.x = __expf(lg[0] - mm);
            pq.y = __expf(lg[1] - mm);
            pq.z = __expf(lg[2] - mm);
            pq.w = __expf(lg[3] - mm);
            *(float4*)&pw[lane * 4] = pq;
        }
        int e = 0;
        for (; e + 1 < deg; e += 2) {
            int oA = ow[e], oB = ow[e + 1];
            float pA = pw[e * 4 + hd], pB = pw[(e + 1) * 4 + hd];
            int uA = (int)H1[oA + lane];
            int uB = (int)H1[oB + lane];
            den += pA + pB;
            floatx2 a0 = __builtin_amdgcn_cvt_pk_f32_fp8(uA, false);
            floatx2 a1 = __builtin_amdgcn_cvt_pk_f32_fp8(uA, true);
            floatx2 b0 = __builtin_amdgcn_cvt_pk_f32_fp8(uB, false);
            floatx2 b1 = __builtin_amdgcn_cvt_pk_f32_fp8(uB, true);
            acc.x += pA * a0.x; acc.y += pA * a0.y;
            acc.z += pA * a1.x; acc.w += pA * a1.y;
            acc.x += pB * b0.x; acc.y += pB * b0.y;
            acc.z += pB * b1.x; acc.w += pB * b1.y;
        }
        if (e < deg) {
            int oA = ow[e];
            float pA = pw[e * 4 + hd];
            int uA = (int)H1[oA + lane];
            den += pA;
            floatx2 a0 = __builtin_amdgcn_cvt_pk_f32_fp8(uA, false);
            floatx2 a1 = __builtin_amdgcn_cvt_pk_f32_fp8(uA, true);
            acc.x += pA * a0.x; acc.y += pA * a0.y;
            acc.z += pA * a1.x; acc.w += pA * a1.y;
        }
    } else {
        // ---- general online-softmax path ----
        float m_old = -INFINITY;
        for (int base = 0; base < deg; base += WCAP) {
            int cl = min(WCAP, deg - base);
            float lg[4] = {-INFINITY, -INFINITY, -INFINITY, -INFINITY};
            if (lane < cl) {
                int s = csr_src[rs + base + lane];
                ow[lane] = s * 64;
                float4 as4 = *(const float4*)&a_s[s * 4];
                float e0 = as4.x + ad4.x; lg[0] = e0 > 0.f ? e0 : SLOPE * e0;
                float e1 = as4.y + ad4.y; lg[1] = e1 > 0.f ? e1 : SLOPE * e1;
                float e2 = as4.z + ad4.z; lg[2] = e2 > 0.f ? e2 : SLOPE * e2;
                float e3 = as4.w + ad4.w; lg[3] = e3 > 0.f ? e3 : SLOPE * e3;
            }
            float mm = fmaxf(fmaxf(lg[0], lg[1]), fmaxf(lg[2], lg[3]));
            #pragma unroll
            for (int off = 1; off < 64; off <<= 1) mm = fmaxf(mm, __shfl_xor(mm, off));
            float m_new = fmaxf(m_old, mm);
            float alpha = __expf(m_old - m_new);
            m_old = m_new;
            if (lane < cl) {
                float4 pq;
                pq.x = __expf(lg[0] - m_new);
                pq.y = __expf(lg[1] - m_new);
                pq.z = __expf(lg[2] - m_new);
                pq.w = __expf(lg[3] - m_new);
                *(float4*)&pw[lane * 4] = pq;
            }
            acc.x *= alpha; acc.y *= alpha; acc.z *= alpha; acc.w *= alpha;
            den *= alpha;
            int e = 0;
            for (; e + 1 < cl; e += 2) {
                int oA = ow[e], oB = ow[e + 1];
                float pA = pw[e * 4 + hd], pB = pw[(e + 1) * 4 + hd];
                int uA = (int)H1[oA + lane];
                int uB = (int)H1[oB + lane];
                den += pA + pB;
                floatx2 a0 = __builtin_amdgcn_cvt_pk_f32_fp8(uA, false);
                floatx2 a1 = __builtin_amdgcn_cvt_pk_f32_fp8(uA, true);
                floatx2 b0 = __builtin_amdgcn_cvt_pk_f32_fp8(uB, false);
                floatx2 b1 = __builtin_amdgcn_cvt_pk_f32_fp8(uB, true);
                acc.x += pA * a0.x; acc.y += pA * a0.y;
                acc.z += pA * a1.x; acc.w += pA * a1.y;
                acc.x += pB * b0.x; acc.y += pB * b0.y;
                acc.z += pB * b1.x; acc.w += pB * b1.y;
            }
            if (e < cl) {
                int oA = ow[e];
                float pA = pw[e * 4 + hd];
                int uA = (int)H1[oA + lane];
                den += pA;
                floatx2 a0 = __builtin_amdgcn_cvt_pk_f32_fp8(uA, false);
                floatx2 a1 = __builtin_amdgcn_cvt_pk_f32_fp8(uA, true);
                acc.x += pA * a0.x; acc.y += pA * a0.y;
                acc.z += pA * a1.x; acc.w += pA * a1.y;
            }
        }
    }
    float inv = 1.f / den;
    int c0 = lane * 4;
    float4 bi = *(const float4*)&bias[c0];
    float4 gg = *(const float4*)&g[c0];
    float4 bb = *(const float4*)&be[c0];
    float4 mm4 = *(const float4*)&rm[c0];
    float4 vv = *(const float4*)&rv[c0];
    float v0 = fmaxf(acc.x * inv + bi.x, 0.f);
    float v1 = fmaxf(acc.y * inv + bi.y, 0.f);
    float v2 = fmaxf(acc.z * inv + bi.z, 0.f);
    float v3 = fmaxf(acc.w * inv + bi.w, 0.f);
    v0 = (v0 - mm4.x) * rsqrtf(vv.x + BN_EPS) * gg.x + bb.x;
    v1 = (v1 - mm4.y) * rsqrtf(vv.y + BN_EPS) * gg.y + bb.y;
    v2 = (v2 - mm4.z) * rsqrtf(vv.z + BN_EPS) * gg.z + bb.z;
    v3 = (v3 - mm4.w) * rsqrtf(vv.w + BN_EPS) * gg.w + bb.w;
    unsigned long long o =
        (unsigned long long)f2bf(v0) |
        ((unsigned long long)f2bf(v1) << 16) |
        ((unsigned long long)f2bf(v2) << 32) |
        ((unsigned long long)f2bf(v3) << 48);
    __builtin_nontemporal_store(o, (unsigned long long*)&out16[(long long)d * FEAT + c0]);
}

// ===== fused head: mean-pool bf16 h2 + relu(pooled@lw1+lb1) @ lw2 + lb2 =====
__global__ __launch_bounds__(256) void head_fused(
    const unsigned short* __restrict__ h2, const int* __restrict__ batch,
    const float* __restrict__ lw1, const float* __restrict__ lb1,
    const float* __restrict__ lw2, const float* __restrict__ lb2,
    float* __restrict__ out) {
    int gph = blockIdx.x;
    int t = threadIdx.x;
    __shared__ float pooled[FEAT];
    __shared__ float zl[OUT_DIM];
    __shared__ int lo_s, hi_s;
    if (t == 0) {
        int lo = 0, hi = N_NODES;
        while (lo < hi) { int mid = (lo + hi) >> 1; if (batch[mid] < gph) lo = mid + 1; else hi = mid; }
        lo_s = lo;
        int lo2 = 0, hi2 = N_NODES;
        while (lo2 < hi2) { int mid = (lo2 + hi2) >> 1; if (batch[mid] < gph + 1) lo2 = mid + 1; else hi2 = mid; }
        hi_s = lo2;
    }
    __syncthreads();
    int lo = lo_s, hi = hi_s;
    float a0 = 0.f, a1 = 0.f, a2 = 0.f, a3 = 0.f;
    int n = lo;
    for (; n + 3 < hi; n += 4) {
        a0 += __uint_as_float((unsigned)h2[(long long)n * FEAT + t] << 16);
        a1 += __uint_as_float((unsigned)h2[(long long)(n + 1) * FEAT + t] << 16);
        a2 += __uint_as_float((unsigned)h2[(long long)(n + 2) * FEAT + t] << 16);
        a3 += __uint_as_float((unsigned)h2[(long long)(n + 3) * FEAT + t] << 16);
    }
    for (; n < hi; n++) a0 += __uint_as_float((unsigned)h2[(long long)n * FEAT + t] << 16);
    float cnt = fmaxf((float)(hi - lo), 1.f);
    pooled[t] = (a0 + a1 + a2 + a3) / cnt;
    __syncthreads();
    int j = t >> 1, kh = t & 1;
    float zp = 0.f;
    #pragma unroll 8
    for (int k = kh * 128; k < kh * 128 + 128; k++)
        zp += pooled[k] * lw1[k * OUT_DIM + j];
    zp += __shfl_xor(zp, 1);
    if (kh == 0) zl[j] = fmaxf(zp + lb1[j], 0.f);
    __syncthreads();
    int w = t >> 6, lane = t & 63;
    if (w < 2) {
        float p = zl[lane] * lw2[lane * 2 + w] + zl[lane + 64] * lw2[(lane + 64) * 2 + w];
        #pragma unroll
        for (int off = 1; off < 64; off <<= 1) p += __shfl_xor(p, off);
        if (lane == 0) out[gph * 2 + w] = p + lb2[w];
    }
}

extern "C" void kernel_launch(void* const* d_in, const int* in_sizes, int n_in,
                              void* d_out, int out_size, void* d_ws, size_t ws_size,
                              hipStream_t stream) {
    const float* x       = (const float*)d_in[0];
    const int*   ei      = (const int*)d_in[1];
    const int*   batch   = (const int*)d_in[2];
    const float* W1      = (const float*)d_in[3];
    const float* att_s1  = (const float*)d_in[4];
    const float* att_d1  = (const float*)d_in[5];
    const float* b1      = (const float*)d_in[6];
    const float* g1      = (const float*)d_in[7];
    const float* be1     = (const float*)d_in[8];
    const float* rm1     = (const float*)d_in[9];
    const float* rv1     = (const float*)d_in[10];
    const float* W2      = (const float*)d_in[11];
    const float* att_s2  = (const float*)d_in[12];
    const float* att_d2  = (const float*)d_in[13];
    const float* b2      = (const float*)d_in[14];
    const float* g2      = (const float*)d_in[15];
    const float* be2     = (const float*)d_in[16];
    const float* rm2     = (const float*)d_in[17];
    const float* rv2     = (const float*)d_in[18];
    const float* lw1     = (const float*)d_in[19];
    const float* lb1     = (const float*)d_in[20];
    const float* lw2     = (const float*)d_in[21];
    const float* lb2     = (const float*)d_in[22];
    float* out           = (float*)d_out;

    const int* src = ei;
    const int* dst = ei + N_EDGES;

    char* p = (char*)d_ws;
    auto carve = [&p](size_t bytes) -> void* {
        void* r = (void*)p;
        p += (bytes + 63) & ~(size_t)63;
        return r;
    };
    unsigned short* h2bf = (unsigned short*)carve(sizeof(short) * (size_t)N_NODES * FEAT);
    float* a_s    = (float*)carve(sizeof(float) * N_NODES * HEADS);
    float* a_d    = (float*)carve(sizeof(float) * N_NODES * HEADS);
    int*   deg    = (int*)carve(sizeof(int) * N_NODES);
    int*   epos   = (int*)carve(sizeof(int) * (N_EDGES + N_NODES));
    int*   csr    = (int*)carve(sizeof(int) * (N_EDGES + N_NODES));
    int*   rstart = (int*)carve(sizeof(int) * (N_NODES + 4));
    int*   bsum   = (int*)carve(sizeof(int) * 256);
    int*   boff   = (int*)carve(sizeof(int) * 256);
    unsigned char*  h8   = (unsigned char*)carve((size_t)M_PAD * FEAT);
    unsigned short* h1bf = (unsigned short*)carve(sizeof(short) * (size_t)M_PAD * FEAT);
    unsigned short* w1t  = (unsigned short*)carve(sizeof(short) * FEAT * F_IN);
    unsigned short* w2t  = (unsigned short*)carve(sizeof(short) * FEAT * FEAT);

    const int Et = N_EDGES + N_NODES;

    // ---- prep: weight transposes + deg zero + h1bf pad zero ----
    prep<<<((F_IN + FEAT) * 256 + 255) / 256, 256, 0, stream>>>(
        W1, W2, w1t, w2t, deg,
        (unsigned long long*)(h1bf + (size_t)N_NODES * FEAT));

    // ---- CSR build ----
    degree_count<<<(Et + 255) / 256, 256, 0, stream>>>(src, dst, deg, epos);
    scan_k1<<<NCHUNK, 256, 0, stream>>>(deg, bsum);
    scan_k2<<<1, 256, 0, stream>>>(bsum, boff, rstart);
    scan_k3<<<NCHUNK, 256, 0, stream>>>(deg, boff, rstart);
    scatter_edges<<<(Et + 255) / 256, 256, 0, stream>>>(src, dst, rstart, epos, csr);

    // ---- Layer 1 (A = fp32 x, converted in staging) ----
    gemm_mfma_gat<true><<<M_PAD / 128, 256, 0, stream>>>(x, w1t, att_s1, att_d1,
                                                         h8, a_s, a_d, F_IN);
    gat_fused<<<N_NODES / 4, 256, 0, stream>>>(rstart, csr, a_s, a_d, h8,
                                               b1, g1, be1, rm1, rv1, h1bf);

    // ---- Layer 2 ----
    gemm_mfma_gat<false><<<M_PAD / 128, 256, 0, stream>>>(h1bf, w2t, att_s2, att_d2,
                                                          h8, a_s, a_d, FEAT);
    gat_fused<<<N_NODES / 4, 256, 0, stream>>>(rstart, csr, a_s, a_d, h8,
                                               b2, g2, be2, rm2, rv2, h2bf);

    // ---- fused head ----
    head_fused<<<NG, 256, 0, stream>>>(h2bf, batch, lw1, lb1, lw2, lb2, out);
}

// Round 16
// 322.402 us; speedup vs baseline: 6.9042x; 1.0543x over previous
//
#include <hip/hip_runtime.h>
#include <hip/hip_bf16.h>
#include <math.h>

#define N_NODES 50000
#define M_PAD   50048                    // 391 * 128
#define N_EDGES 800000
#define F_IN 128
#define HID 64
#define HEADS 4
#define FEAT 256        // HEADS*HID
#define OUT_DIM 128
#define N_CLS 2
#define NG 500
#define SLOPE 0.2f
#define BN_EPS 1e-5f
#define ECAP 64          // ELL slots per node (Poisson(17) -> overflow ~never)

typedef __attribute__((ext_vector_type(8))) short short8;
typedef __attribute__((ext_vector_type(4))) float floatx4;
typedef __attribute__((ext_vector_type(2))) float floatx2;

__device__ inline unsigned short f2bf(float f) {
    unsigned int u = __float_as_uint(f);
    unsigned int lsb = (u >> 16) & 1u;
    return (unsigned short)((u + 0x7fffu + lsb) >> 16);
}

// ==== bf16 MFMA GEMM fused with GAT prologue; full-width 128x256 tile ====
// C = A[Mpad,K] @ BT[256,K]^T. One block per 128-row stripe (A staged ONCE).
// Wave w owns head w: cols w*64..w*64+63, all 128 rows (8x4 MFMA tiles).
// Writes fp8-e4m3 h8[Mpad,256] + fp32 a_s/a_d[N,4] from fp32 accumulators.
template<bool AF32>
__global__ __launch_bounds__(256, 2) void gemm_mfma_gat(
    const void* __restrict__ Av, const unsigned short* __restrict__ BT,
    const float* __restrict__ att_src, const float* __restrict__ att_dst,
    unsigned char* __restrict__ h8, float* __restrict__ a_s,
    float* __restrict__ a_d, int K) {
    constexpr int LS = 40;      // staging row stride (bf16)
    constexpr int C8 = 272;     // fp8 C-repack row stride (bytes, 16B-aligned)
    __shared__ __align__(16) unsigned char smem_raw[128 * C8];   // 34816 B
    unsigned short* As = (unsigned short*)smem_raw;              // 128*LS shorts
    unsigned short* Bs = As + 128 * LS;                          // 256*LS shorts
    unsigned char*  s8 = smem_raw;                               // reused after barrier
    int t = threadIdx.x;
    int lane = t & 63, w = t >> 6;
    int row0 = blockIdx.x * 128;
    int mrow = lane & 15, quad = lane >> 4;

    floatx4 acc[8][4] = {};

    int rA = t >> 2, cA = (t & 3) * 8;

    const unsigned short* Ab = (const unsigned short*)Av;
    const float* Af = (const float*)Av;

    for (int k0 = 0; k0 < K; k0 += 32) {
        #pragma unroll
        for (int j = 0; j < 2; j++) {
            int r = rA + j * 64;
            if (AF32) {
                uint4 pk = make_uint4(0, 0, 0, 0);
                if (row0 + r < N_NODES) {
                    float4 f0 = *(const float4*)&Af[(long long)(row0 + r) * K + k0 + cA];
                    float4 f1 = *(const float4*)&Af[(long long)(row0 + r) * K + k0 + cA + 4];
                    pk.x = (unsigned)f2bf(f0.x) | ((unsigned)f2bf(f0.y) << 16);
                    pk.y = (unsigned)f2bf(f0.z) | ((unsigned)f2bf(f0.w) << 16);
                    pk.z = (unsigned)f2bf(f1.x) | ((unsigned)f2bf(f1.y) << 16);
                    pk.w = (unsigned)f2bf(f1.z) | ((unsigned)f2bf(f1.w) << 16);
                }
                *(uint4*)&As[r * LS + cA] = pk;
            } else {
                *(uint4*)&As[r * LS + cA] = *(const uint4*)&Ab[(long long)(row0 + r) * K + k0 + cA];
            }
        }
        #pragma unroll
        for (int j = 0; j < 4; j++) {
            int r = rA + j * 64;
            *(uint4*)&Bs[r * LS + cA] = *(const uint4*)&BT[(long long)r * K + k0 + cA];
        }
        __syncthreads();
        short8 bf[4];
        #pragma unroll
        for (int ni = 0; ni < 4; ni++)
            bf[ni] = *(const short8*)&Bs[(w * 64 + ni * 16 + mrow) * LS + quad * 8];
        #pragma unroll
        for (int mi = 0; mi < 8; mi++) {
            short8 af = *(const short8*)&As[(mi * 16 + mrow) * LS + quad * 8];
            #pragma unroll
            for (int ni = 0; ni < 4; ni++)
                acc[mi][ni] = __builtin_amdgcn_mfma_f32_16x16x32_bf16(af, bf[ni],
                                                                      acc[mi][ni], 0, 0, 0);
        }
        __syncthreads();
    }

    // ---- attention scores (wave w == head w) ----
    float ats[4], atd[4];
    #pragma unroll
    for (int ni = 0; ni < 4; ni++) {
        ats[ni] = att_src[w * 64 + ni * 16 + mrow];
        atd[ni] = att_dst[w * 64 + ni * 16 + mrow];
    }
    #pragma unroll
    for (int mi = 0; mi < 8; mi++) {
        #pragma unroll
        for (int r = 0; r < 4; r++) {
            int row = row0 + mi * 16 + quad * 4 + r;
            float ps = 0.f, pd = 0.f;
            #pragma unroll
            for (int ni = 0; ni < 4; ni++) {
                float v = acc[mi][ni][r];
                ps += v * ats[ni];
                pd += v * atd[ni];
            }
            #pragma unroll
            for (int off = 1; off < 16; off <<= 1) {
                ps += __shfl_xor(ps, off);
                pd += __shfl_xor(pd, off);
            }
            if (mrow == 0 && row < N_NODES) {
                a_s[row * 4 + w] = ps;
                a_d[row * 4 + w] = pd;
            }
        }
    }

    // ---- repack C tile as fp8 through LDS, coalesced uint4 stores ----
    #pragma unroll
    for (int mi = 0; mi < 8; mi++)
        #pragma unroll
        for (int r = 0; r < 4; r++) {
            int row = mi * 16 + quad * 4 + r;
            #pragma unroll
            for (int ni = 0; ni < 4; ni += 2) {
                int pk = __builtin_amdgcn_cvt_pk_fp8_f32(acc[mi][ni][r],
                                                         acc[mi][ni + 1][r], 0, false);
                s8[row * C8 + w * 64 + ni * 16 + mrow]       = (unsigned char)(pk & 0xff);
                s8[row * C8 + w * 64 + (ni + 1) * 16 + mrow] = (unsigned char)((pk >> 8) & 0xff);
            }
        }
    __syncthreads();
    {
        int r2 = t >> 1, half = t & 1;
        const uint4* sp = (const uint4*)&s8[r2 * C8 + half * 128];
        uint4* dp = (uint4*)&h8[(long long)(row0 + r2) * FEAT + half * 128];
        #pragma unroll
        for (int k = 0; k < 8; k++)
            dp[k] = sp[k];
    }
}

// ===== prep: weight transposes + deg zero + ovf_cnt zero + h1bf pad zero =====
__global__ void prep(const float* __restrict__ W1, const float* __restrict__ W2,
                     unsigned short* __restrict__ W1T, unsigned short* __restrict__ W2T,
                     int* __restrict__ deg, int* __restrict__ ovf_cnt,
                     unsigned long long* __restrict__ h1bf_pad) {
    int i = blockIdx.x * 256 + threadIdx.x;
    if (i < F_IN * 256) {
        int k = i >> 8, n = i & 255;
        W1T[n * F_IN + k] = f2bf(W1[i]);
    }
    int j = i - F_IN * 256;
    if (j >= 0 && j < FEAT * 256) {
        int k = j >> 8, n = j & 255;
        W2T[n * FEAT + k] = f2bf(W2[j]);
    }
    if (i < N_NODES) deg[i] = 0;
    if (i == 0) *ovf_cnt = 0;
    if (i < (M_PAD - N_NODES) * FEAT / 4) h1bf_pad[i] = 0ULL;
}

// ===== ELL build: degree count + direct scatter in ONE pass (no scan) =====
__global__ void build_ell(const int* __restrict__ src, const int* __restrict__ dst,
                          int* __restrict__ deg, int* __restrict__ ell,
                          int* __restrict__ ovf_cnt, int* __restrict__ ovf) {
    int e = blockIdx.x * blockDim.x + threadIdx.x;
    if (e >= N_EDGES + N_NODES) return;
    int s, d;
    if (e < N_EDGES) { s = src[e]; d = dst[e]; } else { s = d = e - N_EDGES; }
    int pos = atomicAdd(&deg[d], 1);
    if (pos < ECAP) {
        ell[d * ECAP + pos] = s;
    } else {
        int j = atomicAdd(ovf_cnt, 1);
        ovf[2 * j] = s;
        ovf[2 * j + 1] = d;
    }
}

// ===== fused GAT, wave-per-node; fp8 gather from ELL, packed decode =====
// shared-max softmax (exact), in-loop denominator, bf16 output.
// deg<=ECAP: single-chunk fast path. deg>ECAP: exact online path over ELL
// chunk + overflow-list scan (never triggers on Poisson(17) data).
__global__ __launch_bounds__(256) void gat_fused(
    const int* __restrict__ deg_arr, const int* __restrict__ ell,
    const int* __restrict__ ovf_cnt, const int* __restrict__ ovf,
    const float* __restrict__ a_s, const float* __restrict__ a_d,
    const unsigned char* __restrict__ h8, const float* __restrict__ bias,
    const float* __restrict__ g, const float* __restrict__ be,
    const float* __restrict__ rm, const float* __restrict__ rv,
    unsigned short* __restrict__ out16) {
    int t = threadIdx.x;
    int lane = t & 63;
    int w = t >> 6;
    int hd = lane >> 4;
    int d = blockIdx.x * 4 + w;

    __shared__ float p_lds[4 * ECAP * 4];
    __shared__ int   o_lds[4 * ECAP];
    float* pw = &p_lds[w * ECAP * 4];
    int*   ow = &o_lds[w * ECAP];

    const unsigned int* __restrict__ H1 = (const unsigned int*)h8;

    int deg = deg_arr[d];
    float4 ad4 = *(const float4*)&a_d[d * 4];

    float den = 0.f;
    float4 acc = make_float4(0.f, 0.f, 0.f, 0.f);

    if (deg <= ECAP) {
        // ---- single-chunk fast path ----
        float lg[4] = {-INFINITY, -INFINITY, -INFINITY, -INFINITY};
        if (lane < deg) {
            int s = ell[d * ECAP + lane];
            ow[lane] = s * 64;
            float4 as4 = *(const float4*)&a_s[s * 4];
            float e0 = as4.x + ad4.x; lg[0] = e0 > 0.f ? e0 : SLOPE * e0;
            float e1 = as4.y + ad4.y; lg[1] = e1 > 0.f ? e1 : SLOPE * e1;
            float e2 = as4.z + ad4.z; lg[2] = e2 > 0.f ? e2 : SLOPE * e2;
            float e3 = as4.w + ad4.w; lg[3] = e3 > 0.f ? e3 : SLOPE * e3;
        }
        float mm = fmaxf(fmaxf(lg[0], lg[1]), fmaxf(lg[2], lg[3]));
        #pragma unroll
        for (int off = 1; off < 64; off <<= 1) mm = fmaxf(mm, __shfl_xor(mm, off));
        if (lane < deg) {
            float4 pq;
            pq.x = __expf(lg[0] - mm);
            pq.y = __expf(lg[1] - mm);
            pq.z = __expf(lg[2] - mm);
            pq.w = __expf(lg[3] - mm);
            *(float4*)&pw[lane * 4] = pq;
        }
        int e = 0;
        for (; e + 1 < deg; e += 2) {
            int oA = ow[e], oB = ow[e + 1];
            float pA = pw[e * 4 + hd], pB = pw[(e + 1) * 4 + hd];
            int uA = (int)H1[oA + lane];
            int uB = (int)H1[oB + lane];
            den += pA + pB;
            floatx2 a0 = __builtin_amdgcn_cvt_pk_f32_fp8(uA, false);
            floatx2 a1 = __builtin_amdgcn_cvt_pk_f32_fp8(uA, true);
            floatx2 b0 = __builtin_amdgcn_cvt_pk_f32_fp8(uB, false);
            floatx2 b1 = __builtin_amdgcn_cvt_pk_f32_fp8(uB, true);
            acc.x += pA * a0.x; acc.y += pA * a0.y;
            acc.z += pA * a1.x; acc.w += pA * a1.y;
            acc.x += pB * b0.x; acc.y += pB * b0.y;
            acc.z += pB * b1.x; acc.w += pB * b1.y;
        }
        if (e < deg) {
            int oA = ow[e];
            float pA = pw[e * 4 + hd];
            int uA = (int)H1[oA + lane];
            den += pA;
            floatx2 a0 = __builtin_amdgcn_cvt_pk_f32_fp8(uA, false);
            floatx2 a1 = __builtin_amdgcn_cvt_pk_f32_fp8(uA, true);
            acc.x += pA * a0.x; acc.y += pA * a0.y;
            acc.z += pA * a1.x; acc.w += pA * a1.y;
        }
    } else {
        // ---- exact online path: ELP chunk (ECAP edges) + overflow scan ----
        float m_old;
        {
            int s = ell[d * ECAP + lane];
            ow[lane] = s * 64;
            float4 as4 = *(const float4*)&a_s[s * 4];
            float lg[4];
            float e0 = as4.x + ad4.x; lg[0] = e0 > 0.f ? e0 : SLOPE * e0;
            float e1 = as4.y + ad4.y; lg[1] = e1 > 0.f ? e1 : SLOPE * e1;
            float e2 = as4.z + ad4.z; lg[2] = e2 > 0.f ? e2 : SLOPE * e2;
            float e3 = as4.w + ad4.w; lg[3] = e3 > 0.f ? e3 : SLOPE * e3;
            float mm = fmaxf(fmaxf(lg[0], lg[1]), fmaxf(lg[2], lg[3]));
            #pragma unroll
            for (int off = 1; off < 64; off <<= 1) mm = fmaxf(mm, __shfl_xor(mm, off));
            m_old = mm;
            float4 pq;
            pq.x = __expf(lg[0] - mm);
            pq.y = __expf(lg[1] - mm);
            pq.z = __expf(lg[2] - mm);
            pq.w = __expf(lg[3] - mm);
            *(float4*)&pw[lane * 4] = pq;
            for (int e = 0; e < ECAP; e++) {
                int oA = ow[e];
                float pA = pw[e * 4 + hd];
                int uA = (int)H1[oA + lane];
                den += pA;
                floatx2 a0 = __builtin_amdgcn_cvt_pk_f32_fp8(uA, false);
                floatx2 a1 = __builtin_amdgcn_cvt_pk_f32_fp8(uA, true);
                acc.x += pA * a0.x; acc.y += pA * a0.y;
                acc.z += pA * a1.x; acc.w += pA * a1.y;
            }
        }
        int nov = *ovf_cnt;
        for (int i = 0; i < nov; i++) {
            int s2 = ovf[2 * i], d2 = ovf[2 * i + 1];
            if (d2 != d) continue;
            float4 as4 = *(const float4*)&a_s[s2 * 4];
            float lg[4];
            float e0 = as4.x + ad4.x; lg[0] = e0 > 0.f ? e0 : SLOPE * e0;
            float e1 = as4.y + ad4.y; lg[1] = e1 > 0.f ? e1 : SLOPE * e1;
            float e2 = as4.z + ad4.z; lg[2] = e2 > 0.f ? e2 : SLOPE * e2;
            float e3 = as4.w + ad4.w; lg[3] = e3 > 0.f ? e3 : SLOPE * e3;
            float mmax = fmaxf(fmaxf(lg[0], lg[1]), fmaxf(lg[2], lg[3]));
            float m_new = fmaxf(m_old, mmax);
            float alpha = __expf(m_old - m_new);
            m_old = m_new;
            float ph = __expf(lg[hd] - m_new);
            acc.x *= alpha; acc.y *= alpha; acc.z *= alpha; acc.w *= alpha;
            den = den * alpha + ph;
            int u = (int)H1[s2 * 64 + lane];
            floatx2 a0 = __builtin_amdgcn_cvt_pk_f32_fp8(u, false);
            floatx2 a1 = __builtin_amdgcn_cvt_pk_f32_fp8(u, true);
            acc.x += ph * a0.x; acc.y += ph * a0.y;
            acc.z += ph * a1.x; acc.w += ph * a1.y;
        }
    }
    float inv = 1.f / den;
    int c0 = lane * 4;
    float4 bi = *(const float4*)&bias[c0];
    float4 gg = *(const float4*)&g[c0];
    float4 bb = *(const float4*)&be[c0];
    float4 mm4 = *(const float4*)&rm[c0];
    float4 vv = *(const float4*)&rv[c0];
    float v0 = fmaxf(acc.x * inv + bi.x, 0.f);
    float v1 = fmaxf(acc.y * inv + bi.y, 0.f);
    float v2 = fmaxf(acc.z * inv + bi.z, 0.f);
    float v3 = fmaxf(acc.w * inv + bi.w, 0.f);
    v0 = (v0 - mm4.x) * rsqrtf(vv.x + BN_EPS) * gg.x + bb.x;
    v1 = (v1 - mm4.y) * rsqrtf(vv.y + BN_EPS) * gg.y + bb.y;
    v2 = (v2 - mm4.z) * rsqrtf(vv.z + BN_EPS) * gg.z + bb.z;
    v3 = (v3 - mm4.w) * rsqrtf(vv.w + BN_EPS) * gg.w + bb.w;
    unsigned long long o =
        (unsigned long long)f2bf(v0) |
        ((unsigned long long)f2bf(v1) << 16) |
        ((unsigned long long)f2bf(v2) << 32) |
        ((unsigned long long)f2bf(v3) << 48);
    __builtin_nontemporal_store(o, (unsigned long long*)&out16[(long long)d * FEAT + c0]);
}

// ===== fused head: mean-pool bf16 h2 + relu(pooled@lw1+lb1) @ lw2 + lb2 =====
__global__ __launch_bounds__(256) void head_fused(
    const unsigned short* __restrict__ h2, const int* __restrict__ batch,
    const float* __restrict__ lw1, const float* __restrict__ lb1,
    const float* __restrict__ lw2, const float* __restrict__ lb2,
    float* __restrict__ out) {
    int gph = blockIdx.x;
    int t = threadIdx.x;
    __shared__ float pooled[FEAT];
    __shared__ float zl[OUT_DIM];
    __shared__ int lo_s, hi_s;
    if (t == 0) {
        int lo = 0, hi = N_NODES;
        while (lo < hi) { int mid = (lo + hi) >> 1; if (batch[mid] < gph) lo = mid + 1; else hi = mid; }
        lo_s = lo;
        int lo2 = 0, hi2 = N_NODES;
        while (lo2 < hi2) { int mid = (lo2 + hi2) >> 1; if (batch[mid] < gph + 1) lo2 = mid + 1; else hi2 = mid; }
        hi_s = lo2;
    }
    __syncthreads();
    int lo = lo_s, hi = hi_s;
    float a0 = 0.f, a1 = 0.f, a2 = 0.f, a3 = 0.f;
    int n = lo;
    for (; n + 3 < hi; n += 4) {
        a0 += __uint_as_float((unsigned)h2[(long long)n * FEAT + t] << 16);
        a1 += __uint_as_float((unsigned)h2[(long long)(n + 1) * FEAT + t] << 16);
        a2 += __uint_as_float((unsigned)h2[(long long)(n + 2) * FEAT + t] << 16);
        a3 += __uint_as_float((unsigned)h2[(long long)(n + 3) * FEAT + t] << 16);
    }
    for (; n < hi; n++) a0 += __uint_as_float((unsigned)h2[(long long)n * FEAT + t] << 16);
    float cnt = fmaxf((float)(hi - lo), 1.f);
    pooled[t] = (a0 + a1 + a2 + a3) / cnt;
    __syncthreads();
    int j = t >> 1, kh = t & 1;
    float zp = 0.f;
    #pragma unroll 8
    for (int k = kh * 128; k < kh * 128 + 128; k++)
        zp += pooled[k] * lw1[k * OUT_DIM + j];
    zp += __shfl_xor(zp, 1);
    if (kh == 0) zl[j] = fmaxf(zp + lb1[j], 0.f);
    __syncthreads();
    int w = t >> 6, lane = t & 63;
    if (w < 2) {
        float p = zl[lane] * lw2[lane * 2 + w] + zl[lane + 64] * lw2[(lane + 64) * 2 + w];
        #pragma unroll
        for (int off = 1; off < 64; off <<= 1) p += __shfl_xor(p, off);
        if (lane == 0) out[gph * 2 + w] = p + lb2[w];
    }
}

extern "C" void kernel_launch(void* const* d_in, const int* in_sizes, int n_in,
                              void* d_out, int out_size, void* d_ws, size_t ws_size,
                              hipStream_t stream) {
    const float* x       = (const float*)d_in[0];
    const int*   ei      = (const int*)d_in[1];
    const int*   batch   = (const int*)d_in[2];
    const float* W1      = (const float*)d_in[3];
    const float* att_s1  = (const float*)d_in[4];
    const float* att_d1  = (const float*)d_in[5];
    const float* b1      = (const float*)d_in[6];
    const float* g1      = (const float*)d_in[7];
    const float* be1     = (const float*)d_in[8];
    const float* rm1     = (const float*)d_in[9];
    const float* rv1     = (const float*)d_in[10];
    const float* W2      = (const float*)d_in[11];
    const float* att_s2  = (const float*)d_in[12];
    const float* att_d2  = (const float*)d_in[13];
    const float* b2      = (const float*)d_in[14];
    const float* g2      = (const float*)d_in[15];
    const float* be2     = (const float*)d_in[16];
    const float* rm2     = (const float*)d_in[17];
    const float* rv2     = (const float*)d_in[18];
    const float* lw1     = (const float*)d_in[19];
    const float* lb1     = (const float*)d_in[20];
    const float* lw2     = (const float*)d_in[21];
    const float* lb2     = (const float*)d_in[22];
    float* out           = (float*)d_out;

    const int* src = ei;
    const int* dst = ei + N_EDGES;

    char* p = (char*)d_ws;
    auto carve = [&p](size_t bytes) -> void* {
        void* r = (void*)p;
        p += (bytes + 63) & ~(size_t)63;
        return r;
    };
    unsigned short* h2bf = (unsigned short*)carve(sizeof(short) * (size_t)N_NODES * FEAT);
    float* a_s    = (float*)carve(sizeof(float) * N_NODES * HEADS);
    float* a_d    = (float*)carve(sizeof(float) * N_NODES * HEADS);
    int*   deg    = (int*)carve(sizeof(int) * N_NODES);
    int*   ell    = (int*)carve(sizeof(int) * (size_t)N_NODES * ECAP);
    int*   ovf_cnt= (int*)carve(sizeof(int) * 16);
    int*   ovf    = (int*)carve(sizeof(int) * 2 * (N_EDGES + N_NODES));
    unsigned char*  h8   = (unsigned char*)carve((size_t)M_PAD * FEAT);
    unsigned short* h1bf = (unsigned short*)carve(sizeof(short) * (size_t)M_PAD * FEAT);
    unsigned short* w1t  = (unsigned short*)carve(sizeof(short) * FEAT * F_IN);
    unsigned short* w2t  = (unsigned short*)carve(sizeof(short) * FEAT * FEAT);

    const int Et = N_EDGES + N_NODES;

    // ---- prep: weight transposes + deg/ovf zero + h1bf pad zero ----
    prep<<<((F_IN + FEAT) * 256 + 255) / 256, 256, 0, stream>>>(
        W1, W2, w1t, w2t, deg, ovf_cnt,
        (unsigned long long*)(h1bf + (size_t)N_NODES * FEAT));

    // ---- ELL build (replaces degree_count + 3-kernel scan + scatter) ----
    build_ell<<<(Et + 255) / 256, 256, 0, stream>>>(src, dst, deg, ell, ovf_cnt, ovf);

    // ---- Layer 1 (A = fp32 x, converted in staging) ----
    gemm_mfma_gat<true><<<M_PAD / 128, 256, 0, stream>>>(x, w1t, att_s1, att_d1,
                                                         h8, a_s, a_d, F_IN);
    gat_fused<<<N_NODES / 4, 256, 0, stream>>>(deg, ell, ovf_cnt, ovf, a_s, a_d, h8,
                                               b1, g1, be1, rm1, rv1, h1bf);

    // ---- Layer 2 ----
    gemm_mfma_gat<false><<<M_PAD / 128, 256, 0, stream>>>(h1bf, w2t, att_s2, att_d2,
                                                          h8, a_s, a_d, FEAT);
    gat_fused<<<N_NODES / 4, 256, 0, stream>>>(deg, ell, ovf_cnt, ovf, a_s, a_d, h8,
                                               b2, g2, be2, rm2, rv2, h2bf);

    // ---- fused head ----
    head_fused<<<NG, 256, 0, stream>>>(h2bf, batch, lw1, lb1, lw2, lb2, out);
}

// Round 17
// 312.800 us; speedup vs baseline: 7.1162x; 1.0307x over previous
//
#include <hip/hip_runtime.h>
#include <hip/hip_bf16.h>
#include <math.h>

#define N_NODES 50000
#define M_PAD   50048                    // 391 * 128
#define N_EDGES 800000
#define F_IN 128
#define HID 64
#define HEADS 4
#define FEAT 256        // HEADS*HID
#define OUT_DIM 128
#define N_CLS 2
#define NG 500
#define SLOPE 0.2f
#define BN_EPS 1e-5f
#define ECAP 64          // ELL slots per node (Poisson(17) -> overflow ~never)
#define ET (N_EDGES + N_NODES)
#define EQ ((ET + 3) / 4)                // edges per strided group in build_ell

typedef __attribute__((ext_vector_type(8))) short short8;
typedef __attribute__((ext_vector_type(4))) float floatx4;
typedef __attribute__((ext_vector_type(2))) float floatx2;

__device__ inline unsigned short f2bf(float f) {
    unsigned int u = __float_as_uint(f);
    unsigned int lsb = (u >> 16) & 1u;
    return (unsigned short)((u + 0x7fffu + lsb) >> 16);
}

// ==== bf16 MFMA GEMM fused with GAT prologue; full-width 128x256 tile ====
template<bool AF32>
__global__ __launch_bounds__(256, 2) void gemm_mfma_gat(
    const void* __restrict__ Av, const unsigned short* __restrict__ BT,
    const float* __restrict__ att_src, const float* __restrict__ att_dst,
    unsigned char* __restrict__ h8, float* __restrict__ a_s,
    float* __restrict__ a_d, int K) {
    constexpr int LS = 40;      // staging row stride (bf16)
    constexpr int C8 = 272;     // fp8 C-repack row stride (bytes, 16B-aligned)
    __shared__ __align__(16) unsigned char smem_raw[128 * C8];   // 34816 B
    unsigned short* As = (unsigned short*)smem_raw;
    unsigned short* Bs = As + 128 * LS;
    unsigned char*  s8 = smem_raw;
    int t = threadIdx.x;
    int lane = t & 63, w = t >> 6;
    int row0 = blockIdx.x * 128;
    int mrow = lane & 15, quad = lane >> 4;

    floatx4 acc[8][4] = {};

    int rA = t >> 2, cA = (t & 3) * 8;

    const unsigned short* Ab = (const unsigned short*)Av;
    const float* Af = (const float*)Av;

    for (int k0 = 0; k0 < K; k0 += 32) {
        #pragma unroll
        for (int j = 0; j < 2; j++) {
            int r = rA + j * 64;
            if (AF32) {
                uint4 pk = make_uint4(0, 0, 0, 0);
                if (row0 + r < N_NODES) {
                    float4 f0 = *(const float4*)&Af[(long long)(row0 + r) * K + k0 + cA];
                    float4 f1 = *(const float4*)&Af[(long long)(row0 + r) * K + k0 + cA + 4];
                    pk.x = (unsigned)f2bf(f0.x) | ((unsigned)f2bf(f0.y) << 16);
                    pk.y = (unsigned)f2bf(f0.z) | ((unsigned)f2bf(f0.w) << 16);
                    pk.z = (unsigned)f2bf(f1.x) | ((unsigned)f2bf(f1.y) << 16);
                    pk.w = (unsigned)f2bf(f1.z) | ((unsigned)f2bf(f1.w) << 16);
                }
                *(uint4*)&As[r * LS + cA] = pk;
            } else {
                *(uint4*)&As[r * LS + cA] = *(const uint4*)&Ab[(long long)(row0 + r) * K + k0 + cA];
            }
        }
        #pragma unroll
        for (int j = 0; j < 4; j++) {
            int r = rA + j * 64;
            *(uint4*)&Bs[r * LS + cA] = *(const uint4*)&BT[(long long)r * K + k0 + cA];
        }
        __syncthreads();
        short8 bf[4];
        #pragma unroll
        for (int ni = 0; ni < 4; ni++)
            bf[ni] = *(const short8*)&Bs[(w * 64 + ni * 16 + mrow) * LS + quad * 8];
        #pragma unroll
        for (int mi = 0; mi < 8; mi++) {
            short8 af = *(const short8*)&As[(mi * 16 + mrow) * LS + quad * 8];
            #pragma unroll
            for (int ni = 0; ni < 4; ni++)
                acc[mi][ni] = __builtin_amdgcn_mfma_f32_16x16x32_bf16(af, bf[ni],
                                                                      acc[mi][ni], 0, 0, 0);
        }
        __syncthreads();
    }

    // ---- attention scores (wave w == head w) ----
    float ats[4], atd[4];
    #pragma unroll
    for (int ni = 0; ni < 4; ni++) {
        ats[ni] = att_src[w * 64 + ni * 16 + mrow];
        atd[ni] = att_dst[w * 64 + ni * 16 + mrow];
    }
    #pragma unroll
    for (int mi = 0; mi < 8; mi++) {
        #pragma unroll
        for (int r = 0; r < 4; r++) {
            int row = row0 + mi * 16 + quad * 4 + r;
            float ps = 0.f, pd = 0.f;
            #pragma unroll
            for (int ni = 0; ni < 4; ni++) {
                float v = acc[mi][ni][r];
                ps += v * ats[ni];
                pd += v * atd[ni];
            }
            #pragma unroll
            for (int off = 1; off < 16; off <<= 1) {
                ps += __shfl_xor(ps, off);
                pd += __shfl_xor(pd, off);
            }
            if (mrow == 0 && row < N_NODES) {
                a_s[row * 4 + w] = ps;
                a_d[row * 4 + w] = pd;
            }
        }
    }

    // ---- repack C tile as fp8 through LDS, coalesced uint4 stores ----
    #pragma unroll
    for (int mi = 0; mi < 8; mi++)
        #pragma unroll
        for (int r = 0; r < 4; r++) {
            int row = mi * 16 + quad * 4 + r;
            #pragma unroll
            for (int ni = 0; ni < 4; ni += 2) {
                int pk = __builtin_amdgcn_cvt_pk_fp8_f32(acc[mi][ni][r],
                                                         acc[mi][ni + 1][r], 0, false);
                s8[row * C8 + w * 64 + ni * 16 + mrow]       = (unsigned char)(pk & 0xff);
                s8[row * C8 + w * 64 + (ni + 1) * 16 + mrow] = (unsigned char)((pk >> 8) & 0xff);
            }
        }
    __syncthreads();
    {
        int r2 = t >> 1, half = t & 1;
        const uint4* sp = (const uint4*)&s8[r2 * C8 + half * 128];
        uint4* dp = (uint4*)&h8[(long long)(row0 + r2) * FEAT + half * 128];
        #pragma unroll
        for (int k = 0; k < 8; k++)
            dp[k] = sp[k];
    }
}

// ===== prep: weight transposes + deg zero + ovf_cnt zero + h1bf pad zero =====
__global__ void prep(const float* __restrict__ W1, const float* __restrict__ W2,
                     unsigned short* __restrict__ W1T, unsigned short* __restrict__ W2T,
                     int* __restrict__ deg, int* __restrict__ ovf_cnt,
                     unsigned long long* __restrict__ h1bf_pad) {
    int i = blockIdx.x * 256 + threadIdx.x;
    if (i < F_IN * 256) {
        int k = i >> 8, n = i & 255;
        W1T[n * F_IN + k] = f2bf(W1[i]);
    }
    int j = i - F_IN * 256;
    if (j >= 0 && j < FEAT * 256) {
        int k = j >> 8, n = j & 255;
        W2T[n * FEAT + k] = f2bf(W2[j]);
    }
    if (i < N_NODES) deg[i] = 0;
    if (i == 0) *ovf_cnt = 0;
    if (i < (M_PAD - N_NODES) * FEAT / 4) h1bf_pad[i] = 0ULL;
}

// ===== ELL build, 4 edges/thread for atomic-latency ILP =====
__global__ __launch_bounds__(256) void build_ell(
    const int* __restrict__ src, const int* __restrict__ dst,
    int* __restrict__ deg, int* __restrict__ ell,
    int* __restrict__ ovf_cnt, int* __restrict__ ovf) {
    int i = blockIdx.x * 256 + threadIdx.x;
    if (i >= EQ) return;
    int ee[4], ss[4], dd[4], pp[4];
    int nv = 0;
    #pragma unroll
    for (int j = 0; j < 4; j++) {
        int e = i + j * EQ;
        if (e < ET) {
            ee[nv] = e;
            if (e < N_EDGES) { ss[nv] = src[e]; dd[nv] = dst[e]; }
            else             { ss[nv] = dd[nv] = e - N_EDGES; }
            nv++;
        }
    }
    // issue all atomics back-to-back (independent -> overlapped round trips)
    #pragma unroll
    for (int j = 0; j < 4; j++)
        if (j < nv) pp[j] = atomicAdd(&deg[dd[j]], 1);
    #pragma unroll
    for (int j = 0; j < 4; j++) {
        if (j >= nv) continue;
        if (pp[j] < ECAP) {
            ell[dd[j] * ECAP + pp[j]] = ss[j];
        } else {
            int k = atomicAdd(ovf_cnt, 1);
            ovf[2 * k] = ss[j];
            ovf[2 * k + 1] = dd[j];
        }
    }
}

// ===== fused GAT, wave-per-node; fp8 gather from ELL, packed decode =====
__global__ __launch_bounds__(256) void gat_fused(
    const int* __restrict__ deg_arr, const int* __restrict__ ell,
    const int* __restrict__ ovf_cnt, const int* __restrict__ ovf,
    const float* __restrict__ a_s, const float* __restrict__ a_d,
    const unsigned char* __restrict__ h8, const float* __restrict__ bias,
    const float* __restrict__ g, const float* __restrict__ be,
    const float* __restrict__ rm, const float* __restrict__ rv,
    unsigned short* __restrict__ out16) {
    int t = threadIdx.x;
    int lane = t & 63;
    int w = t >> 6;
    int hd = lane >> 4;
    int d = blockIdx.x * 4 + w;

    __shared__ float p_lds[4 * ECAP * 4];
    __shared__ int   o_lds[4 * ECAP];
    float* pw = &p_lds[w * ECAP * 4];
    int*   ow = &o_lds[w * ECAP];

    const unsigned int* __restrict__ H1 = (const unsigned int*)h8;

    int deg = deg_arr[d];
    float4 ad4 = *(const float4*)&a_d[d * 4];

    float den = 0.f;
    float4 acc = make_float4(0.f, 0.f, 0.f, 0.f);

    if (deg <= ECAP) {
        float lg[4] = {-INFINITY, -INFINITY, -INFINITY, -INFINITY};
        if (lane < deg) {
            int s = ell[d * ECAP + lane];
            ow[lane] = s * 64;
            float4 as4 = *(const float4*)&a_s[s * 4];
            float e0 = as4.x + ad4.x; lg[0] = e0 > 0.f ? e0 : SLOPE * e0;
            float e1 = as4.y + ad4.y; lg[1] = e1 > 0.f ? e1 : SLOPE * e1;
            float e2 = as4.z + ad4.z; lg[2] = e2 > 0.f ? e2 : SLOPE * e2;
            float e3 = as4.w + ad4.w; lg[3] = e3 > 0.f ? e3 : SLOPE * e3;
        }
        float mm = fmaxf(fmaxf(lg[0], lg[1]), fmaxf(lg[2], lg[3]));
        #pragma unroll
        for (int off = 1; off < 64; off <<= 1) mm = fmaxf(mm, __shfl_xor(mm, off));
        if (lane < deg) {
            float4 pq;
            pq.x = __expf(lg[0] - mm);
            pq.y = __expf(lg[1] - mm);
            pq.z = __expf(lg[2] - mm);
            pq.w = __expf(lg[3] - mm);
            *(float4*)&pw[lane * 4] = pq;
        }
        int e = 0;
        for (; e + 1 < deg; e += 2) {
            int oA = ow[e], oB = ow[e + 1];
            float pA = pw[e * 4 + hd], pB = pw[(e + 1) * 4 + hd];
            int uA = (int)H1[oA + lane];
            int uB = (int)H1[oB + lane];
            den += pA + pB;
            floatx2 a0 = __builtin_amdgcn_cvt_pk_f32_fp8(uA, false);
            floatx2 a1 = __builtin_amdgcn_cvt_pk_f32_fp8(uA, true);
            floatx2 b0 = __builtin_amdgcn_cvt_pk_f32_fp8(uB, false);
            floatx2 b1 = __builtin_amdgcn_cvt_pk_f32_fp8(uB, true);
            acc.x += pA * a0.x; acc.y += pA * a0.y;
            acc.z += pA * a1.x; acc.w += pA * a1.y;
            acc.x += pB * b0.x; acc.y += pB * b0.y;
            acc.z += pB * b1.x; acc.w += pB * b1.y;
        }
        if (e < deg) {
            int oA = ow[e];
            float pA = pw[e * 4 + hd];
            int uA = (int)H1[oA + lane];
            den += pA;
            floatx2 a0 = __builtin_amdgcn_cvt_pk_f32_fp8(uA, false);
            floatx2 a1 = __builtin_amdgcn_cvt_pk_f32_fp8(uA, true);
            acc.x += pA * a0.x; acc.y += pA * a0.y;
            acc.z += pA * a1.x; acc.w += pA * a1.y;
        }
    } else {
        // exact online path: ELL chunk (ECAP edges) + overflow scan
        float m_old;
        {
            int s = ell[d * ECAP + lane];
            ow[lane] = s * 64;
            float4 as4 = *(const float4*)&a_s[s * 4];
            float lg[4];
            float e0 = as4.x + ad4.x; lg[0] = e0 > 0.f ? e0 : SLOPE * e0;
            float e1 = as4.y + ad4.y; lg[1] = e1 > 0.f ? e1 : SLOPE * e1;
            float e2 = as4.z + ad4.z; lg[2] = e2 > 0.f ? e2 : SLOPE * e2;
            float e3 = as4.w + ad4.w; lg[3] = e3 > 0.f ? e3 : SLOPE * e3;
            float mm = fmaxf(fmaxf(lg[0], lg[1]), fmaxf(lg[2], lg[3]));
            #pragma unroll
            for (int off = 1; off < 64; off <<= 1) mm = fmaxf(mm, __shfl_xor(mm, off));
            m_old = mm;
            float4 pq;
            pq.x = __expf(lg[0] - mm);
            pq.y = __expf(lg[1] - mm);
            pq.z = __expf(lg[2] - mm);
            pq.w = __expf(lg[3] - mm);
            *(float4*)&pw[lane * 4] = pq;
            for (int e = 0; e < ECAP; e++) {
                int oA = ow[e];
                float pA = pw[e * 4 + hd];
                int uA = (int)H1[oA + lane];
                den += pA;
                floatx2 a0 = __builtin_amdgcn_cvt_pk_f32_fp8(uA, false);
                floatx2 a1 = __builtin_amdgcn_cvt_pk_f32_fp8(uA, true);
                acc.x += pA * a0.x; acc.y += pA * a0.y;
                acc.z += pA * a1.x; acc.w += pA * a1.y;
            }
        }
        int nov = *ovf_cnt;
        for (int i = 0; i < nov; i++) {
            int s2 = ovf[2 * i], d2 = ovf[2 * i + 1];
            if (d2 != d) continue;
            float4 as4 = *(const float4*)&a_s[s2 * 4];
            float lg[4];
            float e0 = as4.x + ad4.x; lg[0] = e0 > 0.f ? e0 : SLOPE * e0;
            float e1 = as4.y + ad4.y; lg[1] = e1 > 0.f ? e1 : SLOPE * e1;
            float e2 = as4.z + ad4.z; lg[2] = e2 > 0.f ? e2 : SLOPE * e2;
            float e3 = as4.w + ad4.w; lg[3] = e3 > 0.f ? e3 : SLOPE * e3;
            float mmax = fmaxf(fmaxf(lg[0], lg[1]), fmaxf(lg[2], lg[3]));
            float m_new = fmaxf(m_old, mmax);
            float alpha = __expf(m_old - m_new);
            m_old = m_new;
            float ph = __expf(lg[hd] - m_new);
            acc.x *= alpha; acc.y *= alpha; acc.z *= alpha; acc.w *= alpha;
            den = den * alpha + ph;
            int u = (int)H1[s2 * 64 + lane];
            floatx2 a0 = __builtin_amdgcn_cvt_pk_f32_fp8(u, false);
            floatx2 a1 = __builtin_amdgcn_cvt_pk_f32_fp8(u, true);
            acc.x += ph * a0.x; acc.y += ph * a0.y;
            acc.z += ph * a1.x; acc.w += ph * a1.y;
        }
    }
    float inv = 1.f / den;
    int c0 = lane * 4;
    float4 bi = *(const float4*)&bias[c0];
    float4 gg = *(const float4*)&g[c0];
    float4 bb = *(const float4*)&be[c0];
    float4 mm4 = *(const float4*)&rm[c0];
    float4 vv = *(const float4*)&rv[c0];
    float v0 = fmaxf(acc.x * inv + bi.x, 0.f);
    float v1 = fmaxf(acc.y * inv + bi.y, 0.f);
    float v2 = fmaxf(acc.z * inv + bi.z, 0.f);
    float v3 = fmaxf(acc.w * inv + bi.w, 0.f);
    v0 = (v0 - mm4.x) * rsqrtf(vv.x + BN_EPS) * gg.x + bb.x;
    v1 = (v1 - mm4.y) * rsqrtf(vv.y + BN_EPS) * gg.y + bb.y;
    v2 = (v2 - mm4.z) * rsqrtf(vv.z + BN_EPS) * gg.z + bb.z;
    v3 = (v3 - mm4.w) * rsqrtf(vv.w + BN_EPS) * gg.w + bb.w;
    unsigned long long o =
        (unsigned long long)f2bf(v0) |
        ((unsigned long long)f2bf(v1) << 16) |
        ((unsigned long long)f2bf(v2) << 32) |
        ((unsigned long long)f2bf(v3) << 48);
    __builtin_nontemporal_store(o, (unsigned long long*)&out16[(long long)d * FEAT + c0]);
}

// ===== fused head: mean-pool bf16 h2 + relu(pooled@lw1+lb1) @ lw2 + lb2 =====
__global__ __launch_bounds__(256) void head_fused(
    const unsigned short* __restrict__ h2, const int* __restrict__ batch,
    const float* __restrict__ lw1, const float* __restrict__ lb1,
    const float* __restrict__ lw2, const float* __restrict__ lb2,
    float* __restrict__ out) {
    int gph = blockIdx.x;
    int t = threadIdx.x;
    __shared__ float pooled[FEAT];
    __shared__ float zl[OUT_DIM];
    __shared__ int lo_s, hi_s;
    if (t == 0) {
        int lo = 0, hi = N_NODES;
        while (lo < hi) { int mid = (lo + hi) >> 1; if (batch[mid] < gph) lo = mid + 1; else hi = mid; }
        lo_s = lo;
        int lo2 = 0, hi2 = N_NODES;
        while (lo2 < hi2) { int mid = (lo2 + hi2) >> 1; if (batch[mid] < gph + 1) lo2 = mid + 1; else hi2 = mid; }
        hi_s = lo2;
    }
    __syncthreads();
    int lo = lo_s, hi = hi_s;
    float a0 = 0.f, a1 = 0.f, a2 = 0.f, a3 = 0.f;
    int n = lo;
    for (; n + 3 < hi; n += 4) {
        a0 += __uint_as_float((unsigned)h2[(long long)n * FEAT + t] << 16);
        a1 += __uint_as_float((unsigned)h2[(long long)(n + 1) * FEAT + t] << 16);
        a2 += __uint_as_float((unsigned)h2[(long long)(n + 2) * FEAT + t] << 16);
        a3 += __uint_as_float((unsigned)h2[(long long)(n + 3) * FEAT + t] << 16);
    }
    for (; n < hi; n++) a0 += __uint_as_float((unsigned)h2[(long long)n * FEAT + t] << 16);
    float cnt = fmaxf((float)(hi - lo), 1.f);
    pooled[t] = (a0 + a1 + a2 + a3) / cnt;
    __syncthreads();
    int j = t >> 1, kh = t & 1;
    float zp = 0.f;
    #pragma unroll 8
    for (int k = kh * 128; k < kh * 128 + 128; k++)
        zp += pooled[k] * lw1[k * OUT_DIM + j];
    zp += __shfl_xor(zp, 1);
    if (kh == 0) zl[j] = fmaxf(zp + lb1[j], 0.f);
    __syncthreads();
    int w = t >> 6, lane = t & 63;
    if (w < 2) {
        float p = zl[lane] * lw2[lane * 2 + w] + zl[lane + 64] * lw2[(lane + 64) * 2 + w];
        #pragma unroll
        for (int off = 1; off < 64; off <<= 1) p += __shfl_xor(p, off);
        if (lane == 0) out[gph * 2 + w] = p + lb2[w];
    }
}

extern "C" void kernel_launch(void* const* d_in, const int* in_sizes, int n_in,
                              void* d_out, int out_size, void* d_ws, size_t ws_size,
                              hipStream_t stream) {
    const float* x       = (const float*)d_in[0];
    const int*   ei      = (const int*)d_in[1];
    const int*   batch   = (const int*)d_in[2];
    const float* W1      = (const float*)d_in[3];
    const float* att_s1  = (const float*)d_in[4];
    const float* att_d1  = (const float*)d_in[5];
    const float* b1      = (const float*)d_in[6];
    const float* g1      = (const float*)d_in[7];
    const float* be1     = (const float*)d_in[8];
    const float* rm1     = (const float*)d_in[9];
    const float* rv1     = (const float*)d_in[10];
    const float* W2      = (const float*)d_in[11];
    const float* att_s2  = (const float*)d_in[12];
    const float* att_d2  = (const float*)d_in[13];
    const float* b2      = (const float*)d_in[14];
    const float* g2      = (const float*)d_in[15];
    const float* be2     = (const float*)d_in[16];
    const float* rm2     = (const float*)d_in[17];
    const float* rv2     = (const float*)d_in[18];
    const float* lw1     = (const float*)d_in[19];
    const float* lb1     = (const float*)d_in[20];
    const float* lw2     = (const float*)d_in[21];
    const float* lb2     = (const float*)d_in[22];
    float* out           = (float*)d_out;

    const int* src = ei;
    const int* dst = ei + N_EDGES;

    char* p = (char*)d_ws;
    auto carve = [&p](size_t bytes) -> void* {
        void* r = (void*)p;
        p += (bytes + 63) & ~(size_t)63;
        return r;
    };
    unsigned short* h2bf = (unsigned short*)carve(sizeof(short) * (size_t)N_NODES * FEAT);
    float* a_s    = (float*)carve(sizeof(float) * N_NODES * HEADS);
    float* a_d    = (float*)carve(sizeof(float) * N_NODES * HEADS);
    int*   deg    = (int*)carve(sizeof(int) * N_NODES);
    int*   ell    = (int*)carve(sizeof(int) * (size_t)N_NODES * ECAP);
    int*   ovf_cnt= (int*)carve(sizeof(int) * 16);
    int*   ovf    = (int*)carve(sizeof(int) * 2 * ET);
    unsigned char*  h8   = (unsigned char*)carve((size_t)M_PAD * FEAT);
    unsigned short* h1bf = (unsigned short*)carve(sizeof(short) * (size_t)M_PAD * FEAT);
    unsigned short* w1t  = (unsigned short*)carve(sizeof(short) * FEAT * F_IN);
    unsigned short* w2t  = (unsigned short*)carve(sizeof(short) * FEAT * FEAT);

    // ---- prep: weight transposes + deg/ovf zero + h1bf pad zero ----
    prep<<<((F_IN + FEAT) * 256 + 255) / 256, 256, 0, stream>>>(
        W1, W2, w1t, w2t, deg, ovf_cnt,
        (unsigned long long*)(h1bf + (size_t)N_NODES * FEAT));

    // ---- ELL build (4 edges/thread for atomic ILP) ----
    build_ell<<<(EQ + 255) / 256, 256, 0, stream>>>(src, dst, deg, ell, ovf_cnt, ovf);

    // ---- Layer 1 (A = fp32 x, converted in staging) ----
    gemm_mfma_gat<true><<<M_PAD / 128, 256, 0, stream>>>(x, w1t, att_s1, att_d1,
                                                         h8, a_s, a_d, F_IN);
    gat_fused<<<N_NODES / 4, 256, 0, stream>>>(deg, ell, ovf_cnt, ovf, a_s, a_d, h8,
                                               b1, g1, be1, rm1, rv1, h1bf);

    // ---- Layer 2 ----
    gemm_mfma_gat<false><<<M_PAD / 128, 256, 0, stream>>>(h1bf, w2t, att_s2, att_d2,
                                                          h8, a_s, a_d, FEAT);
    gat_fused<<<N_NODES / 4, 256, 0, stream>>>(deg, ell, ovf_cnt, ovf, a_s, a_d, h8,
                                               b2, g2, be2, rm2, rv2, h2bf);

    // ---- fused head ----
    head_fused<<<NG, 256, 0, stream>>>(h2bf, batch, lw1, lb1, lw2, lb2, out);
}

// Round 18
// 307.086 us; speedup vs baseline: 7.2486x; 1.0186x over previous
//
#include <hip/hip_runtime.h>
#include <hip/hip_bf16.h>
#include <math.h>

#define N_NODES 50000
#define M_PAD   50048                    // 391 * 128
#define NBLK_GEMM (M_PAD / 128)          // 391
#define N_EDGES 800000
#define F_IN 128
#define HID 64
#define HEADS 4
#define FEAT 256        // HEADS*HID
#define OUT_DIM 128
#define N_CLS 2
#define NG 500
#define SLOPE 0.2f
#define BN_EPS 1e-5f
#define ECAP 64          // ELL slots per node (Poisson(17) -> overflow ~never)
#define ET (N_EDGES + N_NODES)
#define EH ((ET + 1) / 2)                // 2 edges per thread in build
#define NBLK_BUILD ((EH + 255) / 256)    // 1661

typedef __attribute__((ext_vector_type(8))) short short8;
typedef __attribute__((ext_vector_type(4))) float floatx4;
typedef __attribute__((ext_vector_type(2))) float floatx2;

__device__ inline unsigned short f2bf(float f) {
    unsigned int u = __float_as_uint(f);
    unsigned int lsb = (u >> 16) & 1u;
    return (unsigned short)((u + 0x7fffu + lsb) >> 16);
}

// ==== bf16 MFMA GEMM fused with GAT prologue; full-width 128x256 tile ====
// Optionally carries ELL-build blocks (blockIdx >= NBLK_GEMM) to overlap the
// latency-bound edge scatter with the MFMA GEMM (independent work).
template<bool AF32, bool BUILD>
__global__ __launch_bounds__(256, 2) void gemm_mfma_gat(
    const void* __restrict__ Av, const unsigned short* __restrict__ BT,
    const float* __restrict__ att_src, const float* __restrict__ att_dst,
    unsigned char* __restrict__ h8, float* __restrict__ a_s,
    float* __restrict__ a_d, int K,
    const int* __restrict__ src, const int* __restrict__ dst,
    int* __restrict__ deg, int* __restrict__ ell,
    int* __restrict__ ovf_cnt, int* __restrict__ ovf) {
    constexpr int LS = 40;      // staging row stride (bf16)
    constexpr int C8 = 272;     // fp8 C-repack row stride (bytes, 16B-aligned)
    __shared__ __align__(16) unsigned char smem_raw[128 * C8];   // 34816 B
    int t = threadIdx.x;

    if (BUILD && blockIdx.x >= NBLK_GEMM) {
        // ---------- ELL build block: 2 edges/thread ----------
        int i = (blockIdx.x - NBLK_GEMM) * 256 + t;
        if (i >= EH) return;
        int ss[2], dd[2], pp[2];
        int nv = 0;
        #pragma unroll
        for (int j = 0; j < 2; j++) {
            int e = i + j * EH;
            if (e < ET) {
                if (e < N_EDGES) { ss[nv] = src[e]; dd[nv] = dst[e]; }
                else             { ss[nv] = dd[nv] = e - N_EDGES; }
                nv++;
            }
        }
        #pragma unroll
        for (int j = 0; j < 2; j++)
            if (j < nv) pp[j] = atomicAdd(&deg[dd[j]], 1);
        #pragma unroll
        for (int j = 0; j < 2; j++) {
            if (j >= nv) continue;
            if (pp[j] < ECAP) {
                ell[dd[j] * ECAP + pp[j]] = ss[j];
            } else {
                int k = atomicAdd(ovf_cnt, 1);
                ovf[2 * k] = ss[j];
                ovf[2 * k + 1] = dd[j];
            }
        }
        return;
    }

    // ---------- GEMM block ----------
    unsigned short* As = (unsigned short*)smem_raw;
    unsigned short* Bs = As + 128 * LS;
    unsigned char*  s8 = smem_raw;
    int lane = t & 63, w = t >> 6;
    int row0 = blockIdx.x * 128;
    int mrow = lane & 15, quad = lane >> 4;

    floatx4 acc[8][4] = {};

    int rA = t >> 2, cA = (t & 3) * 8;

    const unsigned short* Ab = (const unsigned short*)Av;
    const float* Af = (const float*)Av;

    for (int k0 = 0; k0 < K; k0 += 32) {
        #pragma unroll
        for (int j = 0; j < 2; j++) {
            int r = rA + j * 64;
            if (AF32) {
                uint4 pk = make_uint4(0, 0, 0, 0);
                if (row0 + r < N_NODES) {
                    float4 f0 = *(const float4*)&Af[(long long)(row0 + r) * K + k0 + cA];
                    float4 f1 = *(const float4*)&Af[(long long)(row0 + r) * K + k0 + cA + 4];
                    pk.x = (unsigned)f2bf(f0.x) | ((unsigned)f2bf(f0.y) << 16);
                    pk.y = (unsigned)f2bf(f0.z) | ((unsigned)f2bf(f0.w) << 16);
                    pk.z = (unsigned)f2bf(f1.x) | ((unsigned)f2bf(f1.y) << 16);
                    pk.w = (unsigned)f2bf(f1.z) | ((unsigned)f2bf(f1.w) << 16);
                }
                *(uint4*)&As[r * LS + cA] = pk;
            } else {
                *(uint4*)&As[r * LS + cA] = *(const uint4*)&Ab[(long long)(row0 + r) * K + k0 + cA];
            }
        }
        #pragma unroll
        for (int j = 0; j < 4; j++) {
            int r = rA + j * 64;
            *(uint4*)&Bs[r * LS + cA] = *(const uint4*)&BT[(long long)r * K + k0 + cA];
        }
        __syncthreads();
        short8 bf[4];
        #pragma unroll
        for (int ni = 0; ni < 4; ni++)
            bf[ni] = *(const short8*)&Bs[(w * 64 + ni * 16 + mrow) * LS + quad * 8];
        #pragma unroll
        for (int mi = 0; mi < 8; mi++) {
            short8 af = *(const short8*)&As[(mi * 16 + mrow) * LS + quad * 8];
            #pragma unroll
            for (int ni = 0; ni < 4; ni++)
                acc[mi][ni] = __builtin_amdgcn_mfma_f32_16x16x32_bf16(af, bf[ni],
                                                                      acc[mi][ni], 0, 0, 0);
        }
        __syncthreads();
    }

    // ---- attention scores (wave w == head w) ----
    float ats[4], atd[4];
    #pragma unroll
    for (int ni = 0; ni < 4; ni++) {
        ats[ni] = att_src[w * 64 + ni * 16 + mrow];
        atd[ni] = att_dst[w * 64 + ni * 16 + mrow];
    }
    #pragma unroll
    for (int mi = 0; mi < 8; mi++) {
        #pragma unroll
        for (int r = 0; r < 4; r++) {
            int row = row0 + mi * 16 + quad * 4 + r;
            float ps = 0.f, pd = 0.f;
            #pragma unroll
            for (int ni = 0; ni < 4; ni++) {
                float v = acc[mi][ni][r];
                ps += v * ats[ni];
                pd += v * atd[ni];
            }
            #pragma unroll
            for (int off = 1; off < 16; off <<= 1) {
                ps += __shfl_xor(ps, off);
                pd += __shfl_xor(pd, off);
            }
            if (mrow == 0 && row < N_NODES) {
                a_s[row * 4 + w] = ps;
                a_d[row * 4 + w] = pd;
            }
        }
    }

    // ---- repack C tile as fp8 through LDS, coalesced uint4 stores ----
    #pragma unroll
    for (int mi = 0; mi < 8; mi++)
        #pragma unroll
        for (int r = 0; r < 4; r++) {
            int row = mi * 16 + quad * 4 + r;
            #pragma unroll
            for (int ni = 0; ni < 4; ni += 2) {
                int pk = __builtin_amdgcn_cvt_pk_fp8_f32(acc[mi][ni][r],
                                                         acc[mi][ni + 1][r], 0, false);
                s8[row * C8 + w * 64 + ni * 16 + mrow]       = (unsigned char)(pk & 0xff);
                s8[row * C8 + w * 64 + (ni + 1) * 16 + mrow] = (unsigned char)((pk >> 8) & 0xff);
            }
        }
    __syncthreads();
    {
        int r2 = t >> 1, half = t & 1;
        const uint4* sp = (const uint4*)&s8[r2 * C8 + half * 128];
        uint4* dp = (uint4*)&h8[(long long)(row0 + r2) * FEAT + half * 128];
        #pragma unroll
        for (int k = 0; k < 8; k++)
            dp[k] = sp[k];
    }
}

// ===== prep: weight transposes + deg zero + ovf_cnt zero + h1bf pad zero =====
__global__ void prep(const float* __restrict__ W1, const float* __restrict__ W2,
                     unsigned short* __restrict__ W1T, unsigned short* __restrict__ W2T,
                     int* __restrict__ deg, int* __restrict__ ovf_cnt,
                     unsigned long long* __restrict__ h1bf_pad) {
    int i = blockIdx.x * 256 + threadIdx.x;
    if (i < F_IN * 256) {
        int k = i >> 8, n = i & 255;
        W1T[n * F_IN + k] = f2bf(W1[i]);
    }
    int j = i - F_IN * 256;
    if (j >= 0 && j < FEAT * 256) {
        int k = j >> 8, n = j & 255;
        W2T[n * FEAT + k] = f2bf(W2[j]);
    }
    if (i < N_NODES) deg[i] = 0;
    if (i == 0) *ovf_cnt = 0;
    if (i < (M_PAD - N_NODES) * FEAT / 4) h1bf_pad[i] = 0ULL;
}

// ===== fused GAT, wave-per-node; fp8 gather from ELL, packed decode =====
__global__ __launch_bounds__(256) void gat_fused(
    const int* __restrict__ deg_arr, const int* __restrict__ ell,
    const int* __restrict__ ovf_cnt, const int* __restrict__ ovf,
    const float* __restrict__ a_s, const float* __restrict__ a_d,
    const unsigned char* __restrict__ h8, const float* __restrict__ bias,
    const float* __restrict__ g, const float* __restrict__ be,
    const float* __restrict__ rm, const float* __restrict__ rv,
    unsigned short* __restrict__ out16) {
    int t = threadIdx.x;
    int lane = t & 63;
    int w = t >> 6;
    int hd = lane >> 4;
    int d = blockIdx.x * 4 + w;

    __shared__ float p_lds[4 * ECAP * 4];
    __shared__ int   o_lds[4 * ECAP];
    float* pw = &p_lds[w * ECAP * 4];
    int*   ow = &o_lds[w * ECAP];

    const unsigned int* __restrict__ H1 = (const unsigned int*)h8;

    int deg = deg_arr[d];
    float4 ad4 = *(const float4*)&a_d[d * 4];

    float den = 0.f;
    float4 acc = make_float4(0.f, 0.f, 0.f, 0.f);

    if (deg <= ECAP) {
        float lg[4] = {-INFINITY, -INFINITY, -INFINITY, -INFINITY};
        if (lane < deg) {
            int s = ell[d * ECAP + lane];
            ow[lane] = s * 64;
            float4 as4 = *(const float4*)&a_s[s * 4];
            float e0 = as4.x + ad4.x; lg[0] = e0 > 0.f ? e0 : SLOPE * e0;
            float e1 = as4.y + ad4.y; lg[1] = e1 > 0.f ? e1 : SLOPE * e1;
            float e2 = as4.z + ad4.z; lg[2] = e2 > 0.f ? e2 : SLOPE * e2;
            float e3 = as4.w + ad4.w; lg[3] = e3 > 0.f ? e3 : SLOPE * e3;
        }
        float mm = fmaxf(fmaxf(lg[0], lg[1]), fmaxf(lg[2], lg[3]));
        #pragma unroll
        for (int off = 1; off < 64; off <<= 1) mm = fmaxf(mm, __shfl_xor(mm, off));
        if (lane < deg) {
            float4 pq;
            pq.x = __expf(lg[0] - mm);
            pq.y = __expf(lg[1] - mm);
            pq.z = __expf(lg[2] - mm);
            pq.w = __expf(lg[3] - mm);
            *(float4*)&pw[lane * 4] = pq;
        }
        int e = 0;
        for (; e + 1 < deg; e += 2) {
            int oA = ow[e], oB = ow[e + 1];
            float pA = pw[e * 4 + hd], pB = pw[(e + 1) * 4 + hd];
            int uA = (int)H1[oA + lane];
            int uB = (int)H1[oB + lane];
            den += pA + pB;
            floatx2 a0 = __builtin_amdgcn_cvt_pk_f32_fp8(uA, false);
            floatx2 a1 = __builtin_amdgcn_cvt_pk_f32_fp8(uA, true);
            floatx2 b0 = __builtin_amdgcn_cvt_pk_f32_fp8(uB, false);
            floatx2 b1 = __builtin_amdgcn_cvt_pk_f32_fp8(uB, true);
            acc.x += pA * a0.x; acc.y += pA * a0.y;
            acc.z += pA * a1.x; acc.w += pA * a1.y;
            acc.x += pB * b0.x; acc.y += pB * b0.y;
            acc.z += pB * b1.x; acc.w += pB * b1.y;
        }
        if (e < deg) {
            int oA = ow[e];
            float pA = pw[e * 4 + hd];
            int uA = (int)H1[oA + lane];
            den += pA;
            floatx2 a0 = __builtin_amdgcn_cvt_pk_f32_fp8(uA, false);
            floatx2 a1 = __builtin_amdgcn_cvt_pk_f32_fp8(uA, true);
            acc.x += pA * a0.x; acc.y += pA * a0.y;
            acc.z += pA * a1.x; acc.w += pA * a1.y;
        }
    } else {
        // exact online path: ELL chunk (ECAP edges) + overflow scan
        float m_old;
        {
            int s = ell[d * ECAP + lane];
            ow[lane] = s * 64;
            float4 as4 = *(const float4*)&a_s[s * 4];
            float lg[4];
            float e0 = as4.x + ad4.x; lg[0] = e0 > 0.f ? e0 : SLOPE * e0;
            float e1 = as4.y + ad4.y; lg[1] = e1 > 0.f ? e1 : SLOPE * e1;
            float e2 = as4.z + ad4.z; lg[2] = e2 > 0.f ? e2 : SLOPE * e2;
            float e3 = as4.w + ad4.w; lg[3] = e3 > 0.f ? e3 : SLOPE * e3;
            float mm = fmaxf(fmaxf(lg[0], lg[1]), fmaxf(lg[2], lg[3]));
            #pragma unroll
            for (int off = 1; off < 64; off <<= 1) mm = fmaxf(mm, __shfl_xor(mm, off));
            m_old = mm;
            float4 pq;
            pq.x = __expf(lg[0] - mm);
            pq.y = __expf(lg[1] - mm);
            pq.z = __expf(lg[2] - mm);
            pq.w = __expf(lg[3] - mm);
            *(float4*)&pw[lane * 4] = pq;
            for (int e = 0; e < ECAP; e++) {
                int oA = ow[e];
                float pA = pw[e * 4 + hd];
                int uA = (int)H1[oA + lane];
                den += pA;
                floatx2 a0 = __builtin_amdgcn_cvt_pk_f32_fp8(uA, false);
                floatx2 a1 = __builtin_amdgcn_cvt_pk_f32_fp8(uA, true);
                acc.x += pA * a0.x; acc.y += pA * a0.y;
                acc.z += pA * a1.x; acc.w += pA * a1.y;
            }
        }
        int nov = *ovf_cnt;
        for (int i = 0; i < nov; i++) {
            int s2 = ovf[2 * i], d2 = ovf[2 * i + 1];
            if (d2 != d) continue;
            float4 as4 = *(const float4*)&a_s[s2 * 4];
            float lg[4];
            float e0 = as4.x + ad4.x; lg[0] = e0 > 0.f ? e0 : SLOPE * e0;
            float e1 = as4.y + ad4.y; lg[1] = e1 > 0.f ? e1 : SLOPE * e1;
            float e2 = as4.z + ad4.z; lg[2] = e2 > 0.f ? e2 : SLOPE * e2;
            float e3 = as4.w + ad4.w; lg[3] = e3 > 0.f ? e3 : SLOPE * e3;
            float mmax = fmaxf(fmaxf(lg[0], lg[1]), fmaxf(lg[2], lg[3]));
            float m_new = fmaxf(m_old, mmax);
            float alpha = __expf(m_old - m_new);
            m_old = m_new;
            float ph = __expf(lg[hd] - m_new);
            acc.x *= alpha; acc.y *= alpha; acc.z *= alpha; acc.w *= alpha;
            den = den * alpha + ph;
            int u = (int)H1[s2 * 64 + lane];
            floatx2 a0 = __builtin_amdgcn_cvt_pk_f32_fp8(u, false);
            floatx2 a1 = __builtin_amdgcn_cvt_pk_f32_fp8(u, true);
            acc.x += ph * a0.x; acc.y += ph * a0.y;
            acc.z += ph * a1.x; acc.w += ph * a1.y;
        }
    }
    float inv = 1.f / den;
    int c0 = lane * 4;
    float4 bi = *(const float4*)&bias[c0];
    float4 gg = *(const float4*)&g[c0];
    float4 bb = *(const float4*)&be[c0];
    float4 mm4 = *(const float4*)&rm[c0];
    float4 vv = *(const float4*)&rv[c0];
    float v0 = fmaxf(acc.x * inv + bi.x, 0.f);
    float v1 = fmaxf(acc.y * inv + bi.y, 0.f);
    float v2 = fmaxf(acc.z * inv + bi.z, 0.f);
    float v3 = fmaxf(acc.w * inv + bi.w, 0.f);
    v0 = (v0 - mm4.x) * rsqrtf(vv.x + BN_EPS) * gg.x + bb.x;
    v1 = (v1 - mm4.y) * rsqrtf(vv.y + BN_EPS) * gg.y + bb.y;
    v2 = (v2 - mm4.z) * rsqrtf(vv.z + BN_EPS) * gg.z + bb.z;
    v3 = (v3 - mm4.w) * rsqrtf(vv.w + BN_EPS) * gg.w + bb.w;
    unsigned long long o =
        (unsigned long long)f2bf(v0) |
        ((unsigned long long)f2bf(v1) << 16) |
        ((unsigned long long)f2bf(v2) << 32) |
        ((unsigned long long)f2bf(v3) << 48);
    __builtin_nontemporal_store(o, (unsigned long long*)&out16[(long long)d * FEAT + c0]);
}

// ===== fused head: mean-pool bf16 h2 + relu(pooled@lw1+lb1) @ lw2 + lb2 =====
__global__ __launch_bounds__(256) void head_fused(
    const unsigned short* __restrict__ h2, const int* __restrict__ batch,
    const float* __restrict__ lw1, const float* __restrict__ lb1,
    const float* __restrict__ lw2, const float* __restrict__ lb2,
    float* __restrict__ out) {
    int gph = blockIdx.x;
    int t = threadIdx.x;
    __shared__ float pooled[FEAT];
    __shared__ float zl[OUT_DIM];
    __shared__ int lo_s, hi_s;
    if (t == 0) {
        int lo = 0, hi = N_NODES;
        while (lo < hi) { int mid = (lo + hi) >> 1; if (batch[mid] < gph) lo = mid + 1; else hi = mid; }
        lo_s = lo;
        int lo2 = 0, hi2 = N_NODES;
        while (lo2 < hi2) { int mid = (lo2 + hi2) >> 1; if (batch[mid] < gph + 1) lo2 = mid + 1; else hi2 = mid; }
        hi_s = lo2;
    }
    __syncthreads();
    int lo = lo_s, hi = hi_s;
    float a0 = 0.f, a1 = 0.f, a2 = 0.f, a3 = 0.f;
    int n = lo;
    for (; n + 3 < hi; n += 4) {
        a0 += __uint_as_float((unsigned)h2[(long long)n * FEAT + t] << 16);
        a1 += __uint_as_float((unsigned)h2[(long long)(n + 1) * FEAT + t] << 16);
        a2 += __uint_as_float((unsigned)h2[(long long)(n + 2) * FEAT + t] << 16);
        a3 += __uint_as_float((unsigned)h2[(long long)(n + 3) * FEAT + t] << 16);
    }
    for (; n < hi; n++) a0 += __uint_as_float((unsigned)h2[(long long)n * FEAT + t] << 16);
    float cnt = fmaxf((float)(hi - lo), 1.f);
    pooled[t] = (a0 + a1 + a2 + a3) / cnt;
    __syncthreads();
    int j = t >> 1, kh = t & 1;
    float zp = 0.f;
    #pragma unroll 8
    for (int k = kh * 128; k < kh * 128 + 128; k++)
        zp += pooled[k] * lw1[k * OUT_DIM + j];
    zp += __shfl_xor(zp, 1);
    if (kh == 0) zl[j] = fmaxf(zp + lb1[j], 0.f);
    __syncthreads();
    int w = t >> 6, lane = t & 63;
    if (w < 2) {
        float p = zl[lane] * lw2[lane * 2 + w] + zl[lane + 64] * lw2[(lane + 64) * 2 + w];
        #pragma unroll
        for (int off = 1; off < 64; off <<= 1) p += __shfl_xor(p, off);
        if (lane == 0) out[gph * 2 + w] = p + lb2[w];
    }
}

extern "C" void kernel_launch(void* const* d_in, const int* in_sizes, int n_in,
                              void* d_out, int out_size, void* d_ws, size_t ws_size,
                              hipStream_t stream) {
    const float* x       = (const float*)d_in[0];
    const int*   ei      = (const int*)d_in[1];
    const int*   batch   = (const int*)d_in[2];
    const float* W1      = (const float*)d_in[3];
    const float* att_s1  = (const float*)d_in[4];
    const float* att_d1  = (const float*)d_in[5];
    const float* b1      = (const float*)d_in[6];
    const float* g1      = (const float*)d_in[7];
    const float* be1     = (const float*)d_in[8];
    const float* rm1     = (const float*)d_in[9];
    const float* rv1     = (const float*)d_in[10];
    const float* W2      = (const float*)d_in[11];
    const float* att_s2  = (const float*)d_in[12];
    const float* att_d2  = (const float*)d_in[13];
    const float* b2      = (const float*)d_in[14];
    const float* g2      = (const float*)d_in[15];
    const float* be2     = (const float*)d_in[16];
    const float* rm2     = (const float*)d_in[17];
    const float* rv2     = (const float*)d_in[18];
    const float* lw1     = (const float*)d_in[19];
    const float* lb1     = (const float*)d_in[20];
    const float* lw2     = (const float*)d_in[21];
    const float* lb2     = (const float*)d_in[22];
    float* out           = (float*)d_out;

    const int* src = ei;
    const int* dst = ei + N_EDGES;

    char* p = (char*)d_ws;
    auto carve = [&p](size_t bytes) -> void* {
        void* r = (void*)p;
        p += (bytes + 63) & ~(size_t)63;
        return r;
    };
    unsigned short* h2bf = (unsigned short*)carve(sizeof(short) * (size_t)N_NODES * FEAT);
    float* a_s    = (float*)carve(sizeof(float) * N_NODES * HEADS);
    float* a_d    = (float*)carve(sizeof(float) * N_NODES * HEADS);
    int*   deg    = (int*)carve(sizeof(int) * N_NODES);
    int*   ell    = (int*)carve(sizeof(int) * (size_t)N_NODES * ECAP);
    int*   ovf_cnt= (int*)carve(sizeof(int) * 16);
    int*   ovf    = (int*)carve(sizeof(int) * 2 * ET);
    unsigned char*  h8   = (unsigned char*)carve((size_t)M_PAD * FEAT);
    unsigned short* h1bf = (unsigned short*)carve(sizeof(short) * (size_t)M_PAD * FEAT);
    unsigned short* w1t  = (unsigned short*)carve(sizeof(short) * FEAT * F_IN);
    unsigned short* w2t  = (unsigned short*)carve(sizeof(short) * FEAT * FEAT);

    // ---- prep: weight transposes + deg/ovf zero + h1bf pad zero ----
    prep<<<((F_IN + FEAT) * 256 + 255) / 256, 256, 0, stream>>>(
        W1, W2, w1t, w2t, deg, ovf_cnt,
        (unsigned long long*)(h1bf + (size_t)N_NODES * FEAT));

    // ---- Layer 1 GEMM + ELL build in one heterogeneous launch ----
    gemm_mfma_gat<true, true><<<NBLK_GEMM + NBLK_BUILD, 256, 0, stream>>>(
        x, w1t, att_s1, att_d1, h8, a_s, a_d, F_IN,
        src, dst, deg, ell, ovf_cnt, ovf);
    gat_fused<<<N_NODES / 4, 256, 0, stream>>>(deg, ell, ovf_cnt, ovf, a_s, a_d, h8,
                                               b1, g1, be1, rm1, rv1, h1bf);

    // ---- Layer 2 ----
    gemm_mfma_gat<false, false><<<NBLK_GEMM, 256, 0, stream>>>(
        h1bf, w2t, att_s2, att_d2, h8, a_s, a_d, FEAT,
        nullptr, nullptr, nullptr, nullptr, nullptr, nullptr);
    gat_fused<<<N_NODES / 4, 256, 0, stream>>>(deg, ell, ovf_cnt, ovf, a_s, a_d, h8,
                                               b2, g2, be2, rm2, rv2, h2bf);

    // ---- fused head ----
    head_fused<<<NG, 256, 0, stream>>>(h2bf, batch, lw1, lb1, lw2, lb2, out);
}